// Round 3
// baseline (6730.331 us; speedup 1.0000x reference)
//
#include <hip/hip_runtime.h>
#include <hip/hip_bf16.h>

#define NP 100000
#define NL 10000
#define ND 500
#define H 128
#define HH (H * H)
#define E1 2000000
#define E2 500000
#define NOUT 10

typedef __hip_bfloat16 bf16;

// load from workspace-typed arrays
__device__ __forceinline__ float ldv(const float* p, size_t i) { return p[i]; }
__device__ __forceinline__ float ldv(const bf16* p, size_t i) { return __bfloat162float(p[i]); }
__device__ __forceinline__ void stv(float* p, size_t i, float v) { p[i] = v; }
__device__ __forceinline__ void stv(bf16* p, size_t i, float v) { p[i] = __float2bfloat16(v); }

// load from a RAW INPUT buffer whose dtype is decided at runtime (f32m: 1=f32, 0=bf16)
__device__ __forceinline__ float ldin(const void* p, size_t i, int f32m) {
    return f32m ? ((const float*)p)[i] : __bfloat162float(((const bf16*)p)[i]);
}

// ---------------- input dtype detection ----------------
// Reads x_patient as u16 words. True bf16 data: even words are normal(0,1) bf16
// values -> exponent in [114,141] nearly always. f32 data: even words are low
// mantissa halves -> ~uniform exponent bits, ~11% plausible. Threshold 50%.
__global__ void k_detect(const unsigned short* __restrict__ xp, int* __restrict__ flags) {
    int t = threadIdx.x;  // 256 threads, 1 block
    int cnt = 0;
    for (int i = t; i < 4096; i += 256) {
        unsigned short w = xp[2 * i];
        int e = (w >> 7) & 0xFF;
        if (w == 0 || (e >= 114 && e <= 141)) cnt++;
    }
    __shared__ int sh[256];
    sh[t] = cnt;
    __syncthreads();
    for (int s = 128; s > 0; s >>= 1) {
        if (t < s) sh[t] += sh[t + s];
        __syncthreads();
    }
    if (t == 0) flags[0] = (sh[0] < 2048) ? 1 : 0;  // 1 = f32 inputs
}

// ---------------- initial embeddings: out[i,h] = b[h] + sum_k x[i,k] W[k,h] ----------------
template <typename T>
__global__ void k_embed(const void* __restrict__ x, const void* __restrict__ W,
                        const void* __restrict__ b, T* __restrict__ out, int N, int K,
                        const int* __restrict__ flags) {
    int f32m = flags[0];
    int idx = blockIdx.x * 256 + threadIdx.x;
    if (idx >= N * H) return;
    int i = idx >> 7, h = idx & 127;
    float acc = ldin(b, h, f32m);
    for (int k = 0; k < K; ++k)
        acc = fmaf(ldin(x, (size_t)i * K + k, f32m), ldin(W, (size_t)k * H + h, f32m), acc);
    stv(out, (size_t)idx, acc);
}

// ---------------- degree counts ----------------
__global__ void k_count(const int* __restrict__ s, const int* __restrict__ d,
                        float* __restrict__ cs, float* __restrict__ cd, int nE) {
    int e = blockIdx.x * 256 + threadIdx.x;
    if (e >= nE) return;
    atomicAdd(&cs[s[e]], 1.f);
    atomicAdd(&cd[d[e]], 1.f);
}

__global__ void k_invert(float* __restrict__ c, int n) {
    int i = blockIdx.x * 256 + threadIdx.x;
    if (i < n) c[i] = 1.f / fmaxf(c[i], 1.f);
}

// ------- out[N,H] (= or +=) in[N,H] @ W[H,H] (+ bias); W/bias raw-input unless WF32 -------
template <typename TIn, bool WF32, bool ADD, bool BIAS>
__global__ void k_mm(float* __restrict__ out, const TIn* __restrict__ in,
                     const void* __restrict__ W, const void* __restrict__ bias, int N,
                     const int* __restrict__ flags) {
    int f32m = WF32 ? 1 : flags[0];
    __shared__ float s[4][H];
    int h = threadIdx.x;  // 0..127
    int r0 = blockIdx.x * 4;
#pragma unroll
    for (int r = 0; r < 4; ++r)
        s[r][h] = (r0 + r < N) ? ldv(in, (size_t)(r0 + r) * H + h) : 0.f;
    __syncthreads();
    float a0 = 0.f, a1 = 0.f, a2 = 0.f, a3 = 0.f;
    for (int k = 0; k < H; ++k) {
        float w = ldin(W, (size_t)k * H + h, f32m);
        a0 = fmaf(s[0][k], w, a0);
        a1 = fmaf(s[1][k], w, a1);
        a2 = fmaf(s[2][k], w, a2);
        a3 = fmaf(s[3][k], w, a3);
    }
    float bb = BIAS ? ldin(bias, (size_t)h, f32m) : 0.f;
    float acc[4] = {a0, a1, a2, a3};
#pragma unroll
    for (int r = 0; r < 4; ++r) {
        if (r0 + r < N) {
            size_t o = (size_t)(r0 + r) * H + h;
            float a = acc[r] + bb;
            out[o] = ADD ? (out[o] + a) : a;
        }
    }
}

// ---------------- edge scatter: agg[si[e],:] += tbl[gi[e],:] * inv[si[e]] ----------------
template <typename T>
__global__ void k_scatter(const T* __restrict__ tbl, const int* __restrict__ gi,
                          const int* __restrict__ si, const float* __restrict__ inv,
                          float* __restrict__ agg, int nE) {
    size_t t = (size_t)blockIdx.x * 256 + threadIdx.x;
    if (t >= (size_t)nE * 128) return;
    int e = (int)(t >> 7);
    int h = (int)(t & 127);
    int g = gi[e], s = si[e];
    atomicAdd(&agg[(size_t)s * H + h], ldv(tbl, (size_t)g * H + h) * inv[s]);
}

// ---------------- Wr2+Wr3 / bl2+bl3 prep ----------------
__global__ void k_prep23(const void* __restrict__ Wr, const void* __restrict__ bl,
                         float* __restrict__ w23, float* __restrict__ b23,
                         const int* __restrict__ flags) {
    int f32m = flags[0];
    int idx = blockIdx.x * 256 + threadIdx.x;
    if (idx < HH) w23[idx] = ldin(Wr, (size_t)2 * HH + idx, f32m) + ldin(Wr, (size_t)3 * HH + idx, f32m);
    if (idx < H) b23[idx] = ldin(bl, (size_t)2 * H + idx, f32m) + ldin(bl, (size_t)3 * H + idx, f32m);
}

// ---------------- BatchNorm ----------------
__global__ void k_bn_stats(const float* __restrict__ x, float* __restrict__ sums, int N) {
    int h = threadIdx.x & 127;
    int sub = threadIdx.x >> 7;  // 0..1
    float s = 0.f, s2 = 0.f;
    for (int i = blockIdx.x * 2 + sub; i < N; i += gridDim.x * 2) {
        float v = x[(size_t)i * H + h];
        s += v;
        s2 = fmaf(v, v, s2);
    }
    __shared__ float ls[256], ls2[256];
    ls[threadIdx.x] = s;
    ls2[threadIdx.x] = s2;
    __syncthreads();
    if (sub == 0) {
        atomicAdd(&sums[h], s + ls[128 + h]);
        atomicAdd(&sums[H + h], s2 + ls2[128 + h]);
    }
}

template <typename T>
__global__ void k_bn_apply(const float* __restrict__ x, T* __restrict__ y,
                           const float* __restrict__ sums, const void* __restrict__ g,
                           const void* __restrict__ b, int N, float invN,
                           const int* __restrict__ flags) {
    int f32m = flags[0];
    int idx = blockIdx.x * 256 + threadIdx.x;
    if (idx >= N * H) return;
    int h = idx & 127;
    float m = sums[h] * invN;
    float v = fmaf(-m, m, sums[H + h] * invN);
    float sc = rsqrtf(v + 1e-5f) * ldin(g, h, f32m);
    float r = fmaf(x[idx] - m, sc, ldin(b, h, f32m));
    stv(y, (size_t)idx, fmaxf(r, 0.f));
}

// ---------------- head: fc1+relu, fc2, log_softmax ----------------
template <typename T>
__global__ void k_head(const T* __restrict__ hp, const void* __restrict__ W1,
                       const void* __restrict__ b1, const void* __restrict__ W2,
                       const void* __restrict__ b2, void* __restrict__ out,
                       const int* __restrict__ flags) {
    int f32m = flags[0];
    __shared__ float h1[4][64];
    __shared__ float lg[4][16];
    int sub = threadIdx.x >> 6;  // 0..3
    int j = threadIdx.x & 63;
    int p = blockIdx.x * 4 + sub;  // NP % 4 == 0 -> always < NP
    const T* row = hp + (size_t)p * H;
    float acc = ldin(b1, j, f32m);
#pragma unroll 8
    for (int k = 0; k < H; ++k)
        acc = fmaf(ldv(row, (size_t)k), ldin(W1, (size_t)k * 64 + j, f32m), acc);
    h1[sub][j] = fmaxf(acc, 0.f);
    __syncthreads();
    if (j < NOUT) {
        float a = ldin(b2, j, f32m);
#pragma unroll
        for (int k = 0; k < 64; ++k)
            a = fmaf(h1[sub][k], ldin(W2, (size_t)k * NOUT + j, f32m), a);
        lg[sub][j] = a;
    }
    __syncthreads();
    if (j < NOUT) {
        float m = -1e30f;
#pragma unroll
        for (int k = 0; k < NOUT; ++k) m = fmaxf(m, lg[sub][k]);
        float s = 0.f;
#pragma unroll
        for (int k = 0; k < NOUT; ++k) s += __expf(lg[sub][k] - m);
        float r = lg[sub][j] - m - __logf(s);
        if (f32m)
            ((float*)out)[(size_t)p * NOUT + j] = r;
        else
            ((bf16*)out)[(size_t)p * NOUT + j] = __float2bfloat16(r);
    }
}

// ---------------- one hetero layer ----------------
template <typename T>
static void run_layer(const void* Wl, const void* bl, const void* Wr, const void* bng,
                      const void* bnb, T* hp, T* hl, T* hd, float* aggp, float* tl, float* aglr,
                      float* td, float* agdr, const float* invl, const float* invd,
                      const float* invpl, const float* invpd, const int* e1s, const int* e1d,
                      const int* e2s, const int* e2d, float* w23, float* b23, float* bns,
                      const int* flags, hipStream_t stream) {
    const char* Wlc = (const char*)Wl;   // byte offsets depend on dtype; use element helper
    // NOTE: Wl/Wr sub-matrix offsets are in ELEMENTS; ldin indexes elements, so pass base + elem offset
    // via lambda-free arithmetic below using flags only inside kernels. We pass element offsets by
    // pointer arithmetic on the typed view: do it with a helper that offsets by elements in BYTES
    // for both dtypes. Simplest: offset inside kernels via index. Here we pre-offset assuming dtype
    // size known per-mode is impossible host-side, so kernels receive the FULL tensor and an element
    // base built into the index. We therefore pass base pointers and bake offsets into launches:
    (void)Wlc;
    // a. raw means of hp into lab/disease tables (mean commutes with @W)
    hipMemsetAsync(aglr, 0, (size_t)NL * H * 4, stream);
    hipMemsetAsync(agdr, 0, (size_t)ND * H * 4, stream);
    k_scatter<T><<<(unsigned)((size_t)E1 * 128 / 256), 256, 0, stream>>>(hp, e1s, e1d, invl, aglr, E1);
    k_scatter<T><<<(unsigned)((size_t)E2 * 128 / 256), 256, 0, stream>>>(hp, e2s, e2d, invd, agdr, E2);
    // b. small transforms for patient direction: tl = hl@Wl2, td = hd@Wl3
    k_mm<T, false, false, false><<<NL / 4, 128, 0, stream>>>(tl, hl, (const void*)nullptr, (const void*)nullptr, NL, flags);
    k_mm<T, false, false, false><<<(ND + 3) / 4, 128, 0, stream>>>(td, hd, (const void*)nullptr, (const void*)nullptr, ND, flags);
    // (placeholders replaced below — see k_mm_off wrappers)
}

// k_mm with element offset into W/bias (offset applied inside kernel, dtype-agnostic)
template <typename TIn, bool WF32, bool ADD, bool BIAS>
__global__ void k_mm_off(float* __restrict__ out, const TIn* __restrict__ in,
                         const void* __restrict__ W, size_t woff, const void* __restrict__ bias,
                         size_t boff, int N, const int* __restrict__ flags) {
    int f32m = WF32 ? 1 : flags[0];
    __shared__ float s[4][H];
    int h = threadIdx.x;
    int r0 = blockIdx.x * 4;
#pragma unroll
    for (int r = 0; r < 4; ++r)
        s[r][h] = (r0 + r < N) ? ldv(in, (size_t)(r0 + r) * H + h) : 0.f;
    __syncthreads();
    float a0 = 0.f, a1 = 0.f, a2 = 0.f, a3 = 0.f;
    for (int k = 0; k < H; ++k) {
        float w = ldin(W, woff + (size_t)k * H + h, f32m);
        a0 = fmaf(s[0][k], w, a0);
        a1 = fmaf(s[1][k], w, a1);
        a2 = fmaf(s[2][k], w, a2);
        a3 = fmaf(s[3][k], w, a3);
    }
    float bb = BIAS ? ldin(bias, boff + (size_t)h, f32m) : 0.f;
    float acc[4] = {a0, a1, a2, a3};
#pragma unroll
    for (int r = 0; r < 4; ++r) {
        if (r0 + r < N) {
            size_t o = (size_t)(r0 + r) * H + h;
            float a = acc[r] + bb;
            out[o] = ADD ? (out[o] + a) : a;
        }
    }
}

// bn_apply with element offsets for g/b
template <typename T>
__global__ void k_bn_apply_off(const float* __restrict__ x, T* __restrict__ y,
                               const float* __restrict__ sums, const void* __restrict__ g,
                               size_t goff, const void* __restrict__ b, size_t boff, int N,
                               float invN, const int* __restrict__ flags) {
    int f32m = flags[0];
    int idx = blockIdx.x * 256 + threadIdx.x;
    if (idx >= N * H) return;
    int h = idx & 127;
    float m = sums[h] * invN;
    float v = fmaf(-m, m, sums[H + h] * invN);
    float sc = rsqrtf(v + 1e-5f) * ldin(g, goff + h, f32m);
    float r = fmaf(x[idx] - m, sc, ldin(b, boff + h, f32m));
    stv(y, (size_t)idx, fmaxf(r, 0.f));
}

template <typename T>
static void run_layer2(const void* Wl, const void* bl, const void* Wr, const void* bng,
                       const void* bnb, T* hp, T* hl, T* hd, float* aggp, float* tl, float* aglr,
                       float* td, float* agdr, const float* invl, const float* invd,
                       const float* invpl, const float* invpd, const int* e1s, const int* e1d,
                       const int* e2s, const int* e2d, float* w23, float* b23, float* bns,
                       const int* flags, hipStream_t stream) {
    // a. raw means of hp into lab/disease tables (mean commutes with @W)
    hipMemsetAsync(aglr, 0, (size_t)NL * H * 4, stream);
    hipMemsetAsync(agdr, 0, (size_t)ND * H * 4, stream);
    k_scatter<T><<<(unsigned)((size_t)E1 * 128 / 256), 256, 0, stream>>>(hp, e1s, e1d, invl, aglr, E1);
    k_scatter<T><<<(unsigned)((size_t)E2 * 128 / 256), 256, 0, stream>>>(hp, e2s, e2d, invd, agdr, E2);
    // b. tl = hl@Wl[2], td = hd@Wl[3]
    k_mm_off<T, false, false, false><<<NL / 4, 128, 0, stream>>>(tl, hl, Wl, (size_t)2 * HH, nullptr, 0, NL, flags);
    k_mm_off<T, false, false, false><<<(ND + 3) / 4, 128, 0, stream>>>(td, hd, Wl, (size_t)3 * HH, nullptr, 0, ND, flags);
    // c. patient aggregation
    hipMemsetAsync(aggp, 0, (size_t)NP * H * 4, stream);
    k_scatter<float><<<(unsigned)((size_t)E1 * 128 / 256), 256, 0, stream>>>(tl, e1d, e1s, invpl, aggp, E1);
    k_scatter<float><<<(unsigned)((size_t)E2 * 128 / 256), 256, 0, stream>>>(td, e2d, e2s, invpd, aggp, E2);
    // d. self term: aggp += hp @ (Wr2+Wr3) + (bl2+bl3)
    k_prep23<<<(HH + 255) / 256, 256, 0, stream>>>(Wr, bl, w23, b23, flags);
    k_mm_off<T, true, true, true><<<NP / 4, 128, 0, stream>>>(aggp, hp, w23, 0, b23, 0, NP, flags);
    // e. BN+relu patients -> hp
    hipMemsetAsync(bns, 0, 2 * H * 4, stream);
    k_bn_stats<<<1024, 256, 0, stream>>>(aggp, bns, NP);
    k_bn_apply_off<T><<<(NP * H + 255) / 256, 256, 0, stream>>>(aggp, hp, bns, bng, 0, bnb, 0, NP, 1.f / NP, flags);
    // f. labs: tl = aglr@Wl[0] + bl[0] + hl@Wr[0]; BN -> hl
    k_mm_off<float, false, false, true><<<NL / 4, 128, 0, stream>>>(tl, aglr, Wl, 0, bl, 0, NL, flags);
    k_mm_off<T, false, true, false><<<NL / 4, 128, 0, stream>>>(tl, hl, Wr, 0, nullptr, 0, NL, flags);
    hipMemsetAsync(bns, 0, 2 * H * 4, stream);
    k_bn_stats<<<256, 256, 0, stream>>>(tl, bns, NL);
    k_bn_apply_off<T><<<(NL * H + 255) / 256, 256, 0, stream>>>(tl, hl, bns, bng, H, bnb, H, NL, 1.f / NL, flags);
    // g. diseases: td = agdr@Wl[1] + bl[1] + hd@Wr[1]; BN -> hd
    k_mm_off<float, false, false, true><<<(ND + 3) / 4, 128, 0, stream>>>(td, agdr, Wl, (size_t)1 * HH, bl, H, ND, flags);
    k_mm_off<T, false, true, false><<<(ND + 3) / 4, 128, 0, stream>>>(td, hd, Wr, (size_t)1 * HH, nullptr, 0, ND, flags);
    hipMemsetAsync(bns, 0, 2 * H * 4, stream);
    k_bn_stats<<<64, 256, 0, stream>>>(td, bns, ND);
    k_bn_apply_off<T><<<(ND * H + 255) / 256, 256, 0, stream>>>(td, hd, bns, bng, 2 * H, bnb, 2 * H, ND, 1.f / ND, flags);
}

template <typename T>
static void run_all(void* const* d_in, void* d_out, void* d_ws, hipStream_t stream) {
    const void* x_p = d_in[0];
    const void* x_l = d_in[1];
    const void* x_d = d_in[2];
    const void* Wp = d_in[3];
    const void* bp = d_in[4];
    const void* Wlab = d_in[5];
    const void* blab = d_in[6];
    const void* Wdis = d_in[7];
    const void* bdis = d_in[8];
    const void* Wl1 = d_in[9];
    const void* bl1 = d_in[10];
    const void* Wr1 = d_in[11];
    const void* Wl2 = d_in[12];
    const void* bl2 = d_in[13];
    const void* Wr2 = d_in[14];
    const void* bn1g = d_in[15];
    const void* bn1b = d_in[16];
    const void* bn2g = d_in[17];
    const void* bn2b = d_in[18];
    const void* fc1W = d_in[19];
    const void* fc1b = d_in[20];
    const void* fc2W = d_in[21];
    const void* fc2b = d_in[22];
    const int* e1s = (const int*)d_in[23];
    const int* e1d = (const int*)d_in[24];
    const int* e2s = (const int*)d_in[25];
    const int* e2d = (const int*)d_in[26];

    // ---- workspace layout: flags + small arrays FIRST, big arrays last ----
    float* ws = (float*)d_ws;
    size_t o = 0;
    auto af = [&](size_t n) { float* p = ws + o; o += n; return p; };
    int* flags = (int*)af(16);
    float* invl = af(NL);
    float* invd = af(ND);
    float* invpl = af(NP);
    float* invpd = af(NP);
    float* w23 = af(HH);
    float* b23 = af(H);
    float* bns = af(2 * H);
    float* tl = af((size_t)NL * H);
    float* aglr = af((size_t)NL * H);
    float* td = af((size_t)ND * H);
    float* agdr = af((size_t)ND * H);
    float* aggp = af((size_t)NP * H);
    T* hp = (T*)(ws + o); o += ((size_t)NP * H * sizeof(T)) / 4;
    T* hl = (T*)(ws + o); o += ((size_t)NL * H * sizeof(T)) / 4;
    T* hd = (T*)(ws + o); o += ((size_t)ND * H * sizeof(T)) / 4;

    // ---- input dtype detection ----
    k_detect<<<1, 256, 0, stream>>>((const unsigned short*)x_p, flags);

    // ---- degree counts (structure-only; shared by both layers) ----
    hipMemsetAsync(invl, 0, (size_t)(NL + ND + 2 * NP) * 4, stream);  // contiguous region
    k_count<<<(E1 + 255) / 256, 256, 0, stream>>>(e1s, e1d, invpl, invl, E1);
    k_count<<<(E2 + 255) / 256, 256, 0, stream>>>(e2s, e2d, invpd, invd, E2);
    k_invert<<<(NL + ND + 2 * NP + 255) / 256, 256, 0, stream>>>(invl, NL + ND + 2 * NP);

    // ---- initial embeddings ----
    k_embed<T><<<(NP * H + 255) / 256, 256, 0, stream>>>(x_p, Wp, bp, hp, NP, 16, flags);
    k_embed<T><<<(NL * H + 255) / 256, 256, 0, stream>>>(x_l, Wlab, blab, hl, NL, 1, flags);
    k_embed<T><<<(ND * H + 255) / 256, 256, 0, stream>>>(x_d, Wdis, bdis, hd, ND, 2, flags);

    // ---- two hetero layers ----
    run_layer2<T>(Wl1, bl1, Wr1, bn1g, bn1b, hp, hl, hd, aggp, tl, aglr, td, agdr, invl, invd,
                  invpl, invpd, e1s, e1d, e2s, e2d, w23, b23, bns, flags, stream);
    run_layer2<T>(Wl2, bl2, Wr2, bn2g, bn2b, hp, hl, hd, aggp, tl, aglr, td, agdr, invl, invd,
                  invpl, invpd, e1s, e1d, e2s, e2d, w23, b23, bns, flags, stream);

    // ---- head ----
    k_head<T><<<NP / 4, 256, 0, stream>>>(hp, fc1W, fc1b, fc2W, fc2b, d_out, flags);
}

extern "C" void kernel_launch(void* const* d_in, const int* in_sizes, int n_in, void* d_out,
                              int out_size, void* d_ws, size_t ws_size, hipStream_t stream) {
    const size_t fixed = 16 + (size_t)NL + ND + NP + NP + HH + H + 2 * H + 2 * (size_t)NL * H +
                         2 * (size_t)ND * H + (size_t)NP * H;
    const size_t elemsT = (size_t)(NP + NL + ND) * H;
    const size_t need_f32 = fixed * 4 + elemsT * 4;  // ~114 MiB
    if (ws_size >= need_f32)
        run_all<float>(d_in, d_out, d_ws, stream);
    else
        run_all<bf16>(d_in, d_out, d_ws, stream);  // ~87 MiB fallback
}

// Round 4
// 3502.836 us; speedup vs baseline: 1.9214x; 1.9214x over previous
//
#include <hip/hip_runtime.h>
#include <hip/hip_bf16.h>

#define NP 100000
#define NL 10000
#define ND 500
#define H 128
#define HH (H * H)
#define E1 2000000
#define E2 500000
#define NOUT 10

typedef __hip_bfloat16 bf16;

__device__ __forceinline__ float ldv(const float* p, size_t i) { return p[i]; }
__device__ __forceinline__ float ldv(const bf16* p, size_t i) { return __bfloat162float(p[i]); }
__device__ __forceinline__ void stv(float* p, size_t i, float v) { p[i] = v; }
__device__ __forceinline__ void stv(bf16* p, size_t i, float v) { p[i] = __float2bfloat16(v); }

// raw input buffer with runtime dtype (f32m: 1=f32, 0=bf16)
__device__ __forceinline__ float ldin(const void* p, size_t i, int f32m) {
    return f32m ? ((const float*)p)[i] : __bfloat162float(((const bf16*)p)[i]);
}

// ---------------- input dtype detection (kept from round 2; measured: picks bf16) -------
__global__ void k_detect(const unsigned short* __restrict__ xp, int* __restrict__ flags) {
    int t = threadIdx.x;
    int cnt = 0;
    for (int i = t; i < 4096; i += 256) {
        unsigned short w = xp[2 * i];
        int e = (w >> 7) & 0xFF;
        if (w == 0 || (e >= 114 && e <= 141)) cnt++;
    }
    __shared__ int sh[256];
    sh[t] = cnt;
    __syncthreads();
    for (int s = 128; s > 0; s >>= 1) {
        if (t < s) sh[t] += sh[t + s];
        __syncthreads();
    }
    if (t == 0) flags[0] = (sh[0] < 2048) ? 1 : 0;  // 1 = f32 inputs
}

// ---------------- embeddings ----------------
template <typename T>
__global__ void k_embed(const void* __restrict__ x, const void* __restrict__ W,
                        const void* __restrict__ b, T* __restrict__ out, int N, int K,
                        const int* __restrict__ flags) {
    int f32m = flags[0];
    int idx = blockIdx.x * 256 + threadIdx.x;
    if (idx >= N * H) return;
    int i = idx >> 7, h = idx & 127;
    float acc = ldin(b, h, f32m);
    for (int k = 0; k < K; ++k)
        acc = fmaf(ldin(x, (size_t)i * K + k, f32m), ldin(W, (size_t)k * H + h, f32m), acc);
    stv(out, (size_t)idx, acc);
}

// ---------------- CSR build: counts, scan, fill ----------------
__global__ void k_count2(const int* __restrict__ s, const int* __restrict__ d,
                         int* __restrict__ cs, int* __restrict__ cd, int nE) {
    int e = blockIdx.x * 256 + threadIdx.x;
    if (e >= nE) return;
    atomicAdd(&cs[s[e]], 1);
    atomicAdd(&cd[d[e]], 1);
}

#define SCAN_ELEMS 2048
// per-block exclusive scan (256 thr x 8 elems) + block sums
__global__ void k_scan1(const int* __restrict__ in, int* __restrict__ out,
                        int* __restrict__ bsums, int n) {
    int t = threadIdx.x;
    int base = blockIdx.x * SCAN_ELEMS + t * 8;
    int v[8], tsum = 0;
#pragma unroll
    for (int j = 0; j < 8; ++j) {
        v[j] = (base + j < n) ? in[base + j] : 0;
        tsum += v[j];
    }
    __shared__ int sh[256];
    sh[t] = tsum;
    __syncthreads();
    for (int d = 1; d < 256; d <<= 1) {
        int x = (t >= d) ? sh[t - d] : 0;
        __syncthreads();
        sh[t] += x;
        __syncthreads();
    }
    int texcl = sh[t] - tsum;
    if (t == 255) bsums[blockIdx.x] = sh[255];
    int run = texcl;
#pragma unroll
    for (int j = 0; j < 8; ++j) {
        if (base + j < n) out[base + j] = run;
        run += v[j];
    }
}

// single-block exclusive scan of block sums (nb <= 256)
__global__ void k_scan2(int* __restrict__ bsums, int nb) {
    int t = threadIdx.x;
    int v = (t < nb) ? bsums[t] : 0;
    __shared__ int sh[256];
    sh[t] = v;
    __syncthreads();
    for (int d = 1; d < 256; d <<= 1) {
        int x = (t >= d) ? sh[t - d] : 0;
        __syncthreads();
        sh[t] += x;
        __syncthreads();
    }
    if (t < nb) bsums[t] = sh[t] - v;
}

__global__ void k_scan3(int* __restrict__ out, const int* __restrict__ bsums, int n) {
    int i = blockIdx.x * 256 + threadIdx.x;
    if (i < n) out[i] += bsums[i / SCAN_ELEMS];
}

// fill neighbor lists; cur_* start as offsets, end as END offsets (start = end - cnt)
__global__ void k_fill(const int* __restrict__ s, const int* __restrict__ d,
                       int* __restrict__ cur_s, int* __restrict__ nbr_s,
                       int* __restrict__ cur_d, int* __restrict__ nbr_d, int nE) {
    int e = blockIdx.x * 256 + threadIdx.x;
    if (e >= nE) return;
    int ss = s[e], dd = d[e];
    nbr_d[atomicAdd(&cur_d[dd], 1)] = ss;
    nbr_s[atomicAdd(&cur_s[ss], 1)] = dd;
}

// ---------------- gather: out[row,:] = mean over nbr rows of tbl ----------------
template <typename T>
__global__ void k_gather(const T* __restrict__ tbl, const int* __restrict__ endo,
                         const int* __restrict__ cnt, const int* __restrict__ nbr,
                         float* __restrict__ out, int nDst) {
    int row = blockIdx.x;
    if (row >= nDst) return;
    int h = threadIdx.x;
    int end = endo[row], c = cnt[row];
    float acc = 0.f;
    for (int j = end - c; j < end; ++j)
        acc += ldv(tbl, (size_t)nbr[j] * H + h);
    out[(size_t)row * H + h] = acc / fmaxf((float)c, 1.f);
}

// fused patient gather: mean over labs (tlp) + mean over diseases (tdp)
__global__ void k_gather_pat(const float* __restrict__ t1, const float* __restrict__ t2,
                             const int* __restrict__ e1o, const int* __restrict__ c1,
                             const int* __restrict__ n1, const int* __restrict__ e2o,
                             const int* __restrict__ c2, const int* __restrict__ n2,
                             float* __restrict__ out) {
    int row = blockIdx.x;
    int h = threadIdx.x;
    int end1 = e1o[row], cc1 = c1[row];
    float a1 = 0.f;
    for (int j = end1 - cc1; j < end1; ++j)
        a1 += t1[(size_t)n1[j] * H + h];
    int end2 = e2o[row], cc2 = c2[row];
    float a2 = 0.f;
    for (int j = end2 - cc2; j < end2; ++j)
        a2 += t2[(size_t)n2[j] * H + h];
    out[(size_t)row * H + h] =
        a1 / fmaxf((float)cc1, 1.f) + a2 / fmaxf((float)cc2, 1.f);
}

// ---------------- Wr2+Wr3 / bl2+bl3 prep ----------------
__global__ void k_prep23(const void* __restrict__ Wr, const void* __restrict__ bl,
                         float* __restrict__ w23, float* __restrict__ b23,
                         const int* __restrict__ flags) {
    int f32m = flags[0];
    int idx = blockIdx.x * 256 + threadIdx.x;
    if (idx < HH)
        w23[idx] = ldin(Wr, (size_t)2 * HH + idx, f32m) + ldin(Wr, (size_t)3 * HH + idx, f32m);
    if (idx < H)
        b23[idx] = ldin(bl, (size_t)2 * H + idx, f32m) + ldin(bl, (size_t)3 * H + idx, f32m);
}

// ------- out[N,H] (= or +=) in[N,H] @ W[H,H] (+ bias); element offsets into W/bias -------
template <typename TIn, bool WF32, bool ADD, bool BIAS>
__global__ void k_mm_off(float* __restrict__ out, const TIn* __restrict__ in,
                         const void* __restrict__ W, size_t woff, const void* __restrict__ bias,
                         size_t boff, int N, const int* __restrict__ flags) {
    int f32m = WF32 ? 1 : flags[0];
    __shared__ float s[4][H];
    int h = threadIdx.x;
    int r0 = blockIdx.x * 4;
#pragma unroll
    for (int r = 0; r < 4; ++r)
        s[r][h] = (r0 + r < N) ? ldv(in, (size_t)(r0 + r) * H + h) : 0.f;
    __syncthreads();
    float a0 = 0.f, a1 = 0.f, a2 = 0.f, a3 = 0.f;
    for (int k = 0; k < H; ++k) {
        float w = ldin(W, woff + (size_t)k * H + h, f32m);
        a0 = fmaf(s[0][k], w, a0);
        a1 = fmaf(s[1][k], w, a1);
        a2 = fmaf(s[2][k], w, a2);
        a3 = fmaf(s[3][k], w, a3);
    }
    float bb = BIAS ? ldin(bias, boff + (size_t)h, f32m) : 0.f;
    float acc[4] = {a0, a1, a2, a3};
#pragma unroll
    for (int r = 0; r < 4; ++r) {
        if (r0 + r < N) {
            size_t o = (size_t)(r0 + r) * H + h;
            float a = acc[r] + bb;
            out[o] = ADD ? (out[o] + a) : a;
        }
    }
}

// ---------------- BatchNorm ----------------
__global__ void k_bn_stats(const float* __restrict__ x, float* __restrict__ sums, int N) {
    int h = threadIdx.x & 127;
    int sub = threadIdx.x >> 7;
    float s = 0.f, s2 = 0.f;
    for (int i = blockIdx.x * 2 + sub; i < N; i += gridDim.x * 2) {
        float v = x[(size_t)i * H + h];
        s += v;
        s2 = fmaf(v, v, s2);
    }
    __shared__ float ls[256], ls2[256];
    ls[threadIdx.x] = s;
    ls2[threadIdx.x] = s2;
    __syncthreads();
    if (sub == 0) {
        atomicAdd(&sums[h], s + ls[128 + h]);
        atomicAdd(&sums[H + h], s2 + ls2[128 + h]);
    }
}

template <typename T>
__global__ void k_bn_apply_off(const float* __restrict__ x, T* __restrict__ y,
                               const float* __restrict__ sums, const void* __restrict__ g,
                               size_t goff, const void* __restrict__ b, size_t boff, int N,
                               float invN, const int* __restrict__ flags) {
    int f32m = flags[0];
    int idx = blockIdx.x * 256 + threadIdx.x;
    if (idx >= N * H) return;
    int h = idx & 127;
    float m = sums[h] * invN;
    float v = fmaf(-m, m, sums[H + h] * invN);
    float sc = rsqrtf(v + 1e-5f) * ldin(g, goff + h, f32m);
    float r = fmaf(x[idx] - m, sc, ldin(b, boff + h, f32m));
    stv(y, (size_t)idx, fmaxf(r, 0.f));
}

// ---------------- head ----------------
template <typename T>
__global__ void k_head(const T* __restrict__ hp, const void* __restrict__ W1,
                       const void* __restrict__ b1, const void* __restrict__ W2,
                       const void* __restrict__ b2, void* __restrict__ out,
                       const int* __restrict__ flags) {
    int f32m = flags[0];
    __shared__ float h1[4][64];
    __shared__ float lg[4][16];
    int sub = threadIdx.x >> 6;
    int j = threadIdx.x & 63;
    int p = blockIdx.x * 4 + sub;  // NP % 4 == 0
    const T* row = hp + (size_t)p * H;
    float acc = ldin(b1, j, f32m);
#pragma unroll 8
    for (int k = 0; k < H; ++k)
        acc = fmaf(ldv(row, (size_t)k), ldin(W1, (size_t)k * 64 + j, f32m), acc);
    h1[sub][j] = fmaxf(acc, 0.f);
    __syncthreads();
    if (j < NOUT) {
        float a = ldin(b2, j, f32m);
#pragma unroll
        for (int k = 0; k < 64; ++k)
            a = fmaf(h1[sub][k], ldin(W2, (size_t)k * NOUT + j, f32m), a);
        lg[sub][j] = a;
    }
    __syncthreads();
    if (j < NOUT) {
        float m = -1e30f;
#pragma unroll
        for (int k = 0; k < NOUT; ++k) m = fmaxf(m, lg[sub][k]);
        float s = 0.f;
#pragma unroll
        for (int k = 0; k < NOUT; ++k) s += __expf(lg[sub][k] - m);
        float r = lg[sub][j] - m - __logf(s);
        if (f32m)
            ((float*)out)[(size_t)p * NOUT + j] = r;
        else
            ((bf16*)out)[(size_t)p * NOUT + j] = __float2bfloat16(r);
    }
}

// helper: run exclusive scan of cnt -> off for one segment
static void run_scan(const int* cnt, int* off, int* bsums, int n, hipStream_t stream) {
    int nb = (n + SCAN_ELEMS - 1) / SCAN_ELEMS;
    k_scan1<<<nb, 256, 0, stream>>>(cnt, off, bsums, n);
    k_scan2<<<1, 256, 0, stream>>>(bsums, nb);
    k_scan3<<<(n + 255) / 256, 256, 0, stream>>>(off, bsums, n);
}

// ---------------- one hetero layer ----------------
template <typename T>
static void run_layer(const void* Wl, const void* bl, const void* Wr, const void* bng,
                      const void* bnb, T* hp, T* hl, T* hd, float* aggp, float* bufL, float* tlp,
                      float* bufD, float* tdp, const int* cnt_l, const int* end_l,
                      const int* nbr_l, const int* cnt_d, const int* end_d, const int* nbr_d,
                      const int* cnt_p1, const int* end_p1, const int* nbr_p1, const int* cnt_p2,
                      const int* end_p2, const int* nbr_p2, float* w23, float* b23, float* bns,
                      const int* flags, hipStream_t stream) {
    // 1. patient-direction transforms of small tables (use OLD hl, hd)
    k_mm_off<T, false, false, false><<<NL / 4, 128, 0, stream>>>(tlp, hl, Wl, (size_t)2 * HH, nullptr, 0, NL, flags);
    k_mm_off<T, false, false, false><<<ND / 4, 128, 0, stream>>>(tdp, hd, Wl, (size_t)3 * HH, nullptr, 0, ND, flags);
    // 2. gather means of raw hp into lab/disease buffers (mean commutes with @W)
    k_gather<T><<<NL, 128, 0, stream>>>(hp, end_l, cnt_l, nbr_l, bufL, NL);
    k_gather<T><<<ND, 128, 0, stream>>>(hp, end_d, cnt_d, nbr_d, bufD, ND);
    // 3. fused patient gather (means of tlp and tdp)
    k_gather_pat<<<NP, 128, 0, stream>>>(tlp, tdp, end_p1, cnt_p1, nbr_p1, end_p2, cnt_p2, nbr_p2, aggp);
    // 4. self term: aggp += hp @ (Wr2+Wr3) + (bl2+bl3)
    k_prep23<<<(HH + 255) / 256, 256, 0, stream>>>(Wr, bl, w23, b23, flags);
    k_mm_off<T, true, true, true><<<NP / 4, 128, 0, stream>>>(aggp, hp, w23, 0, b23, 0, NP, flags);
    // 5. BN+relu patients -> hp
    hipMemsetAsync(bns, 0, 2 * H * 4, stream);
    k_bn_stats<<<1024, 256, 0, stream>>>(aggp, bns, NP);
    k_bn_apply_off<T><<<(NP * H + 255) / 256, 256, 0, stream>>>(aggp, hp, bns, bng, 0, bnb, 0, NP, 1.f / NP, flags);
    // 6. labs: bufL = bufL@Wl[0]+bl[0] (in-place ok: block reads own rows to LDS first),
    //          bufL += (old) hl@Wr[0]; BN -> hl
    k_mm_off<float, false, false, true><<<NL / 4, 128, 0, stream>>>(bufL, bufL, Wl, 0, bl, 0, NL, flags);
    k_mm_off<T, false, true, false><<<NL / 4, 128, 0, stream>>>(bufL, hl, Wr, 0, nullptr, 0, NL, flags);
    hipMemsetAsync(bns, 0, 2 * H * 4, stream);
    k_bn_stats<<<256, 256, 0, stream>>>(bufL, bns, NL);
    k_bn_apply_off<T><<<(NL * H + 255) / 256, 256, 0, stream>>>(bufL, hl, bns, bng, H, bnb, H, NL, 1.f / NL, flags);
    // 7. diseases
    k_mm_off<float, false, false, true><<<ND / 4, 128, 0, stream>>>(bufD, bufD, Wl, (size_t)1 * HH, bl, H, ND, flags);
    k_mm_off<T, false, true, false><<<ND / 4, 128, 0, stream>>>(bufD, hd, Wr, (size_t)1 * HH, nullptr, 0, ND, flags);
    hipMemsetAsync(bns, 0, 2 * H * 4, stream);
    k_bn_stats<<<64, 256, 0, stream>>>(bufD, bns, ND);
    k_bn_apply_off<T><<<(ND * H + 255) / 256, 256, 0, stream>>>(bufD, hd, bns, bng, 2 * H, bnb, 2 * H, ND, 1.f / ND, flags);
}

template <typename T>
static void run_all(void* const* d_in, void* d_out, void* d_ws, hipStream_t stream) {
    const void* x_p = d_in[0];
    const void* x_l = d_in[1];
    const void* x_d = d_in[2];
    const void* Wp = d_in[3];
    const void* bp = d_in[4];
    const void* Wlab = d_in[5];
    const void* blab = d_in[6];
    const void* Wdis = d_in[7];
    const void* bdis = d_in[8];
    const void* Wl1 = d_in[9];
    const void* bl1 = d_in[10];
    const void* Wr1 = d_in[11];
    const void* Wl2 = d_in[12];
    const void* bl2 = d_in[13];
    const void* Wr2 = d_in[14];
    const void* bn1g = d_in[15];
    const void* bn1b = d_in[16];
    const void* bn2g = d_in[17];
    const void* bn2b = d_in[18];
    const void* fc1W = d_in[19];
    const void* fc1b = d_in[20];
    const void* fc2W = d_in[21];
    const void* fc2b = d_in[22];
    const int* e1s = (const int*)d_in[23];
    const int* e1d = (const int*)d_in[24];
    const int* e2s = (const int*)d_in[25];
    const int* e2d = (const int*)d_in[26];

    // ---- workspace layout: small first, large last ----
    char* wsb = (char*)d_ws;
    size_t o = 0;
    auto af = [&](size_t nwords) { void* p = wsb + o * 4; o += nwords; return p; };
    int* flags = (int*)af(16);
    float* w23 = (float*)af(HH);
    float* b23 = (float*)af(H);
    float* bns = (float*)af(2 * H);
    int* bsums = (int*)af(256);
    // counts (contiguous block for single memset): [lab NL][dis ND][p1 NP][p2 NP]
    int* cnt_l = (int*)af(NL);
    int* cnt_d = (int*)af(ND);
    int* cnt_p1 = (int*)af(NP);
    int* cnt_p2 = (int*)af(NP);
    int* end_l = (int*)af(NL);
    int* end_d = (int*)af(ND);
    int* end_p1 = (int*)af(NP);
    int* end_p2 = (int*)af(NP);
    float* bufD = (float*)af((size_t)ND * H);
    float* tdp = (float*)af((size_t)ND * H);
    float* bufL = (float*)af((size_t)NL * H);
    float* tlp = (float*)af((size_t)NL * H);
    int* nbr_l = (int*)af(E1);
    int* nbr_p1 = (int*)af(E1);
    int* nbr_d = (int*)af(E2);
    int* nbr_p2 = (int*)af(E2);
    float* aggp = (float*)af((size_t)NP * H);
    T* hp = (T*)af(((size_t)NP * H * sizeof(T) + 3) / 4);
    T* hl = (T*)af(((size_t)NL * H * sizeof(T) + 3) / 4);
    T* hd = (T*)af(((size_t)ND * H * sizeof(T) + 3) / 4);

    // ---- dtype detection ----
    k_detect<<<1, 256, 0, stream>>>((const unsigned short*)x_p, flags);

    // ---- CSR build (structure-only; shared by both layers) ----
    hipMemsetAsync(cnt_l, 0, (size_t)(NL + ND + 2 * NP) * 4, stream);
    k_count2<<<(E1 + 255) / 256, 256, 0, stream>>>(e1s, e1d, cnt_p1, cnt_l, E1);
    k_count2<<<(E2 + 255) / 256, 256, 0, stream>>>(e2s, e2d, cnt_p2, cnt_d, E2);
    run_scan(cnt_l, end_l, bsums, NL, stream);
    run_scan(cnt_d, end_d, bsums, ND, stream);
    run_scan(cnt_p1, end_p1, bsums, NP, stream);
    run_scan(cnt_p2, end_p2, bsums, NP, stream);
    k_fill<<<(E1 + 255) / 256, 256, 0, stream>>>(e1s, e1d, end_p1, nbr_p1, end_l, nbr_l, E1);
    k_fill<<<(E2 + 255) / 256, 256, 0, stream>>>(e2s, e2d, end_p2, nbr_p2, end_d, nbr_d, E2);
    // after fill, end_* hold END offsets (start = end - cnt)

    // ---- initial embeddings ----
    k_embed<T><<<(NP * H + 255) / 256, 256, 0, stream>>>(x_p, Wp, bp, hp, NP, 16, flags);
    k_embed<T><<<(NL * H + 255) / 256, 256, 0, stream>>>(x_l, Wlab, blab, hl, NL, 1, flags);
    k_embed<T><<<(ND * H + 255) / 256, 256, 0, stream>>>(x_d, Wdis, bdis, hd, ND, 2, flags);

    // ---- two hetero layers ----
    run_layer<T>(Wl1, bl1, Wr1, bn1g, bn1b, hp, hl, hd, aggp, bufL, tlp, bufD, tdp, cnt_l, end_l,
                 nbr_l, cnt_d, end_d, nbr_d, cnt_p1, end_p1, nbr_p1, cnt_p2, end_p2, nbr_p2, w23,
                 b23, bns, flags, stream);
    run_layer<T>(Wl2, bl2, Wr2, bn2g, bn2b, hp, hl, hd, aggp, bufL, tlp, bufD, tdp, cnt_l, end_l,
                 nbr_l, cnt_d, end_d, nbr_d, cnt_p1, end_p1, nbr_p1, cnt_p2, end_p2, nbr_p2, w23,
                 b23, bns, flags, stream);

    // ---- head ----
    k_head<T><<<NP / 4, 256, 0, stream>>>(hp, fc1W, fc1b, fc2W, fc2b, d_out, flags);
}

extern "C" void kernel_launch(void* const* d_in, const int* in_sizes, int n_in, void* d_out,
                              int out_size, void* d_ws, size_t ws_size, hipStream_t stream) {
    // words of fixed (fp32/int) workspace
    const size_t fixed = 16 + HH + H + 2 * H + 256 + 2 * ((size_t)NL + ND + 2 * NP) +
                         2 * (size_t)ND * H + 2 * (size_t)NL * H + 2 * (size_t)E1 +
                         2 * (size_t)E2 + (size_t)NP * H;
    const size_t elemsT = (size_t)(NP + NL + ND) * H;
    const size_t need_f32 = fixed * 4 + elemsT * 4;  // ~140 MiB
    if (ws_size >= need_f32)
        run_all<float>(d_in, d_out, d_ws, stream);
    else
        run_all<bf16>(d_in, d_out, d_ws, stream);  // ~112 MiB fallback
}

// Round 5
// 3187.879 us; speedup vs baseline: 2.1112x; 1.0988x over previous
//
#include <hip/hip_runtime.h>
#include <hip/hip_bf16.h>

#define NP 100000
#define NL 10000
#define ND 500
#define H 128
#define HH (H * H)
#define E1 2000000
#define E2 500000
#define NOUT 10

typedef __hip_bfloat16 bf16;

__device__ __forceinline__ float ldv(const float* p, size_t i) { return p[i]; }
__device__ __forceinline__ float ldv(const bf16* p, size_t i) { return __bfloat162float(p[i]); }
__device__ __forceinline__ void stv(float* p, size_t i, float v) { p[i] = v; }
__device__ __forceinline__ void stv(bf16* p, size_t i, float v) { p[i] = __float2bfloat16(v); }

// raw input buffer with runtime dtype (f32m: 1=f32, 0=bf16)
__device__ __forceinline__ float ldin(const void* p, size_t i, int f32m) {
    return f32m ? ((const float*)p)[i] : __bfloat162float(((const bf16*)p)[i]);
}

// ---------------- input dtype detection (measured: picks bf16 on this harness) ----------
__global__ void k_detect(const unsigned short* __restrict__ xp, int* __restrict__ flags) {
    int t = threadIdx.x;
    int cnt = 0;
    for (int i = t; i < 4096; i += 256) {
        unsigned short w = xp[2 * i];
        int e = (w >> 7) & 0xFF;
        if (w == 0 || (e >= 114 && e <= 141)) cnt++;
    }
    __shared__ int sh[256];
    sh[t] = cnt;
    __syncthreads();
    for (int s = 128; s > 0; s >>= 1) {
        if (t < s) sh[t] += sh[t + s];
        __syncthreads();
    }
    if (t == 0) flags[0] = (sh[0] < 2048) ? 1 : 0;  // 1 = f32 inputs
}

// ---------------- fused initial embeddings (hp bf16; hl/hd TA) ----------------
template <typename TA>
__global__ void k_embed_all(const void* __restrict__ xp, const void* __restrict__ xl,
                            const void* __restrict__ xd, const void* __restrict__ Wp,
                            const void* __restrict__ bp, const void* __restrict__ Wlab,
                            const void* __restrict__ blab, const void* __restrict__ Wdis,
                            const void* __restrict__ bdis, bf16* __restrict__ hp,
                            TA* __restrict__ hl, TA* __restrict__ hd,
                            const int* __restrict__ flags) {
    int f32m = flags[0];
    int idx = blockIdx.x * 256 + threadIdx.x;
    int h = idx & 127;
    if (idx < NP * H) {
        int i = idx >> 7;
        float acc = ldin(bp, h, f32m);
#pragma unroll
        for (int k = 0; k < 16; ++k)
            acc = fmaf(ldin(xp, (size_t)i * 16 + k, f32m), ldin(Wp, (size_t)k * H + h, f32m), acc);
        hp[idx] = __float2bfloat16(acc);
    } else if (idx < (NP + NL) * H) {
        int i = (idx - NP * H) >> 7;
        float acc = fmaf(ldin(xl, i, f32m), ldin(Wlab, h, f32m), ldin(blab, h, f32m));
        stv(hl, (size_t)i * H + h, acc);
    } else if (idx < (NP + NL + ND) * H) {
        int i = (idx - (NP + NL) * H) >> 7;
        float acc = ldin(bdis, h, f32m);
        acc = fmaf(ldin(xd, (size_t)i * 2 + 0, f32m), ldin(Wdis, h, f32m), acc);
        acc = fmaf(ldin(xd, (size_t)i * 2 + 1, f32m), ldin(Wdis, H + h, f32m), acc);
        stv(hd, (size_t)i * H + h, acc);
    }
}

// ---------------- CSR build ----------------
// cnt/end segments: [lab NL][dis ND][p1 NP][p2 NP]; nbr pool: [lab E1][dis E2][p1 E1][p2 E2]
__global__ void k_count_all(const int* __restrict__ e1s, const int* __restrict__ e1d,
                            const int* __restrict__ e2s, const int* __restrict__ e2d,
                            int* __restrict__ cnt) {
    int e = blockIdx.x * 256 + threadIdx.x;
    if (e < E1) {
        atomicAdd(&cnt[e1d[e]], 1);
        atomicAdd(&cnt[NL + ND + e1s[e]], 1);
    } else if (e < E1 + E2) {
        int i = e - E1;
        atomicAdd(&cnt[NL + e2d[i]], 1);
        atomicAdd(&cnt[NL + ND + NP + e2s[i]], 1);
    }
}

#define SCAN_ELEMS 2048
__global__ void k_scan1(const int* __restrict__ in, int* __restrict__ out,
                        int* __restrict__ bsums, int n) {
    int t = threadIdx.x;
    int base = blockIdx.x * SCAN_ELEMS + t * 8;
    int v[8], tsum = 0;
#pragma unroll
    for (int j = 0; j < 8; ++j) {
        v[j] = (base + j < n) ? in[base + j] : 0;
        tsum += v[j];
    }
    __shared__ int sh[256];
    sh[t] = tsum;
    __syncthreads();
    for (int d = 1; d < 256; d <<= 1) {
        int x = (t >= d) ? sh[t - d] : 0;
        __syncthreads();
        sh[t] += x;
        __syncthreads();
    }
    int run = sh[t] - tsum;
    if (t == 255) bsums[blockIdx.x] = sh[255];
#pragma unroll
    for (int j = 0; j < 8; ++j) {
        if (base + j < n) out[base + j] = run;
        run += v[j];
    }
}

__global__ void k_scan2(int* __restrict__ bsums, int nb) {
    int t = threadIdx.x;
    int v = (t < nb) ? bsums[t] : 0;
    __shared__ int sh[256];
    sh[t] = v;
    __syncthreads();
    for (int d = 1; d < 256; d <<= 1) {
        int x = (t >= d) ? sh[t - d] : 0;
        __syncthreads();
        sh[t] += x;
        __syncthreads();
    }
    if (t < nb) bsums[t] = sh[t] - v;
}

__global__ void k_scan3(int* __restrict__ out, const int* __restrict__ bsums, int n) {
    int i = blockIdx.x * 256 + threadIdx.x;
    if (i < n) out[i] += bsums[i / SCAN_ELEMS];
}

__global__ void k_fill_all(const int* __restrict__ e1s, const int* __restrict__ e1d,
                           const int* __restrict__ e2s, const int* __restrict__ e2d,
                           int* __restrict__ end, int* __restrict__ nbr) {
    int e = blockIdx.x * 256 + threadIdx.x;
    if (e < E1) {
        int ss = e1s[e], dd = e1d[e];
        nbr[atomicAdd(&end[dd], 1)] = ss;
        nbr[atomicAdd(&end[NL + ND + ss], 1)] = dd;
    } else if (e < E1 + E2) {
        int i = e - E1;
        int ss = e2s[i], dd = e2d[i];
        nbr[atomicAdd(&end[NL + e2d[i]], 1)] = ss;
        nbr[atomicAdd(&end[NL + ND + NP + ss], 1)] = dd;
    }
}

// ---------------- fused lab+dis gather of raw hp means ----------------
__global__ void k_gather_ld(const bf16* __restrict__ hp, const int* __restrict__ end,
                            const int* __restrict__ cnt, const int* __restrict__ nbr,
                            float* __restrict__ bufL, float* __restrict__ bufD) {
    bool lab = blockIdx.x < NL;
    int row = lab ? blockIdx.x : blockIdx.x - NL;
    int seg = lab ? row : NL + row;
    float* out = lab ? bufL : bufD;
    int h = threadIdx.x;
    int e = end[seg], c = cnt[seg];
    float acc = 0.f;
    for (int j = e - c; j < e; ++j)
        acc += __bfloat162float(hp[(size_t)nbr[j] * H + h]);
    out[(size_t)row * H + h] = acc / fmaxf((float)c, 1.f);
}

// ---------------- small transforms: tlp = hl@Wl[2], tdp = hd@Wl[3] (bf16 out) ----------
template <typename TA>
__global__ void k_mm_small(const TA* __restrict__ hl, const TA* __restrict__ hd,
                           const void* __restrict__ Wl, bf16* __restrict__ tlp,
                           bf16* __restrict__ tdp, const int* __restrict__ flags) {
    int f32m = flags[0];
    bool lab = blockIdx.x < NL / 4;
    const TA* in = lab ? hl : hd;
    bf16* out = lab ? tlp : tdp;
    size_t woff = lab ? (size_t)2 * HH : (size_t)3 * HH;
    int r0 = (lab ? blockIdx.x : blockIdx.x - NL / 4) * 4;
    __shared__ float s[4][H];
    int h = threadIdx.x;
#pragma unroll
    for (int r = 0; r < 4; ++r) s[r][h] = ldv(in, (size_t)(r0 + r) * H + h);
    __syncthreads();
    float a0 = 0.f, a1 = 0.f, a2 = 0.f, a3 = 0.f;
    for (int k = 0; k < H; ++k) {
        float w = ldin(Wl, woff + (size_t)k * H + h, f32m);
        a0 = fmaf(s[0][k], w, a0);
        a1 = fmaf(s[1][k], w, a1);
        a2 = fmaf(s[2][k], w, a2);
        a3 = fmaf(s[3][k], w, a3);
    }
    out[(size_t)(r0 + 0) * H + h] = __float2bfloat16(a0);
    out[(size_t)(r0 + 1) * H + h] = __float2bfloat16(a1);
    out[(size_t)(r0 + 2) * H + h] = __float2bfloat16(a2);
    out[(size_t)(r0 + 3) * H + h] = __float2bfloat16(a3);
}

// ---------------- Wr2+Wr3 / bl2+bl3 prep (f32 out) ----------------
__global__ void k_prep23(const void* __restrict__ Wr, const void* __restrict__ bl,
                         float* __restrict__ w23, float* __restrict__ b23,
                         const int* __restrict__ flags) {
    int f32m = flags[0];
    int idx = blockIdx.x * 256 + threadIdx.x;
    if (idx < HH)
        w23[idx] = ldin(Wr, (size_t)2 * HH + idx, f32m) + ldin(Wr, (size_t)3 * HH + idx, f32m);
    if (idx < H)
        b23[idx] = ldin(bl, (size_t)2 * H + idx, f32m) + ldin(bl, (size_t)3 * H + idx, f32m);
}

// -------- fused patient pass: aggp = mean_lab(tlp) + mean_dis(tdp) + hp@w23 + b23 --------
#define PR 8  // patient pairs per block (16 patients)
template <typename TA>
__global__ void k_patient(const bf16* __restrict__ hp, const bf16* __restrict__ tlp,
                          const bf16* __restrict__ tdp, const int* __restrict__ end,
                          const int* __restrict__ cnt, const int* __restrict__ nbr,
                          const float* __restrict__ w23, const float* __restrict__ b23,
                          TA* __restrict__ aggp) {
    int sub = threadIdx.x >> 7;  // 0..1
    int h = threadIdx.x & 127;
    int p0 = blockIdx.x * 2 * PR;
    float acc[PR];
    const int* end1 = end + NL + ND;
    const int* cnt1 = cnt + NL + ND;
    const int* end2 = end + NL + ND + NP;
    const int* cnt2 = cnt + NL + ND + NP;
#pragma unroll
    for (int r = 0; r < PR; ++r) {
        int p = p0 + 2 * r + sub;
        int e1 = end1[p], c1 = cnt1[p];
        float a1 = 0.f;
        for (int j = e1 - c1; j < e1; ++j)
            a1 += __bfloat162float(tlp[(size_t)nbr[j] * H + h]);
        int e2 = end2[p], c2 = cnt2[p];
        float a2 = 0.f;
        for (int j = e2 - c2; j < e2; ++j)
            a2 += __bfloat162float(tdp[(size_t)nbr[j] * H + h]);
        acc[r] = a1 / fmaxf((float)c1, 1.f) + a2 / fmaxf((float)c2, 1.f) + b23[h];
    }
    __shared__ float rows[2 * PR][H];
#pragma unroll
    for (int r = 0; r < PR; ++r)
        rows[2 * r + sub][h] = __bfloat162float(hp[(size_t)(p0 + 2 * r + sub) * H + h]);
    __syncthreads();
    for (int k = 0; k < H; ++k) {
        float w = w23[k * H + h];
#pragma unroll
        for (int r = 0; r < PR; ++r) acc[r] = fmaf(rows[2 * r + sub][k], w, acc[r]);
    }
#pragma unroll
    for (int r = 0; r < PR; ++r)
        stv(aggp, (size_t)(p0 + 2 * r + sub) * H + h, acc[r]);
}

// -------- fused lab/dis second stage (in-place): buf = buf@Wl + bl + hX@Wr --------
template <typename TA>
__global__ void k_mm_labdis(float* __restrict__ bufL, float* __restrict__ bufD,
                            const TA* __restrict__ hl, const TA* __restrict__ hd,
                            const void* __restrict__ Wl, const void* __restrict__ bl,
                            const void* __restrict__ Wr, const int* __restrict__ flags) {
    int f32m = flags[0];
    bool lab = blockIdx.x < NL / 4;
    float* buf = lab ? bufL : bufD;
    const TA* hx = lab ? hl : hd;
    size_t woff = lab ? 0 : (size_t)HH;
    size_t boff = lab ? 0 : (size_t)H;
    int r0 = (lab ? blockIdx.x : blockIdx.x - NL / 4) * 4;
    __shared__ float sB[4][H], sH[4][H];
    int h = threadIdx.x;
#pragma unroll
    for (int r = 0; r < 4; ++r) {
        sB[r][h] = buf[(size_t)(r0 + r) * H + h];
        sH[r][h] = ldv(hx, (size_t)(r0 + r) * H + h);
    }
    __syncthreads();
    float a0 = ldin(bl, boff + h, f32m);
    float a1 = a0, a2 = a0, a3 = a0;
    for (int k = 0; k < H; ++k) {
        float w = ldin(Wl, woff + (size_t)k * H + h, f32m);
        a0 = fmaf(sB[0][k], w, a0);
        a1 = fmaf(sB[1][k], w, a1);
        a2 = fmaf(sB[2][k], w, a2);
        a3 = fmaf(sB[3][k], w, a3);
    }
    for (int k = 0; k < H; ++k) {
        float w = ldin(Wr, woff + (size_t)k * H + h, f32m);
        a0 = fmaf(sH[0][k], w, a0);
        a1 = fmaf(sH[1][k], w, a1);
        a2 = fmaf(sH[2][k], w, a2);
        a3 = fmaf(sH[3][k], w, a3);
    }
    buf[(size_t)(r0 + 0) * H + h] = a0;
    buf[(size_t)(r0 + 1) * H + h] = a1;
    buf[(size_t)(r0 + 2) * H + h] = a2;
    buf[(size_t)(r0 + 3) * H + h] = a3;
}

// ---------------- BatchNorm ----------------
template <typename TA>
__global__ void k_bn_stats_pat(const TA* __restrict__ x, float* __restrict__ sums) {
    int h = threadIdx.x & 127;
    int sub = threadIdx.x >> 7;
    float s = 0.f, s2 = 0.f;
    for (int i = blockIdx.x * 2 + sub; i < NP; i += gridDim.x * 2) {
        float v = ldv(x, (size_t)i * H + h);
        s += v;
        s2 = fmaf(v, v, s2);
    }
    __shared__ float ls[256], ls2[256];
    ls[threadIdx.x] = s;
    ls2[threadIdx.x] = s2;
    __syncthreads();
    if (sub == 0) {
        atomicAdd(&sums[h], s + ls[128 + h]);
        atomicAdd(&sums[H + h], s2 + ls2[128 + h]);
    }
}

__global__ void k_bn_stats_ld(const float* __restrict__ bufL, const float* __restrict__ bufD,
                              float* __restrict__ sums) {
    bool lab = blockIdx.x < 256;
    const float* x = lab ? bufL : bufD;
    int N = lab ? NL : ND;
    float* sm = sums + (lab ? 2 * H : 4 * H);
    int bid = lab ? blockIdx.x : blockIdx.x - 256;
    int nb = lab ? 256 : 64;
    int h = threadIdx.x & 127;
    int sub = threadIdx.x >> 7;
    float s = 0.f, s2 = 0.f;
    for (int i = bid * 2 + sub; i < N; i += nb * 2) {
        float v = x[(size_t)i * H + h];
        s += v;
        s2 = fmaf(v, v, s2);
    }
    __shared__ float ls[256], ls2[256];
    ls[threadIdx.x] = s;
    ls2[threadIdx.x] = s2;
    __syncthreads();
    if (sub == 0) {
        atomicAdd(&sm[h], s + ls[128 + h]);
        atomicAdd(&sm[H + h], s2 + ls2[128 + h]);
    }
}

template <typename TA>
__global__ void k_bn_apply_pat(const TA* __restrict__ x, bf16* __restrict__ hp,
                               const float* __restrict__ sums, const void* __restrict__ g,
                               const void* __restrict__ b, const int* __restrict__ flags) {
    int f32m = flags[0];
    int idx = blockIdx.x * 256 + threadIdx.x;
    if (idx >= NP * H) return;
    int h = idx & 127;
    const float invN = 1.f / NP;
    float m = sums[h] * invN;
    float v = fmaf(-m, m, sums[H + h] * invN);
    float sc = rsqrtf(v + 1e-5f) * ldin(g, h, f32m);
    float r = fmaf(ldv(x, (size_t)idx) - m, sc, ldin(b, h, f32m));
    hp[idx] = __float2bfloat16(fmaxf(r, 0.f));
}

template <typename TA>
__global__ void k_bn_apply_ld(const float* __restrict__ bufL, const float* __restrict__ bufD,
                              TA* __restrict__ hl, TA* __restrict__ hd,
                              const float* __restrict__ sums, const void* __restrict__ g,
                              const void* __restrict__ b, const int* __restrict__ flags) {
    int f32m = flags[0];
    int idx = blockIdx.x * 256 + threadIdx.x;
    int h = idx & 127;
    if (idx < NL * H) {
        const float invN = 1.f / NL;
        float m = sums[2 * H + h] * invN;
        float v = fmaf(-m, m, sums[3 * H + h] * invN);
        float sc = rsqrtf(v + 1e-5f) * ldin(g, H + h, f32m);
        float r = fmaf(bufL[idx] - m, sc, ldin(b, H + h, f32m));
        stv(hl, (size_t)idx, fmaxf(r, 0.f));
    } else if (idx < (NL + ND) * H) {
        int j = idx - NL * H;
        const float invN = 1.f / ND;
        float m = sums[4 * H + h] * invN;
        float v = fmaf(-m, m, sums[5 * H + h] * invN);
        float sc = rsqrtf(v + 1e-5f) * ldin(g, 2 * H + h, f32m);
        float r = fmaf(bufD[j] - m, sc, ldin(b, 2 * H + h, f32m));
        stv(hd, (size_t)j, fmaxf(r, 0.f));
    }
}

// ---------------- head ----------------
__global__ void k_head(const bf16* __restrict__ hp, const void* __restrict__ W1,
                       const void* __restrict__ b1, const void* __restrict__ W2,
                       const void* __restrict__ b2, void* __restrict__ out,
                       const int* __restrict__ flags) {
    int f32m = flags[0];
    __shared__ float h1[4][64];
    __shared__ float lg[4][16];
    int sub = threadIdx.x >> 6;
    int j = threadIdx.x & 63;
    int p = blockIdx.x * 4 + sub;
    const bf16* row = hp + (size_t)p * H;
    float acc = ldin(b1, j, f32m);
#pragma unroll 8
    for (int k = 0; k < H; ++k)
        acc = fmaf(__bfloat162float(row[k]), ldin(W1, (size_t)k * 64 + j, f32m), acc);
    h1[sub][j] = fmaxf(acc, 0.f);
    __syncthreads();
    if (j < NOUT) {
        float a = ldin(b2, j, f32m);
#pragma unroll
        for (int k = 0; k < 64; ++k)
            a = fmaf(h1[sub][k], ldin(W2, (size_t)k * NOUT + j, f32m), a);
        lg[sub][j] = a;
    }
    __syncthreads();
    if (j < NOUT) {
        float m = -1e30f;
#pragma unroll
        for (int k = 0; k < NOUT; ++k) m = fmaxf(m, lg[sub][k]);
        float s = 0.f;
#pragma unroll
        for (int k = 0; k < NOUT; ++k) s += __expf(lg[sub][k] - m);
        float r = lg[sub][j] - m - __logf(s);
        if (f32m)
            ((float*)out)[(size_t)p * NOUT + j] = r;
        else
            ((bf16*)out)[(size_t)p * NOUT + j] = __float2bfloat16(r);
    }
}

// ---------------- one hetero layer ----------------
template <typename TA>
static void run_layer(const void* Wl, const void* bl, const void* Wr, const void* bng,
                      const void* bnb, bf16* hp, TA* hl, TA* hd, TA* aggp, float* bufL,
                      float* bufD, bf16* tlp, bf16* tdp, const int* cnt, const int* end,
                      const int* nbr, float* w23, float* b23, float* bns, const int* flags,
                      hipStream_t stream) {
    k_mm_small<TA><<<NL / 4 + ND / 4, 128, 0, stream>>>(hl, hd, Wl, tlp, tdp, flags);
    k_gather_ld<<<NL + ND, 128, 0, stream>>>(hp, end, cnt, nbr, bufL, bufD);
    k_prep23<<<(HH + 255) / 256, 256, 0, stream>>>(Wr, bl, w23, b23, flags);
    k_patient<TA><<<NP / (2 * PR), 256, 0, stream>>>(hp, tlp, tdp, end, cnt, nbr, w23, b23, aggp);
    k_mm_labdis<TA><<<NL / 4 + ND / 4, 128, 0, stream>>>(bufL, bufD, hl, hd, Wl, bl, Wr, flags);
    hipMemsetAsync(bns, 0, 6 * H * 4, stream);
    k_bn_stats_pat<TA><<<1024, 256, 0, stream>>>(aggp, bns);
    k_bn_stats_ld<<<320, 256, 0, stream>>>(bufL, bufD, bns);
    k_bn_apply_pat<TA><<<(NP * H + 255) / 256, 256, 0, stream>>>(aggp, hp, bns, bng, bnb, flags);
    k_bn_apply_ld<TA><<<((NL + ND) * H + 255) / 256, 256, 0, stream>>>(bufL, bufD, hl, hd, bns,
                                                                       bng, bnb, flags);
}

template <typename TA>
static void run_all(void* const* d_in, void* d_out, void* d_ws, hipStream_t stream) {
    const int* e1s = (const int*)d_in[23];
    const int* e1d = (const int*)d_in[24];
    const int* e2s = (const int*)d_in[25];
    const int* e2d = (const int*)d_in[26];

    const int NCNT = NL + ND + 2 * NP;       // 210500
    const int NPOOL = 2 * (E1 + E2);         // 5000000

    char* wsb = (char*)d_ws;
    size_t o = 0;
    auto af = [&](size_t nwords) { void* p = wsb + o * 4; o += nwords; return p; };
    int* flags = (int*)af(16);
    float* w23 = (float*)af(HH);
    float* b23 = (float*)af(H);
    float* bns = (float*)af(6 * H);
    int* bsums = (int*)af(256);
    int* cnt = (int*)af(NCNT);
    int* end = (int*)af(NCNT);
    int* nbr = (int*)af(NPOOL);
    float* bufL = (float*)af((size_t)NL * H);
    float* bufD = (float*)af((size_t)ND * H);
    bf16* tlp = (bf16*)af((size_t)NL * H / 2);
    bf16* tdp = (bf16*)af((size_t)ND * H / 2);
    bf16* hp = (bf16*)af((size_t)NP * H / 2);
    TA* aggp = (TA*)af((size_t)NP * H * sizeof(TA) / 4);
    TA* hl = (TA*)af((size_t)NL * H * sizeof(TA) / 4);
    TA* hd = (TA*)af((size_t)ND * H * sizeof(TA) / 4);

    k_detect<<<1, 256, 0, stream>>>((const unsigned short*)d_in[0], flags);

    // CSR build (once; reused by both layers)
    hipMemsetAsync(cnt, 0, (size_t)NCNT * 4, stream);
    k_count_all<<<(E1 + E2 + 255) / 256, 256, 0, stream>>>(e1s, e1d, e2s, e2d, cnt);
    int nb = (NCNT + SCAN_ELEMS - 1) / SCAN_ELEMS;
    k_scan1<<<nb, 256, 0, stream>>>(cnt, end, bsums, NCNT);
    k_scan2<<<1, 256, 0, stream>>>(bsums, nb);
    k_scan3<<<(NCNT + 255) / 256, 256, 0, stream>>>(end, bsums, NCNT);
    k_fill_all<<<(E1 + E2 + 255) / 256, 256, 0, stream>>>(e1s, e1d, e2s, e2d, end, nbr);
    // end now holds END offsets (start = end - cnt)

    k_embed_all<TA><<<((NP + NL + ND) * H + 255) / 256, 256, 0, stream>>>(
        d_in[0], d_in[1], d_in[2], d_in[3], d_in[4], d_in[5], d_in[6], d_in[7], d_in[8], hp, hl,
        hd, flags);

    run_layer<TA>(d_in[9], d_in[10], d_in[11], d_in[15], d_in[16], hp, hl, hd, aggp, bufL, bufD,
                  tlp, tdp, cnt, end, nbr, w23, b23, bns, flags, stream);
    run_layer<TA>(d_in[12], d_in[13], d_in[14], d_in[17], d_in[18], hp, hl, hd, aggp, bufL, bufD,
                  tlp, tdp, cnt, end, nbr, w23, b23, bns, flags, stream);

    k_head<<<NP / 4, 256, 0, stream>>>(hp, d_in[19], d_in[20], d_in[21], d_in[22], d_out, flags);
}

extern "C" void kernel_launch(void* const* d_in, const int* in_sizes, int n_in, void* d_out,
                              int out_size, void* d_ws, size_t ws_size, hipStream_t stream) {
    const size_t NCNT = NL + ND + 2 * (size_t)NP;
    const size_t NPOOL = 2 * ((size_t)E1 + E2);
    const size_t fixed_words = 16 + HH + H + 6 * H + 256 + 2 * NCNT + NPOOL + (size_t)NL * H +
                               (size_t)ND * H + (size_t)NL * H / 2 + (size_t)ND * H / 2 +
                               (size_t)NP * H / 2;
    const size_t ta_elems = (size_t)(NP + NL + ND) * H;
    const size_t need_f32 = fixed_words * 4 + ta_elems * 4;  // ~112 MiB
    if (ws_size >= need_f32)
        run_all<float>(d_in, d_out, d_ws, stream);
    else
        run_all<bf16>(d_in, d_out, d_ws, stream);  // ~84 MiB
}

// Round 6
// 2843.696 us; speedup vs baseline: 2.3668x; 1.1210x over previous
//
#include <hip/hip_runtime.h>
#include <hip/hip_bf16.h>

#define NP 100000
#define NL 10000
#define ND 500
#define H 128
#define HH (H * H)
#define E1 2000000
#define E2 500000
#define NOUT 10

typedef __hip_bfloat16 bf16;

__device__ __forceinline__ float ldv(const float* p, size_t i) { return p[i]; }
__device__ __forceinline__ float ldv(const bf16* p, size_t i) { return __bfloat162float(p[i]); }
__device__ __forceinline__ void stv(float* p, size_t i, float v) { p[i] = v; }
__device__ __forceinline__ void stv(bf16* p, size_t i, float v) { p[i] = __float2bfloat16(v); }

__device__ __forceinline__ float bfbits2f(unsigned short s) {
    union { unsigned int u; float f; } v;
    v.u = (unsigned int)s << 16;
    return v.f;
}
// load 2 consecutive bf16 (4B-aligned) -> float2
__device__ __forceinline__ float2 ld_bf2(const bf16* p) {
    unsigned int u = *(const unsigned int*)p;
    return make_float2(bfbits2f((unsigned short)(u & 0xFFFFu)), bfbits2f((unsigned short)(u >> 16)));
}

// raw input buffer with runtime dtype (f32m: 1=f32, 0=bf16)
__device__ __forceinline__ float ldin(const void* p, size_t i, int f32m) {
    return f32m ? ((const float*)p)[i] : __bfloat162float(((const bf16*)p)[i]);
}

// ---------------- input dtype detection (measured: picks bf16 on this harness) ----------
__global__ void k_detect(const unsigned short* __restrict__ xp, int* __restrict__ flags) {
    int t = threadIdx.x;
    int cnt = 0;
    for (int i = t; i < 4096; i += 256) {
        unsigned short w = xp[2 * i];
        int e = (w >> 7) & 0xFF;
        if (w == 0 || (e >= 114 && e <= 141)) cnt++;
    }
    __shared__ int sh[256];
    sh[t] = cnt;
    __syncthreads();
    for (int s = 128; s > 0; s >>= 1) {
        if (t < s) sh[t] += sh[t + s];
        __syncthreads();
    }
    if (t == 0) flags[0] = (sh[0] < 2048) ? 1 : 0;  // 1 = f32 inputs
}

// ---------------- fused initial embeddings (hp bf16; hl/hd TA) ----------------
template <typename TA>
__global__ void k_embed_all(const void* __restrict__ xp, const void* __restrict__ xl,
                            const void* __restrict__ xd, const void* __restrict__ Wp,
                            const void* __restrict__ bp, const void* __restrict__ Wlab,
                            const void* __restrict__ blab, const void* __restrict__ Wdis,
                            const void* __restrict__ bdis, bf16* __restrict__ hp,
                            TA* __restrict__ hl, TA* __restrict__ hd,
                            const int* __restrict__ flags) {
    int f32m = flags[0];
    int idx = blockIdx.x * 256 + threadIdx.x;
    int h = idx & 127;
    if (idx < NP * H) {
        int i = idx >> 7;
        float acc = ldin(bp, h, f32m);
#pragma unroll
        for (int k = 0; k < 16; ++k)
            acc = fmaf(ldin(xp, (size_t)i * 16 + k, f32m), ldin(Wp, (size_t)k * H + h, f32m), acc);
        hp[idx] = __float2bfloat16(acc);
    } else if (idx < (NP + NL) * H) {
        int i = (idx - NP * H) >> 7;
        float acc = fmaf(ldin(xl, i, f32m), ldin(Wlab, h, f32m), ldin(blab, h, f32m));
        stv(hl, (size_t)i * H + h, acc);
    } else if (idx < (NP + NL + ND) * H) {
        int i = (idx - (NP + NL) * H) >> 7;
        float acc = ldin(bdis, h, f32m);
        acc = fmaf(ldin(xd, (size_t)i * 2 + 0, f32m), ldin(Wdis, h, f32m), acc);
        acc = fmaf(ldin(xd, (size_t)i * 2 + 1, f32m), ldin(Wdis, H + h, f32m), acc);
        stv(hd, (size_t)i * H + h, acc);
    }
}

// ---------------- CSR build ----------------
// cnt/off segments: [lab NL][dis ND][p1 NP][p2 NP]; nbr pool: same order, sizes E1,E2,E1,E2
// count pass also records each edge's within-segment rank (the atomicAdd return value),
// so the fill pass needs NO atomics.
__global__ void k_count_all(const int* __restrict__ e1s, const int* __restrict__ e1d,
                            const int* __restrict__ e2s, const int* __restrict__ e2d,
                            int* __restrict__ cnt, int* __restrict__ r1d, int* __restrict__ r1s,
                            int* __restrict__ r2d, int* __restrict__ r2s) {
    int e = blockIdx.x * 256 + threadIdx.x;
    if (e < E1) {
        r1d[e] = atomicAdd(&cnt[e1d[e]], 1);
        r1s[e] = atomicAdd(&cnt[NL + ND + e1s[e]], 1);
    } else if (e < E1 + E2) {
        int i = e - E1;
        r2d[i] = atomicAdd(&cnt[NL + e2d[i]], 1);
        r2s[i] = atomicAdd(&cnt[NL + ND + NP + e2s[i]], 1);
    }
}

#define SCAN_ELEMS 2048
__global__ void k_scan1(const int* __restrict__ in, int* __restrict__ out,
                        int* __restrict__ bsums, int n) {
    int t = threadIdx.x;
    int base = blockIdx.x * SCAN_ELEMS + t * 8;
    int v[8], tsum = 0;
#pragma unroll
    for (int j = 0; j < 8; ++j) {
        v[j] = (base + j < n) ? in[base + j] : 0;
        tsum += v[j];
    }
    __shared__ int sh[256];
    sh[t] = tsum;
    __syncthreads();
    for (int d = 1; d < 256; d <<= 1) {
        int x = (t >= d) ? sh[t - d] : 0;
        __syncthreads();
        sh[t] += x;
        __syncthreads();
    }
    int run = sh[t] - tsum;
    if (t == 255) bsums[blockIdx.x] = sh[255];
#pragma unroll
    for (int j = 0; j < 8; ++j) {
        if (base + j < n) out[base + j] = run;
        run += v[j];
    }
}

__global__ void k_scan2(int* __restrict__ bsums, int nb) {
    int t = threadIdx.x;
    int v = (t < nb) ? bsums[t] : 0;
    __shared__ int sh[256];
    sh[t] = v;
    __syncthreads();
    for (int d = 1; d < 256; d <<= 1) {
        int x = (t >= d) ? sh[t - d] : 0;
        __syncthreads();
        sh[t] += x;
        __syncthreads();
    }
    if (t < nb) bsums[t] = sh[t] - v;
}

__global__ void k_scan3(int* __restrict__ out, const int* __restrict__ bsums, int n) {
    int i = blockIdx.x * 256 + threadIdx.x;
    if (i < n) out[i] += bsums[i / SCAN_ELEMS];
}

// atomic-free fill: position = off[seg] + recorded rank
__global__ void k_fill_all(const int* __restrict__ e1s, const int* __restrict__ e1d,
                           const int* __restrict__ e2s, const int* __restrict__ e2d,
                           const int* __restrict__ off, const int* __restrict__ r1d,
                           const int* __restrict__ r1s, const int* __restrict__ r2d,
                           const int* __restrict__ r2s, int* __restrict__ nbr) {
    int e = blockIdx.x * 256 + threadIdx.x;
    if (e < E1) {
        int ss = e1s[e], dd = e1d[e];
        nbr[off[dd] + r1d[e]] = ss;
        nbr[off[NL + ND + ss] + r1s[e]] = dd;
    } else if (e < E1 + E2) {
        int i = e - E1;
        int ss = e2s[i], dd = e2d[i];
        nbr[off[NL + dd] + r2d[i]] = ss;
        nbr[off[NL + ND + NP + ss] + r2s[i]] = dd;
    }
}

// ---------------- lab+dis gather of raw hp means: one WAVE per dst row ----------------
__global__ void k_gather_ld(const bf16* __restrict__ hp, const int* __restrict__ off,
                            const int* __restrict__ cnt, const int* __restrict__ nbr,
                            float* __restrict__ bufL, float* __restrict__ bufD) {
    int wid = (blockIdx.x * 256 + threadIdx.x) >> 6;
    int lane = threadIdx.x & 63;
    if (wid >= NL + ND) return;
    int s0 = off[wid], c = cnt[wid];
    const int* nb = nbr + s0;
    float2 acc = make_float2(0.f, 0.f);
    for (int j = 0; j < c; ++j) {
        int g = nb[j];
        float2 v = ld_bf2(hp + (size_t)g * H + 2 * lane);
        acc.x += v.x;
        acc.y += v.y;
    }
    float inv = 1.f / fmaxf((float)c, 1.f);
    float* out = (wid < NL) ? (bufL + (size_t)wid * H) : (bufD + (size_t)(wid - NL) * H);
    *(float2*)(out + 2 * lane) = make_float2(acc.x * inv, acc.y * inv);
}

// ---------------- small transforms: tlp = hl@Wl[2], tdp = hd@Wl[3] (bf16 out) ----------
template <typename TA>
__global__ void k_mm_small(const TA* __restrict__ hl, const TA* __restrict__ hd,
                           const void* __restrict__ Wl, bf16* __restrict__ tlp,
                           bf16* __restrict__ tdp, const int* __restrict__ flags) {
    int f32m = flags[0];
    bool lab = blockIdx.x < NL / 4;
    const TA* in = lab ? hl : hd;
    bf16* out = lab ? tlp : tdp;
    size_t woff = lab ? (size_t)2 * HH : (size_t)3 * HH;
    int r0 = (lab ? blockIdx.x : blockIdx.x - NL / 4) * 4;
    __shared__ float s[4][H];
    int h = threadIdx.x;
#pragma unroll
    for (int r = 0; r < 4; ++r) s[r][h] = ldv(in, (size_t)(r0 + r) * H + h);
    __syncthreads();
    float a0 = 0.f, a1 = 0.f, a2 = 0.f, a3 = 0.f;
    for (int k = 0; k < H; ++k) {
        float w = ldin(Wl, woff + (size_t)k * H + h, f32m);
        a0 = fmaf(s[0][k], w, a0);
        a1 = fmaf(s[1][k], w, a1);
        a2 = fmaf(s[2][k], w, a2);
        a3 = fmaf(s[3][k], w, a3);
    }
    out[(size_t)(r0 + 0) * H + h] = __float2bfloat16(a0);
    out[(size_t)(r0 + 1) * H + h] = __float2bfloat16(a1);
    out[(size_t)(r0 + 2) * H + h] = __float2bfloat16(a2);
    out[(size_t)(r0 + 3) * H + h] = __float2bfloat16(a3);
}

// ---------------- Wr2+Wr3 / bl2+bl3 prep (f32 out) ----------------
__global__ void k_prep23(const void* __restrict__ Wr, const void* __restrict__ bl,
                         float* __restrict__ w23, float* __restrict__ b23,
                         const int* __restrict__ flags) {
    int f32m = flags[0];
    int idx = blockIdx.x * 256 + threadIdx.x;
    if (idx < HH)
        w23[idx] = ldin(Wr, (size_t)2 * HH + idx, f32m) + ldin(Wr, (size_t)3 * HH + idx, f32m);
    if (idx < H)
        b23[idx] = ldin(bl, (size_t)2 * H + idx, f32m) + ldin(bl, (size_t)3 * H + idx, f32m);
}

// -------- fused patient pass: aggp = mean_lab(tlp) + mean_dis(tdp) + hp@w23 + b23 --------
// 4 waves/block; each wave owns 4 patients; lane covers 2 columns (float2).
template <typename TA>
__global__ void k_patient(const bf16* __restrict__ hp, const bf16* __restrict__ tlp,
                          const bf16* __restrict__ tdp, const int* __restrict__ off,
                          const int* __restrict__ cnt, const int* __restrict__ nbr,
                          const float* __restrict__ w23, const float* __restrict__ b23,
                          TA* __restrict__ aggp) {
    int w = threadIdx.x >> 6;
    int lane = threadIdx.x & 63;
    int c0 = 2 * lane;
    int p0 = blockIdx.x * 16 + w * 4;
    const int* off1 = off + NL + ND;
    const int* cnt1 = cnt + NL + ND;
    const int* off2 = off + NL + ND + NP;
    const int* cnt2 = cnt + NL + ND + NP;
    float2 bb = *(const float2*)(b23 + c0);
    float2 acc[4];
#pragma unroll
    for (int r = 0; r < 4; ++r) {
        int p = p0 + r;
        int s1 = off1[p], c1 = cnt1[p];
        float2 a1 = make_float2(0.f, 0.f);
        for (int j = s1; j < s1 + c1; ++j) {
            float2 v = ld_bf2(tlp + (size_t)nbr[j] * H + c0);
            a1.x += v.x;
            a1.y += v.y;
        }
        int s2 = off2[p], c2 = cnt2[p];
        float2 a2 = make_float2(0.f, 0.f);
        for (int j = s2; j < s2 + c2; ++j) {
            float2 v = ld_bf2(tdp + (size_t)nbr[j] * H + c0);
            a2.x += v.x;
            a2.y += v.y;
        }
        float i1 = 1.f / fmaxf((float)c1, 1.f), i2 = 1.f / fmaxf((float)c2, 1.f);
        acc[r].x = a1.x * i1 + a2.x * i2 + bb.x;
        acc[r].y = a1.y * i1 + a2.y * i2 + bb.y;
    }
    __shared__ float rows[16][H];  // wave-private slices: no cross-wave barrier needed
#pragma unroll
    for (int r = 0; r < 4; ++r) {
        float2 v = ld_bf2(hp + (size_t)(p0 + r) * H + c0);
        rows[w * 4 + r][c0] = v.x;
        rows[w * 4 + r][c0 + 1] = v.y;
    }
    for (int k = 0; k < H; ++k) {
        float2 wv = *(const float2*)(w23 + (size_t)k * H + c0);
#pragma unroll
        for (int r = 0; r < 4; ++r) {
            float x = rows[w * 4 + r][k];
            acc[r].x = fmaf(x, wv.x, acc[r].x);
            acc[r].y = fmaf(x, wv.y, acc[r].y);
        }
    }
#pragma unroll
    for (int r = 0; r < 4; ++r) {
        stv(aggp, (size_t)(p0 + r) * H + c0, acc[r].x);
        stv(aggp, (size_t)(p0 + r) * H + c0 + 1, acc[r].y);
    }
}

// -------- fused lab/dis second stage (in-place): buf = buf@Wl + bl + hX@Wr --------
template <typename TA>
__global__ void k_mm_labdis(float* __restrict__ bufL, float* __restrict__ bufD,
                            const TA* __restrict__ hl, const TA* __restrict__ hd,
                            const void* __restrict__ Wl, const void* __restrict__ bl,
                            const void* __restrict__ Wr, const int* __restrict__ flags) {
    int f32m = flags[0];
    bool lab = blockIdx.x < NL / 4;
    float* buf = lab ? bufL : bufD;
    const TA* hx = lab ? hl : hd;
    size_t woff = lab ? 0 : (size_t)HH;
    size_t boff = lab ? 0 : (size_t)H;
    int r0 = (lab ? blockIdx.x : blockIdx.x - NL / 4) * 4;
    __shared__ float sB[4][H], sH[4][H];
    int h = threadIdx.x;
#pragma unroll
    for (int r = 0; r < 4; ++r) {
        sB[r][h] = buf[(size_t)(r0 + r) * H + h];
        sH[r][h] = ldv(hx, (size_t)(r0 + r) * H + h);
    }
    __syncthreads();
    float a0 = ldin(bl, boff + h, f32m);
    float a1 = a0, a2 = a0, a3 = a0;
    for (int k = 0; k < H; ++k) {
        float w = ldin(Wl, woff + (size_t)k * H + h, f32m);
        a0 = fmaf(sB[0][k], w, a0);
        a1 = fmaf(sB[1][k], w, a1);
        a2 = fmaf(sB[2][k], w, a2);
        a3 = fmaf(sB[3][k], w, a3);
    }
    for (int k = 0; k < H; ++k) {
        float w = ldin(Wr, woff + (size_t)k * H + h, f32m);
        a0 = fmaf(sH[0][k], w, a0);
        a1 = fmaf(sH[1][k], w, a1);
        a2 = fmaf(sH[2][k], w, a2);
        a3 = fmaf(sH[3][k], w, a3);
    }
    buf[(size_t)(r0 + 0) * H + h] = a0;
    buf[(size_t)(r0 + 1) * H + h] = a1;
    buf[(size_t)(r0 + 2) * H + h] = a2;
    buf[(size_t)(r0 + 3) * H + h] = a3;
}

// ---------------- BatchNorm ----------------
template <typename TA>
__global__ void k_bn_stats_pat(const TA* __restrict__ x, float* __restrict__ sums) {
    int h = threadIdx.x & 127;
    int sub = threadIdx.x >> 7;
    float s = 0.f, s2 = 0.f;
    for (int i = blockIdx.x * 2 + sub; i < NP; i += gridDim.x * 2) {
        float v = ldv(x, (size_t)i * H + h);
        s += v;
        s2 = fmaf(v, v, s2);
    }
    __shared__ float ls[256], ls2[256];
    ls[threadIdx.x] = s;
    ls2[threadIdx.x] = s2;
    __syncthreads();
    if (sub == 0) {
        atomicAdd(&sums[h], s + ls[128 + h]);
        atomicAdd(&sums[H + h], s2 + ls2[128 + h]);
    }
}

__global__ void k_bn_stats_ld(const float* __restrict__ bufL, const float* __restrict__ bufD,
                              float* __restrict__ sums) {
    bool lab = blockIdx.x < 256;
    const float* x = lab ? bufL : bufD;
    int N = lab ? NL : ND;
    float* sm = sums + (lab ? 2 * H : 4 * H);
    int bid = lab ? blockIdx.x : blockIdx.x - 256;
    int nb = lab ? 256 : 64;
    int h = threadIdx.x & 127;
    int sub = threadIdx.x >> 7;
    float s = 0.f, s2 = 0.f;
    for (int i = bid * 2 + sub; i < N; i += nb * 2) {
        float v = x[(size_t)i * H + h];
        s += v;
        s2 = fmaf(v, v, s2);
    }
    __shared__ float ls[256], ls2[256];
    ls[threadIdx.x] = s;
    ls2[threadIdx.x] = s2;
    __syncthreads();
    if (sub == 0) {
        atomicAdd(&sm[h], s + ls[128 + h]);
        atomicAdd(&sm[H + h], s2 + ls2[128 + h]);
    }
}

template <typename TA>
__global__ void k_bn_apply_pat(const TA* __restrict__ x, bf16* __restrict__ hp,
                               const float* __restrict__ sums, const void* __restrict__ g,
                               const void* __restrict__ b, const int* __restrict__ flags) {
    int f32m = flags[0];
    int idx = blockIdx.x * 256 + threadIdx.x;
    if (idx >= NP * H) return;
    int h = idx & 127;
    const float invN = 1.f / NP;
    float m = sums[h] * invN;
    float v = fmaf(-m, m, sums[H + h] * invN);
    float sc = rsqrtf(v + 1e-5f) * ldin(g, h, f32m);
    float r = fmaf(ldv(x, (size_t)idx) - m, sc, ldin(b, h, f32m));
    hp[idx] = __float2bfloat16(fmaxf(r, 0.f));
}

template <typename TA>
__global__ void k_bn_apply_ld(const float* __restrict__ bufL, const float* __restrict__ bufD,
                              TA* __restrict__ hl, TA* __restrict__ hd,
                              const float* __restrict__ sums, const void* __restrict__ g,
                              const void* __restrict__ b, const int* __restrict__ flags) {
    int f32m = flags[0];
    int idx = blockIdx.x * 256 + threadIdx.x;
    int h = idx & 127;
    if (idx < NL * H) {
        const float invN = 1.f / NL;
        float m = sums[2 * H + h] * invN;
        float v = fmaf(-m, m, sums[3 * H + h] * invN);
        float sc = rsqrtf(v + 1e-5f) * ldin(g, H + h, f32m);
        float r = fmaf(bufL[idx] - m, sc, ldin(b, H + h, f32m));
        stv(hl, (size_t)idx, fmaxf(r, 0.f));
    } else if (idx < (NL + ND) * H) {
        int j = idx - NL * H;
        const float invN = 1.f / ND;
        float m = sums[4 * H + h] * invN;
        float v = fmaf(-m, m, sums[5 * H + h] * invN);
        float sc = rsqrtf(v + 1e-5f) * ldin(g, 2 * H + h, f32m);
        float r = fmaf(bufD[j] - m, sc, ldin(b, 2 * H + h, f32m));
        stv(hd, (size_t)j, fmaxf(r, 0.f));
    }
}

// ---------------- head ----------------
__global__ void k_head(const bf16* __restrict__ hp, const void* __restrict__ W1,
                       const void* __restrict__ b1, const void* __restrict__ W2,
                       const void* __restrict__ b2, void* __restrict__ out,
                       const int* __restrict__ flags) {
    int f32m = flags[0];
    __shared__ float rowsh[4][H];
    __shared__ float h1[4][64];
    __shared__ float lg[4][16];
    int sub = threadIdx.x >> 6;
    int j = threadIdx.x & 63;
    int p = blockIdx.x * 4 + sub;
    float2 rv = ld_bf2(hp + (size_t)p * H + 2 * j);
    rowsh[sub][2 * j] = rv.x;
    rowsh[sub][2 * j + 1] = rv.y;
    // rowsh/h1/lg slices are wave-private (sub == wave id); barriers kept for safety
    float acc = ldin(b1, j, f32m);
#pragma unroll 8
    for (int k = 0; k < H; ++k)
        acc = fmaf(rowsh[sub][k], ldin(W1, (size_t)k * 64 + j, f32m), acc);
    h1[sub][j] = fmaxf(acc, 0.f);
    __syncthreads();
    if (j < NOUT) {
        float a = ldin(b2, j, f32m);
#pragma unroll
        for (int k = 0; k < 64; ++k)
            a = fmaf(h1[sub][k], ldin(W2, (size_t)k * NOUT + j, f32m), a);
        lg[sub][j] = a;
    }
    __syncthreads();
    if (j < NOUT) {
        float m = -1e30f;
#pragma unroll
        for (int k = 0; k < NOUT; ++k) m = fmaxf(m, lg[sub][k]);
        float s = 0.f;
#pragma unroll
        for (int k = 0; k < NOUT; ++k) s += __expf(lg[sub][k] - m);
        float r = lg[sub][j] - m - __logf(s);
        if (f32m)
            ((float*)out)[(size_t)p * NOUT + j] = r;
        else
            ((bf16*)out)[(size_t)p * NOUT + j] = __float2bfloat16(r);
    }
}

// ---------------- one hetero layer ----------------
template <typename TA>
static void run_layer(const void* Wl, const void* bl, const void* Wr, const void* bng,
                      const void* bnb, bf16* hp, TA* hl, TA* hd, TA* aggp, float* bufL,
                      float* bufD, bf16* tlp, bf16* tdp, const int* cnt, const int* off,
                      const int* nbr, float* w23, float* b23, float* bns, const int* flags,
                      hipStream_t stream) {
    k_mm_small<TA><<<NL / 4 + ND / 4, 128, 0, stream>>>(hl, hd, Wl, tlp, tdp, flags);
    k_gather_ld<<<(NL + ND + 3) / 4, 256, 0, stream>>>(hp, off, cnt, nbr, bufL, bufD);
    k_prep23<<<(HH + 255) / 256, 256, 0, stream>>>(Wr, bl, w23, b23, flags);
    k_patient<TA><<<NP / 16, 256, 0, stream>>>(hp, tlp, tdp, off, cnt, nbr, w23, b23, aggp);
    k_mm_labdis<TA><<<NL / 4 + ND / 4, 128, 0, stream>>>(bufL, bufD, hl, hd, Wl, bl, Wr, flags);
    hipMemsetAsync(bns, 0, 6 * H * 4, stream);
    k_bn_stats_pat<TA><<<1024, 256, 0, stream>>>(aggp, bns);
    k_bn_stats_ld<<<320, 256, 0, stream>>>(bufL, bufD, bns);
    k_bn_apply_pat<TA><<<(NP * H + 255) / 256, 256, 0, stream>>>(aggp, hp, bns, bng, bnb, flags);
    k_bn_apply_ld<TA><<<((NL + ND) * H + 255) / 256, 256, 0, stream>>>(bufL, bufD, hl, hd, bns,
                                                                       bng, bnb, flags);
}

template <typename TA>
static void run_all(void* const* d_in, void* d_out, void* d_ws, hipStream_t stream) {
    const int* e1s = (const int*)d_in[23];
    const int* e1d = (const int*)d_in[24];
    const int* e2s = (const int*)d_in[25];
    const int* e2d = (const int*)d_in[26];

    const int NCNT = NL + ND + 2 * NP;  // 210500
    const int NPOOL = 2 * (E1 + E2);    // 5000000

    char* wsb = (char*)d_ws;
    size_t o = 0;
    auto af = [&](size_t nwords) { void* p = wsb + o * 4; o += nwords; return p; };
    int* flags = (int*)af(16);
    float* w23 = (float*)af(HH);
    float* b23 = (float*)af(H);
    float* bns = (float*)af(6 * H);
    int* bsums = (int*)af(256);
    int* cnt = (int*)af(NCNT);
    int* off = (int*)af(NCNT);
    int* r1d = (int*)af(E1);
    int* r1s = (int*)af(E1);
    int* r2d = (int*)af(E2);
    int* r2s = (int*)af(E2);
    int* nbr = (int*)af(NPOOL);
    float* bufL = (float*)af((size_t)NL * H);
    float* bufD = (float*)af((size_t)ND * H);
    bf16* tlp = (bf16*)af((size_t)NL * H / 2);
    bf16* tdp = (bf16*)af((size_t)ND * H / 2);
    bf16* hp = (bf16*)af((size_t)NP * H / 2);
    TA* aggp = (TA*)af((size_t)NP * H * sizeof(TA) / 4);
    TA* hl = (TA*)af((size_t)NL * H * sizeof(TA) / 4);
    TA* hd = (TA*)af((size_t)ND * H * sizeof(TA) / 4);

    k_detect<<<1, 256, 0, stream>>>((const unsigned short*)d_in[0], flags);

    // CSR build (once; reused by both layers)
    hipMemsetAsync(cnt, 0, (size_t)NCNT * 4, stream);
    k_count_all<<<(E1 + E2 + 255) / 256, 256, 0, stream>>>(e1s, e1d, e2s, e2d, cnt, r1d, r1s,
                                                           r2d, r2s);
    int nb = (NCNT + SCAN_ELEMS - 1) / SCAN_ELEMS;
    k_scan1<<<nb, 256, 0, stream>>>(cnt, off, bsums, NCNT);
    k_scan2<<<1, 256, 0, stream>>>(bsums, nb);
    k_scan3<<<(NCNT + 255) / 256, 256, 0, stream>>>(off, bsums, NCNT);
    k_fill_all<<<(E1 + E2 + 255) / 256, 256, 0, stream>>>(e1s, e1d, e2s, e2d, off, r1d, r1s, r2d,
                                                          r2s, nbr);
    // off holds START offsets (unmodified by fill)

    k_embed_all<TA><<<((NP + NL + ND) * H + 255) / 256, 256, 0, stream>>>(
        d_in[0], d_in[1], d_in[2], d_in[3], d_in[4], d_in[5], d_in[6], d_in[7], d_in[8], hp, hl,
        hd, flags);

    run_layer<TA>(d_in[9], d_in[10], d_in[11], d_in[15], d_in[16], hp, hl, hd, aggp, bufL, bufD,
                  tlp, tdp, cnt, off, nbr, w23, b23, bns, flags, stream);
    run_layer<TA>(d_in[12], d_in[13], d_in[14], d_in[17], d_in[18], hp, hl, hd, aggp, bufL, bufD,
                  tlp, tdp, cnt, off, nbr, w23, b23, bns, flags, stream);

    k_head<<<NP / 4, 256, 0, stream>>>(hp, d_in[19], d_in[20], d_in[21], d_in[22], d_out, flags);
}

extern "C" void kernel_launch(void* const* d_in, const int* in_sizes, int n_in, void* d_out,
                              int out_size, void* d_ws, size_t ws_size, hipStream_t stream) {
    const size_t NCNT = NL + ND + 2 * (size_t)NP;
    const size_t NPOOL = 2 * ((size_t)E1 + E2);
    const size_t fixed_words = 16 + HH + H + 6 * H + 256 + 2 * NCNT + NPOOL +
                               2 * ((size_t)E1 + E2) + (size_t)NL * H + (size_t)ND * H +
                               (size_t)NL * H / 2 + (size_t)ND * H / 2 + (size_t)NP * H / 2;
    const size_t ta_elems = (size_t)(NP + NL + ND) * H;
    const size_t need_f32 = fixed_words * 4 + ta_elems * 4;  // ~132 MiB
    if (ws_size >= need_f32)
        run_all<float>(d_in, d_out, d_ws, stream);
    else
        run_all<bf16>(d_in, d_out, d_ws, stream);  // ~104 MiB
}

// Round 7
// 1978.900 us; speedup vs baseline: 3.4010x; 1.4370x over previous
//
#include <hip/hip_runtime.h>
#include <hip/hip_bf16.h>

#define NP 100000
#define NL 10000
#define ND 500
#define H 128
#define HH (H * H)
#define E1 2000000
#define E2 500000
#define NOUT 10

typedef __hip_bfloat16 bf16;

__device__ __forceinline__ float ldv(const float* p, size_t i) { return p[i]; }
__device__ __forceinline__ float ldv(const bf16* p, size_t i) { return __bfloat162float(p[i]); }
__device__ __forceinline__ void stv(float* p, size_t i, float v) { p[i] = v; }
__device__ __forceinline__ void stv(bf16* p, size_t i, float v) { p[i] = __float2bfloat16(v); }

__device__ __forceinline__ float bfbits2f(unsigned short s) {
    union { unsigned int u; float f; } v;
    v.u = (unsigned int)s << 16;
    return v.f;
}
// load 2 consecutive bf16 (4B-aligned) -> float2
__device__ __forceinline__ float2 ld_bf2(const bf16* p) {
    unsigned int u = *(const unsigned int*)p;
    return make_float2(bfbits2f((unsigned short)(u & 0xFFFFu)), bfbits2f((unsigned short)(u >> 16)));
}

// raw input buffer with runtime dtype (f32m: 1=f32, 0=bf16)
__device__ __forceinline__ float ldin(const void* p, size_t i, int f32m) {
    return f32m ? ((const float*)p)[i] : __bfloat162float(((const bf16*)p)[i]);
}

// ---------------- input dtype detection (measured: picks bf16 on this harness) ----------
__global__ void k_detect(const unsigned short* __restrict__ xp, int* __restrict__ flags) {
    int t = threadIdx.x;
    int cnt = 0;
    for (int i = t; i < 4096; i += 256) {
        unsigned short w = xp[2 * i];
        int e = (w >> 7) & 0xFF;
        if (w == 0 || (e >= 114 && e <= 141)) cnt++;
    }
    __shared__ int sh[256];
    sh[t] = cnt;
    __syncthreads();
    for (int s = 128; s > 0; s >>= 1) {
        if (t < s) sh[t] += sh[t + s];
        __syncthreads();
    }
    if (t == 0) flags[0] = (sh[0] < 2048) ? 1 : 0;  // 1 = f32 inputs
}

// ---------------- fused initial embeddings (hp bf16; hl/hd TA) ----------------
template <typename TA>
__global__ void k_embed_all(const void* __restrict__ xp, const void* __restrict__ xl,
                            const void* __restrict__ xd, const void* __restrict__ Wp,
                            const void* __restrict__ bp, const void* __restrict__ Wlab,
                            const void* __restrict__ blab, const void* __restrict__ Wdis,
                            const void* __restrict__ bdis, bf16* __restrict__ hp,
                            TA* __restrict__ hl, TA* __restrict__ hd,
                            const int* __restrict__ flags) {
    int f32m = flags[0];
    int idx = blockIdx.x * 256 + threadIdx.x;
    int h = idx & 127;
    if (idx < NP * H) {
        int i = idx >> 7;
        float acc = ldin(bp, h, f32m);
#pragma unroll
        for (int k = 0; k < 16; ++k)
            acc = fmaf(ldin(xp, (size_t)i * 16 + k, f32m), ldin(Wp, (size_t)k * H + h, f32m), acc);
        hp[idx] = __float2bfloat16(acc);
    } else if (idx < (NP + NL) * H) {
        int i = (idx - NP * H) >> 7;
        float acc = fmaf(ldin(xl, i, f32m), ldin(Wlab, h, f32m), ldin(blab, h, f32m));
        stv(hl, (size_t)i * H + h, acc);
    } else if (idx < (NP + NL + ND) * H) {
        int i = (idx - (NP + NL) * H) >> 7;
        float acc = ldin(bdis, h, f32m);
        acc = fmaf(ldin(xd, (size_t)i * 2 + 0, f32m), ldin(Wdis, h, f32m), acc);
        acc = fmaf(ldin(xd, (size_t)i * 2 + 1, f32m), ldin(Wdis, H + h, f32m), acc);
        stv(hd, (size_t)i * H + h, acc);
    }
}

// ---------------- CSR build ----------------
// cnt/off segments: [lab NL][dis ND][p1 NP][p2 NP]; nbr pool: same order, sizes E1,E2,E1,E2
// count pass records each edge's within-segment rank so fill needs NO atomics.
__global__ void k_count_all(const int* __restrict__ e1s, const int* __restrict__ e1d,
                            const int* __restrict__ e2s, const int* __restrict__ e2d,
                            int* __restrict__ cnt, int* __restrict__ r1d, int* __restrict__ r1s,
                            int* __restrict__ r2d, int* __restrict__ r2s) {
    int e = blockIdx.x * 256 + threadIdx.x;
    if (e < E1) {
        r1d[e] = atomicAdd(&cnt[e1d[e]], 1);
        r1s[e] = atomicAdd(&cnt[NL + ND + e1s[e]], 1);
    } else if (e < E1 + E2) {
        int i = e - E1;
        r2d[i] = atomicAdd(&cnt[NL + e2d[i]], 1);
        r2s[i] = atomicAdd(&cnt[NL + ND + NP + e2s[i]], 1);
    }
}

#define SCAN_ELEMS 2048
__global__ void k_scan1(const int* __restrict__ in, int* __restrict__ out,
                        int* __restrict__ bsums, int n) {
    int t = threadIdx.x;
    int base = blockIdx.x * SCAN_ELEMS + t * 8;
    int v[8], tsum = 0;
#pragma unroll
    for (int j = 0; j < 8; ++j) {
        v[j] = (base + j < n) ? in[base + j] : 0;
        tsum += v[j];
    }
    __shared__ int sh[256];
    sh[t] = tsum;
    __syncthreads();
    for (int d = 1; d < 256; d <<= 1) {
        int x = (t >= d) ? sh[t - d] : 0;
        __syncthreads();
        sh[t] += x;
        __syncthreads();
    }
    int run = sh[t] - tsum;
    if (t == 255) bsums[blockIdx.x] = sh[255];
#pragma unroll
    for (int j = 0; j < 8; ++j) {
        if (base + j < n) out[base + j] = run;
        run += v[j];
    }
}

__global__ void k_scan2(int* __restrict__ bsums, int nb) {
    int t = threadIdx.x;
    int v = (t < nb) ? bsums[t] : 0;
    __shared__ int sh[256];
    sh[t] = v;
    __syncthreads();
    for (int d = 1; d < 256; d <<= 1) {
        int x = (t >= d) ? sh[t - d] : 0;
        __syncthreads();
        sh[t] += x;
        __syncthreads();
    }
    if (t < nb) bsums[t] = sh[t] - v;
}

__global__ void k_scan3(int* __restrict__ out, const int* __restrict__ bsums, int n) {
    int i = blockIdx.x * 256 + threadIdx.x;
    if (i < n) out[i] += bsums[i / SCAN_ELEMS];
}

// atomic-free fill: position = off[seg] + recorded rank
__global__ void k_fill_all(const int* __restrict__ e1s, const int* __restrict__ e1d,
                           const int* __restrict__ e2s, const int* __restrict__ e2d,
                           const int* __restrict__ off, const int* __restrict__ r1d,
                           const int* __restrict__ r1s, const int* __restrict__ r2d,
                           const int* __restrict__ r2s, int* __restrict__ nbr) {
    int e = blockIdx.x * 256 + threadIdx.x;
    if (e < E1) {
        int ss = e1s[e], dd = e1d[e];
        nbr[off[dd] + r1d[e]] = ss;
        nbr[off[NL + ND + ss] + r1s[e]] = dd;
    } else if (e < E1 + E2) {
        int i = e - E1;
        int ss = e2s[i], dd = e2d[i];
        nbr[off[NL + dd] + r2d[i]] = ss;
        nbr[off[NL + ND + NP + ss] + r2s[i]] = dd;
    }
}

// ------- lab+dis gather of raw hp means: one WAVE per dst row, 4-way unrolled MLP -------
__global__ void k_gather_ld(const bf16* __restrict__ hp, const int* __restrict__ off,
                            const int* __restrict__ cnt, const int* __restrict__ nbr,
                            float* __restrict__ bufL, float* __restrict__ bufD) {
    int wid = (blockIdx.x * 256 + threadIdx.x) >> 6;
    int lane = threadIdx.x & 63;
    int c0 = 2 * lane;
    if (wid >= NL + ND) return;
    int s0 = off[wid], c = cnt[wid];
    const int* nb = nbr + s0;
    float2 a0 = make_float2(0.f, 0.f), a1 = a0, a2 = a0, a3 = a0;
    int j = 0;
    for (; j + 4 <= c; j += 4) {
        int g0 = nb[j], g1 = nb[j + 1], g2 = nb[j + 2], g3 = nb[j + 3];
        float2 v0 = ld_bf2(hp + (size_t)g0 * H + c0);
        float2 v1 = ld_bf2(hp + (size_t)g1 * H + c0);
        float2 v2 = ld_bf2(hp + (size_t)g2 * H + c0);
        float2 v3 = ld_bf2(hp + (size_t)g3 * H + c0);
        a0.x += v0.x; a0.y += v0.y;
        a1.x += v1.x; a1.y += v1.y;
        a2.x += v2.x; a2.y += v2.y;
        a3.x += v3.x; a3.y += v3.y;
    }
    for (; j < c; ++j) {
        float2 v = ld_bf2(hp + (size_t)nb[j] * H + c0);
        a0.x += v.x; a0.y += v.y;
    }
    float inv = 1.f / fmaxf((float)c, 1.f);
    float sx = (a0.x + a1.x) + (a2.x + a3.x);
    float sy = (a0.y + a1.y) + (a2.y + a3.y);
    float* out = (wid < NL) ? (bufL + (size_t)wid * H) : (bufD + (size_t)(wid - NL) * H);
    *(float2*)(out + c0) = make_float2(sx * inv, sy * inv);
}

// ---------------- small transforms: tlp = hl@Wl[2], tdp = hd@Wl[3] (bf16 out) ----------
template <typename TA>
__global__ void k_mm_small(const TA* __restrict__ hl, const TA* __restrict__ hd,
                           const void* __restrict__ Wl, bf16* __restrict__ tlp,
                           bf16* __restrict__ tdp, const int* __restrict__ flags) {
    int f32m = flags[0];
    bool lab = blockIdx.x < NL / 4;
    const TA* in = lab ? hl : hd;
    bf16* out = lab ? tlp : tdp;
    size_t woff = lab ? (size_t)2 * HH : (size_t)3 * HH;
    int r0 = (lab ? blockIdx.x : blockIdx.x - NL / 4) * 4;
    __shared__ float s[4][H];
    int h = threadIdx.x;
#pragma unroll
    for (int r = 0; r < 4; ++r) s[r][h] = ldv(in, (size_t)(r0 + r) * H + h);
    __syncthreads();
    float a0 = 0.f, a1 = 0.f, a2 = 0.f, a3 = 0.f;
    for (int k = 0; k < H; ++k) {
        float w = ldin(Wl, woff + (size_t)k * H + h, f32m);
        a0 = fmaf(s[0][k], w, a0);
        a1 = fmaf(s[1][k], w, a1);
        a2 = fmaf(s[2][k], w, a2);
        a3 = fmaf(s[3][k], w, a3);
    }
    out[(size_t)(r0 + 0) * H + h] = __float2bfloat16(a0);
    out[(size_t)(r0 + 1) * H + h] = __float2bfloat16(a1);
    out[(size_t)(r0 + 2) * H + h] = __float2bfloat16(a2);
    out[(size_t)(r0 + 3) * H + h] = __float2bfloat16(a3);
}

// ---------------- Wr2+Wr3 / bl2+bl3 prep (f32 out) ----------------
__global__ void k_prep23(const void* __restrict__ Wr, const void* __restrict__ bl,
                         float* __restrict__ w23, float* __restrict__ b23,
                         const int* __restrict__ flags) {
    int f32m = flags[0];
    int idx = blockIdx.x * 256 + threadIdx.x;
    if (idx < HH)
        w23[idx] = ldin(Wr, (size_t)2 * HH + idx, f32m) + ldin(Wr, (size_t)3 * HH + idx, f32m);
    if (idx < H)
        b23[idx] = ldin(bl, (size_t)2 * H + idx, f32m) + ldin(bl, (size_t)3 * H + idx, f32m);
}

// -------- fused patient pass: aggp = mean_lab(tlp) + mean_dis(tdp) + hp@w23 + b23 --------
// 4 waves/block; each wave owns 4 patients; lane covers 2 columns (float2).
// Neighbor loops 2-way unrolled within each of the 4 independent row chains.
template <typename TA>
__global__ void k_patient(const bf16* __restrict__ hp, const bf16* __restrict__ tlp,
                          const bf16* __restrict__ tdp, const int* __restrict__ off,
                          const int* __restrict__ cnt, const int* __restrict__ nbr,
                          const float* __restrict__ w23, const float* __restrict__ b23,
                          TA* __restrict__ aggp) {
    int w = threadIdx.x >> 6;
    int lane = threadIdx.x & 63;
    int c0 = 2 * lane;
    int p0 = blockIdx.x * 16 + w * 4;
    const int* off1 = off + NL + ND;
    const int* cnt1 = cnt + NL + ND;
    const int* off2 = off + NL + ND + NP;
    const int* cnt2 = cnt + NL + ND + NP;
    float2 bb = *(const float2*)(b23 + c0);
    float2 acc[4];
#pragma unroll
    for (int r = 0; r < 4; ++r) {
        int p = p0 + r;
        int s1 = off1[p], c1 = cnt1[p];
        const int* nb1 = nbr + s1;
        float2 a1a = make_float2(0.f, 0.f), a1b = a1a;
        int j = 0;
        for (; j + 2 <= c1; j += 2) {
            float2 va = ld_bf2(tlp + (size_t)nb1[j] * H + c0);
            float2 vb = ld_bf2(tlp + (size_t)nb1[j + 1] * H + c0);
            a1a.x += va.x; a1a.y += va.y;
            a1b.x += vb.x; a1b.y += vb.y;
        }
        if (j < c1) {
            float2 v = ld_bf2(tlp + (size_t)nb1[j] * H + c0);
            a1a.x += v.x; a1a.y += v.y;
        }
        int s2 = off2[p], c2 = cnt2[p];
        const int* nb2 = nbr + s2;
        float2 a2a = make_float2(0.f, 0.f), a2b = a2a;
        j = 0;
        for (; j + 2 <= c2; j += 2) {
            float2 va = ld_bf2(tdp + (size_t)nb2[j] * H + c0);
            float2 vb = ld_bf2(tdp + (size_t)nb2[j + 1] * H + c0);
            a2a.x += va.x; a2a.y += va.y;
            a2b.x += vb.x; a2b.y += vb.y;
        }
        if (j < c2) {
            float2 v = ld_bf2(tdp + (size_t)nb2[j] * H + c0);
            a2a.x += v.x; a2a.y += v.y;
        }
        float i1 = 1.f / fmaxf((float)c1, 1.f), i2 = 1.f / fmaxf((float)c2, 1.f);
        acc[r].x = (a1a.x + a1b.x) * i1 + (a2a.x + a2b.x) * i2 + bb.x;
        acc[r].y = (a1a.y + a1b.y) * i1 + (a2a.y + a2b.y) * i2 + bb.y;
    }
    __shared__ float rows[16][H];  // wave-private slices: no cross-wave barrier needed
#pragma unroll
    for (int r = 0; r < 4; ++r) {
        float2 v = ld_bf2(hp + (size_t)(p0 + r) * H + c0);
        rows[w * 4 + r][c0] = v.x;
        rows[w * 4 + r][c0 + 1] = v.y;
    }
    for (int k = 0; k < H; ++k) {
        float2 wv = *(const float2*)(w23 + (size_t)k * H + c0);
#pragma unroll
        for (int r = 0; r < 4; ++r) {
            float x = rows[w * 4 + r][k];
            acc[r].x = fmaf(x, wv.x, acc[r].x);
            acc[r].y = fmaf(x, wv.y, acc[r].y);
        }
    }
#pragma unroll
    for (int r = 0; r < 4; ++r) {
        stv(aggp, (size_t)(p0 + r) * H + c0, acc[r].x);
        stv(aggp, (size_t)(p0 + r) * H + c0 + 1, acc[r].y);
    }
}

// -------- fused lab/dis second stage (in-place): buf = buf@Wl + bl + hX@Wr --------
template <typename TA>
__global__ void k_mm_labdis(float* __restrict__ bufL, float* __restrict__ bufD,
                            const TA* __restrict__ hl, const TA* __restrict__ hd,
                            const void* __restrict__ Wl, const void* __restrict__ bl,
                            const void* __restrict__ Wr, const int* __restrict__ flags) {
    int f32m = flags[0];
    bool lab = blockIdx.x < NL / 4;
    float* buf = lab ? bufL : bufD;
    const TA* hx = lab ? hl : hd;
    size_t woff = lab ? 0 : (size_t)HH;
    size_t boff = lab ? 0 : (size_t)H;
    int r0 = (lab ? blockIdx.x : blockIdx.x - NL / 4) * 4;
    __shared__ float sB[4][H], sH[4][H];
    int h = threadIdx.x;
#pragma unroll
    for (int r = 0; r < 4; ++r) {
        sB[r][h] = buf[(size_t)(r0 + r) * H + h];
        sH[r][h] = ldv(hx, (size_t)(r0 + r) * H + h);
    }
    __syncthreads();
    float a0 = ldin(bl, boff + h, f32m);
    float a1 = a0, a2 = a0, a3 = a0;
    for (int k = 0; k < H; ++k) {
        float w = ldin(Wl, woff + (size_t)k * H + h, f32m);
        a0 = fmaf(sB[0][k], w, a0);
        a1 = fmaf(sB[1][k], w, a1);
        a2 = fmaf(sB[2][k], w, a2);
        a3 = fmaf(sB[3][k], w, a3);
    }
    for (int k = 0; k < H; ++k) {
        float w = ldin(Wr, woff + (size_t)k * H + h, f32m);
        a0 = fmaf(sH[0][k], w, a0);
        a1 = fmaf(sH[1][k], w, a1);
        a2 = fmaf(sH[2][k], w, a2);
        a3 = fmaf(sH[3][k], w, a3);
    }
    buf[(size_t)(r0 + 0) * H + h] = a0;
    buf[(size_t)(r0 + 1) * H + h] = a1;
    buf[(size_t)(r0 + 2) * H + h] = a2;
    buf[(size_t)(r0 + 3) * H + h] = a3;
}

// ---------------- BatchNorm ----------------
template <typename TA>
__global__ void k_bn_stats_pat(const TA* __restrict__ x, float* __restrict__ sums) {
    int h = threadIdx.x & 127;
    int sub = threadIdx.x >> 7;
    float s = 0.f, s2 = 0.f;
    for (int i = blockIdx.x * 2 + sub; i < NP; i += gridDim.x * 2) {
        float v = ldv(x, (size_t)i * H + h);
        s += v;
        s2 = fmaf(v, v, s2);
    }
    __shared__ float ls[256], ls2[256];
    ls[threadIdx.x] = s;
    ls2[threadIdx.x] = s2;
    __syncthreads();
    if (sub == 0) {
        atomicAdd(&sums[h], s + ls[128 + h]);
        atomicAdd(&sums[H + h], s2 + ls2[128 + h]);
    }
}

__global__ void k_bn_stats_ld(const float* __restrict__ bufL, const float* __restrict__ bufD,
                              float* __restrict__ sums) {
    bool lab = blockIdx.x < 256;
    const float* x = lab ? bufL : bufD;
    int N = lab ? NL : ND;
    float* sm = sums + (lab ? 2 * H : 4 * H);
    int bid = lab ? blockIdx.x : blockIdx.x - 256;
    int nb = lab ? 256 : 64;
    int h = threadIdx.x & 127;
    int sub = threadIdx.x >> 7;
    float s = 0.f, s2 = 0.f;
    for (int i = bid * 2 + sub; i < N; i += nb * 2) {
        float v = x[(size_t)i * H + h];
        s += v;
        s2 = fmaf(v, v, s2);
    }
    __shared__ float ls[256], ls2[256];
    ls[threadIdx.x] = s;
    ls2[threadIdx.x] = s2;
    __syncthreads();
    if (sub == 0) {
        atomicAdd(&sm[h], s + ls[128 + h]);
        atomicAdd(&sm[H + h], s2 + ls2[128 + h]);
    }
}

template <typename TA>
__global__ void k_bn_apply_pat(const TA* __restrict__ x, bf16* __restrict__ hp,
                               const float* __restrict__ sums, const void* __restrict__ g,
                               const void* __restrict__ b, const int* __restrict__ flags) {
    int f32m = flags[0];
    int idx = blockIdx.x * 256 + threadIdx.x;
    if (idx >= NP * H) return;
    int h = idx & 127;
    const float invN = 1.f / NP;
    float m = sums[h] * invN;
    float v = fmaf(-m, m, sums[H + h] * invN);
    float sc = rsqrtf(v + 1e-5f) * ldin(g, h, f32m);
    float r = fmaf(ldv(x, (size_t)idx) - m, sc, ldin(b, h, f32m));
    hp[idx] = __float2bfloat16(fmaxf(r, 0.f));
}

template <typename TA>
__global__ void k_bn_apply_ld(const float* __restrict__ bufL, const float* __restrict__ bufD,
                              TA* __restrict__ hl, TA* __restrict__ hd,
                              const float* __restrict__ sums, const void* __restrict__ g,
                              const void* __restrict__ b, const int* __restrict__ flags) {
    int f32m = flags[0];
    int idx = blockIdx.x * 256 + threadIdx.x;
    int h = idx & 127;
    if (idx < NL * H) {
        const float invN = 1.f / NL;
        float m = sums[2 * H + h] * invN;
        float v = fmaf(-m, m, sums[3 * H + h] * invN);
        float sc = rsqrtf(v + 1e-5f) * ldin(g, H + h, f32m);
        float r = fmaf(bufL[idx] - m, sc, ldin(b, H + h, f32m));
        stv(hl, (size_t)idx, fmaxf(r, 0.f));
    } else if (idx < (NL + ND) * H) {
        int j = idx - NL * H;
        const float invN = 1.f / ND;
        float m = sums[4 * H + h] * invN;
        float v = fmaf(-m, m, sums[5 * H + h] * invN);
        float sc = rsqrtf(v + 1e-5f) * ldin(g, 2 * H + h, f32m);
        float r = fmaf(bufD[j] - m, sc, ldin(b, 2 * H + h, f32m));
        stv(hd, (size_t)j, fmaxf(r, 0.f));
    }
}

// ---------------- head ----------------
__global__ void k_head(const bf16* __restrict__ hp, const void* __restrict__ W1,
                       const void* __restrict__ b1, const void* __restrict__ W2,
                       const void* __restrict__ b2, void* __restrict__ out,
                       const int* __restrict__ flags) {
    int f32m = flags[0];
    __shared__ float rowsh[4][H];
    __shared__ float h1[4][64];
    __shared__ float lg[4][16];
    int sub = threadIdx.x >> 6;
    int j = threadIdx.x & 63;
    int p = blockIdx.x * 4 + sub;
    float2 rv = ld_bf2(hp + (size_t)p * H + 2 * j);
    rowsh[sub][2 * j] = rv.x;
    rowsh[sub][2 * j + 1] = rv.y;
    float acc = ldin(b1, j, f32m);
#pragma unroll 8
    for (int k = 0; k < H; ++k)
        acc = fmaf(rowsh[sub][k], ldin(W1, (size_t)k * 64 + j, f32m), acc);
    h1[sub][j] = fmaxf(acc, 0.f);
    __syncthreads();
    if (j < NOUT) {
        float a = ldin(b2, j, f32m);
#pragma unroll
        for (int k = 0; k < 64; ++k)
            a = fmaf(h1[sub][k], ldin(W2, (size_t)k * NOUT + j, f32m), a);
        lg[sub][j] = a;
    }
    __syncthreads();
    if (j < NOUT) {
        float m = -1e30f;
#pragma unroll
        for (int k = 0; k < NOUT; ++k) m = fmaxf(m, lg[sub][k]);
        float s = 0.f;
#pragma unroll
        for (int k = 0; k < NOUT; ++k) s += __expf(lg[sub][k] - m);
        float r = lg[sub][j] - m - __logf(s);
        if (f32m)
            ((float*)out)[(size_t)p * NOUT + j] = r;
        else
            ((bf16*)out)[(size_t)p * NOUT + j] = __float2bfloat16(r);
    }
}

// ---------------- one hetero layer ----------------
template <typename TA>
static void run_layer(const void* Wl, const void* bl, const void* Wr, const void* bng,
                      const void* bnb, bf16* hp, TA* hl, TA* hd, TA* aggp, float* bufL,
                      float* bufD, bf16* tlp, bf16* tdp, const int* cnt, const int* off,
                      const int* nbr, float* w23, float* b23, float* bns, const int* flags,
                      hipStream_t stream) {
    k_mm_small<TA><<<NL / 4 + ND / 4, 128, 0, stream>>>(hl, hd, Wl, tlp, tdp, flags);
    k_gather_ld<<<(NL + ND + 3) / 4, 256, 0, stream>>>(hp, off, cnt, nbr, bufL, bufD);
    k_prep23<<<(HH + 255) / 256, 256, 0, stream>>>(Wr, bl, w23, b23, flags);
    k_patient<TA><<<NP / 16, 256, 0, stream>>>(hp, tlp, tdp, off, cnt, nbr, w23, b23, aggp);
    k_mm_labdis<TA><<<NL / 4 + ND / 4, 128, 0, stream>>>(bufL, bufD, hl, hd, Wl, bl, Wr, flags);
    hipMemsetAsync(bns, 0, 6 * H * 4, stream);
    k_bn_stats_pat<TA><<<1024, 256, 0, stream>>>(aggp, bns);
    k_bn_stats_ld<<<320, 256, 0, stream>>>(bufL, bufD, bns);
    k_bn_apply_pat<TA><<<(NP * H + 255) / 256, 256, 0, stream>>>(aggp, hp, bns, bng, bnb, flags);
    k_bn_apply_ld<TA><<<((NL + ND) * H + 255) / 256, 256, 0, stream>>>(bufL, bufD, hl, hd, bns,
                                                                       bng, bnb, flags);
}

template <typename TA>
static void run_all(void* const* d_in, void* d_out, void* d_ws, hipStream_t stream) {
    const int* e1s = (const int*)d_in[23];
    const int* e1d = (const int*)d_in[24];
    const int* e2s = (const int*)d_in[25];
    const int* e2d = (const int*)d_in[26];

    const int NCNT = NL + ND + 2 * NP;  // 210500
    const int NPOOL = 2 * (E1 + E2);    // 5000000

    char* wsb = (char*)d_ws;
    size_t o = 0;
    auto af = [&](size_t nwords) { void* p = wsb + o * 4; o += nwords; return p; };
    int* flags = (int*)af(16);
    float* w23 = (float*)af(HH);
    float* b23 = (float*)af(H);
    float* bns = (float*)af(6 * H);
    int* bsums = (int*)af(256);
    int* cnt = (int*)af(NCNT);
    int* off = (int*)af(NCNT);
    int* r1d = (int*)af(E1);
    int* r1s = (int*)af(E1);
    int* r2d = (int*)af(E2);
    int* r2s = (int*)af(E2);
    int* nbr = (int*)af(NPOOL);
    float* bufL = (float*)af((size_t)NL * H);
    float* bufD = (float*)af((size_t)ND * H);
    bf16* tlp = (bf16*)af((size_t)NL * H / 2);
    bf16* tdp = (bf16*)af((size_t)ND * H / 2);
    bf16* hp = (bf16*)af((size_t)NP * H / 2);
    TA* aggp = (TA*)af((size_t)NP * H * sizeof(TA) / 4);
    TA* hl = (TA*)af((size_t)NL * H * sizeof(TA) / 4);
    TA* hd = (TA*)af((size_t)ND * H * sizeof(TA) / 4);

    k_detect<<<1, 256, 0, stream>>>((const unsigned short*)d_in[0], flags);

    // CSR build (once; reused by both layers)
    hipMemsetAsync(cnt, 0, (size_t)NCNT * 4, stream);
    k_count_all<<<(E1 + E2 + 255) / 256, 256, 0, stream>>>(e1s, e1d, e2s, e2d, cnt, r1d, r1s,
                                                           r2d, r2s);
    int nb = (NCNT + SCAN_ELEMS - 1) / SCAN_ELEMS;
    k_scan1<<<nb, 256, 0, stream>>>(cnt, off, bsums, NCNT);
    k_scan2<<<1, 256, 0, stream>>>(bsums, nb);
    k_scan3<<<(NCNT + 255) / 256, 256, 0, stream>>>(off, bsums, NCNT);
    k_fill_all<<<(E1 + E2 + 255) / 256, 256, 0, stream>>>(e1s, e1d, e2s, e2d, off, r1d, r1s, r2d,
                                                          r2s, nbr);
    // off holds START offsets (unmodified by fill)

    k_embed_all<TA><<<((NP + NL + ND) * H + 255) / 256, 256, 0, stream>>>(
        d_in[0], d_in[1], d_in[2], d_in[3], d_in[4], d_in[5], d_in[6], d_in[7], d_in[8], hp, hl,
        hd, flags);

    run_layer<TA>(d_in[9], d_in[10], d_in[11], d_in[15], d_in[16], hp, hl, hd, aggp, bufL, bufD,
                  tlp, tdp, cnt, off, nbr, w23, b23, bns, flags, stream);
    run_layer<TA>(d_in[12], d_in[13], d_in[14], d_in[17], d_in[18], hp, hl, hd, aggp, bufL, bufD,
                  tlp, tdp, cnt, off, nbr, w23, b23, bns, flags, stream);

    k_head<<<NP / 4, 256, 0, stream>>>(hp, d_in[19], d_in[20], d_in[21], d_in[22], d_out, flags);
}

extern "C" void kernel_launch(void* const* d_in, const int* in_sizes, int n_in, void* d_out,
                              int out_size, void* d_ws, size_t ws_size, hipStream_t stream) {
    const size_t NCNT = NL + ND + 2 * (size_t)NP;
    const size_t NPOOL = 2 * ((size_t)E1 + E2);
    const size_t fixed_words = 16 + HH + H + 6 * H + 256 + 2 * NCNT + NPOOL +
                               2 * ((size_t)E1 + E2) + (size_t)NL * H + (size_t)ND * H +
                               (size_t)NL * H / 2 + (size_t)ND * H / 2 + (size_t)NP * H / 2;
    const size_t ta_elems = (size_t)(NP + NL + ND) * H;
    const size_t need_f32 = fixed_words * 4 + ta_elems * 4;  // ~132 MiB
    if (ws_size >= need_f32)
        run_all<float>(d_in, d_out, d_ws, stream);
    else
        run_all<bf16>(d_in, d_out, d_ws, stream);  // ~104 MiB
}

// Round 8
// 1668.752 us; speedup vs baseline: 4.0332x; 1.1859x over previous
//
#include <hip/hip_runtime.h>
#include <hip/hip_bf16.h>

#define NP 100000
#define NL 10000
#define ND 500
#define H 128
#define HH (H * H)
#define E1 2000000
#define E2 500000
#define NOUT 10
#define NCOPY 8  // XCD count replicas (blockIdx%8 ~ round-robin XCD dispatch)

typedef __hip_bfloat16 bf16;

__device__ __forceinline__ float ldv(const float* p, size_t i) { return p[i]; }
__device__ __forceinline__ float ldv(const bf16* p, size_t i) { return __bfloat162float(p[i]); }
__device__ __forceinline__ void stv(float* p, size_t i, float v) { p[i] = v; }
__device__ __forceinline__ void stv(bf16* p, size_t i, float v) { p[i] = __float2bfloat16(v); }

__device__ __forceinline__ float bfbits2f(unsigned short s) {
    union { unsigned int u; float f; } v;
    v.u = (unsigned int)s << 16;
    return v.f;
}
// load 2 consecutive bf16 (4B-aligned) -> float2
__device__ __forceinline__ float2 ld_bf2(const bf16* p) {
    unsigned int u = *(const unsigned int*)p;
    return make_float2(bfbits2f((unsigned short)(u & 0xFFFFu)), bfbits2f((unsigned short)(u >> 16)));
}
// store float2 -> 2 consecutive bf16 as one 4B store
__device__ __forceinline__ void st_bf2(bf16* p, float2 v) {
    union { unsigned int u; bf16 b[2]; } t;
    t.b[0] = __float2bfloat16(v.x);
    t.b[1] = __float2bfloat16(v.y);
    *(unsigned int*)p = t.u;
}

// raw input buffer with runtime dtype (f32m: 1=f32, 0=bf16)
__device__ __forceinline__ float ldin(const void* p, size_t i, int f32m) {
    return f32m ? ((const float*)p)[i] : __bfloat162float(((const bf16*)p)[i]);
}

// ---------------- input dtype detection (measured: picks bf16 on this harness) ----------
__global__ void k_detect(const unsigned short* __restrict__ xp, int* __restrict__ flags) {
    int t = threadIdx.x;
    int cnt = 0;
    for (int i = t; i < 4096; i += 256) {
        unsigned short w = xp[2 * i];
        int e = (w >> 7) & 0xFF;
        if (w == 0 || (e >= 114 && e <= 141)) cnt++;
    }
    __shared__ int sh[256];
    sh[t] = cnt;
    __syncthreads();
    for (int s = 128; s > 0; s >>= 1) {
        if (t < s) sh[t] += sh[t + s];
        __syncthreads();
    }
    if (t == 0) flags[0] = (sh[0] < 2048) ? 1 : 0;  // 1 = f32 inputs
}

// ---------------- fused initial embeddings (hp bf16; hl/hd TA) ----------------
template <typename TA>
__global__ void k_embed_all(const void* __restrict__ xp, const void* __restrict__ xl,
                            const void* __restrict__ xd, const void* __restrict__ Wp,
                            const void* __restrict__ bp, const void* __restrict__ Wlab,
                            const void* __restrict__ blab, const void* __restrict__ Wdis,
                            const void* __restrict__ bdis, bf16* __restrict__ hp,
                            TA* __restrict__ hl, TA* __restrict__ hd,
                            const int* __restrict__ flags) {
    int f32m = flags[0];
    int idx = blockIdx.x * 256 + threadIdx.x;
    int h = idx & 127;
    if (idx < NP * H) {
        int i = idx >> 7;
        float acc = ldin(bp, h, f32m);
#pragma unroll
        for (int k = 0; k < 16; ++k)
            acc = fmaf(ldin(xp, (size_t)i * 16 + k, f32m), ldin(Wp, (size_t)k * H + h, f32m), acc);
        hp[idx] = __float2bfloat16(acc);
    } else if (idx < (NP + NL) * H) {
        int i = (idx - NP * H) >> 7;
        float acc = fmaf(ldin(xl, i, f32m), ldin(Wlab, h, f32m), ldin(blab, h, f32m));
        stv(hl, (size_t)i * H + h, acc);
    } else if (idx < (NP + NL + ND) * H) {
        int i = (idx - (NP + NL) * H) >> 7;
        float acc = ldin(bdis, h, f32m);
        acc = fmaf(ldin(xd, (size_t)i * 2 + 0, f32m), ldin(Wdis, h, f32m), acc);
        acc = fmaf(ldin(xd, (size_t)i * 2 + 1, f32m), ldin(Wdis, H + h, f32m), acc);
        stv(hd, (size_t)i * H + h, acc);
    }
}

// ---------------- CSR build ----------------
// cnt/off segments: [lab NL][dis ND][p1 NP][p2 NP]; nbr pool same order (E1,E2,E1,E2).
// XCD-privatized count: 8 replicas (blockIdx%8); rank packs (copy<<24)|local_rank.
__global__ void k_count_all(const int* __restrict__ e1s, const int* __restrict__ e1d,
                            const int* __restrict__ e2s, const int* __restrict__ e2d,
                            int* __restrict__ ccnt, int* __restrict__ r1d, int* __restrict__ r1s,
                            int* __restrict__ r2d, int* __restrict__ r2s) {
    const int NCNT = NL + ND + 2 * NP;
    int copy = blockIdx.x & (NCOPY - 1);
    int* c = ccnt + (size_t)copy * NCNT;
    int tag = copy << 24;
    int e = blockIdx.x * 256 + threadIdx.x;
    if (e < E1) {
        r1d[e] = tag | atomicAdd(&c[e1d[e]], 1);
        r1s[e] = tag | atomicAdd(&c[NL + ND + e1s[e]], 1);
    } else if (e < E1 + E2) {
        int i = e - E1;
        r2d[i] = tag | atomicAdd(&c[NL + e2d[i]], 1);
        r2s[i] = tag | atomicAdd(&c[NL + ND + NP + e2s[i]], 1);
    }
}

// per-segment: totals -> cnt; per-copy exclusive bases written back into ccnt
__global__ void k_reduce_copies(int* __restrict__ ccnt, int* __restrict__ cnt, int n) {
    int i = blockIdx.x * 256 + threadIdx.x;
    if (i >= n) return;
    int tot = 0;
#pragma unroll
    for (int k = 0; k < NCOPY; ++k) {
        int v = ccnt[(size_t)k * n + i];
        ccnt[(size_t)k * n + i] = tot;
        tot += v;
    }
    cnt[i] = tot;
}

#define SCAN_ELEMS 2048
__global__ void k_scan1(const int* __restrict__ in, int* __restrict__ out,
                        int* __restrict__ bsums, int n) {
    int t = threadIdx.x;
    int base = blockIdx.x * SCAN_ELEMS + t * 8;
    int v[8], tsum = 0;
#pragma unroll
    for (int j = 0; j < 8; ++j) {
        v[j] = (base + j < n) ? in[base + j] : 0;
        tsum += v[j];
    }
    __shared__ int sh[256];
    sh[t] = tsum;
    __syncthreads();
    for (int d = 1; d < 256; d <<= 1) {
        int x = (t >= d) ? sh[t - d] : 0;
        __syncthreads();
        sh[t] += x;
        __syncthreads();
    }
    int run = sh[t] - tsum;
    if (t == 255) bsums[blockIdx.x] = sh[255];
#pragma unroll
    for (int j = 0; j < 8; ++j) {
        if (base + j < n) out[base + j] = run;
        run += v[j];
    }
}

__global__ void k_scan2(int* __restrict__ bsums, int nb) {
    int t = threadIdx.x;
    int v = (t < nb) ? bsums[t] : 0;
    __shared__ int sh[256];
    sh[t] = v;
    __syncthreads();
    for (int d = 1; d < 256; d <<= 1) {
        int x = (t >= d) ? sh[t - d] : 0;
        __syncthreads();
        sh[t] += x;
        __syncthreads();
    }
    if (t < nb) bsums[t] = sh[t] - v;
}

__global__ void k_scan3(int* __restrict__ out, const int* __restrict__ bsums, int n) {
    int i = blockIdx.x * 256 + threadIdx.x;
    if (i < n) out[i] += bsums[i / SCAN_ELEMS];
}

// atomic-free fill: slot = off[seg] + copy_base[copy][seg] + local_rank
__global__ void k_fill_all(const int* __restrict__ e1s, const int* __restrict__ e1d,
                           const int* __restrict__ e2s, const int* __restrict__ e2d,
                           const int* __restrict__ off, const int* __restrict__ ccnt,
                           const int* __restrict__ r1d, const int* __restrict__ r1s,
                           const int* __restrict__ r2d, const int* __restrict__ r2s,
                           int* __restrict__ nbr) {
    const int NCNT = NL + ND + 2 * NP;
    int e = blockIdx.x * 256 + threadIdx.x;
    if (e < E1) {
        int ss = e1s[e], dd = e1d[e];
        int r = r1d[e];
        nbr[off[dd] + ccnt[(size_t)(r >> 24) * NCNT + dd] + (r & 0xFFFFFF)] = ss;
        r = r1s[e];
        int seg = NL + ND + ss;
        nbr[off[seg] + ccnt[(size_t)(r >> 24) * NCNT + seg] + (r & 0xFFFFFF)] = dd;
    } else if (e < E1 + E2) {
        int i = e - E1;
        int ss = e2s[i], dd = e2d[i];
        int r = r2d[i];
        int seg = NL + dd;
        nbr[off[seg] + ccnt[(size_t)(r >> 24) * NCNT + seg] + (r & 0xFFFFFF)] = ss;
        r = r2s[i];
        seg = NL + ND + NP + ss;
        nbr[off[seg] + ccnt[(size_t)(r >> 24) * NCNT + seg] + (r & 0xFFFFFF)] = dd;
    }
}

// ------- lab+dis gather of raw hp means: one WAVE per dst row, 8-way unrolled MLP -------
__global__ void k_gather_ld(const bf16* __restrict__ hp, const int* __restrict__ off,
                            const int* __restrict__ cnt, const int* __restrict__ nbr,
                            float* __restrict__ bufL, float* __restrict__ bufD) {
    int wid = (blockIdx.x * 256 + threadIdx.x) >> 6;
    int lane = threadIdx.x & 63;
    int c0 = 2 * lane;
    if (wid >= NL + ND) return;
    int s0 = off[wid], c = cnt[wid];
    const int* nb = nbr + s0;
    float2 a[8];
#pragma unroll
    for (int u = 0; u < 8; ++u) a[u] = make_float2(0.f, 0.f);
    int j = 0;
    for (; j + 8 <= c; j += 8) {
#pragma unroll
        for (int u = 0; u < 8; ++u) {
            float2 v = ld_bf2(hp + (size_t)nb[j + u] * H + c0);
            a[u].x += v.x;
            a[u].y += v.y;
        }
    }
    for (; j < c; ++j) {
        float2 v = ld_bf2(hp + (size_t)nb[j] * H + c0);
        a[0].x += v.x;
        a[0].y += v.y;
    }
    float sx = ((a[0].x + a[1].x) + (a[2].x + a[3].x)) + ((a[4].x + a[5].x) + (a[6].x + a[7].x));
    float sy = ((a[0].y + a[1].y) + (a[2].y + a[3].y)) + ((a[4].y + a[5].y) + (a[6].y + a[7].y));
    float inv = 1.f / fmaxf((float)c, 1.f);
    float* out = (wid < NL) ? (bufL + (size_t)wid * H) : (bufD + (size_t)(wid - NL) * H);
    *(float2*)(out + c0) = make_float2(sx * inv, sy * inv);
}

// ---------------- small transforms: tlp = hl@Wl[2], tdp = hd@Wl[3] (bf16 out) ----------
template <typename TA>
__global__ void k_mm_small(const TA* __restrict__ hl, const TA* __restrict__ hd,
                           const void* __restrict__ Wl, bf16* __restrict__ tlp,
                           bf16* __restrict__ tdp, const int* __restrict__ flags) {
    int f32m = flags[0];
    bool lab = blockIdx.x < NL / 4;
    const TA* in = lab ? hl : hd;
    bf16* out = lab ? tlp : tdp;
    size_t woff = lab ? (size_t)2 * HH : (size_t)3 * HH;
    int r0 = (lab ? blockIdx.x : blockIdx.x - NL / 4) * 4;
    __shared__ float s[4][H];
    int h = threadIdx.x;
#pragma unroll
    for (int r = 0; r < 4; ++r) s[r][h] = ldv(in, (size_t)(r0 + r) * H + h);
    __syncthreads();
    float a0 = 0.f, a1 = 0.f, a2 = 0.f, a3 = 0.f;
    for (int k = 0; k < H; ++k) {
        float w = ldin(Wl, woff + (size_t)k * H + h, f32m);
        a0 = fmaf(s[0][k], w, a0);
        a1 = fmaf(s[1][k], w, a1);
        a2 = fmaf(s[2][k], w, a2);
        a3 = fmaf(s[3][k], w, a3);
    }
    out[(size_t)(r0 + 0) * H + h] = __float2bfloat16(a0);
    out[(size_t)(r0 + 1) * H + h] = __float2bfloat16(a1);
    out[(size_t)(r0 + 2) * H + h] = __float2bfloat16(a2);
    out[(size_t)(r0 + 3) * H + h] = __float2bfloat16(a3);
}

// ---------------- Wr2+Wr3 / bl2+bl3 prep (f32 out) ----------------
__global__ void k_prep23(const void* __restrict__ Wr, const void* __restrict__ bl,
                         float* __restrict__ w23, float* __restrict__ b23,
                         const int* __restrict__ flags) {
    int f32m = flags[0];
    int idx = blockIdx.x * 256 + threadIdx.x;
    if (idx < HH)
        w23[idx] = ldin(Wr, (size_t)2 * HH + idx, f32m) + ldin(Wr, (size_t)3 * HH + idx, f32m);
    if (idx < H)
        b23[idx] = ldin(bl, (size_t)2 * H + idx, f32m) + ldin(bl, (size_t)3 * H + idx, f32m);
}

// -------- fused patient pass: aggp = mean_lab(tlp) + mean_dis(tdp) + hp@w23 + b23 --------
// 4 waves/block; each wave owns 4 patients; lane covers 2 columns (float2).
// Lab loop 4-way unrolled (deg~20), dis loop 2-way (deg~5); aggp stored bf16 packed.
__global__ void k_patient(const bf16* __restrict__ hp, const bf16* __restrict__ tlp,
                          const bf16* __restrict__ tdp, const int* __restrict__ off,
                          const int* __restrict__ cnt, const int* __restrict__ nbr,
                          const float* __restrict__ w23, const float* __restrict__ b23,
                          bf16* __restrict__ aggp) {
    int w = threadIdx.x >> 6;
    int lane = threadIdx.x & 63;
    int c0 = 2 * lane;
    int p0 = blockIdx.x * 16 + w * 4;
    const int* off1 = off + NL + ND;
    const int* cnt1 = cnt + NL + ND;
    const int* off2 = off + NL + ND + NP;
    const int* cnt2 = cnt + NL + ND + NP;
    float2 bb = *(const float2*)(b23 + c0);
    float2 acc[4];
#pragma unroll
    for (int r = 0; r < 4; ++r) {
        int p = p0 + r;
        int s1 = off1[p], c1 = cnt1[p];
        const int* nb1 = nbr + s1;
        float2 aa[4];
#pragma unroll
        for (int u = 0; u < 4; ++u) aa[u] = make_float2(0.f, 0.f);
        int j = 0;
        for (; j + 4 <= c1; j += 4) {
#pragma unroll
            for (int u = 0; u < 4; ++u) {
                float2 v = ld_bf2(tlp + (size_t)nb1[j + u] * H + c0);
                aa[u].x += v.x;
                aa[u].y += v.y;
            }
        }
        for (; j < c1; ++j) {
            float2 v = ld_bf2(tlp + (size_t)nb1[j] * H + c0);
            aa[0].x += v.x;
            aa[0].y += v.y;
        }
        float a1x = (aa[0].x + aa[1].x) + (aa[2].x + aa[3].x);
        float a1y = (aa[0].y + aa[1].y) + (aa[2].y + aa[3].y);
        int s2 = off2[p], c2 = cnt2[p];
        const int* nb2 = nbr + s2;
        float2 a2a = make_float2(0.f, 0.f), a2b = a2a;
        j = 0;
        for (; j + 2 <= c2; j += 2) {
            float2 va = ld_bf2(tdp + (size_t)nb2[j] * H + c0);
            float2 vb = ld_bf2(tdp + (size_t)nb2[j + 1] * H + c0);
            a2a.x += va.x; a2a.y += va.y;
            a2b.x += vb.x; a2b.y += vb.y;
        }
        if (j < c2) {
            float2 v = ld_bf2(tdp + (size_t)nb2[j] * H + c0);
            a2a.x += v.x;
            a2a.y += v.y;
        }
        float i1 = 1.f / fmaxf((float)c1, 1.f), i2 = 1.f / fmaxf((float)c2, 1.f);
        acc[r].x = a1x * i1 + (a2a.x + a2b.x) * i2 + bb.x;
        acc[r].y = a1y * i1 + (a2a.y + a2b.y) * i2 + bb.y;
    }
    __shared__ float rows[16][H];  // wave-private slices: no cross-wave barrier needed
#pragma unroll
    for (int r = 0; r < 4; ++r) {
        float2 v = ld_bf2(hp + (size_t)(p0 + r) * H + c0);
        rows[w * 4 + r][c0] = v.x;
        rows[w * 4 + r][c0 + 1] = v.y;
    }
    for (int k = 0; k < H; ++k) {
        float2 wv = *(const float2*)(w23 + (size_t)k * H + c0);
#pragma unroll
        for (int r = 0; r < 4; ++r) {
            float x = rows[w * 4 + r][k];
            acc[r].x = fmaf(x, wv.x, acc[r].x);
            acc[r].y = fmaf(x, wv.y, acc[r].y);
        }
    }
#pragma unroll
    for (int r = 0; r < 4; ++r)
        st_bf2(aggp + (size_t)(p0 + r) * H + c0, acc[r]);
}

// -------- fused lab/dis second stage (in-place): buf = buf@Wl + bl + hX@Wr --------
template <typename TA>
__global__ void k_mm_labdis(float* __restrict__ bufL, float* __restrict__ bufD,
                            const TA* __restrict__ hl, const TA* __restrict__ hd,
                            const void* __restrict__ Wl, const void* __restrict__ bl,
                            const void* __restrict__ Wr, const int* __restrict__ flags) {
    int f32m = flags[0];
    bool lab = blockIdx.x < NL / 4;
    float* buf = lab ? bufL : bufD;
    const TA* hx = lab ? hl : hd;
    size_t woff = lab ? 0 : (size_t)HH;
    size_t boff = lab ? 0 : (size_t)H;
    int r0 = (lab ? blockIdx.x : blockIdx.x - NL / 4) * 4;
    __shared__ float sB[4][H], sH[4][H];
    int h = threadIdx.x;
#pragma unroll
    for (int r = 0; r < 4; ++r) {
        sB[r][h] = buf[(size_t)(r0 + r) * H + h];
        sH[r][h] = ldv(hx, (size_t)(r0 + r) * H + h);
    }
    __syncthreads();
    float a0 = ldin(bl, boff + h, f32m);
    float a1 = a0, a2 = a0, a3 = a0;
    for (int k = 0; k < H; ++k) {
        float w = ldin(Wl, woff + (size_t)k * H + h, f32m);
        a0 = fmaf(sB[0][k], w, a0);
        a1 = fmaf(sB[1][k], w, a1);
        a2 = fmaf(sB[2][k], w, a2);
        a3 = fmaf(sB[3][k], w, a3);
    }
    for (int k = 0; k < H; ++k) {
        float w = ldin(Wr, woff + (size_t)k * H + h, f32m);
        a0 = fmaf(sH[0][k], w, a0);
        a1 = fmaf(sH[1][k], w, a1);
        a2 = fmaf(sH[2][k], w, a2);
        a3 = fmaf(sH[3][k], w, a3);
    }
    buf[(size_t)(r0 + 0) * H + h] = a0;
    buf[(size_t)(r0 + 1) * H + h] = a1;
    buf[(size_t)(r0 + 2) * H + h] = a2;
    buf[(size_t)(r0 + 3) * H + h] = a3;
}

// ---------------- BatchNorm ----------------
__global__ void k_bn_stats_pat(const bf16* __restrict__ x, float* __restrict__ sums) {
    int h = threadIdx.x & 127;
    int sub = threadIdx.x >> 7;
    float s = 0.f, s2 = 0.f;
    for (int i = blockIdx.x * 2 + sub; i < NP; i += gridDim.x * 2) {
        float v = __bfloat162float(x[(size_t)i * H + h]);
        s += v;
        s2 = fmaf(v, v, s2);
    }
    __shared__ float ls[256], ls2[256];
    ls[threadIdx.x] = s;
    ls2[threadIdx.x] = s2;
    __syncthreads();
    if (sub == 0) {
        atomicAdd(&sums[h], s + ls[128 + h]);
        atomicAdd(&sums[H + h], s2 + ls2[128 + h]);
    }
}

__global__ void k_bn_stats_ld(const float* __restrict__ bufL, const float* __restrict__ bufD,
                              float* __restrict__ sums) {
    bool lab = blockIdx.x < 256;
    const float* x = lab ? bufL : bufD;
    int N = lab ? NL : ND;
    float* sm = sums + (lab ? 2 * H : 4 * H);
    int bid = lab ? blockIdx.x : blockIdx.x - 256;
    int nb = lab ? 256 : 64;
    int h = threadIdx.x & 127;
    int sub = threadIdx.x >> 7;
    float s = 0.f, s2 = 0.f;
    for (int i = bid * 2 + sub; i < N; i += nb * 2) {
        float v = x[(size_t)i * H + h];
        s += v;
        s2 = fmaf(v, v, s2);
    }
    __shared__ float ls[256], ls2[256];
    ls[threadIdx.x] = s;
    ls2[threadIdx.x] = s2;
    __syncthreads();
    if (sub == 0) {
        atomicAdd(&sm[h], s + ls[128 + h]);
        atomicAdd(&sm[H + h], s2 + ls2[128 + h]);
    }
}

__global__ void k_bn_apply_pat(const bf16* __restrict__ x, bf16* __restrict__ hp,
                               const float* __restrict__ sums, const void* __restrict__ g,
                               const void* __restrict__ b, const int* __restrict__ flags) {
    int f32m = flags[0];
    int idx = blockIdx.x * 256 + threadIdx.x;
    if (idx >= NP * H) return;
    int h = idx & 127;
    const float invN = 1.f / NP;
    float m = sums[h] * invN;
    float v = fmaf(-m, m, sums[H + h] * invN);
    float sc = rsqrtf(v + 1e-5f) * ldin(g, h, f32m);
    float r = fmaf(__bfloat162float(x[idx]) - m, sc, ldin(b, h, f32m));
    hp[idx] = __float2bfloat16(fmaxf(r, 0.f));
}

template <typename TA>
__global__ void k_bn_apply_ld(const float* __restrict__ bufL, const float* __restrict__ bufD,
                              TA* __restrict__ hl, TA* __restrict__ hd,
                              const float* __restrict__ sums, const void* __restrict__ g,
                              const void* __restrict__ b, const int* __restrict__ flags) {
    int f32m = flags[0];
    int idx = blockIdx.x * 256 + threadIdx.x;
    int h = idx & 127;
    if (idx < NL * H) {
        const float invN = 1.f / NL;
        float m = sums[2 * H + h] * invN;
        float v = fmaf(-m, m, sums[3 * H + h] * invN);
        float sc = rsqrtf(v + 1e-5f) * ldin(g, H + h, f32m);
        float r = fmaf(bufL[idx] - m, sc, ldin(b, H + h, f32m));
        stv(hl, (size_t)idx, fmaxf(r, 0.f));
    } else if (idx < (NL + ND) * H) {
        int j = idx - NL * H;
        const float invN = 1.f / ND;
        float m = sums[4 * H + h] * invN;
        float v = fmaf(-m, m, sums[5 * H + h] * invN);
        float sc = rsqrtf(v + 1e-5f) * ldin(g, 2 * H + h, f32m);
        float r = fmaf(bufD[j] - m, sc, ldin(b, 2 * H + h, f32m));
        stv(hd, (size_t)j, fmaxf(r, 0.f));
    }
}

// ---------------- head ----------------
__global__ void k_head(const bf16* __restrict__ hp, const void* __restrict__ W1,
                       const void* __restrict__ b1, const void* __restrict__ W2,
                       const void* __restrict__ b2, void* __restrict__ out,
                       const int* __restrict__ flags) {
    int f32m = flags[0];
    __shared__ float rowsh[4][H];
    __shared__ float h1[4][64];
    __shared__ float lg[4][16];
    int sub = threadIdx.x >> 6;
    int j = threadIdx.x & 63;
    int p = blockIdx.x * 4 + sub;
    float2 rv = ld_bf2(hp + (size_t)p * H + 2 * j);
    rowsh[sub][2 * j] = rv.x;
    rowsh[sub][2 * j + 1] = rv.y;
    float acc = ldin(b1, j, f32m);
#pragma unroll 8
    for (int k = 0; k < H; ++k)
        acc = fmaf(rowsh[sub][k], ldin(W1, (size_t)k * 64 + j, f32m), acc);
    h1[sub][j] = fmaxf(acc, 0.f);
    __syncthreads();
    if (j < NOUT) {
        float a = ldin(b2, j, f32m);
#pragma unroll
        for (int k = 0; k < 64; ++k)
            a = fmaf(h1[sub][k], ldin(W2, (size_t)k * NOUT + j, f32m), a);
        lg[sub][j] = a;
    }
    __syncthreads();
    if (j < NOUT) {
        float m = -1e30f;
#pragma unroll
        for (int k = 0; k < NOUT; ++k) m = fmaxf(m, lg[sub][k]);
        float s = 0.f;
#pragma unroll
        for (int k = 0; k < NOUT; ++k) s += __expf(lg[sub][k] - m);
        float r = lg[sub][j] - m - __logf(s);
        if (f32m)
            ((float*)out)[(size_t)p * NOUT + j] = r;
        else
            ((bf16*)out)[(size_t)p * NOUT + j] = __float2bfloat16(r);
    }
}

// ---------------- one hetero layer ----------------
template <typename TA>
static void run_layer(const void* Wl, const void* bl, const void* Wr, const void* bng,
                      const void* bnb, bf16* hp, TA* hl, TA* hd, bf16* aggp, float* bufL,
                      float* bufD, bf16* tlp, bf16* tdp, const int* cnt, const int* off,
                      const int* nbr, float* w23, float* b23, float* bns, const int* flags,
                      hipStream_t stream) {
    k_mm_small<TA><<<NL / 4 + ND / 4, 128, 0, stream>>>(hl, hd, Wl, tlp, tdp, flags);
    k_gather_ld<<<(NL + ND + 3) / 4, 256, 0, stream>>>(hp, off, cnt, nbr, bufL, bufD);
    k_prep23<<<(HH + 255) / 256, 256, 0, stream>>>(Wr, bl, w23, b23, flags);
    k_patient<<<NP / 16, 256, 0, stream>>>(hp, tlp, tdp, off, cnt, nbr, w23, b23, aggp);
    k_mm_labdis<TA><<<NL / 4 + ND / 4, 128, 0, stream>>>(bufL, bufD, hl, hd, Wl, bl, Wr, flags);
    hipMemsetAsync(bns, 0, 6 * H * 4, stream);
    k_bn_stats_pat<<<1024, 256, 0, stream>>>(aggp, bns);
    k_bn_stats_ld<<<320, 256, 0, stream>>>(bufL, bufD, bns);
    k_bn_apply_pat<<<(NP * H + 255) / 256, 256, 0, stream>>>(aggp, hp, bns, bng, bnb, flags);
    k_bn_apply_ld<TA><<<((NL + ND) * H + 255) / 256, 256, 0, stream>>>(bufL, bufD, hl, hd, bns,
                                                                       bng, bnb, flags);
}

template <typename TA>
static void run_all(void* const* d_in, void* d_out, void* d_ws, hipStream_t stream) {
    const int* e1s = (const int*)d_in[23];
    const int* e1d = (const int*)d_in[24];
    const int* e2s = (const int*)d_in[25];
    const int* e2d = (const int*)d_in[26];

    const int NCNT = NL + ND + 2 * NP;  // 210500
    const int NPOOL = 2 * (E1 + E2);    // 5000000

    char* wsb = (char*)d_ws;
    size_t o = 0;
    auto af = [&](size_t nwords) { void* p = wsb + o * 4; o += nwords; return p; };
    int* flags = (int*)af(16);
    float* w23 = (float*)af(HH);
    float* b23 = (float*)af(H);
    float* bns = (float*)af(6 * H);
    int* bsums = (int*)af(256);
    int* cnt = (int*)af(NCNT);
    int* off = (int*)af(NCNT);
    int* ccnt = (int*)af((size_t)NCOPY * NCNT);
    int* r1d = (int*)af(E1);
    int* r1s = (int*)af(E1);
    int* r2d = (int*)af(E2);
    int* r2s = (int*)af(E2);
    int* nbr = (int*)af(NPOOL);
    float* bufL = (float*)af((size_t)NL * H);
    float* bufD = (float*)af((size_t)ND * H);
    bf16* tlp = (bf16*)af((size_t)NL * H / 2);
    bf16* tdp = (bf16*)af((size_t)ND * H / 2);
    bf16* hp = (bf16*)af((size_t)NP * H / 2);
    bf16* aggp = (bf16*)af((size_t)NP * H / 2);
    TA* hl = (TA*)af((size_t)NL * H * sizeof(TA) / 4);
    TA* hd = (TA*)af((size_t)ND * H * sizeof(TA) / 4);

    k_detect<<<1, 256, 0, stream>>>((const unsigned short*)d_in[0], flags);

    // CSR build (once; reused by both layers)
    hipMemsetAsync(ccnt, 0, (size_t)NCOPY * NCNT * 4, stream);
    k_count_all<<<(E1 + E2 + 255) / 256, 256, 0, stream>>>(e1s, e1d, e2s, e2d, ccnt, r1d, r1s,
                                                           r2d, r2s);
    k_reduce_copies<<<(NCNT + 255) / 256, 256, 0, stream>>>(ccnt, cnt, NCNT);
    int nb = (NCNT + SCAN_ELEMS - 1) / SCAN_ELEMS;
    k_scan1<<<nb, 256, 0, stream>>>(cnt, off, bsums, NCNT);
    k_scan2<<<1, 256, 0, stream>>>(bsums, nb);
    k_scan3<<<(NCNT + 255) / 256, 256, 0, stream>>>(off, bsums, NCNT);
    k_fill_all<<<(E1 + E2 + 255) / 256, 256, 0, stream>>>(e1s, e1d, e2s, e2d, off, ccnt, r1d,
                                                          r1s, r2d, r2s, nbr);

    k_embed_all<TA><<<((NP + NL + ND) * H + 255) / 256, 256, 0, stream>>>(
        d_in[0], d_in[1], d_in[2], d_in[3], d_in[4], d_in[5], d_in[6], d_in[7], d_in[8], hp, hl,
        hd, flags);

    run_layer<TA>(d_in[9], d_in[10], d_in[11], d_in[15], d_in[16], hp, hl, hd, aggp, bufL, bufD,
                  tlp, tdp, cnt, off, nbr, w23, b23, bns, flags, stream);
    run_layer<TA>(d_in[12], d_in[13], d_in[14], d_in[17], d_in[18], hp, hl, hd, aggp, bufL, bufD,
                  tlp, tdp, cnt, off, nbr, w23, b23, bns, flags, stream);

    k_head<<<NP / 4, 256, 0, stream>>>(hp, d_in[19], d_in[20], d_in[21], d_in[22], d_out, flags);
}

extern "C" void kernel_launch(void* const* d_in, const int* in_sizes, int n_in, void* d_out,
                              int out_size, void* d_ws, size_t ws_size, hipStream_t stream) {
    const size_t NCNT = NL + ND + 2 * (size_t)NP;
    const size_t NPOOL = 2 * ((size_t)E1 + E2);
    const size_t fixed_words = 16 + HH + H + 6 * H + 256 + 2 * NCNT + (size_t)NCOPY * NCNT +
                               NPOOL + 2 * ((size_t)E1 + E2) + (size_t)NL * H + (size_t)ND * H +
                               (size_t)NL * H / 2 + (size_t)ND * H / 2 + (size_t)NP * H / 2 +
                               (size_t)NP * H / 2;
    const size_t ta_elems = (size_t)(NL + ND) * H;
    const size_t need_f32 = fixed_words * 4 + ta_elems * 4;  // ~113 MiB
    if (ws_size >= need_f32)
        run_all<float>(d_in, d_out, d_ws, stream);
    else
        run_all<bf16>(d_in, d_out, d_ws, stream);  // ~110 MiB
}

// Round 9
// 1552.772 us; speedup vs baseline: 4.3344x; 1.0747x over previous
//
#include <hip/hip_runtime.h>
#include <hip/hip_bf16.h>

#define NP 100000
#define NL 10000
#define ND 500
#define H 128
#define HH (H * H)
#define E1 2000000
#define E2 500000
#define NOUT 10
#define NCOPY 8  // XCD count replicas (blockIdx%8 ~ round-robin XCD dispatch)

typedef __hip_bfloat16 bf16;

__device__ __forceinline__ float ldv(const float* p, size_t i) { return p[i]; }
__device__ __forceinline__ float ldv(const bf16* p, size_t i) { return __bfloat162float(p[i]); }
__device__ __forceinline__ void stv(float* p, size_t i, float v) { p[i] = v; }
__device__ __forceinline__ void stv(bf16* p, size_t i, float v) { p[i] = __float2bfloat16(v); }

__device__ __forceinline__ float bfbits2f(unsigned short s) {
    union { unsigned int u; float f; } v;
    v.u = (unsigned int)s << 16;
    return v.f;
}
// load 2 consecutive bf16 (4B-aligned) -> float2
__device__ __forceinline__ float2 ld_bf2(const bf16* p) {
    unsigned int u = *(const unsigned int*)p;
    return make_float2(bfbits2f((unsigned short)(u & 0xFFFFu)), bfbits2f((unsigned short)(u >> 16)));
}
// store float2 -> 2 consecutive bf16 as one 4B store
__device__ __forceinline__ void st_bf2(bf16* p, float2 v) {
    union { unsigned int u; bf16 b[2]; } t;
    t.b[0] = __float2bfloat16(v.x);
    t.b[1] = __float2bfloat16(v.y);
    *(unsigned int*)p = t.u;
}

// raw input buffer with runtime dtype (f32m: 1=f32, 0=bf16)
__device__ __forceinline__ float ldin(const void* p, size_t i, int f32m) {
    return f32m ? ((const float*)p)[i] : __bfloat162float(((const bf16*)p)[i]);
}

// ---------------- input dtype detection (measured: picks bf16 on this harness) ----------
__global__ void k_detect(const unsigned short* __restrict__ xp, int* __restrict__ flags) {
    int t = threadIdx.x;
    int cnt = 0;
    for (int i = t; i < 4096; i += 256) {
        unsigned short w = xp[2 * i];
        int e = (w >> 7) & 0xFF;
        if (w == 0 || (e >= 114 && e <= 141)) cnt++;
    }
    __shared__ int sh[256];
    sh[t] = cnt;
    __syncthreads();
    for (int s = 128; s > 0; s >>= 1) {
        if (t < s) sh[t] += sh[t + s];
        __syncthreads();
    }
    if (t == 0) flags[0] = (sh[0] < 2048) ? 1 : 0;  // 1 = f32 inputs
}

// ---------------- fused initial embeddings (hp bf16; hl/hd TA) ----------------
template <typename TA>
__global__ void k_embed_all(const void* __restrict__ xp, const void* __restrict__ xl,
                            const void* __restrict__ xd, const void* __restrict__ Wp,
                            const void* __restrict__ bp, const void* __restrict__ Wlab,
                            const void* __restrict__ blab, const void* __restrict__ Wdis,
                            const void* __restrict__ bdis, bf16* __restrict__ hp,
                            TA* __restrict__ hl, TA* __restrict__ hd,
                            const int* __restrict__ flags) {
    int f32m = flags[0];
    int idx = blockIdx.x * 256 + threadIdx.x;
    int h = idx & 127;
    if (idx < NP * H) {
        int i = idx >> 7;
        float acc = ldin(bp, h, f32m);
#pragma unroll
        for (int k = 0; k < 16; ++k)
            acc = fmaf(ldin(xp, (size_t)i * 16 + k, f32m), ldin(Wp, (size_t)k * H + h, f32m), acc);
        hp[idx] = __float2bfloat16(acc);
    } else if (idx < (NP + NL) * H) {
        int i = (idx - NP * H) >> 7;
        float acc = fmaf(ldin(xl, i, f32m), ldin(Wlab, h, f32m), ldin(blab, h, f32m));
        stv(hl, (size_t)i * H + h, acc);
    } else if (idx < (NP + NL + ND) * H) {
        int i = (idx - (NP + NL) * H) >> 7;
        float acc = ldin(bdis, h, f32m);
        acc = fmaf(ldin(xd, (size_t)i * 2 + 0, f32m), ldin(Wdis, h, f32m), acc);
        acc = fmaf(ldin(xd, (size_t)i * 2 + 1, f32m), ldin(Wdis, H + h, f32m), acc);
        stv(hd, (size_t)i * H + h, acc);
    }
}

// ---------------- CSR build ----------------
// cnt/off segments: [lab NL][dis ND][p1 NP][p2 NP]; nbr pool same order (E1,E2,E1,E2).
// XCD-privatized count: 8 replicas (blockIdx%8); rank packs (copy<<24)|local_rank.
__global__ void k_count_all(const int* __restrict__ e1s, const int* __restrict__ e1d,
                            const int* __restrict__ e2s, const int* __restrict__ e2d,
                            int* __restrict__ ccnt, int* __restrict__ r1d, int* __restrict__ r1s,
                            int* __restrict__ r2d, int* __restrict__ r2s) {
    const int NCNT = NL + ND + 2 * NP;
    int copy = blockIdx.x & (NCOPY - 1);
    int* c = ccnt + (size_t)copy * NCNT;
    int tag = copy << 24;
    int e = blockIdx.x * 256 + threadIdx.x;
    if (e < E1) {
        r1d[e] = tag | atomicAdd(&c[e1d[e]], 1);
        r1s[e] = tag | atomicAdd(&c[NL + ND + e1s[e]], 1);
    } else if (e < E1 + E2) {
        int i = e - E1;
        r2d[i] = tag | atomicAdd(&c[NL + e2d[i]], 1);
        r2s[i] = tag | atomicAdd(&c[NL + ND + NP + e2s[i]], 1);
    }
}

// per-segment: totals -> cnt; per-copy exclusive bases written back into ccnt
__global__ void k_reduce_copies(int* __restrict__ ccnt, int* __restrict__ cnt, int n) {
    int i = blockIdx.x * 256 + threadIdx.x;
    if (i >= n) return;
    int tot = 0;
#pragma unroll
    for (int k = 0; k < NCOPY; ++k) {
        int v = ccnt[(size_t)k * n + i];
        ccnt[(size_t)k * n + i] = tot;
        tot += v;
    }
    cnt[i] = tot;
}

#define SCAN_ELEMS 2048
__global__ void k_scan1(const int* __restrict__ in, int* __restrict__ out,
                        int* __restrict__ bsums, int n) {
    int t = threadIdx.x;
    int base = blockIdx.x * SCAN_ELEMS + t * 8;
    int v[8], tsum = 0;
#pragma unroll
    for (int j = 0; j < 8; ++j) {
        v[j] = (base + j < n) ? in[base + j] : 0;
        tsum += v[j];
    }
    __shared__ int sh[256];
    sh[t] = tsum;
    __syncthreads();
    for (int d = 1; d < 256; d <<= 1) {
        int x = (t >= d) ? sh[t - d] : 0;
        __syncthreads();
        sh[t] += x;
        __syncthreads();
    }
    int run = sh[t] - tsum;
    if (t == 255) bsums[blockIdx.x] = sh[255];
#pragma unroll
    for (int j = 0; j < 8; ++j) {
        if (base + j < n) out[base + j] = run;
        run += v[j];
    }
}

__global__ void k_scan2(int* __restrict__ bsums, int nb) {
    int t = threadIdx.x;
    int v = (t < nb) ? bsums[t] : 0;
    __shared__ int sh[256];
    sh[t] = v;
    __syncthreads();
    for (int d = 1; d < 256; d <<= 1) {
        int x = (t >= d) ? sh[t - d] : 0;
        __syncthreads();
        sh[t] += x;
        __syncthreads();
    }
    if (t < nb) bsums[t] = sh[t] - v;
}

__global__ void k_scan3(int* __restrict__ out, const int* __restrict__ bsums, int n) {
    int i = blockIdx.x * 256 + threadIdx.x;
    if (i < n) out[i] += bsums[i / SCAN_ELEMS];
}

// atomic-free fill: slot = off[seg] + copy_base[copy][seg] + local_rank
__global__ void k_fill_all(const int* __restrict__ e1s, const int* __restrict__ e1d,
                           const int* __restrict__ e2s, const int* __restrict__ e2d,
                           const int* __restrict__ off, const int* __restrict__ ccnt,
                           const int* __restrict__ r1d, const int* __restrict__ r1s,
                           const int* __restrict__ r2d, const int* __restrict__ r2s,
                           int* __restrict__ nbr) {
    const int NCNT = NL + ND + 2 * NP;
    int e = blockIdx.x * 256 + threadIdx.x;
    if (e < E1) {
        int ss = e1s[e], dd = e1d[e];
        int r = r1d[e];
        nbr[off[dd] + ccnt[(size_t)(r >> 24) * NCNT + dd] + (r & 0xFFFFFF)] = ss;
        r = r1s[e];
        int seg = NL + ND + ss;
        nbr[off[seg] + ccnt[(size_t)(r >> 24) * NCNT + seg] + (r & 0xFFFFFF)] = dd;
    } else if (e < E1 + E2) {
        int i = e - E1;
        int ss = e2s[i], dd = e2d[i];
        int r = r2d[i];
        int seg = NL + dd;
        nbr[off[seg] + ccnt[(size_t)(r >> 24) * NCNT + seg] + (r & 0xFFFFFF)] = ss;
        r = r2s[i];
        seg = NL + ND + NP + ss;
        nbr[off[seg] + ccnt[(size_t)(r >> 24) * NCNT + seg] + (r & 0xFFFFFF)] = dd;
    }
}

// ------- lab+dis gather of raw hp means: one WAVE per dst row, 8-way unrolled MLP -------
__global__ void k_gather_ld(const bf16* __restrict__ hp, const int* __restrict__ off,
                            const int* __restrict__ cnt, const int* __restrict__ nbr,
                            float* __restrict__ bufL, float* __restrict__ bufD) {
    int wid = (blockIdx.x * 256 + threadIdx.x) >> 6;
    int lane = threadIdx.x & 63;
    int c0 = 2 * lane;
    if (wid >= NL + ND) return;
    int s0 = off[wid], c = cnt[wid];
    const int* nb = nbr + s0;
    float2 a[8];
#pragma unroll
    for (int u = 0; u < 8; ++u) a[u] = make_float2(0.f, 0.f);
    int j = 0;
    for (; j + 8 <= c; j += 8) {
#pragma unroll
        for (int u = 0; u < 8; ++u) {
            float2 v = ld_bf2(hp + (size_t)nb[j + u] * H + c0);
            a[u].x += v.x;
            a[u].y += v.y;
        }
    }
    for (; j < c; ++j) {
        float2 v = ld_bf2(hp + (size_t)nb[j] * H + c0);
        a[0].x += v.x;
        a[0].y += v.y;
    }
    float sx = ((a[0].x + a[1].x) + (a[2].x + a[3].x)) + ((a[4].x + a[5].x) + (a[6].x + a[7].x));
    float sy = ((a[0].y + a[1].y) + (a[2].y + a[3].y)) + ((a[4].y + a[5].y) + (a[6].y + a[7].y));
    float inv = 1.f / fmaxf((float)c, 1.f);
    float* out = (wid < NL) ? (bufL + (size_t)wid * H) : (bufD + (size_t)(wid - NL) * H);
    *(float2*)(out + c0) = make_float2(sx * inv, sy * inv);
}

// ---------------- small transforms: tlp = hl@Wl[2], tdp = hd@Wl[3] (bf16 out) ----------
template <typename TA>
__global__ void k_mm_small(const TA* __restrict__ hl, const TA* __restrict__ hd,
                           const void* __restrict__ Wl, bf16* __restrict__ tlp,
                           bf16* __restrict__ tdp, const int* __restrict__ flags) {
    int f32m = flags[0];
    bool lab = blockIdx.x < NL / 4;
    const TA* in = lab ? hl : hd;
    bf16* out = lab ? tlp : tdp;
    size_t woff = lab ? (size_t)2 * HH : (size_t)3 * HH;
    int r0 = (lab ? blockIdx.x : blockIdx.x - NL / 4) * 4;
    __shared__ float s[4][H];
    int h = threadIdx.x;
#pragma unroll
    for (int r = 0; r < 4; ++r) s[r][h] = ldv(in, (size_t)(r0 + r) * H + h);
    __syncthreads();
    float a0 = 0.f, a1 = 0.f, a2 = 0.f, a3 = 0.f;
    for (int k = 0; k < H; ++k) {
        float w = ldin(Wl, woff + (size_t)k * H + h, f32m);
        a0 = fmaf(s[0][k], w, a0);
        a1 = fmaf(s[1][k], w, a1);
        a2 = fmaf(s[2][k], w, a2);
        a3 = fmaf(s[3][k], w, a3);
    }
    out[(size_t)(r0 + 0) * H + h] = __float2bfloat16(a0);
    out[(size_t)(r0 + 1) * H + h] = __float2bfloat16(a1);
    out[(size_t)(r0 + 2) * H + h] = __float2bfloat16(a2);
    out[(size_t)(r0 + 3) * H + h] = __float2bfloat16(a3);
}

// ---------------- Wr2+Wr3 / bl2+bl3 prep (f32 out) ----------------
__global__ void k_prep23(const void* __restrict__ Wr, const void* __restrict__ bl,
                         float* __restrict__ w23, float* __restrict__ b23,
                         const int* __restrict__ flags) {
    int f32m = flags[0];
    int idx = blockIdx.x * 256 + threadIdx.x;
    if (idx < HH)
        w23[idx] = ldin(Wr, (size_t)2 * HH + idx, f32m) + ldin(Wr, (size_t)3 * HH + idx, f32m);
    if (idx < H)
        b23[idx] = ldin(bl, (size_t)2 * H + idx, f32m) + ldin(bl, (size_t)3 * H + idx, f32m);
}

// -------- fused patient pass: aggp = mean_lab(tlp) + mean_dis(tdp) + hp@w23 + b23 --------
__global__ void k_patient(const bf16* __restrict__ hp, const bf16* __restrict__ tlp,
                          const bf16* __restrict__ tdp, const int* __restrict__ off,
                          const int* __restrict__ cnt, const int* __restrict__ nbr,
                          const float* __restrict__ w23, const float* __restrict__ b23,
                          bf16* __restrict__ aggp) {
    int w = threadIdx.x >> 6;
    int lane = threadIdx.x & 63;
    int c0 = 2 * lane;
    int p0 = blockIdx.x * 16 + w * 4;
    const int* off1 = off + NL + ND;
    const int* cnt1 = cnt + NL + ND;
    const int* off2 = off + NL + ND + NP;
    const int* cnt2 = cnt + NL + ND + NP;
    float2 bb = *(const float2*)(b23 + c0);
    float2 acc[4];
#pragma unroll
    for (int r = 0; r < 4; ++r) {
        int p = p0 + r;
        int s1 = off1[p], c1 = cnt1[p];
        const int* nb1 = nbr + s1;
        float2 aa[4];
#pragma unroll
        for (int u = 0; u < 4; ++u) aa[u] = make_float2(0.f, 0.f);
        int j = 0;
        for (; j + 4 <= c1; j += 4) {
#pragma unroll
            for (int u = 0; u < 4; ++u) {
                float2 v = ld_bf2(tlp + (size_t)nb1[j + u] * H + c0);
                aa[u].x += v.x;
                aa[u].y += v.y;
            }
        }
        for (; j < c1; ++j) {
            float2 v = ld_bf2(tlp + (size_t)nb1[j] * H + c0);
            aa[0].x += v.x;
            aa[0].y += v.y;
        }
        float a1x = (aa[0].x + aa[1].x) + (aa[2].x + aa[3].x);
        float a1y = (aa[0].y + aa[1].y) + (aa[2].y + aa[3].y);
        int s2 = off2[p], c2 = cnt2[p];
        const int* nb2 = nbr + s2;
        float2 a2a = make_float2(0.f, 0.f), a2b = a2a;
        j = 0;
        for (; j + 2 <= c2; j += 2) {
            float2 va = ld_bf2(tdp + (size_t)nb2[j] * H + c0);
            float2 vb = ld_bf2(tdp + (size_t)nb2[j + 1] * H + c0);
            a2a.x += va.x; a2a.y += va.y;
            a2b.x += vb.x; a2b.y += vb.y;
        }
        if (j < c2) {
            float2 v = ld_bf2(tdp + (size_t)nb2[j] * H + c0);
            a2a.x += v.x;
            a2a.y += v.y;
        }
        float i1 = 1.f / fmaxf((float)c1, 1.f), i2 = 1.f / fmaxf((float)c2, 1.f);
        acc[r].x = a1x * i1 + (a2a.x + a2b.x) * i2 + bb.x;
        acc[r].y = a1y * i1 + (a2a.y + a2b.y) * i2 + bb.y;
    }
    __shared__ float rows[16][H];  // wave-private slices: no cross-wave barrier needed
#pragma unroll
    for (int r = 0; r < 4; ++r) {
        float2 v = ld_bf2(hp + (size_t)(p0 + r) * H + c0);
        rows[w * 4 + r][c0] = v.x;
        rows[w * 4 + r][c0 + 1] = v.y;
    }
    for (int k = 0; k < H; ++k) {
        float2 wv = *(const float2*)(w23 + (size_t)k * H + c0);
#pragma unroll
        for (int r = 0; r < 4; ++r) {
            float x = rows[w * 4 + r][k];
            acc[r].x = fmaf(x, wv.x, acc[r].x);
            acc[r].y = fmaf(x, wv.y, acc[r].y);
        }
    }
#pragma unroll
    for (int r = 0; r < 4; ++r)
        st_bf2(aggp + (size_t)(p0 + r) * H + c0, acc[r]);
}

// -------- fused lab/dis second stage (in-place): buf = buf@Wl + bl + hX@Wr --------
template <typename TA>
__global__ void k_mm_labdis(float* __restrict__ bufL, float* __restrict__ bufD,
                            const TA* __restrict__ hl, const TA* __restrict__ hd,
                            const void* __restrict__ Wl, const void* __restrict__ bl,
                            const void* __restrict__ Wr, const int* __restrict__ flags) {
    int f32m = flags[0];
    bool lab = blockIdx.x < NL / 4;
    float* buf = lab ? bufL : bufD;
    const TA* hx = lab ? hl : hd;
    size_t woff = lab ? 0 : (size_t)HH;
    size_t boff = lab ? 0 : (size_t)H;
    int r0 = (lab ? blockIdx.x : blockIdx.x - NL / 4) * 4;
    __shared__ float sB[4][H], sH[4][H];
    int h = threadIdx.x;
#pragma unroll
    for (int r = 0; r < 4; ++r) {
        sB[r][h] = buf[(size_t)(r0 + r) * H + h];
        sH[r][h] = ldv(hx, (size_t)(r0 + r) * H + h);
    }
    __syncthreads();
    float a0 = ldin(bl, boff + h, f32m);
    float a1 = a0, a2 = a0, a3 = a0;
    for (int k = 0; k < H; ++k) {
        float w = ldin(Wl, woff + (size_t)k * H + h, f32m);
        a0 = fmaf(sB[0][k], w, a0);
        a1 = fmaf(sB[1][k], w, a1);
        a2 = fmaf(sB[2][k], w, a2);
        a3 = fmaf(sB[3][k], w, a3);
    }
    for (int k = 0; k < H; ++k) {
        float w = ldin(Wr, woff + (size_t)k * H + h, f32m);
        a0 = fmaf(sH[0][k], w, a0);
        a1 = fmaf(sH[1][k], w, a1);
        a2 = fmaf(sH[2][k], w, a2);
        a3 = fmaf(sH[3][k], w, a3);
    }
    buf[(size_t)(r0 + 0) * H + h] = a0;
    buf[(size_t)(r0 + 1) * H + h] = a1;
    buf[(size_t)(r0 + 2) * H + h] = a2;
    buf[(size_t)(r0 + 3) * H + h] = a3;
}

// ---------------- BatchNorm ----------------
__global__ void k_bn_stats_pat(const bf16* __restrict__ x, float* __restrict__ sums) {
    int h = threadIdx.x & 127;
    int sub = threadIdx.x >> 7;
    float s = 0.f, s2 = 0.f;
    for (int i = blockIdx.x * 2 + sub; i < NP; i += gridDim.x * 2) {
        float v = __bfloat162float(x[(size_t)i * H + h]);
        s += v;
        s2 = fmaf(v, v, s2);
    }
    __shared__ float ls[256], ls2[256];
    ls[threadIdx.x] = s;
    ls2[threadIdx.x] = s2;
    __syncthreads();
    if (sub == 0) {
        atomicAdd(&sums[h], s + ls[128 + h]);
        atomicAdd(&sums[H + h], s2 + ls2[128 + h]);
    }
}

__global__ void k_bn_stats_ld(const float* __restrict__ bufL, const float* __restrict__ bufD,
                              float* __restrict__ sums) {
    bool lab = blockIdx.x < 256;
    const float* x = lab ? bufL : bufD;
    int N = lab ? NL : ND;
    float* sm = sums + (lab ? 2 * H : 4 * H);
    int bid = lab ? blockIdx.x : blockIdx.x - 256;
    int nb = lab ? 256 : 64;
    int h = threadIdx.x & 127;
    int sub = threadIdx.x >> 7;
    float s = 0.f, s2 = 0.f;
    for (int i = bid * 2 + sub; i < N; i += nb * 2) {
        float v = x[(size_t)i * H + h];
        s += v;
        s2 = fmaf(v, v, s2);
    }
    __shared__ float ls[256], ls2[256];
    ls[threadIdx.x] = s;
    ls2[threadIdx.x] = s2;
    __syncthreads();
    if (sub == 0) {
        atomicAdd(&sm[h], s + ls[128 + h]);
        atomicAdd(&sm[H + h], s2 + ls2[128 + h]);
    }
}

__global__ void k_bn_apply_pat(const bf16* __restrict__ x, bf16* __restrict__ hp,
                               const float* __restrict__ sums, const void* __restrict__ g,
                               const void* __restrict__ b, const int* __restrict__ flags) {
    int f32m = flags[0];
    int idx = blockIdx.x * 256 + threadIdx.x;
    if (idx >= NP * H) return;
    int h = idx & 127;
    const float invN = 1.f / NP;
    float m = sums[h] * invN;
    float v = fmaf(-m, m, sums[H + h] * invN);
    float sc = rsqrtf(v + 1e-5f) * ldin(g, h, f32m);
    float r = fmaf(__bfloat162float(x[idx]) - m, sc, ldin(b, h, f32m));
    hp[idx] = __float2bfloat16(fmaxf(r, 0.f));
}

template <typename TA>
__global__ void k_bn_apply_ld(const float* __restrict__ bufL, const float* __restrict__ bufD,
                              TA* __restrict__ hl, TA* __restrict__ hd,
                              const float* __restrict__ sums, const void* __restrict__ g,
                              const void* __restrict__ b, const int* __restrict__ flags) {
    int f32m = flags[0];
    int idx = blockIdx.x * 256 + threadIdx.x;
    int h = idx & 127;
    if (idx < NL * H) {
        const float invN = 1.f / NL;
        float m = sums[2 * H + h] * invN;
        float v = fmaf(-m, m, sums[3 * H + h] * invN);
        float sc = rsqrtf(v + 1e-5f) * ldin(g, H + h, f32m);
        float r = fmaf(bufL[idx] - m, sc, ldin(b, H + h, f32m));
        stv(hl, (size_t)idx, fmaxf(r, 0.f));
    } else if (idx < (NL + ND) * H) {
        int j = idx - NL * H;
        const float invN = 1.f / ND;
        float m = sums[4 * H + h] * invN;
        float v = fmaf(-m, m, sums[5 * H + h] * invN);
        float sc = rsqrtf(v + 1e-5f) * ldin(g, 2 * H + h, f32m);
        float r = fmaf(bufD[j] - m, sc, ldin(b, 2 * H + h, f32m));
        stv(hd, (size_t)j, fmaxf(r, 0.f));
    }
}

// ---------------- head: 16 patients/block, weights staged in LDS as f32 ----------------
__global__ void k_head(const bf16* __restrict__ hp, const void* __restrict__ W1,
                       const void* __restrict__ b1, const void* __restrict__ W2,
                       const void* __restrict__ b2, void* __restrict__ out,
                       const int* __restrict__ flags) {
    int f32m = flags[0];
    __shared__ float W1s[H * 64];     // 32 KB; fc1 read: lanes j / j+32 same bank = free 2-way
    __shared__ float W2s[64 * NOUT];  // fc2 read: broadcast groups, distinct banks
    __shared__ float b1s[64], b2s[NOUT];
    __shared__ float rows[16][H];     // broadcast reads in fc1 (compiler fuses to b128)
    __shared__ float h1s[16][65];     // +1 pad: kills 4-way bank conflict in fc2
    __shared__ float lgs[16][16];
    int t = threadIdx.x;
    for (int i = t; i < H * 64; i += 256) W1s[i] = ldin(W1, i, f32m);
    for (int i = t; i < 64 * NOUT; i += 256) W2s[i] = ldin(W2, i, f32m);
    if (t < 64) b1s[t] = ldin(b1, t, f32m);
    else if (t >= 64 && t < 64 + NOUT) b2s[t - 64] = ldin(b2, t - 64, f32m);
    int p0 = blockIdx.x * 16;
    for (int i = t; i < 16 * 64; i += 256) {  // 16 rows x 64 bf16-pairs
        int r = i >> 6, c2 = (i & 63) * 2;
        float2 v = ld_bf2(hp + (size_t)(p0 + r) * H + c2);
        rows[r][c2] = v.x;
        rows[r][c2 + 1] = v.y;
    }
    __syncthreads();
    int w = t >> 6, lane = t & 63;
    // fc1: wave w owns patients 4w..4w+3; lane computes h1[lane] for all 4
    const float* r0 = rows[4 * w + 0];
    const float* r1 = rows[4 * w + 1];
    const float* r2 = rows[4 * w + 2];
    const float* r3 = rows[4 * w + 3];
    float a0 = b1s[lane], a1 = a0, a2 = a0, a3 = a0;
#pragma unroll 4
    for (int k = 0; k < H; ++k) {
        float wv = W1s[k * 64 + lane];
        a0 = fmaf(r0[k], wv, a0);
        a1 = fmaf(r1[k], wv, a1);
        a2 = fmaf(r2[k], wv, a2);
        a3 = fmaf(r3[k], wv, a3);
    }
    // wave-private LDS region; in-wave LDS ops are ordered -> no barrier needed
    h1s[4 * w + 0][lane] = fmaxf(a0, 0.f);
    h1s[4 * w + 1][lane] = fmaxf(a1, 0.f);
    h1s[4 * w + 2][lane] = fmaxf(a2, 0.f);
    h1s[4 * w + 3][lane] = fmaxf(a3, 0.f);
    __syncthreads();  // cheap safety; wave-private in practice
    // fc2: lane = pat*16 + oidx (4 patients x 10 outputs active)
    int pat = lane >> 4, oidx = lane & 15;
    int prow = 4 * w + pat;
    float lg = 0.f;
    if (oidx < NOUT) {
        lg = b2s[oidx];
        const float* hh = h1s[prow];
#pragma unroll 8
        for (int k = 0; k < 64; ++k) lg = fmaf(hh[k], W2s[k * NOUT + oidx], lg);
        lgs[prow][oidx] = lg;
    }
    __syncthreads();
    if (oidx < NOUT) {
        float m = -1e30f;
#pragma unroll
        for (int k = 0; k < NOUT; ++k) m = fmaxf(m, lgs[prow][k]);
        float s = 0.f;
#pragma unroll
        for (int k = 0; k < NOUT; ++k) s += __expf(lgs[prow][k] - m);
        float r = lg - m - __logf(s);
        if (f32m)
            ((float*)out)[(size_t)(p0 + prow) * NOUT + oidx] = r;
        else
            ((bf16*)out)[(size_t)(p0 + prow) * NOUT + oidx] = __float2bfloat16(r);
    }
}

// ---------------- one hetero layer ----------------
template <typename TA>
static void run_layer(const void* Wl, const void* bl, const void* Wr, const void* bng,
                      const void* bnb, bf16* hp, TA* hl, TA* hd, bf16* aggp, float* bufL,
                      float* bufD, bf16* tlp, bf16* tdp, const int* cnt, const int* off,
                      const int* nbr, float* w23, float* b23, float* bns, const int* flags,
                      hipStream_t stream) {
    k_mm_small<TA><<<NL / 4 + ND / 4, 128, 0, stream>>>(hl, hd, Wl, tlp, tdp, flags);
    k_gather_ld<<<(NL + ND + 3) / 4, 256, 0, stream>>>(hp, off, cnt, nbr, bufL, bufD);
    k_prep23<<<(HH + 255) / 256, 256, 0, stream>>>(Wr, bl, w23, b23, flags);
    k_patient<<<NP / 16, 256, 0, stream>>>(hp, tlp, tdp, off, cnt, nbr, w23, b23, aggp);
    k_mm_labdis<TA><<<NL / 4 + ND / 4, 128, 0, stream>>>(bufL, bufD, hl, hd, Wl, bl, Wr, flags);
    hipMemsetAsync(bns, 0, 6 * H * 4, stream);
    k_bn_stats_pat<<<1024, 256, 0, stream>>>(aggp, bns);
    k_bn_stats_ld<<<320, 256, 0, stream>>>(bufL, bufD, bns);
    k_bn_apply_pat<<<(NP * H + 255) / 256, 256, 0, stream>>>(aggp, hp, bns, bng, bnb, flags);
    k_bn_apply_ld<TA><<<((NL + ND) * H + 255) / 256, 256, 0, stream>>>(bufL, bufD, hl, hd, bns,
                                                                       bng, bnb, flags);
}

template <typename TA>
static void run_all(void* const* d_in, void* d_out, void* d_ws, hipStream_t stream) {
    const int* e1s = (const int*)d_in[23];
    const int* e1d = (const int*)d_in[24];
    const int* e2s = (const int*)d_in[25];
    const int* e2d = (const int*)d_in[26];

    const int NCNT = NL + ND + 2 * NP;  // 210500
    const int NPOOL = 2 * (E1 + E2);    // 5000000

    char* wsb = (char*)d_ws;
    size_t o = 0;
    auto af = [&](size_t nwords) { void* p = wsb + o * 4; o += nwords; return p; };
    int* flags = (int*)af(16);
    float* w23 = (float*)af(HH);
    float* b23 = (float*)af(H);
    float* bns = (float*)af(6 * H);
    int* bsums = (int*)af(256);
    int* cnt = (int*)af(NCNT);
    int* off = (int*)af(NCNT);
    int* ccnt = (int*)af((size_t)NCOPY * NCNT);
    int* r1d = (int*)af(E1);
    int* r1s = (int*)af(E1);
    int* r2d = (int*)af(E2);
    int* r2s = (int*)af(E2);
    int* nbr = (int*)af(NPOOL);
    float* bufL = (float*)af((size_t)NL * H);
    float* bufD = (float*)af((size_t)ND * H);
    bf16* tlp = (bf16*)af((size_t)NL * H / 2);
    bf16* tdp = (bf16*)af((size_t)ND * H / 2);
    bf16* hp = (bf16*)af((size_t)NP * H / 2);
    bf16* aggp = (bf16*)af((size_t)NP * H / 2);
    TA* hl = (TA*)af((size_t)NL * H * sizeof(TA) / 4);
    TA* hd = (TA*)af((size_t)ND * H * sizeof(TA) / 4);

    k_detect<<<1, 256, 0, stream>>>((const unsigned short*)d_in[0], flags);

    // CSR build (once; reused by both layers)
    hipMemsetAsync(ccnt, 0, (size_t)NCOPY * NCNT * 4, stream);
    k_count_all<<<(E1 + E2 + 255) / 256, 256, 0, stream>>>(e1s, e1d, e2s, e2d, ccnt, r1d, r1s,
                                                           r2d, r2s);
    k_reduce_copies<<<(NCNT + 255) / 256, 256, 0, stream>>>(ccnt, cnt, NCNT);
    int nb = (NCNT + SCAN_ELEMS - 1) / SCAN_ELEMS;
    k_scan1<<<nb, 256, 0, stream>>>(cnt, off, bsums, NCNT);
    k_scan2<<<1, 256, 0, stream>>>(bsums, nb);
    k_scan3<<<(NCNT + 255) / 256, 256, 0, stream>>>(off, bsums, NCNT);
    k_fill_all<<<(E1 + E2 + 255) / 256, 256, 0, stream>>>(e1s, e1d, e2s, e2d, off, ccnt, r1d,
                                                          r1s, r2d, r2s, nbr);

    k_embed_all<TA><<<((NP + NL + ND) * H + 255) / 256, 256, 0, stream>>>(
        d_in[0], d_in[1], d_in[2], d_in[3], d_in[4], d_in[5], d_in[6], d_in[7], d_in[8], hp, hl,
        hd, flags);

    run_layer<TA>(d_in[9], d_in[10], d_in[11], d_in[15], d_in[16], hp, hl, hd, aggp, bufL, bufD,
                  tlp, tdp, cnt, off, nbr, w23, b23, bns, flags, stream);
    run_layer<TA>(d_in[12], d_in[13], d_in[14], d_in[17], d_in[18], hp, hl, hd, aggp, bufL, bufD,
                  tlp, tdp, cnt, off, nbr, w23, b23, bns, flags, stream);

    k_head<<<NP / 16, 256, 0, stream>>>(hp, d_in[19], d_in[20], d_in[21], d_in[22], d_out, flags);
}

extern "C" void kernel_launch(void* const* d_in, const int* in_sizes, int n_in, void* d_out,
                              int out_size, void* d_ws, size_t ws_size, hipStream_t stream) {
    const size_t NCNT = NL + ND + 2 * (size_t)NP;
    const size_t NPOOL = 2 * ((size_t)E1 + E2);
    const size_t fixed_words = 16 + HH + H + 6 * H + 256 + 2 * NCNT + (size_t)NCOPY * NCNT +
                               NPOOL + 2 * ((size_t)E1 + E2) + (size_t)NL * H + (size_t)ND * H +
                               (size_t)NL * H / 2 + (size_t)ND * H / 2 + (size_t)NP * H / 2 +
                               (size_t)NP * H / 2;
    const size_t ta_elems = (size_t)(NL + ND) * H;
    const size_t need_f32 = fixed_words * 4 + ta_elems * 4;  // ~113 MiB
    if (ws_size >= need_f32)
        run_all<float>(d_in, d_out, d_ws, stream);
    else
        run_all<bf16>(d_in, d_out, d_ws, stream);  // ~110 MiB
}

// Round 10
// 1432.090 us; speedup vs baseline: 4.6997x; 1.0843x over previous
//
#include <hip/hip_runtime.h>
#include <hip/hip_bf16.h>

#define NP 100000
#define NL 10000
#define ND 500
#define H 128
#define HH (H * H)
#define E1 2000000
#define E2 500000
#define NOUT 10
#define NCOPY 8             // XCD count replicas (blockIdx%8 ~ round-robin XCD dispatch)
#define NCNT (NL + ND + 2 * NP)   // 210500 segments: [lab NL][dis ND][p1 NP][p2 NP]
#define NWORDS (NCNT / 2)   // packed u16 pairs

typedef __hip_bfloat16 bf16;

__device__ __forceinline__ float ldv(const float* p, size_t i) { return p[i]; }
__device__ __forceinline__ float ldv(const bf16* p, size_t i) { return __bfloat162float(p[i]); }
__device__ __forceinline__ void stv(float* p, size_t i, float v) { p[i] = v; }
__device__ __forceinline__ void stv(bf16* p, size_t i, float v) { p[i] = __float2bfloat16(v); }

__device__ __forceinline__ float bfbits2f(unsigned short s) {
    union { unsigned int u; float f; } v;
    v.u = (unsigned int)s << 16;
    return v.f;
}
__device__ __forceinline__ float2 ld_bf2(const bf16* p) {
    unsigned int u = *(const unsigned int*)p;
    return make_float2(bfbits2f((unsigned short)(u & 0xFFFFu)), bfbits2f((unsigned short)(u >> 16)));
}
__device__ __forceinline__ void st_bf2(bf16* p, float2 v) {
    union { unsigned int u; bf16 b[2]; } t;
    t.b[0] = __float2bfloat16(v.x);
    t.b[1] = __float2bfloat16(v.y);
    *(unsigned int*)p = t.u;
}
__device__ __forceinline__ float ldin(const void* p, size_t i, int f32m) {
    return f32m ? ((const float*)p)[i] : __bfloat162float(((const bf16*)p)[i]);
}

// ---------------- input dtype detection (measured: picks bf16 on this harness) ----------
__global__ void k_detect(const unsigned short* __restrict__ xp, int* __restrict__ flags) {
    int t = threadIdx.x;
    int cnt = 0;
    for (int i = t; i < 4096; i += 256) {
        unsigned short w = xp[2 * i];
        int e = (w >> 7) & 0xFF;
        if (w == 0 || (e >= 114 && e <= 141)) cnt++;
    }
    __shared__ int sh[256];
    sh[t] = cnt;
    __syncthreads();
    for (int s = 128; s > 0; s >>= 1) {
        if (t < s) sh[t] += sh[t + s];
        __syncthreads();
    }
    if (t == 0) flags[0] = (sh[0] < 2048) ? 1 : 0;  // 1 = f32 inputs
}

// ---------------- fused initial embeddings (hp bf16; hl/hd TA) ----------------
template <typename TA>
__global__ void k_embed_all(const void* __restrict__ xp, const void* __restrict__ xl,
                            const void* __restrict__ xd, const void* __restrict__ Wp,
                            const void* __restrict__ bp, const void* __restrict__ Wlab,
                            const void* __restrict__ blab, const void* __restrict__ Wdis,
                            const void* __restrict__ bdis, bf16* __restrict__ hp,
                            TA* __restrict__ hl, TA* __restrict__ hd,
                            const int* __restrict__ flags) {
    int f32m = flags[0];
    int idx = blockIdx.x * 256 + threadIdx.x;
    int h = idx & 127;
    if (idx < NP * H) {
        int i = idx >> 7;
        float acc = ldin(bp, h, f32m);
#pragma unroll
        for (int k = 0; k < 16; ++k)
            acc = fmaf(ldin(xp, (size_t)i * 16 + k, f32m), ldin(Wp, (size_t)k * H + h, f32m), acc);
        hp[idx] = __float2bfloat16(acc);
    } else if (idx < (NP + NL) * H) {
        int i = (idx - NP * H) >> 7;
        float acc = fmaf(ldin(xl, i, f32m), ldin(Wlab, h, f32m), ldin(blab, h, f32m));
        stv(hl, (size_t)i * H + h, acc);
    } else if (idx < (NP + NL + ND) * H) {
        int i = (idx - (NP + NL) * H) >> 7;
        float acc = ldin(bdis, h, f32m);
        acc = fmaf(ldin(xd, (size_t)i * 2 + 0, f32m), ldin(Wdis, h, f32m), acc);
        acc = fmaf(ldin(xd, (size_t)i * 2 + 1, f32m), ldin(Wdis, H + h, f32m), acc);
        stv(hd, (size_t)i * H + h, acc);
    }
}

// ---------------- CSR build: packed u16 bins, XCD-privatized, atomic-free fill ----------
// ccnt: NCOPY x NWORDS u32 words; each word = two u16 bins (segments 2w, 2w+1).
// rank u16 = (copy<<13) | local_rank  (max seg degree ~1100 << 8191).
__global__ void k_count_all(const int* __restrict__ e1s, const int* __restrict__ e1d,
                            const int* __restrict__ e2s, const int* __restrict__ e2d,
                            unsigned int* __restrict__ ccnt, unsigned short* __restrict__ r1d,
                            unsigned short* __restrict__ r1s, unsigned short* __restrict__ r2d,
                            unsigned short* __restrict__ r2s) {
    int copy = blockIdx.x & (NCOPY - 1);
    unsigned int* c = ccnt + (size_t)copy * NWORDS;
    unsigned short tag = (unsigned short)(copy << 13);
    int e = blockIdx.x * 256 + threadIdx.x;
    if (e < E1) {
        int seg = e1d[e];
        unsigned int old = atomicAdd(&c[seg >> 1], 1u << (16 * (seg & 1)));
        r1d[e] = tag | (unsigned short)((old >> (16 * (seg & 1))) & 0xFFFFu);
        seg = NL + ND + e1s[e];
        old = atomicAdd(&c[seg >> 1], 1u << (16 * (seg & 1)));
        r1s[e] = tag | (unsigned short)((old >> (16 * (seg & 1))) & 0xFFFFu);
    } else if (e < E1 + E2) {
        int i = e - E1;
        int seg = NL + e2d[i];
        unsigned int old = atomicAdd(&c[seg >> 1], 1u << (16 * (seg & 1)));
        r2d[i] = tag | (unsigned short)((old >> (16 * (seg & 1))) & 0xFFFFu);
        seg = NL + ND + NP + e2s[i];
        old = atomicAdd(&c[seg >> 1], 1u << (16 * (seg & 1)));
        r2s[i] = tag | (unsigned short)((old >> (16 * (seg & 1))) & 0xFFFFu);
    }
}

// per-word: totals -> cnt[2i],cnt[2i+1]; per-copy exclusive bases packed back into ccnt
__global__ void k_reduce_copies(unsigned int* __restrict__ ccnt, int* __restrict__ cnt) {
    int i = blockIdx.x * 256 + threadIdx.x;
    if (i >= NWORDS) return;
    unsigned int t0 = 0, t1 = 0;
#pragma unroll
    for (int k = 0; k < NCOPY; ++k) {
        unsigned int v = ccnt[(size_t)k * NWORDS + i];
        ccnt[(size_t)k * NWORDS + i] = t0 | (t1 << 16);
        t0 += v & 0xFFFFu;
        t1 += v >> 16;
    }
    cnt[2 * i] = (int)t0;
    cnt[2 * i + 1] = (int)t1;
}

#define SCAN_ELEMS 2048
__global__ void k_scan1(const int* __restrict__ in, int* __restrict__ out,
                        int* __restrict__ bsums, int n) {
    int t = threadIdx.x;
    int base = blockIdx.x * SCAN_ELEMS + t * 8;
    int v[8], tsum = 0;
#pragma unroll
    for (int j = 0; j < 8; ++j) {
        v[j] = (base + j < n) ? in[base + j] : 0;
        tsum += v[j];
    }
    __shared__ int sh[256];
    sh[t] = tsum;
    __syncthreads();
    for (int d = 1; d < 256; d <<= 1) {
        int x = (t >= d) ? sh[t - d] : 0;
        __syncthreads();
        sh[t] += x;
        __syncthreads();
    }
    int run = sh[t] - tsum;
    if (t == 255) bsums[blockIdx.x] = sh[255];
#pragma unroll
    for (int j = 0; j < 8; ++j) {
        if (base + j < n) out[base + j] = run;
        run += v[j];
    }
}

__global__ void k_scan2(int* __restrict__ bsums, int nb) {
    int t = threadIdx.x;
    int v = (t < nb) ? bsums[t] : 0;
    __shared__ int sh[256];
    sh[t] = v;
    __syncthreads();
    for (int d = 1; d < 256; d <<= 1) {
        int x = (t >= d) ? sh[t - d] : 0;
        __syncthreads();
        sh[t] += x;
        __syncthreads();
    }
    if (t < nb) bsums[t] = sh[t] - v;
}

__global__ void k_scan3(int* __restrict__ out, const int* __restrict__ bsums, int n) {
    int i = blockIdx.x * 256 + threadIdx.x;
    if (i < n) out[i] += bsums[i / SCAN_ELEMS];
}

__device__ __forceinline__ int copy_base(const unsigned int* ccnt, int cp, int seg) {
    unsigned int w = ccnt[(size_t)cp * NWORDS + (seg >> 1)];
    return (int)((w >> (16 * (seg & 1))) & 0xFFFFu);
}

__global__ void k_fill_all(const int* __restrict__ e1s, const int* __restrict__ e1d,
                           const int* __restrict__ e2s, const int* __restrict__ e2d,
                           const int* __restrict__ off, const unsigned int* __restrict__ ccnt,
                           const unsigned short* __restrict__ r1d,
                           const unsigned short* __restrict__ r1s,
                           const unsigned short* __restrict__ r2d,
                           const unsigned short* __restrict__ r2s, int* __restrict__ nbr) {
    int e = blockIdx.x * 256 + threadIdx.x;
    if (e < E1) {
        int ss = e1s[e], dd = e1d[e];
        int r = r1d[e];
        nbr[off[dd] + copy_base(ccnt, r >> 13, dd) + (r & 0x1FFF)] = ss;
        r = r1s[e];
        int seg = NL + ND + ss;
        nbr[off[seg] + copy_base(ccnt, r >> 13, seg) + (r & 0x1FFF)] = dd;
    } else if (e < E1 + E2) {
        int i = e - E1;
        int ss = e2s[i], dd = e2d[i];
        int r = r2d[i];
        int seg = NL + dd;
        nbr[off[seg] + copy_base(ccnt, r >> 13, seg) + (r & 0x1FFF)] = ss;
        r = r2s[i];
        seg = NL + ND + NP + ss;
        nbr[off[seg] + copy_base(ccnt, r >> 13, seg) + (r & 0x1FFF)] = dd;
    }
}

// ---------------- stage1 mega-kernel: dis gather | lab gather | mm_small | prep23 --------
// Block map: [0,ND): dis rows (1 block = 4 waves per row, LDS combine; longest poles first)
//            [ND, ND+NL/4): lab rows (4 waves/block, 1 row/wave)
//            [+0, +1313): mm_small 8 rows/block (lab 1250, dis 63)
//            [+0, +64): prep23
#define S1_DIS ND
#define S1_LAB (NL / 4)
#define S1_MM 1313
#define S1_PREP 64
#define S1_TOTAL (S1_DIS + S1_LAB + S1_MM + S1_PREP)

template <typename TA>
__global__ void k_stage1(const bf16* __restrict__ hp, const int* __restrict__ off,
                         const int* __restrict__ cnt, const int* __restrict__ nbr,
                         float* __restrict__ bufL, float* __restrict__ bufD,
                         const TA* __restrict__ hl, const TA* __restrict__ hd,
                         const void* __restrict__ Wl, bf16* __restrict__ tlp,
                         bf16* __restrict__ tdp, const void* __restrict__ Wr,
                         const void* __restrict__ bl, float* __restrict__ w23,
                         float* __restrict__ b23, const int* __restrict__ flags) {
    __shared__ float part[4][H];   // dis combine
    __shared__ float smm[8][H];    // mm_small staging
    int b = blockIdx.x;
    int t = threadIdx.x;
    if (b < S1_DIS) {
        // ---- disease gather: 4 waves split this row's neighbors ----
        int row = b, seg = NL + row;
        int s0 = off[seg], c = cnt[seg];
        const int* nb = nbr + s0;
        int w = t >> 6, lane = t & 63, c0 = 2 * lane;
        int j = (c * w) >> 2, jend = (c * (w + 1)) >> 2;
        float2 a[8];
#pragma unroll
        for (int u = 0; u < 8; ++u) a[u] = make_float2(0.f, 0.f);
        for (; j + 8 <= jend; j += 8) {
#pragma unroll
            for (int u = 0; u < 8; ++u) {
                float2 v = ld_bf2(hp + (size_t)nb[j + u] * H + c0);
                a[u].x += v.x;
                a[u].y += v.y;
            }
        }
        for (; j < jend; ++j) {
            float2 v = ld_bf2(hp + (size_t)nb[j] * H + c0);
            a[0].x += v.x;
            a[0].y += v.y;
        }
        part[w][c0] = ((a[0].x + a[1].x) + (a[2].x + a[3].x)) + ((a[4].x + a[5].x) + (a[6].x + a[7].x));
        part[w][c0 + 1] = ((a[0].y + a[1].y) + (a[2].y + a[3].y)) + ((a[4].y + a[5].y) + (a[6].y + a[7].y));
        __syncthreads();
        if (t < H) {
            float v = (part[0][t] + part[1][t]) + (part[2][t] + part[3][t]);
            bufD[(size_t)row * H + t] = v / fmaxf((float)c, 1.f);
        }
    } else if (b < S1_DIS + S1_LAB) {
        // ---- lab gather: one wave per row ----
        int w = t >> 6, lane = t & 63, c0 = 2 * lane;
        int row = (b - S1_DIS) * 4 + w;
        int s0 = off[row], c = cnt[row];
        const int* nb = nbr + s0;
        float2 a[8];
#pragma unroll
        for (int u = 0; u < 8; ++u) a[u] = make_float2(0.f, 0.f);
        int j = 0;
        for (; j + 8 <= c; j += 8) {
#pragma unroll
            for (int u = 0; u < 8; ++u) {
                float2 v = ld_bf2(hp + (size_t)nb[j + u] * H + c0);
                a[u].x += v.x;
                a[u].y += v.y;
            }
        }
        for (; j < c; ++j) {
            float2 v = ld_bf2(hp + (size_t)nb[j] * H + c0);
            a[0].x += v.x;
            a[0].y += v.y;
        }
        float sx = ((a[0].x + a[1].x) + (a[2].x + a[3].x)) + ((a[4].x + a[5].x) + (a[6].x + a[7].x));
        float sy = ((a[0].y + a[1].y) + (a[2].y + a[3].y)) + ((a[4].y + a[5].y) + (a[6].y + a[7].y));
        float inv = 1.f / fmaxf((float)c, 1.f);
        *(float2*)(bufL + (size_t)row * H + c0) = make_float2(sx * inv, sy * inv);
    } else if (b < S1_DIS + S1_LAB + S1_MM) {
        // ---- small transforms: tlp = hl@Wl[2], tdp = hd@Wl[3]; 8 rows/block ----
        int f32m = flags[0];
        int bb = b - (S1_DIS + S1_LAB);
        bool lab = bb < 1250;
        const TA* in = lab ? hl : hd;
        bf16* outp = lab ? tlp : tdp;
        int N = lab ? NL : ND;
        size_t woff = lab ? (size_t)2 * HH : (size_t)3 * HH;
        int r0 = (lab ? bb : bb - 1250) * 8;
        int h = t & 127, half = t >> 7;
        for (int r = half; r < 8; r += 2)
            smm[r][h] = (r0 + r < N) ? ldv(in, (size_t)(r0 + r) * H + h) : 0.f;
        __syncthreads();
        int rb = half * 4;
        float a0 = 0.f, a1 = 0.f, a2 = 0.f, a3 = 0.f;
        for (int k = 0; k < H; ++k) {
            float wv = ldin(Wl, woff + (size_t)k * H + h, f32m);
            a0 = fmaf(smm[rb + 0][k], wv, a0);
            a1 = fmaf(smm[rb + 1][k], wv, a1);
            a2 = fmaf(smm[rb + 2][k], wv, a2);
            a3 = fmaf(smm[rb + 3][k], wv, a3);
        }
        float acc[4] = {a0, a1, a2, a3};
#pragma unroll
        for (int r = 0; r < 4; ++r)
            if (r0 + rb + r < N)
                outp[(size_t)(r0 + rb + r) * H + h] = __float2bfloat16(acc[r]);
    } else {
        // ---- prep23: w23 = Wr2+Wr3, b23 = bl2+bl3 ----
        int f32m = flags[0];
        int idx = (b - (S1_DIS + S1_LAB + S1_MM)) * 256 + t;
        if (idx < HH)
            w23[idx] = ldin(Wr, (size_t)2 * HH + idx, f32m) + ldin(Wr, (size_t)3 * HH + idx, f32m);
        if (idx < H)
            b23[idx] = ldin(bl, (size_t)2 * H + idx, f32m) + ldin(bl, (size_t)3 * H + idx, f32m);
    }
}

// -------- fused patient pass: aggp = mean_lab(tlp) + mean_dis(tdp) + hp@w23 + b23 --------
__global__ void k_patient(const bf16* __restrict__ hp, const bf16* __restrict__ tlp,
                          const bf16* __restrict__ tdp, const int* __restrict__ off,
                          const int* __restrict__ cnt, const int* __restrict__ nbr,
                          const float* __restrict__ w23, const float* __restrict__ b23,
                          bf16* __restrict__ aggp) {
    int w = threadIdx.x >> 6;
    int lane = threadIdx.x & 63;
    int c0 = 2 * lane;
    int p0 = blockIdx.x * 16 + w * 4;
    const int* off1 = off + NL + ND;
    const int* cnt1 = cnt + NL + ND;
    const int* off2 = off + NL + ND + NP;
    const int* cnt2 = cnt + NL + ND + NP;
    float2 bb = *(const float2*)(b23 + c0);
    float2 acc[4];
#pragma unroll
    for (int r = 0; r < 4; ++r) {
        int p = p0 + r;
        int s1 = off1[p], c1 = cnt1[p];
        const int* nb1 = nbr + s1;
        float2 aa[4];
#pragma unroll
        for (int u = 0; u < 4; ++u) aa[u] = make_float2(0.f, 0.f);
        int j = 0;
        for (; j + 4 <= c1; j += 4) {
#pragma unroll
            for (int u = 0; u < 4; ++u) {
                float2 v = ld_bf2(tlp + (size_t)nb1[j + u] * H + c0);
                aa[u].x += v.x;
                aa[u].y += v.y;
            }
        }
        for (; j < c1; ++j) {
            float2 v = ld_bf2(tlp + (size_t)nb1[j] * H + c0);
            aa[0].x += v.x;
            aa[0].y += v.y;
        }
        float a1x = (aa[0].x + aa[1].x) + (aa[2].x + aa[3].x);
        float a1y = (aa[0].y + aa[1].y) + (aa[2].y + aa[3].y);
        int s2 = off2[p], c2 = cnt2[p];
        const int* nb2 = nbr + s2;
        float2 a2a = make_float2(0.f, 0.f), a2b = a2a;
        j = 0;
        for (; j + 2 <= c2; j += 2) {
            float2 va = ld_bf2(tdp + (size_t)nb2[j] * H + c0);
            float2 vb = ld_bf2(tdp + (size_t)nb2[j + 1] * H + c0);
            a2a.x += va.x; a2a.y += va.y;
            a2b.x += vb.x; a2b.y += vb.y;
        }
        if (j < c2) {
            float2 v = ld_bf2(tdp + (size_t)nb2[j] * H + c0);
            a2a.x += v.x;
            a2a.y += v.y;
        }
        float i1 = 1.f / fmaxf((float)c1, 1.f), i2 = 1.f / fmaxf((float)c2, 1.f);
        acc[r].x = a1x * i1 + (a2a.x + a2b.x) * i2 + bb.x;
        acc[r].y = a1y * i1 + (a2a.y + a2b.y) * i2 + bb.y;
    }
    __shared__ float rows[16][H];  // wave-private slices
#pragma unroll
    for (int r = 0; r < 4; ++r) {
        float2 v = ld_bf2(hp + (size_t)(p0 + r) * H + c0);
        rows[w * 4 + r][c0] = v.x;
        rows[w * 4 + r][c0 + 1] = v.y;
    }
    for (int k = 0; k < H; ++k) {
        float2 wv = *(const float2*)(w23 + (size_t)k * H + c0);
#pragma unroll
        for (int r = 0; r < 4; ++r) {
            float x = rows[w * 4 + r][k];
            acc[r].x = fmaf(x, wv.x, acc[r].x);
            acc[r].y = fmaf(x, wv.y, acc[r].y);
        }
    }
#pragma unroll
    for (int r = 0; r < 4; ++r)
        st_bf2(aggp + (size_t)(p0 + r) * H + c0, acc[r]);
}

// -------- fused lab/dis second stage (in-place): buf = buf@Wl + bl + hX@Wr --------
template <typename TA>
__global__ void k_mm_labdis(float* __restrict__ bufL, float* __restrict__ bufD,
                            const TA* __restrict__ hl, const TA* __restrict__ hd,
                            const void* __restrict__ Wl, const void* __restrict__ bl,
                            const void* __restrict__ Wr, const int* __restrict__ flags) {
    int f32m = flags[0];
    bool lab = blockIdx.x < NL / 4;
    float* buf = lab ? bufL : bufD;
    const TA* hx = lab ? hl : hd;
    size_t woff = lab ? 0 : (size_t)HH;
    size_t boff = lab ? 0 : (size_t)H;
    int r0 = (lab ? blockIdx.x : blockIdx.x - NL / 4) * 4;
    __shared__ float sB[4][H], sH[4][H];
    int h = threadIdx.x;
#pragma unroll
    for (int r = 0; r < 4; ++r) {
        sB[r][h] = buf[(size_t)(r0 + r) * H + h];
        sH[r][h] = ldv(hx, (size_t)(r0 + r) * H + h);
    }
    __syncthreads();
    float a0 = ldin(bl, boff + h, f32m);
    float a1 = a0, a2 = a0, a3 = a0;
    for (int k = 0; k < H; ++k) {
        float w = ldin(Wl, woff + (size_t)k * H + h, f32m);
        a0 = fmaf(sB[0][k], w, a0);
        a1 = fmaf(sB[1][k], w, a1);
        a2 = fmaf(sB[2][k], w, a2);
        a3 = fmaf(sB[3][k], w, a3);
    }
    for (int k = 0; k < H; ++k) {
        float w = ldin(Wr, woff + (size_t)k * H + h, f32m);
        a0 = fmaf(sH[0][k], w, a0);
        a1 = fmaf(sH[1][k], w, a1);
        a2 = fmaf(sH[2][k], w, a2);
        a3 = fmaf(sH[3][k], w, a3);
    }
    buf[(size_t)(r0 + 0) * H + h] = a0;
    buf[(size_t)(r0 + 1) * H + h] = a1;
    buf[(size_t)(r0 + 2) * H + h] = a2;
    buf[(size_t)(r0 + 3) * H + h] = a3;
}

// ---------------- merged BatchNorm stats: [0,1024) pat | [1024,1280) lab | [1280,1344) dis
__global__ void k_bn_stats(const bf16* __restrict__ aggp, const float* __restrict__ bufL,
                           const float* __restrict__ bufD, float* __restrict__ sums) {
    int h = threadIdx.x & 127;
    int sub = threadIdx.x >> 7;
    float s = 0.f, s2 = 0.f;
    float* sm;
    if (blockIdx.x < 1024) {
        for (int i = blockIdx.x * 2 + sub; i < NP; i += 2048) {
            float v = __bfloat162float(aggp[(size_t)i * H + h]);
            s += v;
            s2 = fmaf(v, v, s2);
        }
        sm = sums;
    } else if (blockIdx.x < 1280) {
        int bid = blockIdx.x - 1024;
        for (int i = bid * 2 + sub; i < NL; i += 512) {
            float v = bufL[(size_t)i * H + h];
            s += v;
            s2 = fmaf(v, v, s2);
        }
        sm = sums + 2 * H;
    } else {
        int bid = blockIdx.x - 1280;
        for (int i = bid * 2 + sub; i < ND; i += 128) {
            float v = bufD[(size_t)i * H + h];
            s += v;
            s2 = fmaf(v, v, s2);
        }
        sm = sums + 4 * H;
    }
    __shared__ float ls[256], ls2[256];
    ls[threadIdx.x] = s;
    ls2[threadIdx.x] = s2;
    __syncthreads();
    if (sub == 0) {
        atomicAdd(&sm[h], s + ls[128 + h]);
        atomicAdd(&sm[H + h], s2 + ls2[128 + h]);
    }
}

// ---------------- merged BatchNorm apply + relu ----------------
template <typename TA>
__global__ void k_bn_apply(const bf16* __restrict__ aggp, const float* __restrict__ bufL,
                           const float* __restrict__ bufD, bf16* __restrict__ hp,
                           TA* __restrict__ hl, TA* __restrict__ hd,
                           const float* __restrict__ sums, const void* __restrict__ g,
                           const void* __restrict__ b, const int* __restrict__ flags) {
    int f32m = flags[0];
    size_t idx = (size_t)blockIdx.x * 256 + threadIdx.x;
    int h = (int)(idx & 127);
    if (idx < (size_t)NP * H) {
        const float invN = 1.f / NP;
        float m = sums[h] * invN;
        float v = fmaf(-m, m, sums[H + h] * invN);
        float sc = rsqrtf(v + 1e-5f) * ldin(g, h, f32m);
        float r = fmaf(__bfloat162float(aggp[idx]) - m, sc, ldin(b, h, f32m));
        hp[idx] = __float2bfloat16(fmaxf(r, 0.f));
    } else if (idx < (size_t)(NP + NL) * H) {
        size_t j = idx - (size_t)NP * H;
        const float invN = 1.f / NL;
        float m = sums[2 * H + h] * invN;
        float v = fmaf(-m, m, sums[3 * H + h] * invN);
        float sc = rsqrtf(v + 1e-5f) * ldin(g, H + h, f32m);
        float r = fmaf(bufL[j] - m, sc, ldin(b, H + h, f32m));
        stv(hl, j, fmaxf(r, 0.f));
    } else if (idx < (size_t)(NP + NL + ND) * H) {
        size_t j = idx - (size_t)(NP + NL) * H;
        const float invN = 1.f / ND;
        float m = sums[4 * H + h] * invN;
        float v = fmaf(-m, m, sums[5 * H + h] * invN);
        float sc = rsqrtf(v + 1e-5f) * ldin(g, 2 * H + h, f32m);
        float r = fmaf(bufD[j] - m, sc, ldin(b, 2 * H + h, f32m));
        stv(hd, j, fmaxf(r, 0.f));
    }
}

// ---------------- head: 16 patients/block, weights staged in LDS as f32 ----------------
__global__ void k_head(const bf16* __restrict__ hp, const void* __restrict__ W1,
                       const void* __restrict__ b1, const void* __restrict__ W2,
                       const void* __restrict__ b2, void* __restrict__ out,
                       const int* __restrict__ flags) {
    int f32m = flags[0];
    __shared__ float W1s[H * 64];
    __shared__ float W2s[64 * NOUT];
    __shared__ float b1s[64], b2s[NOUT];
    __shared__ float rows[16][H];
    __shared__ float h1s[16][65];
    __shared__ float lgs[16][16];
    int t = threadIdx.x;
    for (int i = t; i < H * 64; i += 256) W1s[i] = ldin(W1, i, f32m);
    for (int i = t; i < 64 * NOUT; i += 256) W2s[i] = ldin(W2, i, f32m);
    if (t < 64) b1s[t] = ldin(b1, t, f32m);
    else if (t >= 64 && t < 64 + NOUT) b2s[t - 64] = ldin(b2, t - 64, f32m);
    int p0 = blockIdx.x * 16;
    for (int i = t; i < 16 * 64; i += 256) {
        int r = i >> 6, c2 = (i & 63) * 2;
        float2 v = ld_bf2(hp + (size_t)(p0 + r) * H + c2);
        rows[r][c2] = v.x;
        rows[r][c2 + 1] = v.y;
    }
    __syncthreads();
    int w = t >> 6, lane = t & 63;
    const float* r0 = rows[4 * w + 0];
    const float* r1 = rows[4 * w + 1];
    const float* r2 = rows[4 * w + 2];
    const float* r3 = rows[4 * w + 3];
    float a0 = b1s[lane], a1 = a0, a2 = a0, a3 = a0;
#pragma unroll 4
    for (int k = 0; k < H; ++k) {
        float wv = W1s[k * 64 + lane];
        a0 = fmaf(r0[k], wv, a0);
        a1 = fmaf(r1[k], wv, a1);
        a2 = fmaf(r2[k], wv, a2);
        a3 = fmaf(r3[k], wv, a3);
    }
    h1s[4 * w + 0][lane] = fmaxf(a0, 0.f);
    h1s[4 * w + 1][lane] = fmaxf(a1, 0.f);
    h1s[4 * w + 2][lane] = fmaxf(a2, 0.f);
    h1s[4 * w + 3][lane] = fmaxf(a3, 0.f);
    __syncthreads();
    int pat = lane >> 4, oidx = lane & 15;
    int prow = 4 * w + pat;
    float lg = 0.f;
    if (oidx < NOUT) {
        lg = b2s[oidx];
        const float* hh = h1s[prow];
#pragma unroll 8
        for (int k = 0; k < 64; ++k) lg = fmaf(hh[k], W2s[k * NOUT + oidx], lg);
        lgs[prow][oidx] = lg;
    }
    __syncthreads();
    if (oidx < NOUT) {
        float m = -1e30f;
#pragma unroll
        for (int k = 0; k < NOUT; ++k) m = fmaxf(m, lgs[prow][k]);
        float s = 0.f;
#pragma unroll
        for (int k = 0; k < NOUT; ++k) s += __expf(lgs[prow][k] - m);
        float r = lg - m - __logf(s);
        if (f32m)
            ((float*)out)[(size_t)(p0 + prow) * NOUT + oidx] = r;
        else
            ((bf16*)out)[(size_t)(p0 + prow) * NOUT + oidx] = __float2bfloat16(r);
    }
}

// ---------------- one hetero layer ----------------
template <typename TA>
static void run_layer(const void* Wl, const void* bl, const void* Wr, const void* bng,
                      const void* bnb, bf16* hp, TA* hl, TA* hd, bf16* aggp, float* bufL,
                      float* bufD, bf16* tlp, bf16* tdp, const int* cnt, const int* off,
                      const int* nbr, float* w23, float* b23, float* bns, const int* flags,
                      hipStream_t stream) {
    k_stage1<TA><<<S1_TOTAL, 256, 0, stream>>>(hp, off, cnt, nbr, bufL, bufD, hl, hd, Wl, tlp,
                                               tdp, Wr, bl, w23, b23, flags);
    k_patient<<<NP / 16, 256, 0, stream>>>(hp, tlp, tdp, off, cnt, nbr, w23, b23, aggp);
    k_mm_labdis<TA><<<NL / 4 + ND / 4, 128, 0, stream>>>(bufL, bufD, hl, hd, Wl, bl, Wr, flags);
    hipMemsetAsync(bns, 0, 6 * H * 4, stream);
    k_bn_stats<<<1344, 256, 0, stream>>>(aggp, bufL, bufD, bns);
    k_bn_apply<TA><<<(int)(((size_t)(NP + NL + ND) * H + 255) / 256), 256, 0, stream>>>(
        aggp, bufL, bufD, hp, hl, hd, bns, bng, bnb, flags);
}

template <typename TA>
static void run_all(void* const* d_in, void* d_out, void* d_ws, hipStream_t stream) {
    const int* e1s = (const int*)d_in[23];
    const int* e1d = (const int*)d_in[24];
    const int* e2s = (const int*)d_in[25];
    const int* e2d = (const int*)d_in[26];

    const int NPOOL = 2 * (E1 + E2);  // 5000000

    char* wsb = (char*)d_ws;
    size_t o = 0;
    auto af = [&](size_t nwords) { void* p = wsb + o * 4; o += nwords; return p; };
    int* flags = (int*)af(16);
    float* w23 = (float*)af(HH);
    float* b23 = (float*)af(H);
    float* bns = (float*)af(6 * H);
    int* bsums = (int*)af(256);
    int* cnt = (int*)af(NCNT);
    int* off = (int*)af(NCNT);
    unsigned int* ccnt = (unsigned int*)af((size_t)NCOPY * NWORDS);
    unsigned short* r1d = (unsigned short*)af(E1 / 2);
    unsigned short* r1s = (unsigned short*)af(E1 / 2);
    unsigned short* r2d = (unsigned short*)af(E2 / 2);
    unsigned short* r2s = (unsigned short*)af(E2 / 2);
    int* nbr = (int*)af(NPOOL);
    float* bufL = (float*)af((size_t)NL * H);
    float* bufD = (float*)af((size_t)ND * H);
    bf16* tlp = (bf16*)af((size_t)NL * H / 2);
    bf16* tdp = (bf16*)af((size_t)ND * H / 2);
    bf16* hp = (bf16*)af((size_t)NP * H / 2);
    bf16* aggp = (bf16*)af((size_t)NP * H / 2);
    TA* hl = (TA*)af((size_t)NL * H * sizeof(TA) / 4);
    TA* hd = (TA*)af((size_t)ND * H * sizeof(TA) / 4);

    k_detect<<<1, 256, 0, stream>>>((const unsigned short*)d_in[0], flags);

    // CSR build (once; reused by both layers)
    hipMemsetAsync(ccnt, 0, (size_t)NCOPY * NWORDS * 4, stream);
    k_count_all<<<(E1 + E2 + 255) / 256, 256, 0, stream>>>(e1s, e1d, e2s, e2d, ccnt, r1d, r1s,
                                                           r2d, r2s);
    k_reduce_copies<<<(NWORDS + 255) / 256, 256, 0, stream>>>(ccnt, cnt);
    int nb = (NCNT + SCAN_ELEMS - 1) / SCAN_ELEMS;
    k_scan1<<<nb, 256, 0, stream>>>(cnt, off, bsums, NCNT);
    k_scan2<<<1, 256, 0, stream>>>(bsums, nb);
    k_scan3<<<(NCNT + 255) / 256, 256, 0, stream>>>(off, bsums, NCNT);
    k_fill_all<<<(E1 + E2 + 255) / 256, 256, 0, stream>>>(e1s, e1d, e2s, e2d, off, ccnt, r1d,
                                                          r1s, r2d, r2s, nbr);

    k_embed_all<TA><<<((NP + NL + ND) * H + 255) / 256, 256, 0, stream>>>(
        d_in[0], d_in[1], d_in[2], d_in[3], d_in[4], d_in[5], d_in[6], d_in[7], d_in[8], hp, hl,
        hd, flags);

    run_layer<TA>(d_in[9], d_in[10], d_in[11], d_in[15], d_in[16], hp, hl, hd, aggp, bufL, bufD,
                  tlp, tdp, cnt, off, nbr, w23, b23, bns, flags, stream);
    run_layer<TA>(d_in[12], d_in[13], d_in[14], d_in[17], d_in[18], hp, hl, hd, aggp, bufL, bufD,
                  tlp, tdp, cnt, off, nbr, w23, b23, bns, flags, stream);

    k_head<<<NP / 16, 256, 0, stream>>>(hp, d_in[19], d_in[20], d_in[21], d_in[22], d_out, flags);
}

extern "C" void kernel_launch(void* const* d_in, const int* in_sizes, int n_in, void* d_out,
                              int out_size, void* d_ws, size_t ws_size, hipStream_t stream) {
    const size_t NPOOL = 2 * ((size_t)E1 + E2);
    const size_t fixed_words = 16 + HH + H + 6 * H + 256 + 2 * (size_t)NCNT +
                               (size_t)NCOPY * NWORDS + ((size_t)E1 + E2) + NPOOL +
                               (size_t)NL * H + (size_t)ND * H + (size_t)NL * H / 2 +
                               (size_t)ND * H / 2 + (size_t)NP * H / 2 + (size_t)NP * H / 2;
    const size_t ta_elems = (size_t)(NL + ND) * H;
    const size_t need_f32 = fixed_words * 4 + ta_elems * 4;  // ~100 MiB
    if (ws_size >= need_f32)
        run_all<float>(d_in, d_out, d_ws, stream);
    else
        run_all<bf16>(d_in, d_out, d_ws, stream);  // ~97 MiB
}

// Round 11
// 1366.821 us; speedup vs baseline: 4.9241x; 1.0478x over previous
//
#include <hip/hip_runtime.h>
#include <hip/hip_bf16.h>

#define NP 100000
#define NL 10000
#define ND 500
#define H 128
#define HH (H * H)
#define E1 2000000
#define E2 500000
#define NOUT 10
#define NCOPY 16                  // count replicas; blockIdx%16 ~ 2 per XCD
#define NCNT (NL + ND + 2 * NP)   // 210500 segments: [lab NL][dis ND][p1 NP][p2 NP]
#define CNT_BLOCKS ((E1 + E2 + 255) / 256)            // 9766
#define EMB_BLOCKS (((NP + NL + ND) * H + 255) / 256) // 55250

typedef __hip_bfloat16 bf16;

__device__ __forceinline__ float ldv(const float* p, size_t i) { return p[i]; }
__device__ __forceinline__ float ldv(const bf16* p, size_t i) { return __bfloat162float(p[i]); }
__device__ __forceinline__ void stv(float* p, size_t i, float v) { p[i] = v; }
__device__ __forceinline__ void stv(bf16* p, size_t i, float v) { p[i] = __float2bfloat16(v); }

__device__ __forceinline__ float bfbits2f(unsigned short s) {
    union { unsigned int u; float f; } v;
    v.u = (unsigned int)s << 16;
    return v.f;
}
__device__ __forceinline__ float2 ld_bf2(const bf16* p) {
    unsigned int u = *(const unsigned int*)p;
    return make_float2(bfbits2f((unsigned short)(u & 0xFFFFu)), bfbits2f((unsigned short)(u >> 16)));
}
__device__ __forceinline__ void st_bf2(bf16* p, float2 v) {
    union { unsigned int u; bf16 b[2]; } t;
    t.b[0] = __float2bfloat16(v.x);
    t.b[1] = __float2bfloat16(v.y);
    *(unsigned int*)p = t.u;
}
__device__ __forceinline__ float ldin(const void* p, size_t i, int f32m) {
    return f32m ? ((const float*)p)[i] : __bfloat162float(((const bf16*)p)[i]);
}

// ---------------- input dtype detection (measured: picks bf16 on this harness) ----------
__global__ void k_detect(const unsigned short* __restrict__ xp, int* __restrict__ flags) {
    int t = threadIdx.x;
    int cnt = 0;
    for (int i = t; i < 4096; i += 256) {
        unsigned short w = xp[2 * i];
        int e = (w >> 7) & 0xFF;
        if (w == 0 || (e >= 114 && e <= 141)) cnt++;
    }
    __shared__ int sh[256];
    sh[t] = cnt;
    __syncthreads();
    for (int s = 128; s > 0; s >>= 1) {
        if (t < s) sh[t] += sh[t + s];
        __syncthreads();
    }
    if (t == 0) flags[0] = (sh[0] < 2048) ? 1 : 0;  // 1 = f32 inputs
}

// -------- merged count (XCD-privatized u32 bins, rank=copy<<12|local) + embeddings ------
// count is atomic-bound with ~0.5% VALU; embed blocks ride free in the same launch.
template <typename TA>
__global__ void k_count_embed(const int* __restrict__ e1s, const int* __restrict__ e1d,
                              const int* __restrict__ e2s, const int* __restrict__ e2d,
                              unsigned int* __restrict__ ccnt, unsigned short* __restrict__ r1d,
                              unsigned short* __restrict__ r1s, unsigned short* __restrict__ r2d,
                              unsigned short* __restrict__ r2s, const void* __restrict__ xp,
                              const void* __restrict__ xl, const void* __restrict__ xd,
                              const void* __restrict__ Wp, const void* __restrict__ bp,
                              const void* __restrict__ Wlab, const void* __restrict__ blab,
                              const void* __restrict__ Wdis, const void* __restrict__ bdis,
                              bf16* __restrict__ hp, TA* __restrict__ hl, TA* __restrict__ hd,
                              const int* __restrict__ flags) {
    int b = blockIdx.x, t = threadIdx.x;
    if (b < CNT_BLOCKS) {
        int copy = b & (NCOPY - 1);
        unsigned int* c = ccnt + (size_t)copy * NCNT;
        unsigned int tag = (unsigned int)copy << 12;
        int e = b * 256 + t;
        if (e < E1) {
            unsigned int o1 = atomicAdd(&c[e1d[e]], 1u);
            r1d[e] = (unsigned short)(tag | (o1 & 0xFFFu));
            unsigned int o2 = atomicAdd(&c[NL + ND + e1s[e]], 1u);
            r1s[e] = (unsigned short)(tag | (o2 & 0xFFFu));
        } else if (e < E1 + E2) {
            int i = e - E1;
            unsigned int o1 = atomicAdd(&c[NL + e2d[i]], 1u);
            r2d[i] = (unsigned short)(tag | (o1 & 0xFFFu));
            unsigned int o2 = atomicAdd(&c[NL + ND + NP + e2s[i]], 1u);
            r2s[i] = (unsigned short)(tag | (o2 & 0xFFFu));
        }
    } else {
        int f32m = flags[0];
        int idx = (b - CNT_BLOCKS) * 256 + t;
        int h = idx & 127;
        if (idx < NP * H) {
            int i = idx >> 7;
            float acc = ldin(bp, h, f32m);
#pragma unroll
            for (int k = 0; k < 16; ++k)
                acc = fmaf(ldin(xp, (size_t)i * 16 + k, f32m), ldin(Wp, (size_t)k * H + h, f32m), acc);
            hp[idx] = __float2bfloat16(acc);
        } else if (idx < (NP + NL) * H) {
            int i = (idx - NP * H) >> 7;
            float acc = fmaf(ldin(xl, i, f32m), ldin(Wlab, h, f32m), ldin(blab, h, f32m));
            stv(hl, (size_t)i * H + h, acc);
        } else if (idx < (NP + NL + ND) * H) {
            int i = (idx - (NP + NL) * H) >> 7;
            float acc = ldin(bdis, h, f32m);
            acc = fmaf(ldin(xd, (size_t)i * 2 + 0, f32m), ldin(Wdis, h, f32m), acc);
            acc = fmaf(ldin(xd, (size_t)i * 2 + 1, f32m), ldin(Wdis, H + h, f32m), acc);
            stv(hd, (size_t)i * H + h, acc);
        }
    }
}

// -------- scan1 fused with copy-reduce: per-copy exclusive bases back into ccnt ----------
#define SCAN_ELEMS 2048
__global__ void k_scan1r(unsigned int* __restrict__ ccnt, int* __restrict__ cnt,
                         int* __restrict__ out, int* __restrict__ bsums) {
    int t = threadIdx.x;
    int base = blockIdx.x * SCAN_ELEMS + t * 8;
    int v[8], tsum = 0;
#pragma unroll
    for (int j = 0; j < 8; ++j) {
        int i = base + j;
        int tot = 0;
        if (i < NCNT) {
            unsigned int run = 0;
#pragma unroll
            for (int k = 0; k < NCOPY; ++k) {
                unsigned int x = ccnt[(size_t)k * NCNT + i];
                ccnt[(size_t)k * NCNT + i] = run;
                run += x;
            }
            tot = (int)run;
            cnt[i] = tot;
        }
        v[j] = tot;
        tsum += tot;
    }
    __shared__ int sh[256];
    sh[t] = tsum;
    __syncthreads();
    for (int d = 1; d < 256; d <<= 1) {
        int x = (t >= d) ? sh[t - d] : 0;
        __syncthreads();
        sh[t] += x;
        __syncthreads();
    }
    int run2 = sh[t] - tsum;
    if (t == 255) bsums[blockIdx.x] = sh[255];
#pragma unroll
    for (int j = 0; j < 8; ++j) {
        if (base + j < NCNT) out[base + j] = run2;
        run2 += v[j];
    }
}

__global__ void k_scan2(int* __restrict__ bsums, int nb) {
    int t = threadIdx.x;
    int v = (t < nb) ? bsums[t] : 0;
    __shared__ int sh[256];
    sh[t] = v;
    __syncthreads();
    for (int d = 1; d < 256; d <<= 1) {
        int x = (t >= d) ? sh[t - d] : 0;
        __syncthreads();
        sh[t] += x;
        __syncthreads();
    }
    if (t < nb) bsums[t] = sh[t] - v;
}

__global__ void k_scan3(int* __restrict__ out, const int* __restrict__ bsums, int n) {
    int i = blockIdx.x * 256 + threadIdx.x;
    if (i < n) out[i] += bsums[i / SCAN_ELEMS];
}

// atomic-free fill: slot = off[seg] + copy_base(ccnt) + local_rank
__global__ void k_fill_all(const int* __restrict__ e1s, const int* __restrict__ e1d,
                           const int* __restrict__ e2s, const int* __restrict__ e2d,
                           const int* __restrict__ off, const unsigned int* __restrict__ ccnt,
                           const unsigned short* __restrict__ r1d,
                           const unsigned short* __restrict__ r1s,
                           const unsigned short* __restrict__ r2d,
                           const unsigned short* __restrict__ r2s, int* __restrict__ nbr) {
    int e = blockIdx.x * 256 + threadIdx.x;
    if (e < E1) {
        int ss = e1s[e], dd = e1d[e];
        int r = r1d[e];
        nbr[off[dd] + (int)ccnt[(size_t)(r >> 12) * NCNT + dd] + (r & 0xFFF)] = ss;
        r = r1s[e];
        int seg = NL + ND + ss;
        nbr[off[seg] + (int)ccnt[(size_t)(r >> 12) * NCNT + seg] + (r & 0xFFF)] = dd;
    } else if (e < E1 + E2) {
        int i = e - E1;
        int ss = e2s[i], dd = e2d[i];
        int r = r2d[i];
        int seg = NL + dd;
        nbr[off[seg] + (int)ccnt[(size_t)(r >> 12) * NCNT + seg] + (r & 0xFFF)] = ss;
        r = r2s[i];
        seg = NL + ND + NP + ss;
        nbr[off[seg] + (int)ccnt[(size_t)(r >> 12) * NCNT + seg] + (r & 0xFFF)] = dd;
    }
}

// ---------------- stage1 mega-kernel: dis gather | lab gather | mm_small | prep23 --------
#define S1_DIS ND
#define S1_LAB (NL / 4)
#define S1_MM 1313
#define S1_PREP 64
#define S1_TOTAL (S1_DIS + S1_LAB + S1_MM + S1_PREP)

template <typename TA>
__global__ void k_stage1(const bf16* __restrict__ hp, const int* __restrict__ off,
                         const int* __restrict__ cnt, const int* __restrict__ nbr,
                         float* __restrict__ bufL, float* __restrict__ bufD,
                         const TA* __restrict__ hl, const TA* __restrict__ hd,
                         const void* __restrict__ Wl, bf16* __restrict__ tlp,
                         bf16* __restrict__ tdp, const void* __restrict__ Wr,
                         const void* __restrict__ bl, float* __restrict__ w23,
                         float* __restrict__ b23, const int* __restrict__ flags) {
    __shared__ float part[4][H];
    __shared__ float smm[8][H];
    int b = blockIdx.x;
    int t = threadIdx.x;
    if (b < S1_DIS) {
        int row = b, seg = NL + row;
        int s0 = off[seg], c = cnt[seg];
        const int* nb = nbr + s0;
        int w = t >> 6, lane = t & 63, c0 = 2 * lane;
        int j = (c * w) >> 2, jend = (c * (w + 1)) >> 2;
        float2 a[8];
#pragma unroll
        for (int u = 0; u < 8; ++u) a[u] = make_float2(0.f, 0.f);
        for (; j + 8 <= jend; j += 8) {
#pragma unroll
            for (int u = 0; u < 8; ++u) {
                float2 v = ld_bf2(hp + (size_t)nb[j + u] * H + c0);
                a[u].x += v.x;
                a[u].y += v.y;
            }
        }
        for (; j < jend; ++j) {
            float2 v = ld_bf2(hp + (size_t)nb[j] * H + c0);
            a[0].x += v.x;
            a[0].y += v.y;
        }
        part[w][c0] = ((a[0].x + a[1].x) + (a[2].x + a[3].x)) + ((a[4].x + a[5].x) + (a[6].x + a[7].x));
        part[w][c0 + 1] = ((a[0].y + a[1].y) + (a[2].y + a[3].y)) + ((a[4].y + a[5].y) + (a[6].y + a[7].y));
        __syncthreads();
        if (t < H) {
            float v = (part[0][t] + part[1][t]) + (part[2][t] + part[3][t]);
            bufD[(size_t)row * H + t] = v / fmaxf((float)c, 1.f);
        }
    } else if (b < S1_DIS + S1_LAB) {
        int w = t >> 6, lane = t & 63, c0 = 2 * lane;
        int row = (b - S1_DIS) * 4 + w;
        int s0 = off[row], c = cnt[row];
        const int* nb = nbr + s0;
        float2 a[8];
#pragma unroll
        for (int u = 0; u < 8; ++u) a[u] = make_float2(0.f, 0.f);
        int j = 0;
        for (; j + 8 <= c; j += 8) {
#pragma unroll
            for (int u = 0; u < 8; ++u) {
                float2 v = ld_bf2(hp + (size_t)nb[j + u] * H + c0);
                a[u].x += v.x;
                a[u].y += v.y;
            }
        }
        for (; j < c; ++j) {
            float2 v = ld_bf2(hp + (size_t)nb[j] * H + c0);
            a[0].x += v.x;
            a[0].y += v.y;
        }
        float sx = ((a[0].x + a[1].x) + (a[2].x + a[3].x)) + ((a[4].x + a[5].x) + (a[6].x + a[7].x));
        float sy = ((a[0].y + a[1].y) + (a[2].y + a[3].y)) + ((a[4].y + a[5].y) + (a[6].y + a[7].y));
        float inv = 1.f / fmaxf((float)c, 1.f);
        *(float2*)(bufL + (size_t)row * H + c0) = make_float2(sx * inv, sy * inv);
    } else if (b < S1_DIS + S1_LAB + S1_MM) {
        int f32m = flags[0];
        int bb = b - (S1_DIS + S1_LAB);
        bool lab = bb < 1250;
        const TA* in = lab ? hl : hd;
        bf16* outp = lab ? tlp : tdp;
        int N = lab ? NL : ND;
        size_t woff = lab ? (size_t)2 * HH : (size_t)3 * HH;
        int r0 = (lab ? bb : bb - 1250) * 8;
        int h = t & 127, half = t >> 7;
        for (int r = half; r < 8; r += 2)
            smm[r][h] = (r0 + r < N) ? ldv(in, (size_t)(r0 + r) * H + h) : 0.f;
        __syncthreads();
        int rb = half * 4;
        float a0 = 0.f, a1 = 0.f, a2 = 0.f, a3 = 0.f;
        for (int k = 0; k < H; ++k) {
            float wv = ldin(Wl, woff + (size_t)k * H + h, f32m);
            a0 = fmaf(smm[rb + 0][k], wv, a0);
            a1 = fmaf(smm[rb + 1][k], wv, a1);
            a2 = fmaf(smm[rb + 2][k], wv, a2);
            a3 = fmaf(smm[rb + 3][k], wv, a3);
        }
        float acc[4] = {a0, a1, a2, a3};
#pragma unroll
        for (int r = 0; r < 4; ++r)
            if (r0 + rb + r < N)
                outp[(size_t)(r0 + rb + r) * H + h] = __float2bfloat16(acc[r]);
    } else {
        int f32m = flags[0];
        int idx = (b - (S1_DIS + S1_LAB + S1_MM)) * 256 + t;
        if (idx < HH)
            w23[idx] = ldin(Wr, (size_t)2 * HH + idx, f32m) + ldin(Wr, (size_t)3 * HH + idx, f32m);
        if (idx < H)
            b23[idx] = ldin(bl, (size_t)2 * H + idx, f32m) + ldin(bl, (size_t)3 * H + idx, f32m);
    }
}

// -------- merged: patient pass | lab/dis second stage | bns zeroing ----------------------
#define PAT_BLOCKS (NP / 16)       // 6250
#define MML_LAB (NL / 8)           // 1250
#define MML_DIS ((ND + 7) / 8)     // 63
#define PATMM_TOTAL (PAT_BLOCKS + MML_LAB + MML_DIS)

template <typename TA>
__global__ void k_patmm(const bf16* __restrict__ hp, const bf16* __restrict__ tlp,
                        const bf16* __restrict__ tdp, const int* __restrict__ off,
                        const int* __restrict__ cnt, const int* __restrict__ nbr,
                        const float* __restrict__ w23, const float* __restrict__ b23,
                        bf16* __restrict__ aggp, float* __restrict__ bufL,
                        float* __restrict__ bufD, const TA* __restrict__ hl,
                        const TA* __restrict__ hd, const void* __restrict__ Wl,
                        const void* __restrict__ bl, const void* __restrict__ Wr,
                        float* __restrict__ bns, const int* __restrict__ flags) {
    __shared__ float sh[16][H];  // patient: rows[16]; mm: sB=sh[0..7], sH=sh[8..15]
    int t = threadIdx.x;
    if (blockIdx.x < PAT_BLOCKS) {
        int w = t >> 6, lane = t & 63, c0 = 2 * lane;
        int p0 = blockIdx.x * 16 + w * 4;
        const int* off1 = off + NL + ND;
        const int* cnt1 = cnt + NL + ND;
        const int* off2 = off + NL + ND + NP;
        const int* cnt2 = cnt + NL + ND + NP;
        float2 bb = *(const float2*)(b23 + c0);
        float2 acc[4];
#pragma unroll
        for (int r = 0; r < 4; ++r) {
            int p = p0 + r;
            int s1 = off1[p], c1 = cnt1[p];
            const int* nb1 = nbr + s1;
            float2 aa[4];
#pragma unroll
            for (int u = 0; u < 4; ++u) aa[u] = make_float2(0.f, 0.f);
            int j = 0;
            for (; j + 4 <= c1; j += 4) {
#pragma unroll
                for (int u = 0; u < 4; ++u) {
                    float2 v = ld_bf2(tlp + (size_t)nb1[j + u] * H + c0);
                    aa[u].x += v.x;
                    aa[u].y += v.y;
                }
            }
            for (; j < c1; ++j) {
                float2 v = ld_bf2(tlp + (size_t)nb1[j] * H + c0);
                aa[0].x += v.x;
                aa[0].y += v.y;
            }
            float a1x = (aa[0].x + aa[1].x) + (aa[2].x + aa[3].x);
            float a1y = (aa[0].y + aa[1].y) + (aa[2].y + aa[3].y);
            int s2 = off2[p], c2 = cnt2[p];
            const int* nb2 = nbr + s2;
            float2 a2a = make_float2(0.f, 0.f), a2b = a2a;
            j = 0;
            for (; j + 2 <= c2; j += 2) {
                float2 va = ld_bf2(tdp + (size_t)nb2[j] * H + c0);
                float2 vb = ld_bf2(tdp + (size_t)nb2[j + 1] * H + c0);
                a2a.x += va.x; a2a.y += va.y;
                a2b.x += vb.x; a2b.y += vb.y;
            }
            if (j < c2) {
                float2 v = ld_bf2(tdp + (size_t)nb2[j] * H + c0);
                a2a.x += v.x;
                a2a.y += v.y;
            }
            float i1 = 1.f / fmaxf((float)c1, 1.f), i2 = 1.f / fmaxf((float)c2, 1.f);
            acc[r].x = a1x * i1 + (a2a.x + a2b.x) * i2 + bb.x;
            acc[r].y = a1y * i1 + (a2a.y + a2b.y) * i2 + bb.y;
        }
#pragma unroll
        for (int r = 0; r < 4; ++r) {
            float2 v = ld_bf2(hp + (size_t)(p0 + r) * H + c0);
            sh[w * 4 + r][c0] = v.x;
            sh[w * 4 + r][c0 + 1] = v.y;
        }
        for (int k = 0; k < H; ++k) {
            float2 wv = *(const float2*)(w23 + (size_t)k * H + c0);
#pragma unroll
            for (int r = 0; r < 4; ++r) {
                float x = sh[w * 4 + r][k];
                acc[r].x = fmaf(x, wv.x, acc[r].x);
                acc[r].y = fmaf(x, wv.y, acc[r].y);
            }
        }
#pragma unroll
        for (int r = 0; r < 4; ++r)
            st_bf2(aggp + (size_t)(p0 + r) * H + c0, acc[r]);
    } else {
        int bb = blockIdx.x - PAT_BLOCKS;
        if (bb == 0)
            for (int i = t; i < 6 * H; i += 256) bns[i] = 0.f;  // zero for next bn_stats
        int f32m = flags[0];
        bool lab = bb < MML_LAB;
        float* buf = lab ? bufL : bufD;
        const TA* hx = lab ? hl : hd;
        size_t woff = lab ? 0 : (size_t)HH;
        size_t boff = lab ? 0 : (size_t)H;
        int N = lab ? NL : ND;
        int r0 = (lab ? bb : bb - MML_LAB) * 8;
        int h = t & 127, half = t >> 7;
        for (int r = half; r < 8; r += 2) {
            int ri = r0 + r;
            sh[r][h] = (ri < N) ? buf[(size_t)ri * H + h] : 0.f;
            sh[8 + r][h] = (ri < N) ? ldv(hx, (size_t)ri * H + h) : 0.f;
        }
        __syncthreads();
        int rb = half * 4;
        float bv = ldin(bl, boff + h, f32m);
        float a0 = bv, a1 = bv, a2 = bv, a3 = bv;
        for (int k = 0; k < H; ++k) {
            float wl = ldin(Wl, woff + (size_t)k * H + h, f32m);
            a0 = fmaf(sh[rb + 0][k], wl, a0);
            a1 = fmaf(sh[rb + 1][k], wl, a1);
            a2 = fmaf(sh[rb + 2][k], wl, a2);
            a3 = fmaf(sh[rb + 3][k], wl, a3);
        }
        for (int k = 0; k < H; ++k) {
            float wr = ldin(Wr, woff + (size_t)k * H + h, f32m);
            a0 = fmaf(sh[8 + rb + 0][k], wr, a0);
            a1 = fmaf(sh[8 + rb + 1][k], wr, a1);
            a2 = fmaf(sh[8 + rb + 2][k], wr, a2);
            a3 = fmaf(sh[8 + rb + 3][k], wr, a3);
        }
        float acc[4] = {a0, a1, a2, a3};
#pragma unroll
        for (int r = 0; r < 4; ++r) {
            int ri = r0 + rb + r;
            if (ri < N) buf[(size_t)ri * H + h] = acc[r];
        }
    }
}

// ---------------- merged BatchNorm stats: [0,1024) pat | [1024,1280) lab | [1280,1344) dis
__global__ void k_bn_stats(const bf16* __restrict__ aggp, const float* __restrict__ bufL,
                           const float* __restrict__ bufD, float* __restrict__ sums) {
    int h = threadIdx.x & 127;
    int sub = threadIdx.x >> 7;
    float s = 0.f, s2 = 0.f;
    float* sm;
    if (blockIdx.x < 1024) {
        for (int i = blockIdx.x * 2 + sub; i < NP; i += 2048) {
            float v = __bfloat162float(aggp[(size_t)i * H + h]);
            s += v;
            s2 = fmaf(v, v, s2);
        }
        sm = sums;
    } else if (blockIdx.x < 1280) {
        int bid = blockIdx.x - 1024;
        for (int i = bid * 2 + sub; i < NL; i += 512) {
            float v = bufL[(size_t)i * H + h];
            s += v;
            s2 = fmaf(v, v, s2);
        }
        sm = sums + 2 * H;
    } else {
        int bid = blockIdx.x - 1280;
        for (int i = bid * 2 + sub; i < ND; i += 128) {
            float v = bufD[(size_t)i * H + h];
            s += v;
            s2 = fmaf(v, v, s2);
        }
        sm = sums + 4 * H;
    }
    __shared__ float ls[256], ls2[256];
    ls[threadIdx.x] = s;
    ls2[threadIdx.x] = s2;
    __syncthreads();
    if (sub == 0) {
        atomicAdd(&sm[h], s + ls[128 + h]);
        atomicAdd(&sm[H + h], s2 + ls2[128 + h]);
    }
}

// ---------------- merged BatchNorm apply + relu ----------------
template <typename TA>
__global__ void k_bn_apply(const bf16* __restrict__ aggp, const float* __restrict__ bufL,
                           const float* __restrict__ bufD, bf16* __restrict__ hp,
                           TA* __restrict__ hl, TA* __restrict__ hd,
                           const float* __restrict__ sums, const void* __restrict__ g,
                           const void* __restrict__ b, const int* __restrict__ flags) {
    int f32m = flags[0];
    size_t idx = (size_t)blockIdx.x * 256 + threadIdx.x;
    int h = (int)(idx & 127);
    if (idx < (size_t)NP * H) {
        const float invN = 1.f / NP;
        float m = sums[h] * invN;
        float v = fmaf(-m, m, sums[H + h] * invN);
        float sc = rsqrtf(v + 1e-5f) * ldin(g, h, f32m);
        float r = fmaf(__bfloat162float(aggp[idx]) - m, sc, ldin(b, h, f32m));
        hp[idx] = __float2bfloat16(fmaxf(r, 0.f));
    } else if (idx < (size_t)(NP + NL) * H) {
        size_t j = idx - (size_t)NP * H;
        const float invN = 1.f / NL;
        float m = sums[2 * H + h] * invN;
        float v = fmaf(-m, m, sums[3 * H + h] * invN);
        float sc = rsqrtf(v + 1e-5f) * ldin(g, H + h, f32m);
        float r = fmaf(bufL[j] - m, sc, ldin(b, H + h, f32m));
        stv(hl, j, fmaxf(r, 0.f));
    } else if (idx < (size_t)(NP + NL + ND) * H) {
        size_t j = idx - (size_t)(NP + NL) * H;
        const float invN = 1.f / ND;
        float m = sums[4 * H + h] * invN;
        float v = fmaf(-m, m, sums[5 * H + h] * invN);
        float sc = rsqrtf(v + 1e-5f) * ldin(g, 2 * H + h, f32m);
        float r = fmaf(bufD[j] - m, sc, ldin(b, 2 * H + h, f32m));
        stv(hd, j, fmaxf(r, 0.f));
    }
}

// ---------------- head: 16 patients/block, weights staged in LDS as f32 ----------------
__global__ void k_head(const bf16* __restrict__ hp, const void* __restrict__ W1,
                       const void* __restrict__ b1, const void* __restrict__ W2,
                       const void* __restrict__ b2, void* __restrict__ out,
                       const int* __restrict__ flags) {
    int f32m = flags[0];
    __shared__ float W1s[H * 64];
    __shared__ float W2s[64 * NOUT];
    __shared__ float b1s[64], b2s[NOUT];
    __shared__ float rows[16][H];
    __shared__ float h1s[16][65];
    __shared__ float lgs[16][16];
    int t = threadIdx.x;
    for (int i = t; i < H * 64; i += 256) W1s[i] = ldin(W1, i, f32m);
    for (int i = t; i < 64 * NOUT; i += 256) W2s[i] = ldin(W2, i, f32m);
    if (t < 64) b1s[t] = ldin(b1, t, f32m);
    else if (t >= 64 && t < 64 + NOUT) b2s[t - 64] = ldin(b2, t - 64, f32m);
    int p0 = blockIdx.x * 16;
    for (int i = t; i < 16 * 64; i += 256) {
        int r = i >> 6, c2 = (i & 63) * 2;
        float2 v = ld_bf2(hp + (size_t)(p0 + r) * H + c2);
        rows[r][c2] = v.x;
        rows[r][c2 + 1] = v.y;
    }
    __syncthreads();
    int w = t >> 6, lane = t & 63;
    const float* r0 = rows[4 * w + 0];
    const float* r1 = rows[4 * w + 1];
    const float* r2 = rows[4 * w + 2];
    const float* r3 = rows[4 * w + 3];
    float a0 = b1s[lane], a1 = a0, a2 = a0, a3 = a0;
#pragma unroll 4
    for (int k = 0; k < H; ++k) {
        float wv = W1s[k * 64 + lane];
        a0 = fmaf(r0[k], wv, a0);
        a1 = fmaf(r1[k], wv, a1);
        a2 = fmaf(r2[k], wv, a2);
        a3 = fmaf(r3[k], wv, a3);
    }
    h1s[4 * w + 0][lane] = fmaxf(a0, 0.f);
    h1s[4 * w + 1][lane] = fmaxf(a1, 0.f);
    h1s[4 * w + 2][lane] = fmaxf(a2, 0.f);
    h1s[4 * w + 3][lane] = fmaxf(a3, 0.f);
    __syncthreads();
    int pat = lane >> 4, oidx = lane & 15;
    int prow = 4 * w + pat;
    float lg = 0.f;
    if (oidx < NOUT) {
        lg = b2s[oidx];
        const float* hh = h1s[prow];
#pragma unroll 8
        for (int k = 0; k < 64; ++k) lg = fmaf(hh[k], W2s[k * NOUT + oidx], lg);
        lgs[prow][oidx] = lg;
    }
    __syncthreads();
    if (oidx < NOUT) {
        float m = -1e30f;
#pragma unroll
        for (int k = 0; k < NOUT; ++k) m = fmaxf(m, lgs[prow][k]);
        float s = 0.f;
#pragma unroll
        for (int k = 0; k < NOUT; ++k) s += __expf(lgs[prow][k] - m);
        float r = lg - m - __logf(s);
        if (f32m)
            ((float*)out)[(size_t)(p0 + prow) * NOUT + oidx] = r;
        else
            ((bf16*)out)[(size_t)(p0 + prow) * NOUT + oidx] = __float2bfloat16(r);
    }
}

// ---------------- one hetero layer ----------------
template <typename TA>
static void run_layer(const void* Wl, const void* bl, const void* Wr, const void* bng,
                      const void* bnb, bf16* hp, TA* hl, TA* hd, bf16* aggp, float* bufL,
                      float* bufD, bf16* tlp, bf16* tdp, const int* cnt, const int* off,
                      const int* nbr, float* w23, float* b23, float* bns, const int* flags,
                      hipStream_t stream) {
    k_stage1<TA><<<S1_TOTAL, 256, 0, stream>>>(hp, off, cnt, nbr, bufL, bufD, hl, hd, Wl, tlp,
                                               tdp, Wr, bl, w23, b23, flags);
    k_patmm<TA><<<PATMM_TOTAL, 256, 0, stream>>>(hp, tlp, tdp, off, cnt, nbr, w23, b23, aggp,
                                                 bufL, bufD, hl, hd, Wl, bl, Wr, bns, flags);
    k_bn_stats<<<1344, 256, 0, stream>>>(aggp, bufL, bufD, bns);
    k_bn_apply<TA><<<(int)(((size_t)(NP + NL + ND) * H + 255) / 256), 256, 0, stream>>>(
        aggp, bufL, bufD, hp, hl, hd, bns, bng, bnb, flags);
}

template <typename TA>
static void run_all(void* const* d_in, void* d_out, void* d_ws, hipStream_t stream) {
    const int* e1s = (const int*)d_in[23];
    const int* e1d = (const int*)d_in[24];
    const int* e2s = (const int*)d_in[25];
    const int* e2d = (const int*)d_in[26];
    const int NPOOL = 2 * (E1 + E2);

    char* wsb = (char*)d_ws;
    size_t o = 0;
    auto af = [&](size_t nwords) { void* p = wsb + o * 4; o += nwords; return p; };
    int* flags = (int*)af(16);
    float* w23 = (float*)af(HH);
    float* b23 = (float*)af(H);
    float* bns = (float*)af(6 * H);
    int* bsums = (int*)af(256);
    int* cnt = (int*)af(NCNT);
    int* off = (int*)af(NCNT);
    int* nbr = (int*)af(NPOOL);
    bf16* hp = (bf16*)af((size_t)NP * H / 2);
    TA* hl = (TA*)af((size_t)NL * H * sizeof(TA) / 4);
    TA* hd = (TA*)af((size_t)ND * H * sizeof(TA) / 4);
    // ---- arena: CSR-build view (dead after fill) aliases layer-buffer view ----
    size_t arena = o;
    unsigned short* r1d = (unsigned short*)af(E1 / 2);
    unsigned short* r1s = (unsigned short*)af(E1 / 2);
    unsigned short* r2d = (unsigned short*)af(E2 / 2);
    unsigned short* r2s = (unsigned short*)af(E2 / 2);
    unsigned int* ccnt = (unsigned int*)af((size_t)NCOPY * NCNT);
    size_t endA = o;
    o = arena;
    float* bufL = (float*)af((size_t)NL * H);
    float* bufD = (float*)af((size_t)ND * H);
    bf16* tlp = (bf16*)af((size_t)NL * H / 2);
    bf16* tdp = (bf16*)af((size_t)ND * H / 2);
    bf16* aggp = (bf16*)af((size_t)NP * H / 2);
    size_t endB = o;
    o = endA > endB ? endA : endB;

    k_detect<<<1, 256, 0, stream>>>((const unsigned short*)d_in[0], flags);

    // CSR build (once; reused by both layers) + embeddings merged into count launch
    hipMemsetAsync(ccnt, 0, (size_t)NCOPY * NCNT * 4, stream);
    k_count_embed<TA><<<CNT_BLOCKS + EMB_BLOCKS, 256, 0, stream>>>(
        e1s, e1d, e2s, e2d, ccnt, r1d, r1s, r2d, r2s, d_in[0], d_in[1], d_in[2], d_in[3],
        d_in[4], d_in[5], d_in[6], d_in[7], d_in[8], hp, hl, hd, flags);
    int nb = (NCNT + SCAN_ELEMS - 1) / SCAN_ELEMS;
    k_scan1r<<<nb, 256, 0, stream>>>(ccnt, cnt, off, bsums);
    k_scan2<<<1, 256, 0, stream>>>(bsums, nb);
    k_scan3<<<(NCNT + 255) / 256, 256, 0, stream>>>(off, bsums, NCNT);
    k_fill_all<<<CNT_BLOCKS, 256, 0, stream>>>(e1s, e1d, e2s, e2d, off, ccnt, r1d, r1s, r2d,
                                               r2s, nbr);

    run_layer<TA>(d_in[9], d_in[10], d_in[11], d_in[15], d_in[16], hp, hl, hd, aggp, bufL, bufD,
                  tlp, tdp, cnt, off, nbr, w23, b23, bns, flags, stream);
    run_layer<TA>(d_in[12], d_in[13], d_in[14], d_in[17], d_in[18], hp, hl, hd, aggp, bufL, bufD,
                  tlp, tdp, cnt, off, nbr, w23, b23, bns, flags, stream);

    k_head<<<NP / 16, 256, 0, stream>>>(hp, d_in[19], d_in[20], d_in[21], d_in[22], d_out, flags);
}

extern "C" void kernel_launch(void* const* d_in, const int* in_sizes, int n_in, void* d_out,
                              int out_size, void* d_ws, size_t ws_size, hipStream_t stream) {
    const size_t NPOOL = 2 * ((size_t)E1 + E2);
    const size_t viewA = ((size_t)E1 + E2) + (size_t)NCOPY * NCNT;
    const size_t viewB = (size_t)NL * H + (size_t)ND * H + (size_t)NL * H / 2 +
                         (size_t)ND * H / 2 + (size_t)NP * H / 2;
    const size_t arena = viewA > viewB ? viewA : viewB;
    const size_t fixed_f32 = 16 + HH + H + 6 * H + 256 + 2 * (size_t)NCNT + NPOOL +
                             (size_t)NP * H / 2 + (size_t)NL * H + (size_t)ND * H;
    const size_t need_f32 = (fixed_f32 + arena) * 4;  // ~87 MiB
    if (ws_size >= need_f32)
        run_all<float>(d_in, d_out, d_ws, stream);
    else
        run_all<bf16>(d_in, d_out, d_ws, stream);  // ~84 MiB
}

// Round 12
// 1232.898 us; speedup vs baseline: 5.4590x; 1.1086x over previous
//
#include <hip/hip_runtime.h>
#include <hip/hip_bf16.h>

#define NP 100000
#define NL 10000
#define ND 500
#define H 128
#define HH (H * H)
#define E1 2000000
#define E2 500000
#define NOUT 10
#define NCOPY 16                  // patient-count replicas; blockIdx%16 ~ 2 per XCD
#define NPP (2 * NP)              // patient count segments [p1 NP][p2 NP]
#define NCNT (NL + ND + 2 * NP)   // global segs: [lab NL][dis ND][p1 NP][p2 NP]
#define CHUNK 8192
#define LABHB ((E1 + CHUNK - 1) / CHUNK)              // 245
#define DISHB ((E2 + CHUNK - 1) / CHUNK)              // 62
#define CNT_BLOCKS ((E1 + E2 + 255) / 256)            // 9766
#define EMB_BLOCKS (((NP + NL + ND) * H + 255) / 256) // 55250
#define RED_LAB ((NL + 255) / 256)                    // 40
#define RED_DIS ((ND + 255) / 256)                    // 2
#define RED_P ((NPP + 255) / 256)                     // 782

typedef __hip_bfloat16 bf16;

__device__ __forceinline__ float ldv(const float* p, size_t i) { return p[i]; }
__device__ __forceinline__ float ldv(const bf16* p, size_t i) { return __bfloat162float(p[i]); }
__device__ __forceinline__ void stv(float* p, size_t i, float v) { p[i] = v; }
__device__ __forceinline__ void stv(bf16* p, size_t i, float v) { p[i] = __float2bfloat16(v); }

__device__ __forceinline__ float bfbits2f(unsigned short s) {
    union { unsigned int u; float f; } v;
    v.u = (unsigned int)s << 16;
    return v.f;
}
__device__ __forceinline__ float2 ld_bf2(const bf16* p) {
    unsigned int u = *(const unsigned int*)p;
    return make_float2(bfbits2f((unsigned short)(u & 0xFFFFu)), bfbits2f((unsigned short)(u >> 16)));
}
__device__ __forceinline__ void st_bf2(bf16* p, float2 v) {
    union { unsigned int u; bf16 b[2]; } t;
    t.b[0] = __float2bfloat16(v.x);
    t.b[1] = __float2bfloat16(v.y);
    *(unsigned int*)p = t.u;
}
__device__ __forceinline__ float ldin(const void* p, size_t i, int f32m) {
    return f32m ? ((const float*)p)[i] : __bfloat162float(((const bf16*)p)[i]);
}

// ---------------- input dtype detection (measured: picks bf16 on this harness) ----------
__global__ void k_detect(const unsigned short* __restrict__ xp, int* __restrict__ flags) {
    int t = threadIdx.x;
    int cnt = 0;
    for (int i = t; i < 4096; i += 256) {
        unsigned short w = xp[2 * i];
        int e = (w >> 7) & 0xFF;
        if (w == 0 || (e >= 114 && e <= 141)) cnt++;
    }
    __shared__ int sh[256];
    sh[t] = cnt;
    __syncthreads();
    for (int s = 128; s > 0; s >>= 1) {
        if (t < s) sh[t] += sh[t + s];
        __syncthreads();
    }
    if (t == 0) flags[0] = (sh[0] < 2048) ? 1 : 0;  // 1 = f32 inputs
}

// ---- merged launch: patient global count | lab/dis LDS histograms | embeddings ---------
// patient count: XCD-privatized, 1 atomic/edge, rank=(copy<<12)|local (max deg ~60).
// lab/dis: per-chunk LDS histograms (packed u16 pairs, 20 KB -> 8 blocks/CU kept).
template <typename TA>
__global__ void k_count_embed(const int* __restrict__ e1s, const int* __restrict__ e1d,
                              const int* __restrict__ e2s, const int* __restrict__ e2d,
                              unsigned int* __restrict__ ccnt, unsigned short* __restrict__ r1s,
                              unsigned short* __restrict__ r2s, unsigned int* __restrict__ labHist,
                              unsigned int* __restrict__ disHist, const void* __restrict__ xp,
                              const void* __restrict__ xl, const void* __restrict__ xd,
                              const void* __restrict__ Wp, const void* __restrict__ bp,
                              const void* __restrict__ Wlab, const void* __restrict__ blab,
                              const void* __restrict__ Wdis, const void* __restrict__ bdis,
                              bf16* __restrict__ hp, TA* __restrict__ hl, TA* __restrict__ hd,
                              const int* __restrict__ flags) {
    __shared__ unsigned int histp[NL / 2];  // packed u16 pairs (20 KB)
    int b = blockIdx.x, t = threadIdx.x;
    if (b < CNT_BLOCKS) {
        int copy = b & (NCOPY - 1);
        unsigned int* c = ccnt + (size_t)copy * NPP;
        unsigned int tag = (unsigned int)copy << 12;
        int e = b * 256 + t;
        if (e < E1) {
            unsigned int o = atomicAdd(&c[e1s[e]], 1u);
            r1s[e] = (unsigned short)(tag | (o & 0xFFFu));
        } else if (e < E1 + E2) {
            int i = e - E1;
            unsigned int o = atomicAdd(&c[NP + e2s[i]], 1u);
            r2s[i] = (unsigned short)(tag | (o & 0xFFFu));
        }
    } else if (b < CNT_BLOCKS + LABHB) {
        int c = b - CNT_BLOCKS;
        for (int i = t; i < NL / 2; i += 256) histp[i] = 0;
        __syncthreads();
        int e0 = c * CHUNK, ee = min(E1, e0 + CHUNK);
        for (int e = e0 + t; e < ee; e += 256) {
            int dd = e1d[e];
            atomicAdd(&histp[dd >> 1], 1u << (16 * (dd & 1)));
        }
        __syncthreads();
        for (int i = t; i < NL; i += 256)
            labHist[(size_t)c * NL + i] = (histp[i >> 1] >> (16 * (i & 1))) & 0xFFFFu;
    } else if (b < CNT_BLOCKS + LABHB + DISHB) {
        int c = b - CNT_BLOCKS - LABHB;
        for (int i = t; i < ND / 2; i += 256) histp[i] = 0;
        __syncthreads();
        int e0 = c * CHUNK, ee = min(E2, e0 + CHUNK);
        for (int e = e0 + t; e < ee; e += 256) {
            int dd = e2d[e];
            atomicAdd(&histp[dd >> 1], 1u << (16 * (dd & 1)));
        }
        __syncthreads();
        for (int i = t; i < ND; i += 256)
            disHist[(size_t)c * ND + i] = (histp[i >> 1] >> (16 * (i & 1))) & 0xFFFFu;
    } else {
        int f32m = flags[0];
        int idx = (b - CNT_BLOCKS - LABHB - DISHB) * 256 + t;
        int h = idx & 127;
        if (idx < NP * H) {
            int i = idx >> 7;
            float acc = ldin(bp, h, f32m);
#pragma unroll
            for (int k = 0; k < 16; ++k)
                acc = fmaf(ldin(xp, (size_t)i * 16 + k, f32m), ldin(Wp, (size_t)k * H + h, f32m), acc);
            hp[idx] = __float2bfloat16(acc);
        } else if (idx < (NP + NL) * H) {
            int i = (idx - NP * H) >> 7;
            float acc = fmaf(ldin(xl, i, f32m), ldin(Wlab, h, f32m), ldin(blab, h, f32m));
            stv(hl, (size_t)i * H + h, acc);
        } else if (idx < (NP + NL + ND) * H) {
            int i = (idx - (NP + NL) * H) >> 7;
            float acc = ldin(bdis, h, f32m);
            acc = fmaf(ldin(xd, (size_t)i * 2 + 0, f32m), ldin(Wdis, h, f32m), acc);
            acc = fmaf(ldin(xd, (size_t)i * 2 + 1, f32m), ldin(Wdis, H + h, f32m), acc);
            stv(hd, (size_t)i * H + h, acc);
        }
    }
}

// ---- reduce: chunk/copy exclusive bases written back; totals -> cnt --------------------
__global__ void k_reduce(unsigned int* __restrict__ labHist, unsigned int* __restrict__ disHist,
                         unsigned int* __restrict__ ccnt, int* __restrict__ cnt) {
    int b = blockIdx.x, t = threadIdx.x;
    if (b < RED_LAB) {
        int bin = b * 256 + t;
        if (bin < NL) {
            unsigned int run = 0;
            for (int k = 0; k < LABHB; ++k) {
                unsigned int x = labHist[(size_t)k * NL + bin];
                labHist[(size_t)k * NL + bin] = run;
                run += x;
            }
            cnt[bin] = (int)run;
        }
    } else if (b < RED_LAB + RED_DIS) {
        int bin = (b - RED_LAB) * 256 + t;
        if (bin < ND) {
            unsigned int run = 0;
            for (int k = 0; k < DISHB; ++k) {
                unsigned int x = disHist[(size_t)k * ND + bin];
                disHist[(size_t)k * ND + bin] = run;
                run += x;
            }
            cnt[NL + bin] = (int)run;
        }
    } else {
        int bin = (b - RED_LAB - RED_DIS) * 256 + t;
        if (bin < NPP) {
            unsigned int run = 0;
#pragma unroll
            for (int k = 0; k < NCOPY; ++k) {
                unsigned int x = ccnt[(size_t)k * NPP + bin];
                ccnt[(size_t)k * NPP + bin] = run;
                run += x;
            }
            cnt[NL + ND + bin] = (int)run;
        }
    }
}

#define SCAN_ELEMS 2048
__global__ void k_scan1(const int* __restrict__ in, int* __restrict__ out,
                        int* __restrict__ bsums, int n) {
    int t = threadIdx.x;
    int base = blockIdx.x * SCAN_ELEMS + t * 8;
    int v[8], tsum = 0;
#pragma unroll
    for (int j = 0; j < 8; ++j) {
        v[j] = (base + j < n) ? in[base + j] : 0;
        tsum += v[j];
    }
    __shared__ int sh[256];
    sh[t] = tsum;
    __syncthreads();
    for (int d = 1; d < 256; d <<= 1) {
        int x = (t >= d) ? sh[t - d] : 0;
        __syncthreads();
        sh[t] += x;
        __syncthreads();
    }
    int run = sh[t] - tsum;
    if (t == 255) bsums[blockIdx.x] = sh[255];
#pragma unroll
    for (int j = 0; j < 8; ++j) {
        if (base + j < n) out[base + j] = run;
        run += v[j];
    }
}

__global__ void k_scan2(int* __restrict__ bsums, int nb) {
    int t = threadIdx.x;
    int v = (t < nb) ? bsums[t] : 0;
    __shared__ int sh[256];
    sh[t] = v;
    __syncthreads();
    for (int d = 1; d < 256; d <<= 1) {
        int x = (t >= d) ? sh[t - d] : 0;
        __syncthreads();
        sh[t] += x;
        __syncthreads();
    }
    if (t < nb) bsums[t] = sh[t] - v;
}

__global__ void k_scan3(int* __restrict__ out, const int* __restrict__ bsums, int n) {
    int i = blockIdx.x * 256 + threadIdx.x;
    if (i < n) out[i] += bsums[i / SCAN_ELEMS];
}

// ---- fill: p-side atomic-free via ranks; lab/dis via LDS slot counters (order-free) ----
__global__ void k_fill(const int* __restrict__ e1s, const int* __restrict__ e1d,
                       const int* __restrict__ e2s, const int* __restrict__ e2d,
                       const int* __restrict__ off, const unsigned int* __restrict__ ccnt,
                       const unsigned short* __restrict__ r1s,
                       const unsigned short* __restrict__ r2s,
                       const unsigned int* __restrict__ labHist,
                       const unsigned int* __restrict__ disHist, int* __restrict__ nbr) {
    __shared__ unsigned int slot[NL];  // 40 KB; fill is write-bound, occupancy ok
    int b = blockIdx.x, t = threadIdx.x;
    if (b < CNT_BLOCKS) {
        int e = b * 256 + t;
        if (e < E1) {
            int ss = e1s[e];
            int r = r1s[e];
            int base = (int)ccnt[(size_t)(r >> 12) * NPP + ss];
            nbr[off[NL + ND + ss] + base + (r & 0xFFF)] = e1d[e];
        } else if (e < E1 + E2) {
            int i = e - E1;
            int ss = e2s[i];
            int r = r2s[i];
            int base = (int)ccnt[(size_t)(r >> 12) * NPP + NP + ss];
            nbr[off[NL + ND + NP + ss] + base + (r & 0xFFF)] = e2d[i];
        }
    } else if (b < CNT_BLOCKS + LABHB) {
        int c = b - CNT_BLOCKS;
        for (int i = t; i < NL; i += 256)
            slot[i] = (unsigned int)off[i] + labHist[(size_t)c * NL + i];
        __syncthreads();
        int e0 = c * CHUNK, ee = min(E1, e0 + CHUNK);
        for (int e = e0 + t; e < ee; e += 256) {
            unsigned int pos = atomicAdd(&slot[e1d[e]], 1u);
            nbr[pos] = e1s[e];
        }
    } else {
        int c = b - CNT_BLOCKS - LABHB;
        for (int i = t; i < ND; i += 256)
            slot[i] = (unsigned int)off[NL + i] + disHist[(size_t)c * ND + i];
        __syncthreads();
        int e0 = c * CHUNK, ee = min(E2, e0 + CHUNK);
        for (int e = e0 + t; e < ee; e += 256) {
            unsigned int pos = atomicAdd(&slot[e2d[e]], 1u);
            nbr[pos] = e2s[e];
        }
    }
}

// ---------------- stage1 mega-kernel: dis gather | lab gather | mm_small | prep23 --------
#define S1_DIS ND
#define S1_LAB (NL / 4)
#define S1_MM 1313
#define S1_PREP 64
#define S1_TOTAL (S1_DIS + S1_LAB + S1_MM + S1_PREP)

template <typename TA>
__global__ void k_stage1(const bf16* __restrict__ hp, const int* __restrict__ off,
                         const int* __restrict__ cnt, const int* __restrict__ nbr,
                         float* __restrict__ bufL, float* __restrict__ bufD,
                         const TA* __restrict__ hl, const TA* __restrict__ hd,
                         const void* __restrict__ Wl, bf16* __restrict__ tlp,
                         bf16* __restrict__ tdp, const void* __restrict__ Wr,
                         const void* __restrict__ bl, float* __restrict__ w23,
                         float* __restrict__ b23, const int* __restrict__ flags) {
    __shared__ float part[4][H];
    __shared__ float smm[8][H];
    int b = blockIdx.x;
    int t = threadIdx.x;
    if (b < S1_DIS) {
        int row = b, seg = NL + row;
        int s0 = off[seg], c = cnt[seg];
        const int* nb = nbr + s0;
        int w = t >> 6, lane = t & 63, c0 = 2 * lane;
        int j = (c * w) >> 2, jend = (c * (w + 1)) >> 2;
        float2 a[8];
#pragma unroll
        for (int u = 0; u < 8; ++u) a[u] = make_float2(0.f, 0.f);
        for (; j + 8 <= jend; j += 8) {
#pragma unroll
            for (int u = 0; u < 8; ++u) {
                float2 v = ld_bf2(hp + (size_t)nb[j + u] * H + c0);
                a[u].x += v.x;
                a[u].y += v.y;
            }
        }
        for (; j < jend; ++j) {
            float2 v = ld_bf2(hp + (size_t)nb[j] * H + c0);
            a[0].x += v.x;
            a[0].y += v.y;
        }
        part[w][c0] = ((a[0].x + a[1].x) + (a[2].x + a[3].x)) + ((a[4].x + a[5].x) + (a[6].x + a[7].x));
        part[w][c0 + 1] = ((a[0].y + a[1].y) + (a[2].y + a[3].y)) + ((a[4].y + a[5].y) + (a[6].y + a[7].y));
        __syncthreads();
        if (t < H) {
            float v = (part[0][t] + part[1][t]) + (part[2][t] + part[3][t]);
            bufD[(size_t)row * H + t] = v / fmaxf((float)c, 1.f);
        }
    } else if (b < S1_DIS + S1_LAB) {
        int w = t >> 6, lane = t & 63, c0 = 2 * lane;
        int row = (b - S1_DIS) * 4 + w;
        int s0 = off[row], c = cnt[row];
        const int* nb = nbr + s0;
        float2 a[8];
#pragma unroll
        for (int u = 0; u < 8; ++u) a[u] = make_float2(0.f, 0.f);
        int j = 0;
        for (; j + 8 <= c; j += 8) {
#pragma unroll
            for (int u = 0; u < 8; ++u) {
                float2 v = ld_bf2(hp + (size_t)nb[j + u] * H + c0);
                a[u].x += v.x;
                a[u].y += v.y;
            }
        }
        for (; j < c; ++j) {
            float2 v = ld_bf2(hp + (size_t)nb[j] * H + c0);
            a[0].x += v.x;
            a[0].y += v.y;
        }
        float sx = ((a[0].x + a[1].x) + (a[2].x + a[3].x)) + ((a[4].x + a[5].x) + (a[6].x + a[7].x));
        float sy = ((a[0].y + a[1].y) + (a[2].y + a[3].y)) + ((a[4].y + a[5].y) + (a[6].y + a[7].y));
        float inv = 1.f / fmaxf((float)c, 1.f);
        *(float2*)(bufL + (size_t)row * H + c0) = make_float2(sx * inv, sy * inv);
    } else if (b < S1_DIS + S1_LAB + S1_MM) {
        int f32m = flags[0];
        int bb = b - (S1_DIS + S1_LAB);
        bool lab = bb < 1250;
        const TA* in = lab ? hl : hd;
        bf16* outp = lab ? tlp : tdp;
        int N = lab ? NL : ND;
        size_t woff = lab ? (size_t)2 * HH : (size_t)3 * HH;
        int r0 = (lab ? bb : bb - 1250) * 8;
        int h = t & 127, half = t >> 7;
        for (int r = half; r < 8; r += 2)
            smm[r][h] = (r0 + r < N) ? ldv(in, (size_t)(r0 + r) * H + h) : 0.f;
        __syncthreads();
        int rb = half * 4;
        float a0 = 0.f, a1 = 0.f, a2 = 0.f, a3 = 0.f;
        for (int k = 0; k < H; ++k) {
            float wv = ldin(Wl, woff + (size_t)k * H + h, f32m);
            a0 = fmaf(smm[rb + 0][k], wv, a0);
            a1 = fmaf(smm[rb + 1][k], wv, a1);
            a2 = fmaf(smm[rb + 2][k], wv, a2);
            a3 = fmaf(smm[rb + 3][k], wv, a3);
        }
        float acc[4] = {a0, a1, a2, a3};
#pragma unroll
        for (int r = 0; r < 4; ++r)
            if (r0 + rb + r < N)
                outp[(size_t)(r0 + rb + r) * H + h] = __float2bfloat16(acc[r]);
    } else {
        int f32m = flags[0];
        int idx = (b - (S1_DIS + S1_LAB + S1_MM)) * 256 + t;
        if (idx < HH)
            w23[idx] = ldin(Wr, (size_t)2 * HH + idx, f32m) + ldin(Wr, (size_t)3 * HH + idx, f32m);
        if (idx < H)
            b23[idx] = ldin(bl, (size_t)2 * H + idx, f32m) + ldin(bl, (size_t)3 * H + idx, f32m);
    }
}

// -------- merged: patient pass | lab/dis second stage | bns zeroing ----------------------
#define PAT_BLOCKS (NP / 16)
#define MML_LAB (NL / 8)
#define MML_DIS ((ND + 7) / 8)
#define PATMM_TOTAL (PAT_BLOCKS + MML_LAB + MML_DIS)

template <typename TA>
__global__ void k_patmm(const bf16* __restrict__ hp, const bf16* __restrict__ tlp,
                        const bf16* __restrict__ tdp, const int* __restrict__ off,
                        const int* __restrict__ cnt, const int* __restrict__ nbr,
                        const float* __restrict__ w23, const float* __restrict__ b23,
                        bf16* __restrict__ aggp, float* __restrict__ bufL,
                        float* __restrict__ bufD, const TA* __restrict__ hl,
                        const TA* __restrict__ hd, const void* __restrict__ Wl,
                        const void* __restrict__ bl, const void* __restrict__ Wr,
                        float* __restrict__ bns, const int* __restrict__ flags) {
    __shared__ float sh[16][H];
    int t = threadIdx.x;
    if (blockIdx.x < PAT_BLOCKS) {
        int w = t >> 6, lane = t & 63, c0 = 2 * lane;
        int p0 = blockIdx.x * 16 + w * 4;
        const int* off1 = off + NL + ND;
        const int* cnt1 = cnt + NL + ND;
        const int* off2 = off + NL + ND + NP;
        const int* cnt2 = cnt + NL + ND + NP;
        float2 bb = *(const float2*)(b23 + c0);
        float2 acc[4];
#pragma unroll
        for (int r = 0; r < 4; ++r) {
            int p = p0 + r;
            int s1 = off1[p], c1 = cnt1[p];
            const int* nb1 = nbr + s1;
            float2 aa[4];
#pragma unroll
            for (int u = 0; u < 4; ++u) aa[u] = make_float2(0.f, 0.f);
            int j = 0;
            for (; j + 4 <= c1; j += 4) {
#pragma unroll
                for (int u = 0; u < 4; ++u) {
                    float2 v = ld_bf2(tlp + (size_t)nb1[j + u] * H + c0);
                    aa[u].x += v.x;
                    aa[u].y += v.y;
                }
            }
            for (; j < c1; ++j) {
                float2 v = ld_bf2(tlp + (size_t)nb1[j] * H + c0);
                aa[0].x += v.x;
                aa[0].y += v.y;
            }
            float a1x = (aa[0].x + aa[1].x) + (aa[2].x + aa[3].x);
            float a1y = (aa[0].y + aa[1].y) + (aa[2].y + aa[3].y);
            int s2 = off2[p], c2 = cnt2[p];
            const int* nb2 = nbr + s2;
            float2 a2a = make_float2(0.f, 0.f), a2b = a2a;
            j = 0;
            for (; j + 2 <= c2; j += 2) {
                float2 va = ld_bf2(tdp + (size_t)nb2[j] * H + c0);
                float2 vb = ld_bf2(tdp + (size_t)nb2[j + 1] * H + c0);
                a2a.x += va.x; a2a.y += va.y;
                a2b.x += vb.x; a2b.y += vb.y;
            }
            if (j < c2) {
                float2 v = ld_bf2(tdp + (size_t)nb2[j] * H + c0);
                a2a.x += v.x;
                a2a.y += v.y;
            }
            float i1 = 1.f / fmaxf((float)c1, 1.f), i2 = 1.f / fmaxf((float)c2, 1.f);
            acc[r].x = a1x * i1 + (a2a.x + a2b.x) * i2 + bb.x;
            acc[r].y = a1y * i1 + (a2a.y + a2b.y) * i2 + bb.y;
        }
#pragma unroll
        for (int r = 0; r < 4; ++r) {
            float2 v = ld_bf2(hp + (size_t)(p0 + r) * H + c0);
            sh[w * 4 + r][c0] = v.x;
            sh[w * 4 + r][c0 + 1] = v.y;
        }
        for (int k = 0; k < H; ++k) {
            float2 wv = *(const float2*)(w23 + (size_t)k * H + c0);
#pragma unroll
            for (int r = 0; r < 4; ++r) {
                float x = sh[w * 4 + r][k];
                acc[r].x = fmaf(x, wv.x, acc[r].x);
                acc[r].y = fmaf(x, wv.y, acc[r].y);
            }
        }
#pragma unroll
        for (int r = 0; r < 4; ++r)
            st_bf2(aggp + (size_t)(p0 + r) * H + c0, acc[r]);
    } else {
        int bb = blockIdx.x - PAT_BLOCKS;
        if (bb == 0)
            for (int i = t; i < 6 * H; i += 256) bns[i] = 0.f;
        int f32m = flags[0];
        bool lab = bb < MML_LAB;
        float* buf = lab ? bufL : bufD;
        const TA* hx = lab ? hl : hd;
        size_t woff = lab ? 0 : (size_t)HH;
        size_t boff = lab ? 0 : (size_t)H;
        int N = lab ? NL : ND;
        int r0 = (lab ? bb : bb - MML_LAB) * 8;
        int h = t & 127, half = t >> 7;
        for (int r = half; r < 8; r += 2) {
            int ri = r0 + r;
            sh[r][h] = (ri < N) ? buf[(size_t)ri * H + h] : 0.f;
            sh[8 + r][h] = (ri < N) ? ldv(hx, (size_t)ri * H + h) : 0.f;
        }
        __syncthreads();
        int rb = half * 4;
        float bv = ldin(bl, boff + h, f32m);
        float a0 = bv, a1 = bv, a2 = bv, a3 = bv;
        for (int k = 0; k < H; ++k) {
            float wl = ldin(Wl, woff + (size_t)k * H + h, f32m);
            a0 = fmaf(sh[rb + 0][k], wl, a0);
            a1 = fmaf(sh[rb + 1][k], wl, a1);
            a2 = fmaf(sh[rb + 2][k], wl, a2);
            a3 = fmaf(sh[rb + 3][k], wl, a3);
        }
        for (int k = 0; k < H; ++k) {
            float wr = ldin(Wr, woff + (size_t)k * H + h, f32m);
            a0 = fmaf(sh[8 + rb + 0][k], wr, a0);
            a1 = fmaf(sh[8 + rb + 1][k], wr, a1);
            a2 = fmaf(sh[8 + rb + 2][k], wr, a2);
            a3 = fmaf(sh[8 + rb + 3][k], wr, a3);
        }
        float acc[4] = {a0, a1, a2, a3};
#pragma unroll
        for (int r = 0; r < 4; ++r) {
            int ri = r0 + rb + r;
            if (ri < N) buf[(size_t)ri * H + h] = acc[r];
        }
    }
}

// ---------------- merged BatchNorm stats ----------------
__global__ void k_bn_stats(const bf16* __restrict__ aggp, const float* __restrict__ bufL,
                           const float* __restrict__ bufD, float* __restrict__ sums) {
    int h = threadIdx.x & 127;
    int sub = threadIdx.x >> 7;
    float s = 0.f, s2 = 0.f;
    float* sm;
    if (blockIdx.x < 1024) {
        for (int i = blockIdx.x * 2 + sub; i < NP; i += 2048) {
            float v = __bfloat162float(aggp[(size_t)i * H + h]);
            s += v;
            s2 = fmaf(v, v, s2);
        }
        sm = sums;
    } else if (blockIdx.x < 1280) {
        int bid = blockIdx.x - 1024;
        for (int i = bid * 2 + sub; i < NL; i += 512) {
            float v = bufL[(size_t)i * H + h];
            s += v;
            s2 = fmaf(v, v, s2);
        }
        sm = sums + 2 * H;
    } else {
        int bid = blockIdx.x - 1280;
        for (int i = bid * 2 + sub; i < ND; i += 128) {
            float v = bufD[(size_t)i * H + h];
            s += v;
            s2 = fmaf(v, v, s2);
        }
        sm = sums + 4 * H;
    }
    __shared__ float ls[256], ls2[256];
    ls[threadIdx.x] = s;
    ls2[threadIdx.x] = s2;
    __syncthreads();
    if (sub == 0) {
        atomicAdd(&sm[h], s + ls[128 + h]);
        atomicAdd(&sm[H + h], s2 + ls2[128 + h]);
    }
}

// ---------------- merged BatchNorm apply + relu ----------------
template <typename TA>
__global__ void k_bn_apply(const bf16* __restrict__ aggp, const float* __restrict__ bufL,
                           const float* __restrict__ bufD, bf16* __restrict__ hp,
                           TA* __restrict__ hl, TA* __restrict__ hd,
                           const float* __restrict__ sums, const void* __restrict__ g,
                           const void* __restrict__ b, const int* __restrict__ flags) {
    int f32m = flags[0];
    size_t idx = (size_t)blockIdx.x * 256 + threadIdx.x;
    int h = (int)(idx & 127);
    if (idx < (size_t)NP * H) {
        const float invN = 1.f / NP;
        float m = sums[h] * invN;
        float v = fmaf(-m, m, sums[H + h] * invN);
        float sc = rsqrtf(v + 1e-5f) * ldin(g, h, f32m);
        float r = fmaf(__bfloat162float(aggp[idx]) - m, sc, ldin(b, h, f32m));
        hp[idx] = __float2bfloat16(fmaxf(r, 0.f));
    } else if (idx < (size_t)(NP + NL) * H) {
        size_t j = idx - (size_t)NP * H;
        const float invN = 1.f / NL;
        float m = sums[2 * H + h] * invN;
        float v = fmaf(-m, m, sums[3 * H + h] * invN);
        float sc = rsqrtf(v + 1e-5f) * ldin(g, H + h, f32m);
        float r = fmaf(bufL[j] - m, sc, ldin(b, H + h, f32m));
        stv(hl, j, fmaxf(r, 0.f));
    } else if (idx < (size_t)(NP + NL + ND) * H) {
        size_t j = idx - (size_t)(NP + NL) * H;
        const float invN = 1.f / ND;
        float m = sums[4 * H + h] * invN;
        float v = fmaf(-m, m, sums[5 * H + h] * invN);
        float sc = rsqrtf(v + 1e-5f) * ldin(g, 2 * H + h, f32m);
        float r = fmaf(bufD[j] - m, sc, ldin(b, 2 * H + h, f32m));
        stv(hd, j, fmaxf(r, 0.f));
    }
}

// ---------------- head: 16 patients/block, weights staged in LDS as f32 ----------------
__global__ void k_head(const bf16* __restrict__ hp, const void* __restrict__ W1,
                       const void* __restrict__ b1, const void* __restrict__ W2,
                       const void* __restrict__ b2, void* __restrict__ out,
                       const int* __restrict__ flags) {
    int f32m = flags[0];
    __shared__ float W1s[H * 64];
    __shared__ float W2s[64 * NOUT];
    __shared__ float b1s[64], b2s[NOUT];
    __shared__ float rows[16][H];
    __shared__ float h1s[16][65];
    __shared__ float lgs[16][16];
    int t = threadIdx.x;
    for (int i = t; i < H * 64; i += 256) W1s[i] = ldin(W1, i, f32m);
    for (int i = t; i < 64 * NOUT; i += 256) W2s[i] = ldin(W2, i, f32m);
    if (t < 64) b1s[t] = ldin(b1, t, f32m);
    else if (t >= 64 && t < 64 + NOUT) b2s[t - 64] = ldin(b2, t - 64, f32m);
    int p0 = blockIdx.x * 16;
    for (int i = t; i < 16 * 64; i += 256) {
        int r = i >> 6, c2 = (i & 63) * 2;
        float2 v = ld_bf2(hp + (size_t)(p0 + r) * H + c2);
        rows[r][c2] = v.x;
        rows[r][c2 + 1] = v.y;
    }
    __syncthreads();
    int w = t >> 6, lane = t & 63;
    const float* r0 = rows[4 * w + 0];
    const float* r1 = rows[4 * w + 1];
    const float* r2 = rows[4 * w + 2];
    const float* r3 = rows[4 * w + 3];
    float a0 = b1s[lane], a1 = a0, a2 = a0, a3 = a0;
#pragma unroll 4
    for (int k = 0; k < H; ++k) {
        float wv = W1s[k * 64 + lane];
        a0 = fmaf(r0[k], wv, a0);
        a1 = fmaf(r1[k], wv, a1);
        a2 = fmaf(r2[k], wv, a2);
        a3 = fmaf(r3[k], wv, a3);
    }
    h1s[4 * w + 0][lane] = fmaxf(a0, 0.f);
    h1s[4 * w + 1][lane] = fmaxf(a1, 0.f);
    h1s[4 * w + 2][lane] = fmaxf(a2, 0.f);
    h1s[4 * w + 3][lane] = fmaxf(a3, 0.f);
    __syncthreads();
    int pat = lane >> 4, oidx = lane & 15;
    int prow = 4 * w + pat;
    float lg = 0.f;
    if (oidx < NOUT) {
        lg = b2s[oidx];
        const float* hh = h1s[prow];
#pragma unroll 8
        for (int k = 0; k < 64; ++k) lg = fmaf(hh[k], W2s[k * NOUT + oidx], lg);
        lgs[prow][oidx] = lg;
    }
    __syncthreads();
    if (oidx < NOUT) {
        float m = -1e30f;
#pragma unroll
        for (int k = 0; k < NOUT; ++k) m = fmaxf(m, lgs[prow][k]);
        float s = 0.f;
#pragma unroll
        for (int k = 0; k < NOUT; ++k) s += __expf(lgs[prow][k] - m);
        float r = lg - m - __logf(s);
        if (f32m)
            ((float*)out)[(size_t)(p0 + prow) * NOUT + oidx] = r;
        else
            ((bf16*)out)[(size_t)(p0 + prow) * NOUT + oidx] = __float2bfloat16(r);
    }
}

// ---------------- one hetero layer ----------------
template <typename TA>
static void run_layer(const void* Wl, const void* bl, const void* Wr, const void* bng,
                      const void* bnb, bf16* hp, TA* hl, TA* hd, bf16* aggp, float* bufL,
                      float* bufD, bf16* tlp, bf16* tdp, const int* cnt, const int* off,
                      const int* nbr, float* w23, float* b23, float* bns, const int* flags,
                      hipStream_t stream) {
    k_stage1<TA><<<S1_TOTAL, 256, 0, stream>>>(hp, off, cnt, nbr, bufL, bufD, hl, hd, Wl, tlp,
                                               tdp, Wr, bl, w23, b23, flags);
    k_patmm<TA><<<PATMM_TOTAL, 256, 0, stream>>>(hp, tlp, tdp, off, cnt, nbr, w23, b23, aggp,
                                                 bufL, bufD, hl, hd, Wl, bl, Wr, bns, flags);
    k_bn_stats<<<1344, 256, 0, stream>>>(aggp, bufL, bufD, bns);
    k_bn_apply<TA><<<(int)(((size_t)(NP + NL + ND) * H + 255) / 256), 256, 0, stream>>>(
        aggp, bufL, bufD, hp, hl, hd, bns, bng, bnb, flags);
}

template <typename TA>
static void run_all(void* const* d_in, void* d_out, void* d_ws, hipStream_t stream) {
    const int* e1s = (const int*)d_in[23];
    const int* e1d = (const int*)d_in[24];
    const int* e2s = (const int*)d_in[25];
    const int* e2d = (const int*)d_in[26];
    const int NPOOL = 2 * (E1 + E2);

    char* wsb = (char*)d_ws;
    size_t o = 0;
    auto af = [&](size_t nwords) { void* p = wsb + o * 4; o += nwords; return p; };
    int* flags = (int*)af(16);
    float* w23 = (float*)af(HH);
    float* b23 = (float*)af(H);
    float* bns = (float*)af(6 * H);
    int* bsums = (int*)af(256);
    int* cnt = (int*)af(NCNT);
    int* off = (int*)af(NCNT);
    int* nbr = (int*)af(NPOOL);
    bf16* hp = (bf16*)af((size_t)NP * H / 2);
    TA* hl = (TA*)af((size_t)NL * H * sizeof(TA) / 4);
    TA* hd = (TA*)af((size_t)ND * H * sizeof(TA) / 4);
    // ---- arena: CSR-build view (dead after fill) aliases layer-buffer view ----
    size_t arena = o;
    unsigned short* r1s = (unsigned short*)af(E1 / 2);
    unsigned short* r2s = (unsigned short*)af(E2 / 2);
    unsigned int* ccnt = (unsigned int*)af((size_t)NCOPY * NPP);
    unsigned int* labHist = (unsigned int*)af((size_t)LABHB * NL);
    unsigned int* disHist = (unsigned int*)af((size_t)DISHB * ND);
    size_t endA = o;
    o = arena;
    float* bufL = (float*)af((size_t)NL * H);
    float* bufD = (float*)af((size_t)ND * H);
    bf16* tlp = (bf16*)af((size_t)NL * H / 2);
    bf16* tdp = (bf16*)af((size_t)ND * H / 2);
    bf16* aggp = (bf16*)af((size_t)NP * H / 2);
    size_t endB = o;
    o = endA > endB ? endA : endB;

    k_detect<<<1, 256, 0, stream>>>((const unsigned short*)d_in[0], flags);

    // CSR build (once; reused by both layers); embed + histograms ride in count launch
    hipMemsetAsync(ccnt, 0, (size_t)NCOPY * NPP * 4, stream);
    k_count_embed<TA><<<CNT_BLOCKS + LABHB + DISHB + EMB_BLOCKS, 256, 0, stream>>>(
        e1s, e1d, e2s, e2d, ccnt, r1s, r2s, labHist, disHist, d_in[0], d_in[1], d_in[2],
        d_in[3], d_in[4], d_in[5], d_in[6], d_in[7], d_in[8], hp, hl, hd, flags);
    k_reduce<<<RED_LAB + RED_DIS + RED_P, 256, 0, stream>>>(labHist, disHist, ccnt, cnt);
    int nb = (NCNT + SCAN_ELEMS - 1) / SCAN_ELEMS;
    k_scan1<<<nb, 256, 0, stream>>>(cnt, off, bsums, NCNT);
    k_scan2<<<1, 256, 0, stream>>>(bsums, nb);
    k_scan3<<<(NCNT + 255) / 256, 256, 0, stream>>>(off, bsums, NCNT);
    k_fill<<<CNT_BLOCKS + LABHB + DISHB, 256, 0, stream>>>(e1s, e1d, e2s, e2d, off, ccnt, r1s,
                                                           r2s, labHist, disHist, nbr);

    run_layer<TA>(d_in[9], d_in[10], d_in[11], d_in[15], d_in[16], hp, hl, hd, aggp, bufL, bufD,
                  tlp, tdp, cnt, off, nbr, w23, b23, bns, flags, stream);
    run_layer<TA>(d_in[12], d_in[13], d_in[14], d_in[17], d_in[18], hp, hl, hd, aggp, bufL, bufD,
                  tlp, tdp, cnt, off, nbr, w23, b23, bns, flags, stream);

    k_head<<<NP / 16, 256, 0, stream>>>(hp, d_in[19], d_in[20], d_in[21], d_in[22], d_out, flags);
}

extern "C" void kernel_launch(void* const* d_in, const int* in_sizes, int n_in, void* d_out,
                              int out_size, void* d_ws, size_t ws_size, hipStream_t stream) {
    const size_t NPOOL = 2 * ((size_t)E1 + E2);
    const size_t viewA = (size_t)E1 / 2 + E2 / 2 + (size_t)NCOPY * NPP + (size_t)LABHB * NL +
                         (size_t)DISHB * ND;
    const size_t viewB = (size_t)NL * H + (size_t)ND * H + (size_t)NL * H / 2 +
                         (size_t)ND * H / 2 + (size_t)NP * H / 2;
    const size_t arena = viewA > viewB ? viewA : viewB;
    const size_t fixed_f32 = 16 + HH + H + 6 * H + 256 + 2 * (size_t)NCNT + NPOOL +
                             (size_t)NP * H / 2 + (size_t)NL * H + (size_t)ND * H;
    const size_t need_f32 = (fixed_f32 + arena) * 4;  // ~87 MiB
    if (ws_size >= need_f32)
        run_all<float>(d_in, d_out, d_ws, stream);
    else
        run_all<bf16>(d_in, d_out, d_ws, stream);  // ~84 MiB
}

// Round 13
// 1107.988 us; speedup vs baseline: 6.0744x; 1.1127x over previous
//
#include <hip/hip_runtime.h>
#include <hip/hip_bf16.h>

#define NP 100000
#define NL 10000
#define ND 500
#define H 128
#define HH (H * H)
#define E1 2000000
#define E2 500000
#define NOUT 10
#define NCOPY 16
#define NPP (2 * NP)
#define NCNT (NL + ND + 2 * NP)
#define CHUNK 8192
#define LABHB ((E1 + CHUNK - 1) / CHUNK)
#define DISHB ((E2 + CHUNK - 1) / CHUNK)
#define CNT_BLOCKS ((E1 + E2 + 255) / 256)
#define EMB_BLOCKS (((NP + NL + ND) * H + 255) / 256)
#define RED_LAB ((NL + 255) / 256)
#define RED_DIS ((ND + 255) / 256)
#define RED_P ((NPP + 255) / 256)

typedef __hip_bfloat16 bf16;
typedef __attribute__((ext_vector_type(8))) short bf16x8;
typedef __attribute__((ext_vector_type(4))) float f32x4;

__device__ __forceinline__ float ldv(const float* p, size_t i) { return p[i]; }
__device__ __forceinline__ float ldv(const bf16* p, size_t i) { return __bfloat162float(p[i]); }
__device__ __forceinline__ void stv(float* p, size_t i, float v) { p[i] = v; }
__device__ __forceinline__ void stv(bf16* p, size_t i, float v) { p[i] = __float2bfloat16(v); }

__device__ __forceinline__ float bfbits2f(unsigned short s) {
    union { unsigned int u; float f; } v;
    v.u = (unsigned int)s << 16;
    return v.f;
}
__device__ __forceinline__ float2 ld_bf2(const bf16* p) {
    unsigned int u = *(const unsigned int*)p;
    return make_float2(bfbits2f((unsigned short)(u & 0xFFFFu)), bfbits2f((unsigned short)(u >> 16)));
}
__device__ __forceinline__ void st_bf2(bf16* p, float2 v) {
    union { unsigned int u; bf16 b[2]; } t;
    t.b[0] = __float2bfloat16(v.x);
    t.b[1] = __float2bfloat16(v.y);
    *(unsigned int*)p = t.u;
}
__device__ __forceinline__ float ldin(const void* p, size_t i, int f32m) {
    return f32m ? ((const float*)p)[i] : __bfloat162float(((const bf16*)p)[i]);
}

// ---------------- input dtype detection ----------------
__global__ void k_detect(const unsigned short* __restrict__ xp, int* __restrict__ flags) {
    int t = threadIdx.x;
    int cnt = 0;
    for (int i = t; i < 4096; i += 256) {
        unsigned short w = xp[2 * i];
        int e = (w >> 7) & 0xFF;
        if (w == 0 || (e >= 114 && e <= 141)) cnt++;
    }
    __shared__ int sh[256];
    sh[t] = cnt;
    __syncthreads();
    for (int s = 128; s > 0; s >>= 1) {
        if (t < s) sh[t] += sh[t + s];
        __syncthreads();
    }
    if (t == 0) flags[0] = (sh[0] < 2048) ? 1 : 0;
}

// ---- merged: patient global count | lab/dis LDS histograms | embeddings ---------------
template <typename TA>
__global__ void k_count_embed(const int* __restrict__ e1s, const int* __restrict__ e1d,
                              const int* __restrict__ e2s, const int* __restrict__ e2d,
                              unsigned int* __restrict__ ccnt, unsigned short* __restrict__ r1s,
                              unsigned short* __restrict__ r2s, unsigned int* __restrict__ labHist,
                              unsigned int* __restrict__ disHist, const void* __restrict__ xp,
                              const void* __restrict__ xl, const void* __restrict__ xd,
                              const void* __restrict__ Wp, const void* __restrict__ bp,
                              const void* __restrict__ Wlab, const void* __restrict__ blab,
                              const void* __restrict__ Wdis, const void* __restrict__ bdis,
                              bf16* __restrict__ hp, TA* __restrict__ hl, TA* __restrict__ hd,
                              const int* __restrict__ flags) {
    __shared__ unsigned int histp[NL / 2];
    int b = blockIdx.x, t = threadIdx.x;
    if (b < CNT_BLOCKS) {
        int copy = b & (NCOPY - 1);
        unsigned int* c = ccnt + (size_t)copy * NPP;
        unsigned int tag = (unsigned int)copy << 12;
        int e = b * 256 + t;
        if (e < E1) {
            unsigned int o = atomicAdd(&c[e1s[e]], 1u);
            r1s[e] = (unsigned short)(tag | (o & 0xFFFu));
        } else if (e < E1 + E2) {
            int i = e - E1;
            unsigned int o = atomicAdd(&c[NP + e2s[i]], 1u);
            r2s[i] = (unsigned short)(tag | (o & 0xFFFu));
        }
    } else if (b < CNT_BLOCKS + LABHB) {
        int c = b - CNT_BLOCKS;
        for (int i = t; i < NL / 2; i += 256) histp[i] = 0;
        __syncthreads();
        int e0 = c * CHUNK, ee = min(E1, e0 + CHUNK);
        for (int e = e0 + t; e < ee; e += 256) {
            int dd = e1d[e];
            atomicAdd(&histp[dd >> 1], 1u << (16 * (dd & 1)));
        }
        __syncthreads();
        for (int i = t; i < NL; i += 256)
            labHist[(size_t)c * NL + i] = (histp[i >> 1] >> (16 * (i & 1))) & 0xFFFFu;
    } else if (b < CNT_BLOCKS + LABHB + DISHB) {
        int c = b - CNT_BLOCKS - LABHB;
        for (int i = t; i < ND / 2; i += 256) histp[i] = 0;
        __syncthreads();
        int e0 = c * CHUNK, ee = min(E2, e0 + CHUNK);
        for (int e = e0 + t; e < ee; e += 256) {
            int dd = e2d[e];
            atomicAdd(&histp[dd >> 1], 1u << (16 * (dd & 1)));
        }
        __syncthreads();
        for (int i = t; i < ND; i += 256)
            disHist[(size_t)c * ND + i] = (histp[i >> 1] >> (16 * (i & 1))) & 0xFFFFu;
    } else {
        int f32m = flags[0];
        int idx = (b - CNT_BLOCKS - LABHB - DISHB) * 256 + t;
        int h = idx & 127;
        if (idx < NP * H) {
            int i = idx >> 7;
            float acc = ldin(bp, h, f32m);
#pragma unroll
            for (int k = 0; k < 16; ++k)
                acc = fmaf(ldin(xp, (size_t)i * 16 + k, f32m), ldin(Wp, (size_t)k * H + h, f32m), acc);
            hp[idx] = __float2bfloat16(acc);
        } else if (idx < (NP + NL) * H) {
            int i = (idx - NP * H) >> 7;
            float acc = fmaf(ldin(xl, i, f32m), ldin(Wlab, h, f32m), ldin(blab, h, f32m));
            stv(hl, (size_t)i * H + h, acc);
        } else if (idx < (NP + NL + ND) * H) {
            int i = (idx - (NP + NL) * H) >> 7;
            float acc = ldin(bdis, h, f32m);
            acc = fmaf(ldin(xd, (size_t)i * 2 + 0, f32m), ldin(Wdis, h, f32m), acc);
            acc = fmaf(ldin(xd, (size_t)i * 2 + 1, f32m), ldin(Wdis, H + h, f32m), acc);
            stv(hd, (size_t)i * H + h, acc);
        }
    }
}

// ---- reduce: chunk/copy exclusive bases; totals -> cnt --------------------------------
__global__ void k_reduce(unsigned int* __restrict__ labHist, unsigned int* __restrict__ disHist,
                         unsigned int* __restrict__ ccnt, int* __restrict__ cnt) {
    int b = blockIdx.x, t = threadIdx.x;
    if (b < RED_LAB) {
        int bin = b * 256 + t;
        if (bin < NL) {
            unsigned int run = 0;
            for (int k = 0; k < LABHB; ++k) {
                unsigned int x = labHist[(size_t)k * NL + bin];
                labHist[(size_t)k * NL + bin] = run;
                run += x;
            }
            cnt[bin] = (int)run;
        }
    } else if (b < RED_LAB + RED_DIS) {
        int bin = (b - RED_LAB) * 256 + t;
        if (bin < ND) {
            unsigned int run = 0;
            for (int k = 0; k < DISHB; ++k) {
                unsigned int x = disHist[(size_t)k * ND + bin];
                disHist[(size_t)k * ND + bin] = run;
                run += x;
            }
            cnt[NL + bin] = (int)run;
        }
    } else {
        int bin = (b - RED_LAB - RED_DIS) * 256 + t;
        if (bin < NPP) {
            unsigned int run = 0;
#pragma unroll
            for (int k = 0; k < NCOPY; ++k) {
                unsigned int x = ccnt[(size_t)k * NPP + bin];
                ccnt[(size_t)k * NPP + bin] = run;
                run += x;
            }
            cnt[NL + ND + bin] = (int)run;
        }
    }
}

#define SCAN_ELEMS 2048
__global__ void k_scan1(const int* __restrict__ in, int* __restrict__ out,
                        int* __restrict__ bsums, int n) {
    int t = threadIdx.x;
    int base = blockIdx.x * SCAN_ELEMS + t * 8;
    int v[8], tsum = 0;
#pragma unroll
    for (int j = 0; j < 8; ++j) {
        v[j] = (base + j < n) ? in[base + j] : 0;
        tsum += v[j];
    }
    __shared__ int sh[256];
    sh[t] = tsum;
    __syncthreads();
    for (int d = 1; d < 256; d <<= 1) {
        int x = (t >= d) ? sh[t - d] : 0;
        __syncthreads();
        sh[t] += x;
        __syncthreads();
    }
    int run = sh[t] - tsum;
    if (t == 255) bsums[blockIdx.x] = sh[255];
#pragma unroll
    for (int j = 0; j < 8; ++j) {
        if (base + j < n) out[base + j] = run;
        run += v[j];
    }
}

__global__ void k_scan2(int* __restrict__ bsums, int nb) {
    int t = threadIdx.x;
    int v = (t < nb) ? bsums[t] : 0;
    __shared__ int sh[256];
    sh[t] = v;
    __syncthreads();
    for (int d = 1; d < 256; d <<= 1) {
        int x = (t >= d) ? sh[t - d] : 0;
        __syncthreads();
        sh[t] += x;
        __syncthreads();
    }
    if (t < nb) bsums[t] = sh[t] - v;
}

__global__ void k_scan3(int* __restrict__ out, const int* __restrict__ bsums, int n) {
    int i = blockIdx.x * 256 + threadIdx.x;
    if (i < n) out[i] += bsums[i / SCAN_ELEMS];
}

// ---- fill ------------------------------------------------------------------------------
__global__ void k_fill(const int* __restrict__ e1s, const int* __restrict__ e1d,
                       const int* __restrict__ e2s, const int* __restrict__ e2d,
                       const int* __restrict__ off, const unsigned int* __restrict__ ccnt,
                       const unsigned short* __restrict__ r1s,
                       const unsigned short* __restrict__ r2s,
                       const unsigned int* __restrict__ labHist,
                       const unsigned int* __restrict__ disHist, int* __restrict__ nbr) {
    __shared__ unsigned int slot[NL];
    int b = blockIdx.x, t = threadIdx.x;
    if (b < CNT_BLOCKS) {
        int e = b * 256 + t;
        if (e < E1) {
            int ss = e1s[e];
            int r = r1s[e];
            int base = (int)ccnt[(size_t)(r >> 12) * NPP + ss];
            nbr[off[NL + ND + ss] + base + (r & 0xFFF)] = e1d[e];
        } else if (e < E1 + E2) {
            int i = e - E1;
            int ss = e2s[i];
            int r = r2s[i];
            int base = (int)ccnt[(size_t)(r >> 12) * NPP + NP + ss];
            nbr[off[NL + ND + NP + ss] + base + (r & 0xFFF)] = e2d[i];
        }
    } else if (b < CNT_BLOCKS + LABHB) {
        int c = b - CNT_BLOCKS;
        for (int i = t; i < NL; i += 256)
            slot[i] = (unsigned int)off[i] + labHist[(size_t)c * NL + i];
        __syncthreads();
        int e0 = c * CHUNK, ee = min(E1, e0 + CHUNK);
        for (int e = e0 + t; e < ee; e += 256) {
            unsigned int pos = atomicAdd(&slot[e1d[e]], 1u);
            nbr[pos] = e1s[e];
        }
    } else {
        int c = b - CNT_BLOCKS - LABHB;
        for (int i = t; i < ND; i += 256)
            slot[i] = (unsigned int)off[NL + i] + disHist[(size_t)c * ND + i];
        __syncthreads();
        int e0 = c * CHUNK, ee = min(E2, e0 + CHUNK);
        for (int e = e0 + t; e < ee; e += 256) {
            unsigned int pos = atomicAdd(&slot[e2d[e]], 1u);
            nbr[pos] = e2s[e];
        }
    }
}

// ---------------- stage1: dis gather | lab gather | mm_small | prep23 -------------------
#define S1_DIS ND
#define S1_LAB (NL / 4)
#define S1_MM 1313
#define S1_PREP 64
#define S1_TOTAL (S1_DIS + S1_LAB + S1_MM + S1_PREP)

template <typename TA>
__global__ void k_stage1(const bf16* __restrict__ hp, const int* __restrict__ off,
                         const int* __restrict__ cnt, const int* __restrict__ nbr,
                         float* __restrict__ bufL, float* __restrict__ bufD,
                         const TA* __restrict__ hl, const TA* __restrict__ hd,
                         const void* __restrict__ Wl, bf16* __restrict__ tlp,
                         bf16* __restrict__ tdp, const void* __restrict__ Wr,
                         const void* __restrict__ bl, bf16* __restrict__ w23bT,
                         float* __restrict__ b23, const int* __restrict__ flags) {
    __shared__ float part[4][H];
    __shared__ float smm[8][H];
    int b = blockIdx.x;
    int t = threadIdx.x;
    if (b < S1_DIS) {
        int row = b, seg = NL + row;
        int s0 = off[seg], c = cnt[seg];
        const int* nb = nbr + s0;
        int w = t >> 6, lane = t & 63, c0 = 2 * lane;
        int j = (c * w) >> 2, jend = (c * (w + 1)) >> 2;
        float2 a[8];
#pragma unroll
        for (int u = 0; u < 8; ++u) a[u] = make_float2(0.f, 0.f);
        for (; j + 8 <= jend; j += 8) {
#pragma unroll
            for (int u = 0; u < 8; ++u) {
                float2 v = ld_bf2(hp + (size_t)nb[j + u] * H + c0);
                a[u].x += v.x;
                a[u].y += v.y;
            }
        }
        for (; j < jend; ++j) {
            float2 v = ld_bf2(hp + (size_t)nb[j] * H + c0);
            a[0].x += v.x;
            a[0].y += v.y;
        }
        part[w][c0] = ((a[0].x + a[1].x) + (a[2].x + a[3].x)) + ((a[4].x + a[5].x) + (a[6].x + a[7].x));
        part[w][c0 + 1] = ((a[0].y + a[1].y) + (a[2].y + a[3].y)) + ((a[4].y + a[5].y) + (a[6].y + a[7].y));
        __syncthreads();
        if (t < H) {
            float v = (part[0][t] + part[1][t]) + (part[2][t] + part[3][t]);
            bufD[(size_t)row * H + t] = v / fmaxf((float)c, 1.f);
        }
    } else if (b < S1_DIS + S1_LAB) {
        int w = t >> 6, lane = t & 63, c0 = 2 * lane;
        int row = (b - S1_DIS) * 4 + w;
        int s0 = off[row], c = cnt[row];
        const int* nb = nbr + s0;
        float2 a[8];
#pragma unroll
        for (int u = 0; u < 8; ++u) a[u] = make_float2(0.f, 0.f);
        int j = 0;
        for (; j + 8 <= c; j += 8) {
#pragma unroll
            for (int u = 0; u < 8; ++u) {
                float2 v = ld_bf2(hp + (size_t)nb[j + u] * H + c0);
                a[u].x += v.x;
                a[u].y += v.y;
            }
        }
        for (; j < c; ++j) {
            float2 v = ld_bf2(hp + (size_t)nb[j] * H + c0);
            a[0].x += v.x;
            a[0].y += v.y;
        }
        float sx = ((a[0].x + a[1].x) + (a[2].x + a[3].x)) + ((a[4].x + a[5].x) + (a[6].x + a[7].x));
        float sy = ((a[0].y + a[1].y) + (a[2].y + a[3].y)) + ((a[4].y + a[5].y) + (a[6].y + a[7].y));
        float inv = 1.f / fmaxf((float)c, 1.f);
        *(float2*)(bufL + (size_t)row * H + c0) = make_float2(sx * inv, sy * inv);
    } else if (b < S1_DIS + S1_LAB + S1_MM) {
        int f32m = flags[0];
        int bb = b - (S1_DIS + S1_LAB);
        bool lab = bb < 1250;
        const TA* in = lab ? hl : hd;
        bf16* outp = lab ? tlp : tdp;
        int N = lab ? NL : ND;
        size_t woff = lab ? (size_t)2 * HH : (size_t)3 * HH;
        int r0 = (lab ? bb : bb - 1250) * 8;
        int h = t & 127, half = t >> 7;
        for (int r = half; r < 8; r += 2)
            smm[r][h] = (r0 + r < N) ? ldv(in, (size_t)(r0 + r) * H + h) : 0.f;
        __syncthreads();
        int rb = half * 4;
        float a0 = 0.f, a1 = 0.f, a2 = 0.f, a3 = 0.f;
        for (int k = 0; k < H; ++k) {
            float wv = ldin(Wl, woff + (size_t)k * H + h, f32m);
            a0 = fmaf(smm[rb + 0][k], wv, a0);
            a1 = fmaf(smm[rb + 1][k], wv, a1);
            a2 = fmaf(smm[rb + 2][k], wv, a2);
            a3 = fmaf(smm[rb + 3][k], wv, a3);
        }
        float acc[4] = {a0, a1, a2, a3};
#pragma unroll
        for (int r = 0; r < 4; ++r)
            if (r0 + rb + r < N)
                outp[(size_t)(r0 + rb + r) * H + h] = __float2bfloat16(acc[r]);
    } else {
        // prep23: w23bT[n][k] = bf16(Wr2[k][n] + Wr3[k][n]); b23 = bl2 + bl3 (f32)
        int f32m = flags[0];
        int idx = (b - (S1_DIS + S1_LAB + S1_MM)) * 256 + t;
        if (idx < HH) {
            int k = idx >> 7, n = idx & 127;
            float v = ldin(Wr, (size_t)2 * HH + idx, f32m) + ldin(Wr, (size_t)3 * HH + idx, f32m);
            w23bT[(size_t)n * H + k] = __float2bfloat16(v);
        }
        if (idx < H)
            b23[idx] = ldin(bl, (size_t)2 * H + idx, f32m) + ldin(bl, (size_t)3 * H + idx, f32m);
    }
}

// -------- merged: patient pass (gather + MFMA self-term) | lab/dis 2nd stage | bns zero --
#define PAT_BLOCKS (NP / 16)
#define MML_LAB (NL / 8)
#define MML_DIS ((ND + 7) / 8)
#define PATMM_TOTAL (PAT_BLOCKS + MML_LAB + MML_DIS)
#define HPAD 136  // hp LDS row pad: stride 272B -> 2-way bank alias (free)
#define APAD 132

template <typename TA>
__global__ void k_patmm(const bf16* __restrict__ hp, const bf16* __restrict__ tlp,
                        const bf16* __restrict__ tdp, const int* __restrict__ off,
                        const int* __restrict__ cnt, const int* __restrict__ nbr,
                        const bf16* __restrict__ w23bT, const float* __restrict__ b23,
                        bf16* __restrict__ aggp, float* __restrict__ bufL,
                        float* __restrict__ bufD, const TA* __restrict__ hl,
                        const TA* __restrict__ hd, const void* __restrict__ Wl,
                        const void* __restrict__ bl, const void* __restrict__ Wr,
                        float* __restrict__ bns, const int* __restrict__ flags) {
    __shared__ __align__(16) char smem[16 * HPAD * 2 + 16 * APAD * 4];  // 12.8 KB union
    int t = threadIdx.x;
    if (blockIdx.x < PAT_BLOCKS) {
        bf16(*hpA)[HPAD] = (bf16(*)[HPAD])smem;
        float(*accf)[APAD] = (float(*)[APAD])(smem + 16 * HPAD * 2);
        int w = t >> 6, lane = t & 63, c0 = 2 * lane;
        int p0 = blockIdx.x * 16;
        // stage 16 hp rows into LDS (bf16, u32 copies)
        {
            const unsigned int* hpu = (const unsigned int*)(hp + (size_t)p0 * H);
            for (int i = t; i < 16 * 64; i += 256) {
                int r = i >> 6, c = i & 63;
                *(unsigned int*)&hpA[r][2 * c] = hpu[(size_t)r * 64 + c];
            }
        }
        // gather means (wave w owns patients p0+4w..p0+4w+3), write accf rows 4w..4w+3
        {
            const int* off1 = off + NL + ND;
            const int* cnt1 = cnt + NL + ND;
            const int* off2 = off + NL + ND + NP;
            const int* cnt2 = cnt + NL + ND + NP;
            float2 bb = *(const float2*)(b23 + c0);
#pragma unroll
            for (int r = 0; r < 4; ++r) {
                int p = p0 + w * 4 + r;
                int s1 = off1[p], c1 = cnt1[p];
                const int* nb1 = nbr + s1;
                float2 aa[4];
#pragma unroll
                for (int u = 0; u < 4; ++u) aa[u] = make_float2(0.f, 0.f);
                int j = 0;
                for (; j + 4 <= c1; j += 4) {
#pragma unroll
                    for (int u = 0; u < 4; ++u) {
                        float2 v = ld_bf2(tlp + (size_t)nb1[j + u] * H + c0);
                        aa[u].x += v.x;
                        aa[u].y += v.y;
                    }
                }
                for (; j < c1; ++j) {
                    float2 v = ld_bf2(tlp + (size_t)nb1[j] * H + c0);
                    aa[0].x += v.x;
                    aa[0].y += v.y;
                }
                float a1x = (aa[0].x + aa[1].x) + (aa[2].x + aa[3].x);
                float a1y = (aa[0].y + aa[1].y) + (aa[2].y + aa[3].y);
                int s2 = off2[p], c2 = cnt2[p];
                const int* nb2 = nbr + s2;
                float2 a2a = make_float2(0.f, 0.f), a2b = a2a;
                j = 0;
                for (; j + 2 <= c2; j += 2) {
                    float2 va = ld_bf2(tdp + (size_t)nb2[j] * H + c0);
                    float2 vb = ld_bf2(tdp + (size_t)nb2[j + 1] * H + c0);
                    a2a.x += va.x; a2a.y += va.y;
                    a2b.x += vb.x; a2b.y += vb.y;
                }
                if (j < c2) {
                    float2 v = ld_bf2(tdp + (size_t)nb2[j] * H + c0);
                    a2a.x += v.x;
                    a2a.y += v.y;
                }
                float i1 = 1.f / fmaxf((float)c1, 1.f), i2 = 1.f / fmaxf((float)c2, 1.f);
                accf[w * 4 + r][c0] = a1x * i1 + (a2a.x + a2b.x) * i2 + bb.x;
                accf[w * 4 + r][c0 + 1] = a1y * i1 + (a2a.y + a2b.y) * i2 + bb.y;
            }
        }
        __syncthreads();
        // MFMA self-term: wave w computes cols [32w, 32w+32) for all 16 patients.
        // A frag: A[m=lane&15][k=(lane>>4)*8+j]; C: col=lane&15, row=(lane>>4)*4+reg.
        {
            int m = lane & 15, kg = lane >> 4;
            bf16x8 afr[4];
#pragma unroll
            for (int ks = 0; ks < 4; ++ks)
                afr[ks] = *(const bf16x8*)&hpA[m][ks * 32 + kg * 8];
            int n0 = w * 32;
#pragma unroll
            for (int tt = 0; tt < 2; ++tt) {
                int nc = n0 + tt * 16 + m;
                f32x4 acc = {0.f, 0.f, 0.f, 0.f};
#pragma unroll
                for (int ks = 0; ks < 4; ++ks) {
                    bf16x8 bfr = *(const bf16x8*)&w23bT[(size_t)nc * H + ks * 32 + kg * 8];
                    acc = __builtin_amdgcn_mfma_f32_16x16x32_bf16(afr[ks], bfr, acc, 0, 0, 0);
                }
#pragma unroll
                for (int rg = 0; rg < 4; ++rg)
                    accf[kg * 4 + rg][nc] += acc[rg];
            }
        }
        __syncthreads();
        // writeout accf -> aggp (bf16, coalesced)
        for (int i = t; i < 16 * 64; i += 256) {
            int r = i >> 6, cc = (i & 63) * 2;
            st_bf2(aggp + (size_t)(p0 + r) * H + cc, make_float2(accf[r][cc], accf[r][cc + 1]));
        }
    } else {
        float(*sB)[H] = (float(*)[H])smem;
        float(*sH)[H] = sB + 8;
        int bb = blockIdx.x - PAT_BLOCKS;
        if (bb == 0)
            for (int i = t; i < 6 * H; i += 256) bns[i] = 0.f;
        int f32m = flags[0];
        bool lab = bb < MML_LAB;
        float* buf = lab ? bufL : bufD;
        const TA* hx = lab ? hl : hd;
        size_t woff = lab ? 0 : (size_t)HH;
        size_t boff = lab ? 0 : (size_t)H;
        int N = lab ? NL : ND;
        int r0 = (lab ? bb : bb - MML_LAB) * 8;
        int h = t & 127, half = t >> 7;
        for (int r = half; r < 8; r += 2) {
            int ri = r0 + r;
            sB[r][h] = (ri < N) ? buf[(size_t)ri * H + h] : 0.f;
            sH[r][h] = (ri < N) ? ldv(hx, (size_t)ri * H + h) : 0.f;
        }
        __syncthreads();
        int rb = half * 4;
        float bv = ldin(bl, boff + h, f32m);
        float a0 = bv, a1 = bv, a2 = bv, a3 = bv;
        for (int k = 0; k < H; ++k) {
            float wl = ldin(Wl, woff + (size_t)k * H + h, f32m);
            a0 = fmaf(sB[rb + 0][k], wl, a0);
            a1 = fmaf(sB[rb + 1][k], wl, a1);
            a2 = fmaf(sB[rb + 2][k], wl, a2);
            a3 = fmaf(sB[rb + 3][k], wl, a3);
        }
        for (int k = 0; k < H; ++k) {
            float wr = ldin(Wr, woff + (size_t)k * H + h, f32m);
            a0 = fmaf(sH[rb + 0][k], wr, a0);
            a1 = fmaf(sH[rb + 1][k], wr, a1);
            a2 = fmaf(sH[rb + 2][k], wr, a2);
            a3 = fmaf(sH[rb + 3][k], wr, a3);
        }
        float acc[4] = {a0, a1, a2, a3};
#pragma unroll
        for (int r = 0; r < 4; ++r) {
            int ri = r0 + rb + r;
            if (ri < N) buf[(size_t)ri * H + h] = acc[r];
        }
    }
}

// ---------------- merged BatchNorm stats ----------------
__global__ void k_bn_stats(const bf16* __restrict__ aggp, const float* __restrict__ bufL,
                           const float* __restrict__ bufD, float* __restrict__ sums) {
    int h = threadIdx.x & 127;
    int sub = threadIdx.x >> 7;
    float s = 0.f, s2 = 0.f;
    float* sm;
    if (blockIdx.x < 1024) {
        for (int i = blockIdx.x * 2 + sub; i < NP; i += 2048) {
            float v = __bfloat162float(aggp[(size_t)i * H + h]);
            s += v;
            s2 = fmaf(v, v, s2);
        }
        sm = sums;
    } else if (blockIdx.x < 1280) {
        int bid = blockIdx.x - 1024;
        for (int i = bid * 2 + sub; i < NL; i += 512) {
            float v = bufL[(size_t)i * H + h];
            s += v;
            s2 = fmaf(v, v, s2);
        }
        sm = sums + 2 * H;
    } else {
        int bid = blockIdx.x - 1280;
        for (int i = bid * 2 + sub; i < ND; i += 128) {
            float v = bufD[(size_t)i * H + h];
            s += v;
            s2 = fmaf(v, v, s2);
        }
        sm = sums + 4 * H;
    }
    __shared__ float ls[256], ls2[256];
    ls[threadIdx.x] = s;
    ls2[threadIdx.x] = s2;
    __syncthreads();
    if (sub == 0) {
        atomicAdd(&sm[h], s + ls[128 + h]);
        atomicAdd(&sm[H + h], s2 + ls2[128 + h]);
    }
}

// ---------------- merged BatchNorm apply + relu ----------------
template <typename TA>
__global__ void k_bn_apply(const bf16* __restrict__ aggp, const float* __restrict__ bufL,
                           const float* __restrict__ bufD, bf16* __restrict__ hp,
                           TA* __restrict__ hl, TA* __restrict__ hd,
                           const float* __restrict__ sums, const void* __restrict__ g,
                           const void* __restrict__ b, const int* __restrict__ flags) {
    int f32m = flags[0];
    size_t idx = (size_t)blockIdx.x * 256 + threadIdx.x;
    int h = (int)(idx & 127);
    if (idx < (size_t)NP * H) {
        const float invN = 1.f / NP;
        float m = sums[h] * invN;
        float v = fmaf(-m, m, sums[H + h] * invN);
        float sc = rsqrtf(v + 1e-5f) * ldin(g, h, f32m);
        float r = fmaf(__bfloat162float(aggp[idx]) - m, sc, ldin(b, h, f32m));
        hp[idx] = __float2bfloat16(fmaxf(r, 0.f));
    } else if (idx < (size_t)(NP + NL) * H) {
        size_t j = idx - (size_t)NP * H;
        const float invN = 1.f / NL;
        float m = sums[2 * H + h] * invN;
        float v = fmaf(-m, m, sums[3 * H + h] * invN);
        float sc = rsqrtf(v + 1e-5f) * ldin(g, H + h, f32m);
        float r = fmaf(bufL[j] - m, sc, ldin(b, H + h, f32m));
        stv(hl, j, fmaxf(r, 0.f));
    } else if (idx < (size_t)(NP + NL + ND) * H) {
        size_t j = idx - (size_t)(NP + NL) * H;
        const float invN = 1.f / ND;
        float m = sums[4 * H + h] * invN;
        float v = fmaf(-m, m, sums[5 * H + h] * invN);
        float sc = rsqrtf(v + 1e-5f) * ldin(g, 2 * H + h, f32m);
        float r = fmaf(bufD[j] - m, sc, ldin(b, 2 * H + h, f32m));
        stv(hd, j, fmaxf(r, 0.f));
    }
}

// ---------------- head ----------------
__global__ void k_head(const bf16* __restrict__ hp, const void* __restrict__ W1,
                       const void* __restrict__ b1, const void* __restrict__ W2,
                       const void* __restrict__ b2, void* __restrict__ out,
                       const int* __restrict__ flags) {
    int f32m = flags[0];
    __shared__ float W1s[H * 64];
    __shared__ float W2s[64 * NOUT];
    __shared__ float b1s[64], b2s[NOUT];
    __shared__ float rows[16][H];
    __shared__ float h1s[16][65];
    __shared__ float lgs[16][16];
    int t = threadIdx.x;
    for (int i = t; i < H * 64; i += 256) W1s[i] = ldin(W1, i, f32m);
    for (int i = t; i < 64 * NOUT; i += 256) W2s[i] = ldin(W2, i, f32m);
    if (t < 64) b1s[t] = ldin(b1, t, f32m);
    else if (t >= 64 && t < 64 + NOUT) b2s[t - 64] = ldin(b2, t - 64, f32m);
    int p0 = blockIdx.x * 16;
    for (int i = t; i < 16 * 64; i += 256) {
        int r = i >> 6, c2 = (i & 63) * 2;
        float2 v = ld_bf2(hp + (size_t)(p0 + r) * H + c2);
        rows[r][c2] = v.x;
        rows[r][c2 + 1] = v.y;
    }
    __syncthreads();
    int w = t >> 6, lane = t & 63;
    const float* r0 = rows[4 * w + 0];
    const float* r1 = rows[4 * w + 1];
    const float* r2 = rows[4 * w + 2];
    const float* r3 = rows[4 * w + 3];
    float a0 = b1s[lane], a1 = a0, a2 = a0, a3 = a0;
#pragma unroll 4
    for (int k = 0; k < H; ++k) {
        float wv = W1s[k * 64 + lane];
        a0 = fmaf(r0[k], wv, a0);
        a1 = fmaf(r1[k], wv, a1);
        a2 = fmaf(r2[k], wv, a2);
        a3 = fmaf(r3[k], wv, a3);
    }
    h1s[4 * w + 0][lane] = fmaxf(a0, 0.f);
    h1s[4 * w + 1][lane] = fmaxf(a1, 0.f);
    h1s[4 * w + 2][lane] = fmaxf(a2, 0.f);
    h1s[4 * w + 3][lane] = fmaxf(a3, 0.f);
    __syncthreads();
    int pat = lane >> 4, oidx = lane & 15;
    int prow = 4 * w + pat;
    float lg = 0.f;
    if (oidx < NOUT) {
        lg = b2s[oidx];
        const float* hh = h1s[prow];
#pragma unroll 8
        for (int k = 0; k < 64; ++k) lg = fmaf(hh[k], W2s[k * NOUT + oidx], lg);
        lgs[prow][oidx] = lg;
    }
    __syncthreads();
    if (oidx < NOUT) {
        float m = -1e30f;
#pragma unroll
        for (int k = 0; k < NOUT; ++k) m = fmaxf(m, lgs[prow][k]);
        float s = 0.f;
#pragma unroll
        for (int k = 0; k < NOUT; ++k) s += __expf(lgs[prow][k] - m);
        float r = lg - m - __logf(s);
        if (f32m)
            ((float*)out)[(size_t)(p0 + prow) * NOUT + oidx] = r;
        else
            ((bf16*)out)[(size_t)(p0 + prow) * NOUT + oidx] = __float2bfloat16(r);
    }
}

// ---------------- one hetero layer ----------------
template <typename TA>
static void run_layer(const void* Wl, const void* bl, const void* Wr, const void* bng,
                      const void* bnb, bf16* hp, TA* hl, TA* hd, bf16* aggp, float* bufL,
                      float* bufD, bf16* tlp, bf16* tdp, const int* cnt, const int* off,
                      const int* nbr, bf16* w23bT, float* b23, float* bns, const int* flags,
                      hipStream_t stream) {
    k_stage1<TA><<<S1_TOTAL, 256, 0, stream>>>(hp, off, cnt, nbr, bufL, bufD, hl, hd, Wl, tlp,
                                               tdp, Wr, bl, w23bT, b23, flags);
    k_patmm<TA><<<PATMM_TOTAL, 256, 0, stream>>>(hp, tlp, tdp, off, cnt, nbr, w23bT, b23, aggp,
                                                 bufL, bufD, hl, hd, Wl, bl, Wr, bns, flags);
    k_bn_stats<<<1344, 256, 0, stream>>>(aggp, bufL, bufD, bns);
    k_bn_apply<TA><<<(int)(((size_t)(NP + NL + ND) * H + 255) / 256), 256, 0, stream>>>(
        aggp, bufL, bufD, hp, hl, hd, bns, bng, bnb, flags);
}

template <typename TA>
static void run_all(void* const* d_in, void* d_out, void* d_ws, hipStream_t stream) {
    const int* e1s = (const int*)d_in[23];
    const int* e1d = (const int*)d_in[24];
    const int* e2s = (const int*)d_in[25];
    const int* e2d = (const int*)d_in[26];
    const int NPOOL = 2 * (E1 + E2);

    char* wsb = (char*)d_ws;
    size_t o = 0;
    auto af = [&](size_t nwords) { void* p = wsb + o * 4; o += nwords; return p; };
    int* flags = (int*)af(16);
    bf16* w23bT = (bf16*)af(HH / 2);
    float* b23 = (float*)af(H);
    float* bns = (float*)af(6 * H);
    int* bsums = (int*)af(256);
    int* cnt = (int*)af(NCNT);
    int* off = (int*)af(NCNT);
    int* nbr = (int*)af(NPOOL);
    bf16* hp = (bf16*)af((size_t)NP * H / 2);
    TA* hl = (TA*)af((size_t)NL * H * sizeof(TA) / 4);
    TA* hd = (TA*)af((size_t)ND * H * sizeof(TA) / 4);
    size_t arena = o;
    unsigned short* r1s = (unsigned short*)af(E1 / 2);
    unsigned short* r2s = (unsigned short*)af(E2 / 2);
    unsigned int* ccnt = (unsigned int*)af((size_t)NCOPY * NPP);
    unsigned int* labHist = (unsigned int*)af((size_t)LABHB * NL);
    unsigned int* disHist = (unsigned int*)af((size_t)DISHB * ND);
    size_t endA = o;
    o = arena;
    float* bufL = (float*)af((size_t)NL * H);
    float* bufD = (float*)af((size_t)ND * H);
    bf16* tlp = (bf16*)af((size_t)NL * H / 2);
    bf16* tdp = (bf16*)af((size_t)ND * H / 2);
    bf16* aggp = (bf16*)af((size_t)NP * H / 2);
    size_t endB = o;
    o = endA > endB ? endA : endB;

    k_detect<<<1, 256, 0, stream>>>((const unsigned short*)d_in[0], flags);

    hipMemsetAsync(ccnt, 0, (size_t)NCOPY * NPP * 4, stream);
    k_count_embed<TA><<<CNT_BLOCKS + LABHB + DISHB + EMB_BLOCKS, 256, 0, stream>>>(
        e1s, e1d, e2s, e2d, ccnt, r1s, r2s, labHist, disHist, d_in[0], d_in[1], d_in[2],
        d_in[3], d_in[4], d_in[5], d_in[6], d_in[7], d_in[8], hp, hl, hd, flags);
    k_reduce<<<RED_LAB + RED_DIS + RED_P, 256, 0, stream>>>(labHist, disHist, ccnt, cnt);
    int nb = (NCNT + SCAN_ELEMS - 1) / SCAN_ELEMS;
    k_scan1<<<nb, 256, 0, stream>>>(cnt, off, bsums, NCNT);
    k_scan2<<<1, 256, 0, stream>>>(bsums, nb);
    k_scan3<<<(NCNT + 255) / 256, 256, 0, stream>>>(off, bsums, NCNT);
    k_fill<<<CNT_BLOCKS + LABHB + DISHB, 256, 0, stream>>>(e1s, e1d, e2s, e2d, off, ccnt, r1s,
                                                           r2s, labHist, disHist, nbr);

    run_layer<TA>(d_in[9], d_in[10], d_in[11], d_in[15], d_in[16], hp, hl, hd, aggp, bufL, bufD,
                  tlp, tdp, cnt, off, nbr, w23bT, b23, bns, flags, stream);
    run_layer<TA>(d_in[12], d_in[13], d_in[14], d_in[17], d_in[18], hp, hl, hd, aggp, bufL, bufD,
                  tlp, tdp, cnt, off, nbr, w23bT, b23, bns, flags, stream);

    k_head<<<NP / 16, 256, 0, stream>>>(hp, d_in[19], d_in[20], d_in[21], d_in[22], d_out, flags);
}

extern "C" void kernel_launch(void* const* d_in, const int* in_sizes, int n_in, void* d_out,
                              int out_size, void* d_ws, size_t ws_size, hipStream_t stream) {
    const size_t NPOOL = 2 * ((size_t)E1 + E2);
    const size_t viewA = (size_t)E1 / 2 + E2 / 2 + (size_t)NCOPY * NPP + (size_t)LABHB * NL +
                         (size_t)DISHB * ND;
    const size_t viewB = (size_t)NL * H + (size_t)ND * H + (size_t)NL * H / 2 +
                         (size_t)ND * H / 2 + (size_t)NP * H / 2;
    const size_t arena = viewA > viewB ? viewA : viewB;
    const size_t fixed_f32 = 16 + HH / 2 + H + 6 * H + 256 + 2 * (size_t)NCNT + NPOOL +
                             (size_t)NP * H / 2 + (size_t)NL * H + (size_t)ND * H;
    const size_t need_f32 = (fixed_f32 + arena) * 4;  // ~87 MiB
    if (ws_size >= need_f32)
        run_all<float>(d_in, d_out, d_ws, stream);
    else
        run_all<bf16>(d_in, d_out, d_ws, stream);  // ~84 MiB
}

// Round 14
// 1035.514 us; speedup vs baseline: 6.4995x; 1.0700x over previous
//
#include <hip/hip_runtime.h>
#include <hip/hip_bf16.h>

#define NP 100000
#define NL 10000
#define ND 500
#define H 128
#define HH (H * H)
#define E1 2000000
#define E2 500000
#define NOUT 10
#define NCOPY 16
#define NPP (2 * NP)
#define NCNT (NL + ND + 2 * NP)
#define NROW (NL + ND)
#define CHUNK 8192
#define LABHB ((E1 + CHUNK - 1) / CHUNK)
#define DISHB ((E2 + CHUNK - 1) / CHUNK)
#define CNT_BLOCKS ((E1 + E2 + 255) / 256)
#define EMBP ((NP * H + 255) / 256)
#define RED_LAB ((NL + 255) / 256)
#define RED_DIS ((ND + 255) / 256)
#define RED_P ((NPP + 255) / 256)

typedef __hip_bfloat16 bf16;
typedef __attribute__((ext_vector_type(8))) short bf16x8;
typedef __attribute__((ext_vector_type(4))) float f32x4;

__device__ __forceinline__ float ldv(const float* p, size_t i) { return p[i]; }
__device__ __forceinline__ float ldv(const bf16* p, size_t i) { return __bfloat162float(p[i]); }
__device__ __forceinline__ void stv(float* p, size_t i, float v) { p[i] = v; }
__device__ __forceinline__ void stv(bf16* p, size_t i, float v) { p[i] = __float2bfloat16(v); }

__device__ __forceinline__ float bfbits2f(unsigned short s) {
    union { unsigned int u; float f; } v;
    v.u = (unsigned int)s << 16;
    return v.f;
}
__device__ __forceinline__ float2 ld_bf2(const bf16* p) {
    unsigned int u = *(const unsigned int*)p;
    return make_float2(bfbits2f((unsigned short)(u & 0xFFFFu)), bfbits2f((unsigned short)(u >> 16)));
}
__device__ __forceinline__ void st_bf2(bf16* p, float2 v) {
    union { unsigned int u; bf16 b[2]; } t;
    t.b[0] = __float2bfloat16(v.x);
    t.b[1] = __float2bfloat16(v.y);
    *(unsigned int*)p = t.u;
}
__device__ __forceinline__ float ldin(const void* p, size_t i, int f32m) {
    return f32m ? ((const float*)p)[i] : __bfloat162float(((const bf16*)p)[i]);
}

// ---------------- input dtype detection ----------------
__global__ void k_detect(const unsigned short* __restrict__ xp, int* __restrict__ flags) {
    int t = threadIdx.x;
    int cnt = 0;
    for (int i = t; i < 4096; i += 256) {
        unsigned short w = xp[2 * i];
        int e = (w >> 7) & 0xFF;
        if (w == 0 || (e >= 114 && e <= 141)) cnt++;
    }
    __shared__ int sh[256];
    sh[t] = cnt;
    __syncthreads();
    for (int s = 128; s > 0; s >>= 1) {
        if (t < s) sh[t] += sh[t + s];
        __syncthreads();
    }
    if (t == 0) flags[0] = (sh[0] < 2048) ? 1 : 0;
}

// ---- merged: p-count | lab/dis hists | hp embed | L1 weight-precompute ----------------
// L1 algebra: tlp[i]=xl[i]*uL+vL (rank-1), mean_hp=(mean x_p)@Wp+bp -> precompute products.
#define PB0 CNT_BLOCKS
#define PB1 (PB0 + LABHB)
#define PB2 (PB1 + DISHB)
#define PB3 (PB2 + EMBP)
#define PB4 (PB3 + 16)   // WpWl0/WpWl1
#define PB5 (PB4 + 7)    // 13 vecs
#define PB6 (PB5 + 64)   // w23bT_1
__global__ void k_count_embed(const int* __restrict__ e1s, const int* __restrict__ e1d,
                              const int* __restrict__ e2s, const int* __restrict__ e2d,
                              unsigned int* __restrict__ ccnt, unsigned short* __restrict__ r1s,
                              unsigned short* __restrict__ r2s, unsigned int* __restrict__ labHist,
                              unsigned int* __restrict__ disHist, const void* __restrict__ xp,
                              const void* __restrict__ Wp, const void* __restrict__ bp,
                              const void* __restrict__ Wlab, const void* __restrict__ blab,
                              const void* __restrict__ Wdis, const void* __restrict__ bdis,
                              const void* __restrict__ Wl1, const void* __restrict__ bl1,
                              const void* __restrict__ Wr1, bf16* __restrict__ hp,
                              float* __restrict__ WpWl0, float* __restrict__ WpWl1,
                              float* __restrict__ vecs, bf16* __restrict__ w23bT1,
                              const int* __restrict__ flags) {
    __shared__ unsigned int histp[NL / 2];
    int b = blockIdx.x, t = threadIdx.x;
    if (b < PB0) {
        int copy = b & (NCOPY - 1);
        unsigned int* c = ccnt + (size_t)copy * NPP;
        unsigned int tag = (unsigned int)copy << 12;
        int e = b * 256 + t;
        if (e < E1) {
            unsigned int o = atomicAdd(&c[e1s[e]], 1u);
            r1s[e] = (unsigned short)(tag | (o & 0xFFFu));
        } else if (e < E1 + E2) {
            int i = e - E1;
            unsigned int o = atomicAdd(&c[NP + e2s[i]], 1u);
            r2s[i] = (unsigned short)(tag | (o & 0xFFFu));
        }
    } else if (b < PB1) {
        int c = b - PB0;
        for (int i = t; i < NL / 2; i += 256) histp[i] = 0;
        __syncthreads();
        int e0 = c * CHUNK, ee = min(E1, e0 + CHUNK);
        for (int e = e0 + t; e < ee; e += 256) {
            int dd = e1d[e];
            atomicAdd(&histp[dd >> 1], 1u << (16 * (dd & 1)));
        }
        __syncthreads();
        for (int i = t; i < NL; i += 256)
            labHist[(size_t)c * NL + i] = (histp[i >> 1] >> (16 * (i & 1))) & 0xFFFFu;
    } else if (b < PB2) {
        int c = b - PB1;
        for (int i = t; i < ND / 2; i += 256) histp[i] = 0;
        __syncthreads();
        int e0 = c * CHUNK, ee = min(E2, e0 + CHUNK);
        for (int e = e0 + t; e < ee; e += 256) {
            int dd = e2d[e];
            atomicAdd(&histp[dd >> 1], 1u << (16 * (dd & 1)));
        }
        __syncthreads();
        for (int i = t; i < ND; i += 256)
            disHist[(size_t)c * ND + i] = (histp[i >> 1] >> (16 * (i & 1))) & 0xFFFFu;
    } else if (b < PB3) {
        int f32m = flags[0];
        int idx = (b - PB2) * 256 + t;
        int h = idx & 127;
        int i = idx >> 7;
        float acc = ldin(bp, h, f32m);
#pragma unroll
        for (int k = 0; k < 16; ++k)
            acc = fmaf(ldin(xp, (size_t)i * 16 + k, f32m), ldin(Wp, (size_t)k * H + h, f32m), acc);
        hp[idx] = __float2bfloat16(acc);
    } else if (b < PB4) {
        // WpWl0[k][h] = sum_m Wp[k][m]*Wl1[0][m][h]; WpWl1 with Wl1[1]
        int f32m = flags[0];
        int pb = b - PB3;
        bool first = pb < 8;
        size_t woff = first ? 0 : (size_t)HH;
        float* outp = first ? WpWl0 : WpWl1;
        int k = (first ? pb : pb - 8) * 2 + (t >> 7);
        int h = t & 127;
        float s = 0.f;
        for (int m = 0; m < H; ++m)
            s = fmaf(ldin(Wp, (size_t)k * H + m, f32m), ldin(Wl1, woff + (size_t)m * H + h, f32m), s);
        outp[k * H + h] = s;
    } else if (b < PB5) {
        // 13 precomputed 128-vectors (see map below)
        int f32m = flags[0];
        int idx = (b - PB4) * 256 + t;
        if (idx < 13 * 128) {
            int v = idx >> 7, h = idx & 127;
            float s = 0.f;
            if (v == 12) {
                s = ldin(bl1, 2 * H + h, f32m) + ldin(bl1, 3 * H + h, f32m);
            } else {
                const void* A;
                size_t aoff = 0;
                const void* W;
                size_t woff;
                float add = 0.f;
                switch (v) {
                    case 0: A = Wlab; W = Wl1; woff = 2 * (size_t)HH; break;           // uL
                    case 1: A = blab; W = Wl1; woff = 2 * (size_t)HH; break;           // vL
                    case 2: A = Wdis; W = Wl1; woff = 3 * (size_t)HH; break;           // uD0
                    case 3: A = Wdis; aoff = H; W = Wl1; woff = 3 * (size_t)HH; break; // uD1
                    case 4: A = bdis; W = Wl1; woff = 3 * (size_t)HH; break;           // vD
                    case 5: A = Wlab; W = Wr1; woff = 0; break;                        // uRl
                    case 6: A = blab; W = Wr1; woff = 0; add = ldin(bl1, h, f32m); break; // w_lab
                    case 7: A = Wdis; W = Wr1; woff = (size_t)HH; break;               // uRd0
                    case 8: A = Wdis; aoff = H; W = Wr1; woff = (size_t)HH; break;     // uRd1
                    case 9: A = bdis; W = Wr1; woff = (size_t)HH; add = ldin(bl1, H + h, f32m); break; // w_dis
                    case 10: A = bp; W = Wl1; woff = 0; break;                         // bpWl0
                    default: A = bp; W = Wl1; woff = (size_t)HH; break;                // 11 bpWl1
                }
                for (int m = 0; m < H; ++m)
                    s = fmaf(ldin(A, aoff + m, f32m), ldin(W, woff + (size_t)m * H + h, f32m), s);
                s += add;
            }
            vecs[v * 128 + h] = s;
        }
    } else {
        // w23bT_1[n][k] = bf16(Wr1[2][k][n] + Wr1[3][k][n])
        int f32m = flags[0];
        int idx = (b - PB5) * 256 + t;
        if (idx < HH) {
            int k = idx >> 7, n = idx & 127;
            float v = ldin(Wr1, (size_t)2 * HH + idx, f32m) + ldin(Wr1, (size_t)3 * HH + idx, f32m);
            w23bT1[(size_t)n * H + k] = __float2bfloat16(v);
        }
    }
}

// ---- reduce: chunk/copy exclusive bases; totals -> cnt --------------------------------
__global__ void k_reduce(unsigned int* __restrict__ labHist, unsigned int* __restrict__ disHist,
                         unsigned int* __restrict__ ccnt, int* __restrict__ cnt) {
    int b = blockIdx.x, t = threadIdx.x;
    if (b < RED_LAB) {
        int bin = b * 256 + t;
        if (bin < NL) {
            unsigned int run = 0;
            for (int k = 0; k < LABHB; ++k) {
                unsigned int x = labHist[(size_t)k * NL + bin];
                labHist[(size_t)k * NL + bin] = run;
                run += x;
            }
            cnt[bin] = (int)run;
        }
    } else if (b < RED_LAB + RED_DIS) {
        int bin = (b - RED_LAB) * 256 + t;
        if (bin < ND) {
            unsigned int run = 0;
            for (int k = 0; k < DISHB; ++k) {
                unsigned int x = disHist[(size_t)k * ND + bin];
                disHist[(size_t)k * ND + bin] = run;
                run += x;
            }
            cnt[NL + bin] = (int)run;
        }
    } else {
        int bin = (b - RED_LAB - RED_DIS) * 256 + t;
        if (bin < NPP) {
            unsigned int run = 0;
#pragma unroll
            for (int k = 0; k < NCOPY; ++k) {
                unsigned int x = ccnt[(size_t)k * NPP + bin];
                ccnt[(size_t)k * NPP + bin] = run;
                run += x;
            }
            cnt[NL + ND + bin] = (int)run;
        }
    }
}

#define SCAN_ELEMS 2048
__global__ void k_scan1(const int* __restrict__ in, int* __restrict__ out,
                        int* __restrict__ bsums, int n) {
    int t = threadIdx.x;
    int base = blockIdx.x * SCAN_ELEMS + t * 8;
    int v[8], tsum = 0;
#pragma unroll
    for (int j = 0; j < 8; ++j) {
        v[j] = (base + j < n) ? in[base + j] : 0;
        tsum += v[j];
    }
    __shared__ int sh[256];
    sh[t] = tsum;
    __syncthreads();
    for (int d = 1; d < 256; d <<= 1) {
        int x = (t >= d) ? sh[t - d] : 0;
        __syncthreads();
        sh[t] += x;
        __syncthreads();
    }
    int run = sh[t] - tsum;
    if (t == 255) bsums[blockIdx.x] = sh[255];
#pragma unroll
    for (int j = 0; j < 8; ++j) {
        if (base + j < n) out[base + j] = run;
        run += v[j];
    }
}

__global__ void k_scan2(int* __restrict__ bsums, int nb) {
    int t = threadIdx.x;
    int v = (t < nb) ? bsums[t] : 0;
    __shared__ int sh[256];
    sh[t] = v;
    __syncthreads();
    for (int d = 1; d < 256; d <<= 1) {
        int x = (t >= d) ? sh[t - d] : 0;
        __syncthreads();
        sh[t] += x;
        __syncthreads();
    }
    if (t < nb) bsums[t] = sh[t] - v;
}

__global__ void k_scan3(int* __restrict__ out, const int* __restrict__ bsums, int n) {
    int i = blockIdx.x * 256 + threadIdx.x;
    if (i < n) out[i] += bsums[i / SCAN_ELEMS];
}

// ---- fill ------------------------------------------------------------------------------
__global__ void k_fill(const int* __restrict__ e1s, const int* __restrict__ e1d,
                       const int* __restrict__ e2s, const int* __restrict__ e2d,
                       const int* __restrict__ off, const unsigned int* __restrict__ ccnt,
                       const unsigned short* __restrict__ r1s,
                       const unsigned short* __restrict__ r2s,
                       const unsigned int* __restrict__ labHist,
                       const unsigned int* __restrict__ disHist, int* __restrict__ nbr) {
    __shared__ unsigned int slot[NL];
    int b = blockIdx.x, t = threadIdx.x;
    if (b < CNT_BLOCKS) {
        int e = b * 256 + t;
        if (e < E1) {
            int ss = e1s[e];
            int r = r1s[e];
            int base = (int)ccnt[(size_t)(r >> 12) * NPP + ss];
            nbr[off[NL + ND + ss] + base + (r & 0xFFF)] = e1d[e];
        } else if (e < E1 + E2) {
            int i = e - E1;
            int ss = e2s[i];
            int r = r2s[i];
            int base = (int)ccnt[(size_t)(r >> 12) * NPP + NP + ss];
            nbr[off[NL + ND + NP + ss] + base + (r & 0xFFF)] = e2d[i];
        }
    } else if (b < CNT_BLOCKS + LABHB) {
        int c = b - CNT_BLOCKS;
        for (int i = t; i < NL; i += 256)
            slot[i] = (unsigned int)off[i] + labHist[(size_t)c * NL + i];
        __syncthreads();
        int e0 = c * CHUNK, ee = min(E1, e0 + CHUNK);
        for (int e = e0 + t; e < ee; e += 256) {
            unsigned int pos = atomicAdd(&slot[e1d[e]], 1u);
            nbr[pos] = e1s[e];
        }
    } else {
        int c = b - CNT_BLOCKS - LABHB;
        for (int i = t; i < ND; i += 256)
            slot[i] = (unsigned int)off[NL + i] + disHist[(size_t)c * ND + i];
        __syncthreads();
        int e0 = c * CHUNK, ee = min(E2, e0 + CHUNK);
        for (int e = e0 + t; e < ee; e += 256) {
            unsigned int pos = atomicAdd(&slot[e2d[e]], 1u);
            nbr[pos] = e2s[e];
        }
    }
}

// ---------------- L1 stage1: gather 16-dim mean of x_p per lab/dis row ------------------
__global__ void k_stage1_L1(const void* __restrict__ xp, const int* __restrict__ off,
                            const int* __restrict__ cnt, const int* __restrict__ nbr,
                            float* __restrict__ mxp, const int* __restrict__ flags) {
    int f32m = flags[0];
    int t = threadIdx.x;
    int w = t >> 6, lane = t & 63;
    int row = blockIdx.x * 4 + w;
    if (row >= NROW) return;
    int s0 = off[row], c = cnt[row];
    int slot = lane >> 4, dim = lane & 15;
    float a0 = 0.f, a1 = 0.f, a2 = 0.f, a3 = 0.f;
    int j = slot;
    for (; j + 16 <= c; j += 16) {
        a0 += ldin(xp, (size_t)nbr[s0 + j] * 16 + dim, f32m);
        a1 += ldin(xp, (size_t)nbr[s0 + j + 4] * 16 + dim, f32m);
        a2 += ldin(xp, (size_t)nbr[s0 + j + 8] * 16 + dim, f32m);
        a3 += ldin(xp, (size_t)nbr[s0 + j + 12] * 16 + dim, f32m);
    }
    for (; j < c; j += 4) a0 += ldin(xp, (size_t)nbr[s0 + j] * 16 + dim, f32m);
    float acc = (a0 + a1) + (a2 + a3);
    acc += __shfl_xor(acc, 16);
    acc += __shfl_xor(acc, 32);
    if (lane < 16) mxp[(size_t)row * 16 + lane] = acc / fmaxf((float)c, 1.f);
}

// -------- L1 patmm: scalar gathers + MFMA self-term | lab/dis affine update | bns zero --
#define PAT_BLOCKS (NP / 16)
#define LD1_BLOCKS ((NROW + 1) / 2)
#define HPAD 136
#define APAD 132
__global__ void k_patmm_L1(const bf16* __restrict__ hp, const void* __restrict__ xl,
                           const void* __restrict__ xd, const int* __restrict__ off,
                           const int* __restrict__ cnt, const int* __restrict__ nbr,
                           const bf16* __restrict__ w23bT1, const float* __restrict__ vecs,
                           const float* __restrict__ WpWl0, const float* __restrict__ WpWl1,
                           const float* __restrict__ mxp, bf16* __restrict__ aggp,
                           float* __restrict__ bufL, float* __restrict__ bufD,
                           float* __restrict__ bns, const int* __restrict__ flags) {
    int t = threadIdx.x;
    int f32m = flags[0];
    if (blockIdx.x < PAT_BLOCKS) {
        __shared__ bf16 hpA[16][HPAD];
        __shared__ float accf[16][APAD];
        __shared__ float svec[6][128];  // uL vL uD0 uD1 vD b23
        __shared__ float s_mxl[16], s_onL[16], s_d0[16], s_d1[16], s_onD[16];
        int w = t >> 6, lane = t & 63;
        int p0 = blockIdx.x * 16;
        // stage hp rows
        {
            const unsigned int* hpu = (const unsigned int*)(hp + (size_t)p0 * H);
            for (int i = t; i < 16 * 64; i += 256) {
                int r = i >> 6, c = i & 63;
                *(unsigned int*)&hpA[r][2 * c] = hpu[(size_t)r * 64 + c];
            }
        }
        // stage vecs {0,1,2,3,4,12}
        {
            const int map[6] = {0, 1, 2, 3, 4, 12};
            for (int i = t; i < 6 * 128; i += 256)
                svec[i >> 7][i & 127] = vecs[map[i >> 7] * 128 + (i & 127)];
        }
        // scalar gathers: group g (16 lanes) handles patient p0+g
        {
            int g = t >> 4, sl = t & 15;
            int p = p0 + g;
            int s1 = off[NL + ND + p], c1 = cnt[NL + ND + p];
            float a = 0.f;
            for (int j = sl; j < c1; j += 16) a += ldin(xl, nbr[s1 + j], f32m);
            a += __shfl_xor(a, 1);
            a += __shfl_xor(a, 2);
            a += __shfl_xor(a, 4);
            a += __shfl_xor(a, 8);
            int s2 = off[NL + ND + NP + p], c2 = cnt[NL + ND + NP + p];
            float d0 = 0.f, d1 = 0.f;
            for (int j = sl; j < c2; j += 16) {
                int q = nbr[s2 + j];
                d0 += ldin(xd, (size_t)2 * q, f32m);
                d1 += ldin(xd, (size_t)2 * q + 1, f32m);
            }
            d0 += __shfl_xor(d0, 1); d0 += __shfl_xor(d0, 2);
            d0 += __shfl_xor(d0, 4); d0 += __shfl_xor(d0, 8);
            d1 += __shfl_xor(d1, 1); d1 += __shfl_xor(d1, 2);
            d1 += __shfl_xor(d1, 4); d1 += __shfl_xor(d1, 8);
            if (sl == 0) {
                s_mxl[g] = a / fmaxf((float)c1, 1.f);
                s_onL[g] = (c1 > 0) ? 1.f : 0.f;
                s_d0[g] = d0 / fmaxf((float)c2, 1.f);
                s_d1[g] = d1 / fmaxf((float)c2, 1.f);
                s_onD[g] = (c2 > 0) ? 1.f : 0.f;
            }
        }
        __syncthreads();
        // MFMA self-term (writes accf '=')
        {
            int m = lane & 15, kg = lane >> 4;
            bf16x8 afr[4];
#pragma unroll
            for (int ks = 0; ks < 4; ++ks)
                afr[ks] = *(const bf16x8*)&hpA[m][ks * 32 + kg * 8];
            int n0 = w * 32;
#pragma unroll
            for (int tt = 0; tt < 2; ++tt) {
                int nc = n0 + tt * 16 + m;
                f32x4 acc = {0.f, 0.f, 0.f, 0.f};
#pragma unroll
                for (int ks = 0; ks < 4; ++ks) {
                    bf16x8 bfr = *(const bf16x8*)&w23bT1[(size_t)nc * H + ks * 32 + kg * 8];
                    acc = __builtin_amdgcn_mfma_f32_16x16x32_bf16(afr[ks], bfr, acc, 0, 0, 0);
                }
#pragma unroll
                for (int rg = 0; rg < 4; ++rg)
                    accf[kg * 4 + rg][nc] = acc[rg];
            }
        }
        __syncthreads();
        // writeout: accf + lab/dis affine terms + b23
        for (int i = t; i < 16 * 64; i += 256) {
            int r = i >> 6, cc = (i & 63) * 2;
            float l0 = s_onL[r] * fmaf(s_mxl[r], svec[0][cc], svec[1][cc]);
            float l1 = s_onL[r] * fmaf(s_mxl[r], svec[0][cc + 1], svec[1][cc + 1]);
            float q0 = s_onD[r] * (s_d0[r] * svec[2][cc] + s_d1[r] * svec[3][cc] + svec[4][cc]);
            float q1 = s_onD[r] * (s_d0[r] * svec[2][cc + 1] + s_d1[r] * svec[3][cc + 1] + svec[4][cc + 1]);
            float v0 = accf[r][cc] + l0 + q0 + svec[5][cc];
            float v1 = accf[r][cc + 1] + l1 + q1 + svec[5][cc + 1];
            st_bf2(aggp + (size_t)(p0 + r) * H + cc, make_float2(v0, v1));
        }
    } else {
        int bb = blockIdx.x - PAT_BLOCKS;
        if (bb == 0)
            for (int i = t; i < 6 * H; i += 256) bns[i] = 0.f;
        int rr = bb * 2 + (t >> 7);
        int h = t & 127;
        if (rr >= NROW) return;
        if (rr < NL) {
            // bufL = w_lab + xl*uRl + [c>0](mxp@WpWl0 + bpWl0)
            float acc = vecs[6 * 128 + h] + ldin(xl, rr, f32m) * vecs[5 * 128 + h];
            if (cnt[rr] > 0) {
                float s = vecs[10 * 128 + h];
                const float* mx = mxp + (size_t)rr * 16;
#pragma unroll
                for (int k = 0; k < 16; ++k) s = fmaf(mx[k], WpWl0[k * H + h], s);
                acc += s;
            }
            bufL[(size_t)rr * H + h] = acc;
        } else {
            int rd = rr - NL;
            float acc = vecs[9 * 128 + h] + ldin(xd, (size_t)2 * rd, f32m) * vecs[7 * 128 + h] +
                        ldin(xd, (size_t)2 * rd + 1, f32m) * vecs[8 * 128 + h];
            if (cnt[rr] > 0) {
                float s = vecs[11 * 128 + h];
                const float* mx = mxp + (size_t)rr * 16;
#pragma unroll
                for (int k = 0; k < 16; ++k) s = fmaf(mx[k], WpWl1[k * H + h], s);
                acc += s;
            }
            bufD[(size_t)rd * H + h] = acc;
        }
    }
}

// ---------------- L2 stage1: dis gather | lab gather | mm_small | prep23 ----------------
#define S1_DIS ND
#define S1_LAB (NL / 4)
#define S1_MM 1313
#define S1_PREP 64
#define S1_TOTAL (S1_DIS + S1_LAB + S1_MM + S1_PREP)

template <typename TA>
__global__ void k_stage1(const bf16* __restrict__ hp, const int* __restrict__ off,
                         const int* __restrict__ cnt, const int* __restrict__ nbr,
                         float* __restrict__ bufL, float* __restrict__ bufD,
                         const TA* __restrict__ hl, const TA* __restrict__ hd,
                         const void* __restrict__ Wl, bf16* __restrict__ tlp,
                         bf16* __restrict__ tdp, const void* __restrict__ Wr,
                         const void* __restrict__ bl, bf16* __restrict__ w23bT,
                         float* __restrict__ b23, const int* __restrict__ flags) {
    __shared__ float part[4][H];
    __shared__ float smm[8][H];
    int b = blockIdx.x;
    int t = threadIdx.x;
    if (b < S1_DIS) {
        int row = b, seg = NL + row;
        int s0 = off[seg], c = cnt[seg];
        const int* nb = nbr + s0;
        int w = t >> 6, lane = t & 63, c0 = 2 * lane;
        int j = (c * w) >> 2, jend = (c * (w + 1)) >> 2;
        float2 a[8];
#pragma unroll
        for (int u = 0; u < 8; ++u) a[u] = make_float2(0.f, 0.f);
        for (; j + 8 <= jend; j += 8) {
#pragma unroll
            for (int u = 0; u < 8; ++u) {
                float2 v = ld_bf2(hp + (size_t)nb[j + u] * H + c0);
                a[u].x += v.x;
                a[u].y += v.y;
            }
        }
        for (; j < jend; ++j) {
            float2 v = ld_bf2(hp + (size_t)nb[j] * H + c0);
            a[0].x += v.x;
            a[0].y += v.y;
        }
        part[w][c0] = ((a[0].x + a[1].x) + (a[2].x + a[3].x)) + ((a[4].x + a[5].x) + (a[6].x + a[7].x));
        part[w][c0 + 1] = ((a[0].y + a[1].y) + (a[2].y + a[3].y)) + ((a[4].y + a[5].y) + (a[6].y + a[7].y));
        __syncthreads();
        if (t < H) {
            float v = (part[0][t] + part[1][t]) + (part[2][t] + part[3][t]);
            bufD[(size_t)row * H + t] = v / fmaxf((float)c, 1.f);
        }
    } else if (b < S1_DIS + S1_LAB) {
        int w = t >> 6, lane = t & 63, c0 = 2 * lane;
        int row = (b - S1_DIS) * 4 + w;
        int s0 = off[row], c = cnt[row];
        const int* nb = nbr + s0;
        float2 a[8];
#pragma unroll
        for (int u = 0; u < 8; ++u) a[u] = make_float2(0.f, 0.f);
        int j = 0;
        for (; j + 8 <= c; j += 8) {
#pragma unroll
            for (int u = 0; u < 8; ++u) {
                float2 v = ld_bf2(hp + (size_t)nb[j + u] * H + c0);
                a[u].x += v.x;
                a[u].y += v.y;
            }
        }
        for (; j < c; ++j) {
            float2 v = ld_bf2(hp + (size_t)nb[j] * H + c0);
            a[0].x += v.x;
            a[0].y += v.y;
        }
        float sx = ((a[0].x + a[1].x) + (a[2].x + a[3].x)) + ((a[4].x + a[5].x) + (a[6].x + a[7].x));
        float sy = ((a[0].y + a[1].y) + (a[2].y + a[3].y)) + ((a[4].y + a[5].y) + (a[6].y + a[7].y));
        float inv = 1.f / fmaxf((float)c, 1.f);
        *(float2*)(bufL + (size_t)row * H + c0) = make_float2(sx * inv, sy * inv);
    } else if (b < S1_DIS + S1_LAB + S1_MM) {
        int f32m = flags[0];
        int bb = b - (S1_DIS + S1_LAB);
        bool lab = bb < 1250;
        const TA* in = lab ? hl : hd;
        bf16* outp = lab ? tlp : tdp;
        int N = lab ? NL : ND;
        size_t woff = lab ? (size_t)2 * HH : (size_t)3 * HH;
        int r0 = (lab ? bb : bb - 1250) * 8;
        int h = t & 127, half = t >> 7;
        for (int r = half; r < 8; r += 2)
            smm[r][h] = (r0 + r < N) ? ldv(in, (size_t)(r0 + r) * H + h) : 0.f;
        __syncthreads();
        int rb = half * 4;
        float a0 = 0.f, a1 = 0.f, a2 = 0.f, a3 = 0.f;
        for (int k = 0; k < H; ++k) {
            float wv = ldin(Wl, woff + (size_t)k * H + h, f32m);
            a0 = fmaf(smm[rb + 0][k], wv, a0);
            a1 = fmaf(smm[rb + 1][k], wv, a1);
            a2 = fmaf(smm[rb + 2][k], wv, a2);
            a3 = fmaf(smm[rb + 3][k], wv, a3);
        }
        float acc[4] = {a0, a1, a2, a3};
#pragma unroll
        for (int r = 0; r < 4; ++r)
            if (r0 + rb + r < N)
                outp[(size_t)(r0 + rb + r) * H + h] = __float2bfloat16(acc[r]);
    } else {
        int f32m = flags[0];
        int idx = (b - (S1_DIS + S1_LAB + S1_MM)) * 256 + t;
        if (idx < HH) {
            int k = idx >> 7, n = idx & 127;
            float v = ldin(Wr, (size_t)2 * HH + idx, f32m) + ldin(Wr, (size_t)3 * HH + idx, f32m);
            w23bT[(size_t)n * H + k] = __float2bfloat16(v);
        }
        if (idx < H)
            b23[idx] = ldin(bl, (size_t)2 * H + idx, f32m) + ldin(bl, (size_t)3 * H + idx, f32m);
    }
}

// -------- L2 patmm: patient pass (gather + MFMA) | lab/dis 2nd stage | bns zero ---------
#define MML_LAB (NL / 8)
#define MML_DIS ((ND + 7) / 8)
#define PATMM_TOTAL (PAT_BLOCKS + MML_LAB + MML_DIS)

template <typename TA>
__global__ void k_patmm(const bf16* __restrict__ hp, const bf16* __restrict__ tlp,
                        const bf16* __restrict__ tdp, const int* __restrict__ off,
                        const int* __restrict__ cnt, const int* __restrict__ nbr,
                        const bf16* __restrict__ w23bT, const float* __restrict__ b23,
                        bf16* __restrict__ aggp, float* __restrict__ bufL,
                        float* __restrict__ bufD, const TA* __restrict__ hl,
                        const TA* __restrict__ hd, const void* __restrict__ Wl,
                        const void* __restrict__ bl, const void* __restrict__ Wr,
                        float* __restrict__ bns, const int* __restrict__ flags) {
    __shared__ __align__(16) char smem[16 * HPAD * 2 + 16 * APAD * 4];
    int t = threadIdx.x;
    if (blockIdx.x < PAT_BLOCKS) {
        bf16(*hpA)[HPAD] = (bf16(*)[HPAD])smem;
        float(*accf)[APAD] = (float(*)[APAD])(smem + 16 * HPAD * 2);
        int w = t >> 6, lane = t & 63, c0 = 2 * lane;
        int p0 = blockIdx.x * 16;
        {
            const unsigned int* hpu = (const unsigned int*)(hp + (size_t)p0 * H);
            for (int i = t; i < 16 * 64; i += 256) {
                int r = i >> 6, c = i & 63;
                *(unsigned int*)&hpA[r][2 * c] = hpu[(size_t)r * 64 + c];
            }
        }
        {
            const int* off1 = off + NL + ND;
            const int* cnt1 = cnt + NL + ND;
            const int* off2 = off + NL + ND + NP;
            const int* cnt2 = cnt + NL + ND + NP;
            float2 bb = *(const float2*)(b23 + c0);
#pragma unroll
            for (int r = 0; r < 4; ++r) {
                int p = p0 + w * 4 + r;
                int s1 = off1[p], c1 = cnt1[p];
                const int* nb1 = nbr + s1;
                float2 aa[4];
#pragma unroll
                for (int u = 0; u < 4; ++u) aa[u] = make_float2(0.f, 0.f);
                int j = 0;
                for (; j + 4 <= c1; j += 4) {
#pragma unroll
                    for (int u = 0; u < 4; ++u) {
                        float2 v = ld_bf2(tlp + (size_t)nb1[j + u] * H + c0);
                        aa[u].x += v.x;
                        aa[u].y += v.y;
                    }
                }
                for (; j < c1; ++j) {
                    float2 v = ld_bf2(tlp + (size_t)nb1[j] * H + c0);
                    aa[0].x += v.x;
                    aa[0].y += v.y;
                }
                float a1x = (aa[0].x + aa[1].x) + (aa[2].x + aa[3].x);
                float a1y = (aa[0].y + aa[1].y) + (aa[2].y + aa[3].y);
                int s2 = off2[p], c2 = cnt2[p];
                const int* nb2 = nbr + s2;
                float2 a2a = make_float2(0.f, 0.f), a2b = a2a;
                j = 0;
                for (; j + 2 <= c2; j += 2) {
                    float2 va = ld_bf2(tdp + (size_t)nb2[j] * H + c0);
                    float2 vb = ld_bf2(tdp + (size_t)nb2[j + 1] * H + c0);
                    a2a.x += va.x; a2a.y += va.y;
                    a2b.x += vb.x; a2b.y += vb.y;
                }
                if (j < c2) {
                    float2 v = ld_bf2(tdp + (size_t)nb2[j] * H + c0);
                    a2a.x += v.x;
                    a2a.y += v.y;
                }
                float i1 = 1.f / fmaxf((float)c1, 1.f), i2 = 1.f / fmaxf((float)c2, 1.f);
                accf[w * 4 + r][c0] = a1x * i1 + (a2a.x + a2b.x) * i2 + bb.x;
                accf[w * 4 + r][c0 + 1] = a1y * i1 + (a2a.y + a2b.y) * i2 + bb.y;
            }
        }
        __syncthreads();
        {
            int m = lane & 15, kg = lane >> 4;
            bf16x8 afr[4];
#pragma unroll
            for (int ks = 0; ks < 4; ++ks)
                afr[ks] = *(const bf16x8*)&hpA[m][ks * 32 + kg * 8];
            int n0 = w * 32;
#pragma unroll
            for (int tt = 0; tt < 2; ++tt) {
                int nc = n0 + tt * 16 + m;
                f32x4 acc = {0.f, 0.f, 0.f, 0.f};
#pragma unroll
                for (int ks = 0; ks < 4; ++ks) {
                    bf16x8 bfr = *(const bf16x8*)&w23bT[(size_t)nc * H + ks * 32 + kg * 8];
                    acc = __builtin_amdgcn_mfma_f32_16x16x32_bf16(afr[ks], bfr, acc, 0, 0, 0);
                }
#pragma unroll
                for (int rg = 0; rg < 4; ++rg)
                    accf[kg * 4 + rg][nc] += acc[rg];
            }
        }
        __syncthreads();
        for (int i = t; i < 16 * 64; i += 256) {
            int r = i >> 6, cc = (i & 63) * 2;
            st_bf2(aggp + (size_t)(p0 + r) * H + cc, make_float2(accf[r][cc], accf[r][cc + 1]));
        }
    } else {
        float(*sB)[H] = (float(*)[H])smem;
        float(*sH)[H] = sB + 8;
        int bb = blockIdx.x - PAT_BLOCKS;
        if (bb == 0)
            for (int i = t; i < 6 * H; i += 256) bns[i] = 0.f;
        int f32m = flags[0];
        bool lab = bb < MML_LAB;
        float* buf = lab ? bufL : bufD;
        const TA* hx = lab ? hl : hd;
        size_t woff = lab ? 0 : (size_t)HH;
        size_t boff = lab ? 0 : (size_t)H;
        int N = lab ? NL : ND;
        int r0 = (lab ? bb : bb - MML_LAB) * 8;
        int h = t & 127, half = t >> 7;
        for (int r = half; r < 8; r += 2) {
            int ri = r0 + r;
            sB[r][h] = (ri < N) ? buf[(size_t)ri * H + h] : 0.f;
            sH[r][h] = (ri < N) ? ldv(hx, (size_t)ri * H + h) : 0.f;
        }
        __syncthreads();
        int rb = half * 4;
        float bv = ldin(bl, boff + h, f32m);
        float a0 = bv, a1 = bv, a2 = bv, a3 = bv;
        for (int k = 0; k < H; ++k) {
            float wl = ldin(Wl, woff + (size_t)k * H + h, f32m);
            a0 = fmaf(sB[rb + 0][k], wl, a0);
            a1 = fmaf(sB[rb + 1][k], wl, a1);
            a2 = fmaf(sB[rb + 2][k], wl, a2);
            a3 = fmaf(sB[rb + 3][k], wl, a3);
        }
        for (int k = 0; k < H; ++k) {
            float wr = ldin(Wr, woff + (size_t)k * H + h, f32m);
            a0 = fmaf(sH[rb + 0][k], wr, a0);
            a1 = fmaf(sH[rb + 1][k], wr, a1);
            a2 = fmaf(sH[rb + 2][k], wr, a2);
            a3 = fmaf(sH[rb + 3][k], wr, a3);
        }
        float acc[4] = {a0, a1, a2, a3};
#pragma unroll
        for (int r = 0; r < 4; ++r) {
            int ri = r0 + rb + r;
            if (ri < N) buf[(size_t)ri * H + h] = acc[r];
        }
    }
}

// ---------------- merged BatchNorm stats ----------------
__global__ void k_bn_stats(const bf16* __restrict__ aggp, const float* __restrict__ bufL,
                           const float* __restrict__ bufD, float* __restrict__ sums) {
    int h = threadIdx.x & 127;
    int sub = threadIdx.x >> 7;
    float s = 0.f, s2 = 0.f;
    float* sm;
    if (blockIdx.x < 1024) {
        for (int i = blockIdx.x * 2 + sub; i < NP; i += 2048) {
            float v = __bfloat162float(aggp[(size_t)i * H + h]);
            s += v;
            s2 = fmaf(v, v, s2);
        }
        sm = sums;
    } else if (blockIdx.x < 1280) {
        int bid = blockIdx.x - 1024;
        for (int i = bid * 2 + sub; i < NL; i += 512) {
            float v = bufL[(size_t)i * H + h];
            s += v;
            s2 = fmaf(v, v, s2);
        }
        sm = sums + 2 * H;
    } else {
        int bid = blockIdx.x - 1280;
        for (int i = bid * 2 + sub; i < ND; i += 128) {
            float v = bufD[(size_t)i * H + h];
            s += v;
            s2 = fmaf(v, v, s2);
        }
        sm = sums + 4 * H;
    }
    __shared__ float ls[256], ls2[256];
    ls[threadIdx.x] = s;
    ls2[threadIdx.x] = s2;
    __syncthreads();
    if (sub == 0) {
        atomicAdd(&sm[h], s + ls[128 + h]);
        atomicAdd(&sm[H + h], s2 + ls2[128 + h]);
    }
}

// ---------------- merged BatchNorm apply + relu ----------------
template <typename TA>
__global__ void k_bn_apply(const bf16* __restrict__ aggp, const float* __restrict__ bufL,
                           const float* __restrict__ bufD, bf16* __restrict__ hp,
                           TA* __restrict__ hl, TA* __restrict__ hd,
                           const float* __restrict__ sums, const void* __restrict__ g,
                           const void* __restrict__ b, const int* __restrict__ flags) {
    int f32m = flags[0];
    size_t idx = (size_t)blockIdx.x * 256 + threadIdx.x;
    int h = (int)(idx & 127);
    if (idx < (size_t)NP * H) {
        const float invN = 1.f / NP;
        float m = sums[h] * invN;
        float v = fmaf(-m, m, sums[H + h] * invN);
        float sc = rsqrtf(v + 1e-5f) * ldin(g, h, f32m);
        float r = fmaf(__bfloat162float(aggp[idx]) - m, sc, ldin(b, h, f32m));
        hp[idx] = __float2bfloat16(fmaxf(r, 0.f));
    } else if (idx < (size_t)(NP + NL) * H) {
        size_t j = idx - (size_t)NP * H;
        const float invN = 1.f / NL;
        float m = sums[2 * H + h] * invN;
        float v = fmaf(-m, m, sums[3 * H + h] * invN);
        float sc = rsqrtf(v + 1e-5f) * ldin(g, H + h, f32m);
        float r = fmaf(bufL[j] - m, sc, ldin(b, H + h, f32m));
        stv(hl, j, fmaxf(r, 0.f));
    } else if (idx < (size_t)(NP + NL + ND) * H) {
        size_t j = idx - (size_t)(NP + NL) * H;
        const float invN = 1.f / ND;
        float m = sums[4 * H + h] * invN;
        float v = fmaf(-m, m, sums[5 * H + h] * invN);
        float sc = rsqrtf(v + 1e-5f) * ldin(g, 2 * H + h, f32m);
        float r = fmaf(bufD[j] - m, sc, ldin(b, 2 * H + h, f32m));
        stv(hd, j, fmaxf(r, 0.f));
    }
}

// ---------------- head ----------------
__global__ void k_head(const bf16* __restrict__ hp, const void* __restrict__ W1,
                       const void* __restrict__ b1, const void* __restrict__ W2,
                       const void* __restrict__ b2, void* __restrict__ out,
                       const int* __restrict__ flags) {
    int f32m = flags[0];
    __shared__ float W1s[H * 64];
    __shared__ float W2s[64 * NOUT];
    __shared__ float b1s[64], b2s[NOUT];
    __shared__ float rows[16][H];
    __shared__ float h1s[16][65];
    __shared__ float lgs[16][16];
    int t = threadIdx.x;
    for (int i = t; i < H * 64; i += 256) W1s[i] = ldin(W1, i, f32m);
    for (int i = t; i < 64 * NOUT; i += 256) W2s[i] = ldin(W2, i, f32m);
    if (t < 64) b1s[t] = ldin(b1, t, f32m);
    else if (t >= 64 && t < 64 + NOUT) b2s[t - 64] = ldin(b2, t - 64, f32m);
    int p0 = blockIdx.x * 16;
    for (int i = t; i < 16 * 64; i += 256) {
        int r = i >> 6, c2 = (i & 63) * 2;
        float2 v = ld_bf2(hp + (size_t)(p0 + r) * H + c2);
        rows[r][c2] = v.x;
        rows[r][c2 + 1] = v.y;
    }
    __syncthreads();
    int w = t >> 6, lane = t & 63;
    const float* r0 = rows[4 * w + 0];
    const float* r1 = rows[4 * w + 1];
    const float* r2 = rows[4 * w + 2];
    const float* r3 = rows[4 * w + 3];
    float a0 = b1s[lane], a1 = a0, a2 = a0, a3 = a0;
#pragma unroll 4
    for (int k = 0; k < H; ++k) {
        float wv = W1s[k * 64 + lane];
        a0 = fmaf(r0[k], wv, a0);
        a1 = fmaf(r1[k], wv, a1);
        a2 = fmaf(r2[k], wv, a2);
        a3 = fmaf(r3[k], wv, a3);
    }
    h1s[4 * w + 0][lane] = fmaxf(a0, 0.f);
    h1s[4 * w + 1][lane] = fmaxf(a1, 0.f);
    h1s[4 * w + 2][lane] = fmaxf(a2, 0.f);
    h1s[4 * w + 3][lane] = fmaxf(a3, 0.f);
    __syncthreads();
    int pat = lane >> 4, oidx = lane & 15;
    int prow = 4 * w + pat;
    float lg = 0.f;
    if (oidx < NOUT) {
        lg = b2s[oidx];
        const float* hh = h1s[prow];
#pragma unroll 8
        for (int k = 0; k < 64; ++k) lg = fmaf(hh[k], W2s[k * NOUT + oidx], lg);
        lgs[prow][oidx] = lg;
    }
    __syncthreads();
    if (oidx < NOUT) {
        float m = -1e30f;
#pragma unroll
        for (int k = 0; k < NOUT; ++k) m = fmaxf(m, lgs[prow][k]);
        float s = 0.f;
#pragma unroll
        for (int k = 0; k < NOUT; ++k) s += __expf(lgs[prow][k] - m);
        float r = lg - m - __logf(s);
        if (f32m)
            ((float*)out)[(size_t)(p0 + prow) * NOUT + oidx] = r;
        else
            ((bf16*)out)[(size_t)(p0 + prow) * NOUT + oidx] = __float2bfloat16(r);
    }
}

template <typename TA>
static void run_all(void* const* d_in, void* d_out, void* d_ws, hipStream_t stream) {
    const int* e1s = (const int*)d_in[23];
    const int* e1d = (const int*)d_in[24];
    const int* e2s = (const int*)d_in[25];
    const int* e2d = (const int*)d_in[26];
    const int NPOOL = 2 * (E1 + E2);

    char* wsb = (char*)d_ws;
    size_t o = 0;
    auto af = [&](size_t nwords) { void* p = wsb + o * 4; o += nwords; return p; };
    int* flags = (int*)af(16);
    bf16* w23bT = (bf16*)af(HH / 2);
    bf16* w23bT1 = (bf16*)af(HH / 2);
    float* b23 = (float*)af(H);
    float* bns = (float*)af(6 * H);
    int* bsums = (int*)af(256);
    float* WpWl0 = (float*)af(16 * H);
    float* WpWl1 = (float*)af(16 * H);
    float* vecs = (float*)af(13 * 128);
    int* cnt = (int*)af(NCNT);
    int* off = (int*)af(NCNT);
    int* nbr = (int*)af(NPOOL);
    bf16* hp = (bf16*)af((size_t)NP * H / 2);
    TA* hl = (TA*)af((size_t)NL * H * sizeof(TA) / 4);
    TA* hd = (TA*)af((size_t)ND * H * sizeof(TA) / 4);
    size_t arena = o;
    unsigned short* r1s = (unsigned short*)af(E1 / 2);
    unsigned short* r2s = (unsigned short*)af(E2 / 2);
    unsigned int* ccnt = (unsigned int*)af((size_t)NCOPY * NPP);
    unsigned int* labHist = (unsigned int*)af((size_t)LABHB * NL);
    unsigned int* disHist = (unsigned int*)af((size_t)DISHB * ND);
    size_t endA = o;
    o = arena;
    float* bufL = (float*)af((size_t)NL * H);
    float* bufD = (float*)af((size_t)ND * H);
    bf16* tlp = (bf16*)af((size_t)NL * H / 2);
    bf16* tdp = (bf16*)af((size_t)ND * H / 2);
    bf16* aggp = (bf16*)af((size_t)NP * H / 2);
    float* mxp = (float*)af((size_t)NROW * 16);
    size_t endB = o;
    o = endA > endB ? endA : endB;

    k_detect<<<1, 256, 0, stream>>>((const unsigned short*)d_in[0], flags);

    hipMemsetAsync(ccnt, 0, (size_t)NCOPY * NPP * 4, stream);
    k_count_embed<<<PB6, 256, 0, stream>>>(e1s, e1d, e2s, e2d, ccnt, r1s, r2s, labHist, disHist,
                                           d_in[0], d_in[3], d_in[4], d_in[5], d_in[6], d_in[7],
                                           d_in[8], d_in[9], d_in[10], d_in[11], hp, WpWl0,
                                           WpWl1, vecs, w23bT1, flags);
    k_reduce<<<RED_LAB + RED_DIS + RED_P, 256, 0, stream>>>(labHist, disHist, ccnt, cnt);
    int nb = (NCNT + SCAN_ELEMS - 1) / SCAN_ELEMS;
    k_scan1<<<nb, 256, 0, stream>>>(cnt, off, bsums, NCNT);
    k_scan2<<<1, 256, 0, stream>>>(bsums, nb);
    k_scan3<<<(NCNT + 255) / 256, 256, 0, stream>>>(off, bsums, NCNT);
    k_fill<<<CNT_BLOCKS + LABHB + DISHB, 256, 0, stream>>>(e1s, e1d, e2s, e2d, off, ccnt, r1s,
                                                           r2s, labHist, disHist, nbr);

    // ---- layer 1 (algebraically collapsed) ----
    k_stage1_L1<<<(NROW + 3) / 4, 256, 0, stream>>>(d_in[0], off, cnt, nbr, mxp, flags);
    k_patmm_L1<<<PAT_BLOCKS + LD1_BLOCKS, 256, 0, stream>>>(hp, d_in[1], d_in[2], off, cnt, nbr,
                                                            w23bT1, vecs, WpWl0, WpWl1, mxp,
                                                            aggp, bufL, bufD, bns, flags);
    k_bn_stats<<<1344, 256, 0, stream>>>(aggp, bufL, bufD, bns);
    k_bn_apply<TA><<<(int)(((size_t)(NP + NL + ND) * H + 255) / 256), 256, 0, stream>>>(
        aggp, bufL, bufD, hp, hl, hd, bns, d_in[15], d_in[16], flags);

    // ---- layer 2 (general path) ----
    k_stage1<TA><<<S1_TOTAL, 256, 0, stream>>>(hp, off, cnt, nbr, bufL, bufD, hl, hd, d_in[12],
                                               tlp, tdp, d_in[14], d_in[13], w23bT, b23, flags);
    k_patmm<TA><<<PATMM_TOTAL, 256, 0, stream>>>(hp, tlp, tdp, off, cnt, nbr, w23bT, b23, aggp,
                                                 bufL, bufD, hl, hd, d_in[12], d_in[13],
                                                 d_in[14], bns, flags);
    k_bn_stats<<<1344, 256, 0, stream>>>(aggp, bufL, bufD, bns);
    k_bn_apply<TA><<<(int)(((size_t)(NP + NL + ND) * H + 255) / 256), 256, 0, stream>>>(
        aggp, bufL, bufD, hp, hl, hd, bns, d_in[17], d_in[18], flags);

    k_head<<<NP / 16, 256, 0, stream>>>(hp, d_in[19], d_in[20], d_in[21], d_in[22], d_out, flags);
}

extern "C" void kernel_launch(void* const* d_in, const int* in_sizes, int n_in, void* d_out,
                              int out_size, void* d_ws, size_t ws_size, hipStream_t stream) {
    const size_t NPOOL = 2 * ((size_t)E1 + E2);
    const size_t viewA = (size_t)E1 / 2 + E2 / 2 + (size_t)NCOPY * NPP + (size_t)LABHB * NL +
                         (size_t)DISHB * ND;
    const size_t viewB = (size_t)NL * H + (size_t)ND * H + (size_t)NL * H / 2 +
                         (size_t)ND * H / 2 + (size_t)NP * H / 2 + (size_t)NROW * 16;
    const size_t arena = viewA > viewB ? viewA : viewB;
    const size_t fixed_f32 = 16 + HH + H + 6 * H + 256 + 32 * H + 13 * 128 + 2 * (size_t)NCNT +
                             NPOOL + (size_t)NP * H / 2 + (size_t)NL * H + (size_t)ND * H;
    const size_t need_f32 = (fixed_f32 + arena) * 4;  // ~88 MiB
    if (ws_size >= need_f32)
        run_all<float>(d_in, d_out, d_ws, stream);
    else
        run_all<bf16>(d_in, d_out, d_ws, stream);  // ~85 MiB
}

// Round 15
// 864.353 us; speedup vs baseline: 7.7866x; 1.1980x over previous
//
#include <hip/hip_runtime.h>
#include <hip/hip_bf16.h>

#define NP 100000
#define NL 10000
#define ND 500
#define H 128
#define HH (H * H)
#define E1 2000000
#define E2 500000
#define NOUT 10
#define NCOPY 16
#define NPP (2 * NP)
#define NCNT (NL + ND + 2 * NP)
#define NROW (NL + ND)
#define CHUNK 8192
#define LABHB ((E1 + CHUNK - 1) / CHUNK)
#define DISHB ((E2 + CHUNK - 1) / CHUNK)
#define CNT_BLOCKS ((E1 + E2 + 255) / 256)
#define EMBP ((NP * H + 255) / 256)
#define RED_LAB ((NL + 255) / 256)
#define RED_DIS ((ND + 255) / 256)
#define RED_P ((NPP + 255) / 256)
#define PAT_BLOCKS (NP / 16)

typedef __hip_bfloat16 bf16;
typedef __attribute__((ext_vector_type(8))) short bf16x8;
typedef __attribute__((ext_vector_type(4))) float f32x4;

__device__ __forceinline__ float ldv(const float* p, size_t i) { return p[i]; }
__device__ __forceinline__ float ldv(const bf16* p, size_t i) { return __bfloat162float(p[i]); }
__device__ __forceinline__ void stv(float* p, size_t i, float v) { p[i] = v; }
__device__ __forceinline__ void stv(bf16* p, size_t i, float v) { p[i] = __float2bfloat16(v); }

__device__ __forceinline__ float bfbits2f(unsigned short s) {
    union { unsigned int u; float f; } v;
    v.u = (unsigned int)s << 16;
    return v.f;
}
__device__ __forceinline__ float2 ld_bf2(const bf16* p) {
    unsigned int u = *(const unsigned int*)p;
    return make_float2(bfbits2f((unsigned short)(u & 0xFFFFu)), bfbits2f((unsigned short)(u >> 16)));
}
__device__ __forceinline__ void st_bf2(bf16* p, float2 v) {
    union { unsigned int u; bf16 b[2]; } t;
    t.b[0] = __float2bfloat16(v.x);
    t.b[1] = __float2bfloat16(v.y);
    *(unsigned int*)p = t.u;
}
__device__ __forceinline__ float ldin(const void* p, size_t i, int f32m) {
    return f32m ? ((const float*)p)[i] : __bfloat162float(((const bf16*)p)[i]);
}

// ---------------- input dtype detection ----------------
__global__ void k_detect(const unsigned short* __restrict__ xp, int* __restrict__ flags) {
    int t = threadIdx.x;
    int cnt = 0;
    for (int i = t; i < 4096; i += 256) {
        unsigned short w = xp[2 * i];
        int e = (w >> 7) & 0xFF;
        if (w == 0 || (e >= 114 && e <= 141)) cnt++;
    }
    __shared__ int sh[256];
    sh[t] = cnt;
    __syncthreads();
    for (int s = 128; s > 0; s >>= 1) {
        if (t < s) sh[t] += sh[t + s];
        __syncthreads();
    }
    if (t == 0) flags[0] = (sh[0] < 2048) ? 1 : 0;
}

// ---- merged: p-count | lab/dis hists | hp embed | L1 weight-precompute ----------------
#define PB0 CNT_BLOCKS
#define PB1 (PB0 + LABHB)
#define PB2 (PB1 + DISHB)
#define PB3 (PB2 + EMBP)
#define PB4 (PB3 + 16)
#define PB5 (PB4 + 7)
#define PB6 (PB5 + 64)
__global__ void k_count_embed(const int* __restrict__ e1s, const int* __restrict__ e1d,
                              const int* __restrict__ e2s, const int* __restrict__ e2d,
                              unsigned int* __restrict__ ccnt, unsigned short* __restrict__ r1s,
                              unsigned short* __restrict__ r2s, unsigned int* __restrict__ labHist,
                              unsigned int* __restrict__ disHist, const void* __restrict__ xp,
                              const void* __restrict__ Wp, const void* __restrict__ bp,
                              const void* __restrict__ Wlab, const void* __restrict__ blab,
                              const void* __restrict__ Wdis, const void* __restrict__ bdis,
                              const void* __restrict__ Wl1, const void* __restrict__ bl1,
                              const void* __restrict__ Wr1, bf16* __restrict__ hp,
                              float* __restrict__ WpWl0, float* __restrict__ WpWl1,
                              float* __restrict__ vecs, bf16* __restrict__ w23bT1,
                              const int* __restrict__ flags) {
    __shared__ unsigned int histp[NL / 2];
    int b = blockIdx.x, t = threadIdx.x;
    if (b < PB0) {
        int copy = b & (NCOPY - 1);
        unsigned int* c = ccnt + (size_t)copy * NPP;
        unsigned int tag = (unsigned int)copy << 12;
        int e = b * 256 + t;
        if (e < E1) {
            unsigned int o = atomicAdd(&c[e1s[e]], 1u);
            r1s[e] = (unsigned short)(tag | (o & 0xFFFu));
        } else if (e < E1 + E2) {
            int i = e - E1;
            unsigned int o = atomicAdd(&c[NP + e2s[i]], 1u);
            r2s[i] = (unsigned short)(tag | (o & 0xFFFu));
        }
    } else if (b < PB1) {
        int c = b - PB0;
        for (int i = t; i < NL / 2; i += 256) histp[i] = 0;
        __syncthreads();
        int e0 = c * CHUNK, ee = min(E1, e0 + CHUNK);
        for (int e = e0 + t; e < ee; e += 256) {
            int dd = e1d[e];
            atomicAdd(&histp[dd >> 1], 1u << (16 * (dd & 1)));
        }
        __syncthreads();
        for (int i = t; i < NL; i += 256)
            labHist[(size_t)c * NL + i] = (histp[i >> 1] >> (16 * (i & 1))) & 0xFFFFu;
    } else if (b < PB2) {
        int c = b - PB1;
        for (int i = t; i < ND / 2; i += 256) histp[i] = 0;
        __syncthreads();
        int e0 = c * CHUNK, ee = min(E2, e0 + CHUNK);
        for (int e = e0 + t; e < ee; e += 256) {
            int dd = e2d[e];
            atomicAdd(&histp[dd >> 1], 1u << (16 * (dd & 1)));
        }
        __syncthreads();
        for (int i = t; i < ND; i += 256)
            disHist[(size_t)c * ND + i] = (histp[i >> 1] >> (16 * (i & 1))) & 0xFFFFu;
    } else if (b < PB3) {
        int f32m = flags[0];
        int idx = (b - PB2) * 256 + t;
        int h = idx & 127;
        int i = idx >> 7;
        float acc = ldin(bp, h, f32m);
#pragma unroll
        for (int k = 0; k < 16; ++k)
            acc = fmaf(ldin(xp, (size_t)i * 16 + k, f32m), ldin(Wp, (size_t)k * H + h, f32m), acc);
        hp[idx] = __float2bfloat16(acc);
    } else if (b < PB4) {
        int f32m = flags[0];
        int pb = b - PB3;
        bool first = pb < 8;
        size_t woff = first ? 0 : (size_t)HH;
        float* outp = first ? WpWl0 : WpWl1;
        int k = (first ? pb : pb - 8) * 2 + (t >> 7);
        int h = t & 127;
        float s = 0.f;
        for (int m = 0; m < H; ++m)
            s = fmaf(ldin(Wp, (size_t)k * H + m, f32m), ldin(Wl1, woff + (size_t)m * H + h, f32m), s);
        outp[k * H + h] = s;
    } else if (b < PB5) {
        int f32m = flags[0];
        int idx = (b - PB4) * 256 + t;
        if (idx < 13 * 128) {
            int v = idx >> 7, h = idx & 127;
            float s = 0.f;
            if (v == 12) {
                s = ldin(bl1, 2 * H + h, f32m) + ldin(bl1, 3 * H + h, f32m);
            } else {
                const void* A;
                size_t aoff = 0;
                const void* W;
                size_t woff;
                float add = 0.f;
                switch (v) {
                    case 0: A = Wlab; W = Wl1; woff = 2 * (size_t)HH; break;
                    case 1: A = blab; W = Wl1; woff = 2 * (size_t)HH; break;
                    case 2: A = Wdis; W = Wl1; woff = 3 * (size_t)HH; break;
                    case 3: A = Wdis; aoff = H; W = Wl1; woff = 3 * (size_t)HH; break;
                    case 4: A = bdis; W = Wl1; woff = 3 * (size_t)HH; break;
                    case 5: A = Wlab; W = Wr1; woff = 0; break;
                    case 6: A = blab; W = Wr1; woff = 0; add = ldin(bl1, h, f32m); break;
                    case 7: A = Wdis; W = Wr1; woff = (size_t)HH; break;
                    case 8: A = Wdis; aoff = H; W = Wr1; woff = (size_t)HH; break;
                    case 9: A = bdis; W = Wr1; woff = (size_t)HH; add = ldin(bl1, H + h, f32m); break;
                    case 10: A = bp; W = Wl1; woff = 0; break;
                    default: A = bp; W = Wl1; woff = (size_t)HH; break;
                }
                for (int m = 0; m < H; ++m)
                    s = fmaf(ldin(A, aoff + m, f32m), ldin(W, woff + (size_t)m * H + h, f32m), s);
                s += add;
            }
            vecs[v * 128 + h] = s;
        }
    } else {
        int f32m = flags[0];
        int idx = (b - PB5) * 256 + t;
        if (idx < HH) {
            int k = idx >> 7, n = idx & 127;
            float v = ldin(Wr1, (size_t)2 * HH + idx, f32m) + ldin(Wr1, (size_t)3 * HH + idx, f32m);
            w23bT1[(size_t)n * H + k] = __float2bfloat16(v);
        }
    }
}

// ---- reduce: chunk/copy exclusive bases; totals -> cnt --------------------------------
__global__ void k_reduce(unsigned int* __restrict__ labHist, unsigned int* __restrict__ disHist,
                         unsigned int* __restrict__ ccnt, int* __restrict__ cnt) {
    int b = blockIdx.x, t = threadIdx.x;
    if (b < RED_LAB) {
        int bin = b * 256 + t;
        if (bin < NL) {
            unsigned int run = 0;
            for (int k = 0; k < LABHB; ++k) {
                unsigned int x = labHist[(size_t)k * NL + bin];
                labHist[(size_t)k * NL + bin] = run;
                run += x;
            }
            cnt[bin] = (int)run;
        }
    } else if (b < RED_LAB + RED_DIS) {
        int bin = (b - RED_LAB) * 256 + t;
        if (bin < ND) {
            unsigned int run = 0;
            for (int k = 0; k < DISHB; ++k) {
                unsigned int x = disHist[(size_t)k * ND + bin];
                disHist[(size_t)k * ND + bin] = run;
                run += x;
            }
            cnt[NL + bin] = (int)run;
        }
    } else {
        int bin = (b - RED_LAB - RED_DIS) * 256 + t;
        if (bin < NPP) {
            unsigned int run = 0;
#pragma unroll
            for (int k = 0; k < NCOPY; ++k) {
                unsigned int x = ccnt[(size_t)k * NPP + bin];
                ccnt[(size_t)k * NPP + bin] = run;
                run += x;
            }
            cnt[NL + ND + bin] = (int)run;
        }
    }
}

#define SCAN_ELEMS 2048
__global__ void k_scan1(const int* __restrict__ in, int* __restrict__ out,
                        int* __restrict__ bsums, int n) {
    int t = threadIdx.x;
    int base = blockIdx.x * SCAN_ELEMS + t * 8;
    int v[8], tsum = 0;
#pragma unroll
    for (int j = 0; j < 8; ++j) {
        v[j] = (base + j < n) ? in[base + j] : 0;
        tsum += v[j];
    }
    __shared__ int sh[256];
    sh[t] = tsum;
    __syncthreads();
    for (int d = 1; d < 256; d <<= 1) {
        int x = (t >= d) ? sh[t - d] : 0;
        __syncthreads();
        sh[t] += x;
        __syncthreads();
    }
    int run = sh[t] - tsum;
    if (t == 255) bsums[blockIdx.x] = sh[255];
#pragma unroll
    for (int j = 0; j < 8; ++j) {
        if (base + j < n) out[base + j] = run;
        run += v[j];
    }
}

__global__ void k_scan2(int* __restrict__ bsums, int nb) {
    int t = threadIdx.x;
    int v = (t < nb) ? bsums[t] : 0;
    __shared__ int sh[256];
    sh[t] = v;
    __syncthreads();
    for (int d = 1; d < 256; d <<= 1) {
        int x = (t >= d) ? sh[t - d] : 0;
        __syncthreads();
        sh[t] += x;
        __syncthreads();
    }
    if (t < nb) bsums[t] = sh[t] - v;
}

__global__ void k_scan3(int* __restrict__ out, const int* __restrict__ bsums, int n) {
    int i = blockIdx.x * 256 + threadIdx.x;
    if (i < n) out[i] += bsums[i / SCAN_ELEMS];
}

// ---- fill (+ last block zeros bns for L1 stats) ---------------------------------------
__global__ void k_fill(const int* __restrict__ e1s, const int* __restrict__ e1d,
                       const int* __restrict__ e2s, const int* __restrict__ e2d,
                       const int* __restrict__ off, const unsigned int* __restrict__ ccnt,
                       const unsigned short* __restrict__ r1s,
                       const unsigned short* __restrict__ r2s,
                       const unsigned int* __restrict__ labHist,
                       const unsigned int* __restrict__ disHist, int* __restrict__ nbr,
                       float* __restrict__ bns) {
    __shared__ unsigned int slot[NL];
    int b = blockIdx.x, t = threadIdx.x;
    if (b < CNT_BLOCKS) {
        int e = b * 256 + t;
        if (e < E1) {
            int ss = e1s[e];
            int r = r1s[e];
            int base = (int)ccnt[(size_t)(r >> 12) * NPP + ss];
            nbr[off[NL + ND + ss] + base + (r & 0xFFF)] = e1d[e];
        } else if (e < E1 + E2) {
            int i = e - E1;
            int ss = e2s[i];
            int r = r2s[i];
            int base = (int)ccnt[(size_t)(r >> 12) * NPP + NP + ss];
            nbr[off[NL + ND + NP + ss] + base + (r & 0xFFF)] = e2d[i];
        }
    } else if (b < CNT_BLOCKS + LABHB) {
        int c = b - CNT_BLOCKS;
        for (int i = t; i < NL; i += 256)
            slot[i] = (unsigned int)off[i] + labHist[(size_t)c * NL + i];
        __syncthreads();
        int e0 = c * CHUNK, ee = min(E1, e0 + CHUNK);
        for (int e = e0 + t; e < ee; e += 256) {
            unsigned int pos = atomicAdd(&slot[e1d[e]], 1u);
            nbr[pos] = e1s[e];
        }
    } else if (b < CNT_BLOCKS + LABHB + DISHB) {
        int c = b - CNT_BLOCKS - LABHB;
        for (int i = t; i < ND; i += 256)
            slot[i] = (unsigned int)off[NL + i] + disHist[(size_t)c * ND + i];
        __syncthreads();
        int e0 = c * CHUNK, ee = min(E2, e0 + CHUNK);
        for (int e = e0 + t; e < ee; e += 256) {
            unsigned int pos = atomicAdd(&slot[e2d[e]], 1u);
            nbr[pos] = e2s[e];
        }
    } else {
        for (int i = t; i < 6 * H; i += 256) bns[i] = 0.f;
    }
}

// ---------------- L1 stage1: gather 16-dim mean of x_p per lab/dis row ------------------
__global__ void k_stage1_L1(const void* __restrict__ xp, const int* __restrict__ off,
                            const int* __restrict__ cnt, const int* __restrict__ nbr,
                            float* __restrict__ mxp, const int* __restrict__ flags) {
    int f32m = flags[0];
    int t = threadIdx.x;
    int w = t >> 6, lane = t & 63;
    int row = blockIdx.x * 4 + w;
    if (row >= NROW) return;
    int s0 = off[row], c = cnt[row];
    int slot = lane >> 4, dim = lane & 15;
    float a0 = 0.f, a1 = 0.f, a2 = 0.f, a3 = 0.f;
    int j = slot;
    for (; j + 16 <= c; j += 16) {
        a0 += ldin(xp, (size_t)nbr[s0 + j] * 16 + dim, f32m);
        a1 += ldin(xp, (size_t)nbr[s0 + j + 4] * 16 + dim, f32m);
        a2 += ldin(xp, (size_t)nbr[s0 + j + 8] * 16 + dim, f32m);
        a3 += ldin(xp, (size_t)nbr[s0 + j + 12] * 16 + dim, f32m);
    }
    for (; j < c; j += 4) a0 += ldin(xp, (size_t)nbr[s0 + j] * 16 + dim, f32m);
    float acc = (a0 + a1) + (a2 + a3);
    acc += __shfl_xor(acc, 16);
    acc += __shfl_xor(acc, 32);
    if (lane < 16) mxp[(size_t)row * 16 + lane] = acc / fmaxf((float)c, 1.f);
}

// -------- L1 patmm: scalar gathers + MFMA | lab/dis affine | per-block stats ------------
#define LD1_BLOCKS ((NROW + 1) / 2)
#define HPAD 136
#define APAD 132
__global__ void k_patmm_L1(const bf16* __restrict__ hp, const void* __restrict__ xl,
                           const void* __restrict__ xd, const int* __restrict__ off,
                           const int* __restrict__ cnt, const int* __restrict__ nbr,
                           const bf16* __restrict__ w23bT1, const float* __restrict__ vecs,
                           const float* __restrict__ WpWl0, const float* __restrict__ WpWl1,
                           const float* __restrict__ mxp, bf16* __restrict__ aggp,
                           float* __restrict__ bufL, float* __restrict__ bufD,
                           float* __restrict__ blocksums, const int* __restrict__ flags) {
    int t = threadIdx.x;
    int f32m = flags[0];
    if (blockIdx.x < PAT_BLOCKS) {
        __shared__ bf16 hpA[16][HPAD];
        __shared__ float accf[16][APAD];
        __shared__ float svec[6][128];
        __shared__ float s_mxl[16], s_onL[16], s_d0[16], s_d1[16], s_onD[16];
        int w = t >> 6, lane = t & 63;
        int p0 = blockIdx.x * 16;
        {
            const unsigned int* hpu = (const unsigned int*)(hp + (size_t)p0 * H);
            for (int i = t; i < 16 * 64; i += 256) {
                int r = i >> 6, c = i & 63;
                *(unsigned int*)&hpA[r][2 * c] = hpu[(size_t)r * 64 + c];
            }
        }
        {
            const int map[6] = {0, 1, 2, 3, 4, 12};
            for (int i = t; i < 6 * 128; i += 256)
                svec[i >> 7][i & 127] = vecs[map[i >> 7] * 128 + (i & 127)];
        }
        {
            int g = t >> 4, sl = t & 15;
            int p = p0 + g;
            int s1 = off[NL + ND + p], c1 = cnt[NL + ND + p];
            float a = 0.f;
            for (int j = sl; j < c1; j += 16) a += ldin(xl, nbr[s1 + j], f32m);
            a += __shfl_xor(a, 1);
            a += __shfl_xor(a, 2);
            a += __shfl_xor(a, 4);
            a += __shfl_xor(a, 8);
            int s2 = off[NL + ND + NP + p], c2 = cnt[NL + ND + NP + p];
            float d0 = 0.f, d1 = 0.f;
            for (int j = sl; j < c2; j += 16) {
                int q = nbr[s2 + j];
                d0 += ldin(xd, (size_t)2 * q, f32m);
                d1 += ldin(xd, (size_t)2 * q + 1, f32m);
            }
            d0 += __shfl_xor(d0, 1); d0 += __shfl_xor(d0, 2);
            d0 += __shfl_xor(d0, 4); d0 += __shfl_xor(d0, 8);
            d1 += __shfl_xor(d1, 1); d1 += __shfl_xor(d1, 2);
            d1 += __shfl_xor(d1, 4); d1 += __shfl_xor(d1, 8);
            if (sl == 0) {
                s_mxl[g] = a / fmaxf((float)c1, 1.f);
                s_onL[g] = (c1 > 0) ? 1.f : 0.f;
                s_d0[g] = d0 / fmaxf((float)c2, 1.f);
                s_d1[g] = d1 / fmaxf((float)c2, 1.f);
                s_onD[g] = (c2 > 0) ? 1.f : 0.f;
            }
        }
        __syncthreads();
        {
            int m = lane & 15, kg = lane >> 4;
            bf16x8 afr[4];
#pragma unroll
            for (int ks = 0; ks < 4; ++ks)
                afr[ks] = *(const bf16x8*)&hpA[m][ks * 32 + kg * 8];
            int n0 = w * 32;
#pragma unroll
            for (int tt = 0; tt < 2; ++tt) {
                int nc = n0 + tt * 16 + m;
                f32x4 acc = {0.f, 0.f, 0.f, 0.f};
#pragma unroll
                for (int ks = 0; ks < 4; ++ks) {
                    bf16x8 bfr = *(const bf16x8*)&w23bT1[(size_t)nc * H + ks * 32 + kg * 8];
                    acc = __builtin_amdgcn_mfma_f32_16x16x32_bf16(afr[ks], bfr, acc, 0, 0, 0);
                }
#pragma unroll
                for (int rg = 0; rg < 4; ++rg)
                    accf[kg * 4 + rg][nc] = acc[rg];
            }
        }
        __syncthreads();
        // add affine terms into accf, write aggp
        for (int i = t; i < 16 * 64; i += 256) {
            int r = i >> 6, cc = (i & 63) * 2;
            float l0 = s_onL[r] * fmaf(s_mxl[r], svec[0][cc], svec[1][cc]);
            float l1 = s_onL[r] * fmaf(s_mxl[r], svec[0][cc + 1], svec[1][cc + 1]);
            float q0 = s_onD[r] * (s_d0[r] * svec[2][cc] + s_d1[r] * svec[3][cc] + svec[4][cc]);
            float q1 = s_onD[r] * (s_d0[r] * svec[2][cc + 1] + s_d1[r] * svec[3][cc + 1] + svec[4][cc + 1]);
            float v0 = accf[r][cc] + l0 + q0 + svec[5][cc];
            float v1 = accf[r][cc + 1] + l1 + q1 + svec[5][cc + 1];
            accf[r][cc] = v0;
            accf[r][cc + 1] = v1;
            st_bf2(aggp + (size_t)(p0 + r) * H + cc, make_float2(v0, v1));
        }
        __syncthreads();
        if (t < 128) {
            float s = 0.f, q = 0.f;
#pragma unroll
            for (int r = 0; r < 16; ++r) {
                float v = accf[r][t];
                s += v;
                q = fmaf(v, v, q);
            }
            blocksums[(size_t)blockIdx.x * 256 + t] = s;
            blocksums[(size_t)blockIdx.x * 256 + 128 + t] = q;
        }
    } else {
        int bb = blockIdx.x - PAT_BLOCKS;
        int rr = bb * 2 + (t >> 7);
        int h = t & 127;
        if (rr >= NROW) return;
        if (rr < NL) {
            float acc = vecs[6 * 128 + h] + ldin(xl, rr, f32m) * vecs[5 * 128 + h];
            if (cnt[rr] > 0) {
                float s = vecs[10 * 128 + h];
                const float* mx = mxp + (size_t)rr * 16;
#pragma unroll
                for (int k = 0; k < 16; ++k) s = fmaf(mx[k], WpWl0[k * H + h], s);
                acc += s;
            }
            bufL[(size_t)rr * H + h] = acc;
        } else {
            int rd = rr - NL;
            float acc = vecs[9 * 128 + h] + ldin(xd, (size_t)2 * rd, f32m) * vecs[7 * 128 + h] +
                        ldin(xd, (size_t)2 * rd + 1, f32m) * vecs[8 * 128 + h];
            if (cnt[rr] > 0) {
                float s = vecs[11 * 128 + h];
                const float* mx = mxp + (size_t)rr * 16;
#pragma unroll
                for (int k = 0; k < 16; ++k) s = fmaf(mx[k], WpWl1[k * H + h], s);
                acc += s;
            }
            bufD[(size_t)rd * H + h] = acc;
        }
    }
}

// -------- bnred: patient stats from blocksums (+ lab/dis stats from bufL/D when doLD) ---
__global__ void k_bnred(const float* __restrict__ blocksums, const float* __restrict__ bufL,
                        const float* __restrict__ bufD, float* __restrict__ sums, int doLD) {
    int b = blockIdx.x, t = threadIdx.x;
    if (b < 64) {
        float acc = 0.f;
        for (int r = b; r < PAT_BLOCKS; r += 64) acc += blocksums[(size_t)r * 256 + t];
        atomicAdd(&sums[t], acc);
        return;
    }
    int h = t & 127;
    int sub = t >> 7;
    float s = 0.f, s2 = 0.f;
    float* sm;
    if (b < 320) {
        int bid = b - 64;
        for (int i = bid * 2 + sub; i < NL; i += 512) {
            float v = bufL[(size_t)i * H + h];
            s += v;
            s2 = fmaf(v, v, s2);
        }
        sm = sums + 2 * H;
    } else {
        int bid = b - 320;
        for (int i = bid * 2 + sub; i < ND; i += 128) {
            float v = bufD[(size_t)i * H + h];
            s += v;
            s2 = fmaf(v, v, s2);
        }
        sm = sums + 4 * H;
    }
    __shared__ float ls[256], ls2[256];
    ls[t] = s;
    ls2[t] = s2;
    __syncthreads();
    if (sub == 0) {
        atomicAdd(&sm[h], s + ls[128 + h]);
        atomicAdd(&sm[H + h], s2 + ls2[128 + h]);
    }
}

// ---------------- L1 BatchNorm apply + relu (full: pat+lab+dis) ----------------
template <typename TA>
__global__ void k_bn_apply(const bf16* __restrict__ aggp, const float* __restrict__ bufL,
                           const float* __restrict__ bufD, bf16* __restrict__ hp,
                           TA* __restrict__ hl, TA* __restrict__ hd,
                           const float* __restrict__ sums, const void* __restrict__ g,
                           const void* __restrict__ b, const int* __restrict__ flags) {
    int f32m = flags[0];
    size_t idx = (size_t)blockIdx.x * 256 + threadIdx.x;
    int h = (int)(idx & 127);
    if (idx < (size_t)NP * H) {
        const float invN = 1.f / NP;
        float m = sums[h] * invN;
        float v = fmaf(-m, m, sums[H + h] * invN);
        float sc = rsqrtf(v + 1e-5f) * ldin(g, h, f32m);
        float r = fmaf(__bfloat162float(aggp[idx]) - m, sc, ldin(b, h, f32m));
        hp[idx] = __float2bfloat16(fmaxf(r, 0.f));
    } else if (idx < (size_t)(NP + NL) * H) {
        size_t j = idx - (size_t)NP * H;
        const float invN = 1.f / NL;
        float m = sums[2 * H + h] * invN;
        float v = fmaf(-m, m, sums[3 * H + h] * invN);
        float sc = rsqrtf(v + 1e-5f) * ldin(g, H + h, f32m);
        float r = fmaf(bufL[j] - m, sc, ldin(b, H + h, f32m));
        stv(hl, j, fmaxf(r, 0.f));
    } else if (idx < (size_t)(NP + NL + ND) * H) {
        size_t j = idx - (size_t)(NP + NL) * H;
        const float invN = 1.f / ND;
        float m = sums[4 * H + h] * invN;
        float v = fmaf(-m, m, sums[5 * H + h] * invN);
        float sc = rsqrtf(v + 1e-5f) * ldin(g, 2 * H + h, f32m);
        float r = fmaf(bufD[j] - m, sc, ldin(b, 2 * H + h, f32m));
        stv(hd, j, fmaxf(r, 0.f));
    }
}

// ---------------- L2 stage1: mm_small + prep23 (+ zero bns) -----------------------------
#define S2_MM 1313
#define S2_PREP 64
#define S2_TOTAL (S2_MM + S2_PREP)
template <typename TA>
__global__ void k_stage1_L2(const TA* __restrict__ hl, const TA* __restrict__ hd,
                            const void* __restrict__ Wl, bf16* __restrict__ tlp,
                            bf16* __restrict__ tdp, const void* __restrict__ Wr,
                            const void* __restrict__ bl, bf16* __restrict__ w23bT,
                            float* __restrict__ b23, float* __restrict__ bns,
                            const int* __restrict__ flags) {
    __shared__ float smm[8][H];
    int b = blockIdx.x, t = threadIdx.x;
    int f32m = flags[0];
    if (b < S2_MM) {
        int bb = b;
        bool lab = bb < 1250;
        const TA* in = lab ? hl : hd;
        bf16* outp = lab ? tlp : tdp;
        int N = lab ? NL : ND;
        size_t woff = lab ? (size_t)2 * HH : (size_t)3 * HH;
        int r0 = (lab ? bb : bb - 1250) * 8;
        int h = t & 127, half = t >> 7;
        for (int r = half; r < 8; r += 2)
            smm[r][h] = (r0 + r < N) ? ldv(in, (size_t)(r0 + r) * H + h) : 0.f;
        __syncthreads();
        int rb = half * 4;
        float a0 = 0.f, a1 = 0.f, a2 = 0.f, a3 = 0.f;
        for (int k = 0; k < H; ++k) {
            float wv = ldin(Wl, woff + (size_t)k * H + h, f32m);
            a0 = fmaf(smm[rb + 0][k], wv, a0);
            a1 = fmaf(smm[rb + 1][k], wv, a1);
            a2 = fmaf(smm[rb + 2][k], wv, a2);
            a3 = fmaf(smm[rb + 3][k], wv, a3);
        }
        float acc[4] = {a0, a1, a2, a3};
#pragma unroll
        for (int r = 0; r < 4; ++r)
            if (r0 + rb + r < N)
                outp[(size_t)(r0 + rb + r) * H + h] = __float2bfloat16(acc[r]);
    } else {
        int pb = b - S2_MM;
        if (pb == 0)
            for (int i = t; i < 6 * H; i += 256) bns[i] = 0.f;
        int idx = pb * 256 + t;
        if (idx < HH) {
            int k = idx >> 7, n = idx & 127;
            float v = ldin(Wr, (size_t)2 * HH + idx, f32m) + ldin(Wr, (size_t)3 * HH + idx, f32m);
            w23bT[(size_t)n * H + k] = __float2bfloat16(v);
        }
        if (idx < H)
            b23[idx] = ldin(bl, (size_t)2 * H + idx, f32m) + ldin(bl, (size_t)3 * H + idx, f32m);
    }
}

// -------- L2 patmm: patient pass (gather + MFMA) + per-block stats ----------------------
__global__ void k_patmm_L2(const bf16* __restrict__ hp, const bf16* __restrict__ tlp,
                           const bf16* __restrict__ tdp, const int* __restrict__ off,
                           const int* __restrict__ cnt, const int* __restrict__ nbr,
                           const bf16* __restrict__ w23bT, const float* __restrict__ b23,
                           bf16* __restrict__ aggp, float* __restrict__ blocksums) {
    __shared__ bf16 hpA[16][HPAD];
    __shared__ float accf[16][APAD];
    int t = threadIdx.x;
    int w = t >> 6, lane = t & 63, c0 = 2 * lane;
    int p0 = blockIdx.x * 16;
    {
        const unsigned int* hpu = (const unsigned int*)(hp + (size_t)p0 * H);
        for (int i = t; i < 16 * 64; i += 256) {
            int r = i >> 6, c = i & 63;
            *(unsigned int*)&hpA[r][2 * c] = hpu[(size_t)r * 64 + c];
        }
    }
    {
        const int* off1 = off + NL + ND;
        const int* cnt1 = cnt + NL + ND;
        const int* off2 = off + NL + ND + NP;
        const int* cnt2 = cnt + NL + ND + NP;
        float2 bb = *(const float2*)(b23 + c0);
#pragma unroll
        for (int r = 0; r < 4; ++r) {
            int p = p0 + w * 4 + r;
            int s1 = off1[p], c1 = cnt1[p];
            const int* nb1 = nbr + s1;
            float2 aa[4];
#pragma unroll
            for (int u = 0; u < 4; ++u) aa[u] = make_float2(0.f, 0.f);
            int j = 0;
            for (; j + 4 <= c1; j += 4) {
#pragma unroll
                for (int u = 0; u < 4; ++u) {
                    float2 v = ld_bf2(tlp + (size_t)nb1[j + u] * H + c0);
                    aa[u].x += v.x;
                    aa[u].y += v.y;
                }
            }
            for (; j < c1; ++j) {
                float2 v = ld_bf2(tlp + (size_t)nb1[j] * H + c0);
                aa[0].x += v.x;
                aa[0].y += v.y;
            }
            float a1x = (aa[0].x + aa[1].x) + (aa[2].x + aa[3].x);
            float a1y = (aa[0].y + aa[1].y) + (aa[2].y + aa[3].y);
            int s2 = off2[p], c2 = cnt2[p];
            const int* nb2 = nbr + s2;
            float2 a2a = make_float2(0.f, 0.f), a2b = a2a;
            j = 0;
            for (; j + 2 <= c2; j += 2) {
                float2 va = ld_bf2(tdp + (size_t)nb2[j] * H + c0);
                float2 vb = ld_bf2(tdp + (size_t)nb2[j + 1] * H + c0);
                a2a.x += va.x; a2a.y += va.y;
                a2b.x += vb.x; a2b.y += vb.y;
            }
            if (j < c2) {
                float2 v = ld_bf2(tdp + (size_t)nb2[j] * H + c0);
                a2a.x += v.x;
                a2a.y += v.y;
            }
            float i1 = 1.f / fmaxf((float)c1, 1.f), i2 = 1.f / fmaxf((float)c2, 1.f);
            accf[w * 4 + r][c0] = a1x * i1 + (a2a.x + a2b.x) * i2 + bb.x;
            accf[w * 4 + r][c0 + 1] = a1y * i1 + (a2a.y + a2b.y) * i2 + bb.y;
        }
    }
    __syncthreads();
    {
        int m = lane & 15, kg = lane >> 4;
        bf16x8 afr[4];
#pragma unroll
        for (int ks = 0; ks < 4; ++ks)
            afr[ks] = *(const bf16x8*)&hpA[m][ks * 32 + kg * 8];
        int n0 = w * 32;
#pragma unroll
        for (int tt = 0; tt < 2; ++tt) {
            int nc = n0 + tt * 16 + m;
            f32x4 acc = {0.f, 0.f, 0.f, 0.f};
#pragma unroll
            for (int ks = 0; ks < 4; ++ks) {
                bf16x8 bfr = *(const bf16x8*)&w23bT[(size_t)nc * H + ks * 32 + kg * 8];
                acc = __builtin_amdgcn_mfma_f32_16x16x32_bf16(afr[ks], bfr, acc, 0, 0, 0);
            }
#pragma unroll
            for (int rg = 0; rg < 4; ++rg)
                accf[kg * 4 + rg][nc] += acc[rg];
        }
    }
    __syncthreads();
    for (int i = t; i < 16 * 64; i += 256) {
        int r = i >> 6, cc = (i & 63) * 2;
        st_bf2(aggp + (size_t)(p0 + r) * H + cc, make_float2(accf[r][cc], accf[r][cc + 1]));
    }
    if (t < 128) {
        float s = 0.f, q = 0.f;
#pragma unroll
        for (int r = 0; r < 16; ++r) {
            float v = accf[r][t];
            s += v;
            q = fmaf(v, v, q);
        }
        blocksums[(size_t)blockIdx.x * 256 + t] = s;
        blocksums[(size_t)blockIdx.x * 256 + 128 + t] = q;
    }
}

// ---------------- head with fused patient BN+ReLU ----------------
__global__ void k_head(const bf16* __restrict__ aggp, const float* __restrict__ sums,
                       const void* __restrict__ bng, const void* __restrict__ bnb,
                       const void* __restrict__ W1, const void* __restrict__ b1,
                       const void* __restrict__ W2, const void* __restrict__ b2f,
                       void* __restrict__ out, const int* __restrict__ flags) {
    int f32m = flags[0];
    __shared__ float W1s[H * 64];
    __shared__ float W2s[64 * NOUT];
    __shared__ float b1s[64], b2s[NOUT];
    __shared__ float rows[16][H];
    __shared__ float h1s[16][65];
    __shared__ float lgs[16][16];
    int t = threadIdx.x;
    for (int i = t; i < H * 64; i += 256) W1s[i] = ldin(W1, i, f32m);
    for (int i = t; i < 64 * NOUT; i += 256) W2s[i] = ldin(W2, i, f32m);
    if (t < 64) b1s[t] = ldin(b1, t, f32m);
    else if (t >= 64 && t < 64 + NOUT) b2s[t - 64] = ldin(b2f, t - 64, f32m);
    int p0 = blockIdx.x * 16;
    {
        int cc = (t & 63) * 2;
        const float invN = 1.f / NP;
        float m0 = sums[cc] * invN, m1 = sums[cc + 1] * invN;
        float v0 = fmaf(-m0, m0, sums[128 + cc] * invN);
        float v1 = fmaf(-m1, m1, sums[128 + cc + 1] * invN);
        float sc0 = rsqrtf(v0 + 1e-5f) * ldin(bng, cc, f32m);
        float sc1 = rsqrtf(v1 + 1e-5f) * ldin(bng, cc + 1, f32m);
        float be0 = ldin(bnb, cc, f32m), be1 = ldin(bnb, cc + 1, f32m);
        for (int i = t; i < 16 * 64; i += 256) {
            int r = i >> 6;
            float2 v = ld_bf2(aggp + (size_t)(p0 + r) * H + cc);
            rows[r][cc] = fmaxf(fmaf(v.x - m0, sc0, be0), 0.f);
            rows[r][cc + 1] = fmaxf(fmaf(v.y - m1, sc1, be1), 0.f);
        }
    }
    __syncthreads();
    int w = t >> 6, lane = t & 63;
    const float* r0 = rows[4 * w + 0];
    const float* r1 = rows[4 * w + 1];
    const float* r2 = rows[4 * w + 2];
    const float* r3 = rows[4 * w + 3];
    float a0 = b1s[lane], a1 = a0, a2 = a0, a3 = a0;
#pragma unroll 4
    for (int k = 0; k < H; ++k) {
        float wv = W1s[k * 64 + lane];
        a0 = fmaf(r0[k], wv, a0);
        a1 = fmaf(r1[k], wv, a1);
        a2 = fmaf(r2[k], wv, a2);
        a3 = fmaf(r3[k], wv, a3);
    }
    h1s[4 * w + 0][lane] = fmaxf(a0, 0.f);
    h1s[4 * w + 1][lane] = fmaxf(a1, 0.f);
    h1s[4 * w + 2][lane] = fmaxf(a2, 0.f);
    h1s[4 * w + 3][lane] = fmaxf(a3, 0.f);
    __syncthreads();
    int pat = lane >> 4, oidx = lane & 15;
    int prow = 4 * w + pat;
    float lg = 0.f;
    if (oidx < NOUT) {
        lg = b2s[oidx];
        const float* hh = h1s[prow];
#pragma unroll 8
        for (int k = 0; k < 64; ++k) lg = fmaf(hh[k], W2s[k * NOUT + oidx], lg);
        lgs[prow][oidx] = lg;
    }
    __syncthreads();
    if (oidx < NOUT) {
        float m = -1e30f;
#pragma unroll
        for (int k = 0; k < NOUT; ++k) m = fmaxf(m, lgs[prow][k]);
        float s = 0.f;
#pragma unroll
        for (int k = 0; k < NOUT; ++k) s += __expf(lgs[prow][k] - m);
        float r = lg - m - __logf(s);
        if (f32m)
            ((float*)out)[(size_t)(p0 + prow) * NOUT + oidx] = r;
        else
            ((bf16*)out)[(size_t)(p0 + prow) * NOUT + oidx] = __float2bfloat16(r);
    }
}

template <typename TA>
static void run_all(void* const* d_in, void* d_out, void* d_ws, hipStream_t stream) {
    const int* e1s = (const int*)d_in[23];
    const int* e1d = (const int*)d_in[24];
    const int* e2s = (const int*)d_in[25];
    const int* e2d = (const int*)d_in[26];
    const int NPOOL = 2 * (E1 + E2);

    char* wsb = (char*)d_ws;
    size_t o = 0;
    auto af = [&](size_t nwords) { void* p = wsb + o * 4; o += nwords; return p; };
    int* flags = (int*)af(16);
    bf16* w23bT = (bf16*)af(HH / 2);
    bf16* w23bT1 = (bf16*)af(HH / 2);
    float* b23 = (float*)af(H);
    float* bns = (float*)af(6 * H);
    int* bsums = (int*)af(256);
    float* WpWl0 = (float*)af(16 * H);
    float* WpWl1 = (float*)af(16 * H);
    float* vecs = (float*)af(13 * 128);
    int* cnt = (int*)af(NCNT);
    int* off = (int*)af(NCNT);
    int* nbr = (int*)af(NPOOL);
    bf16* hp = (bf16*)af((size_t)NP * H / 2);
    TA* hl = (TA*)af((size_t)NL * H * sizeof(TA) / 4);
    TA* hd = (TA*)af((size_t)ND * H * sizeof(TA) / 4);
    size_t arena = o;
    unsigned short* r1s = (unsigned short*)af(E1 / 2);
    unsigned short* r2s = (unsigned short*)af(E2 / 2);
    unsigned int* ccnt = (unsigned int*)af((size_t)NCOPY * NPP);
    unsigned int* labHist = (unsigned int*)af((size_t)LABHB * NL);
    unsigned int* disHist = (unsigned int*)af((size_t)DISHB * ND);
    size_t endA = o;
    o = arena;
    float* bufL = (float*)af((size_t)NL * H);
    float* bufD = (float*)af((size_t)ND * H);
    bf16* tlp = (bf16*)af((size_t)NL * H / 2);
    bf16* tdp = (bf16*)af((size_t)ND * H / 2);
    bf16* aggp = (bf16*)af((size_t)NP * H / 2);
    float* mxp = (float*)af((size_t)NROW * 16);
    float* blocksums = (float*)af((size_t)PAT_BLOCKS * 256);
    size_t endB = o;
    o = endA > endB ? endA : endB;

    k_detect<<<1, 256, 0, stream>>>((const unsigned short*)d_in[0], flags);

    hipMemsetAsync(ccnt, 0, (size_t)NCOPY * NPP * 4, stream);
    k_count_embed<<<PB6, 256, 0, stream>>>(e1s, e1d, e2s, e2d, ccnt, r1s, r2s, labHist, disHist,
                                           d_in[0], d_in[3], d_in[4], d_in[5], d_in[6], d_in[7],
                                           d_in[8], d_in[9], d_in[10], d_in[11], hp, WpWl0,
                                           WpWl1, vecs, w23bT1, flags);
    k_reduce<<<RED_LAB + RED_DIS + RED_P, 256, 0, stream>>>(labHist, disHist, ccnt, cnt);
    int nb = (NCNT + SCAN_ELEMS - 1) / SCAN_ELEMS;
    k_scan1<<<nb, 256, 0, stream>>>(cnt, off, bsums, NCNT);
    k_scan2<<<1, 256, 0, stream>>>(bsums, nb);
    k_scan3<<<(NCNT + 255) / 256, 256, 0, stream>>>(off, bsums, NCNT);
    k_fill<<<CNT_BLOCKS + LABHB + DISHB + 1, 256, 0, stream>>>(e1s, e1d, e2s, e2d, off, ccnt,
                                                               r1s, r2s, labHist, disHist, nbr,
                                                               bns);

    // ---- layer 1 (algebraically collapsed) ----
    k_stage1_L1<<<(NROW + 3) / 4, 256, 0, stream>>>(d_in[0], off, cnt, nbr, mxp, flags);
    k_patmm_L1<<<PAT_BLOCKS + LD1_BLOCKS, 256, 0, stream>>>(hp, d_in[1], d_in[2], off, cnt, nbr,
                                                            w23bT1, vecs, WpWl0, WpWl1, mxp,
                                                            aggp, bufL, bufD, blocksums, flags);
    k_bnred<<<384, 256, 0, stream>>>(blocksums, bufL, bufD, bns, 1);
    k_bn_apply<TA><<<(int)(((size_t)(NP + NL + ND) * H + 255) / 256), 256, 0, stream>>>(
        aggp, bufL, bufD, hp, hl, hd, bns, d_in[15], d_in[16], flags);

    // ---- layer 2: lab/dis outputs are dead; only patient path computed ----
    k_stage1_L2<TA><<<S2_TOTAL, 256, 0, stream>>>(hl, hd, d_in[12], tlp, tdp, d_in[14],
                                                  d_in[13], w23bT, b23, bns, flags);
    k_patmm_L2<<<PAT_BLOCKS, 256, 0, stream>>>(hp, tlp, tdp, off, cnt, nbr, w23bT, b23, aggp,
                                               blocksums);
    k_bnred<<<64, 256, 0, stream>>>(blocksums, bufL, bufD, bns, 0);
    // head applies L2 patient BN inline (bn2_g/bn2_b segment 0)
    k_head<<<NP / 16, 256, 0, stream>>>(aggp, bns, d_in[17], d_in[18], d_in[19], d_in[20],
                                        d_in[21], d_in[22], d_out, flags);
}

extern "C" void kernel_launch(void* const* d_in, const int* in_sizes, int n_in, void* d_out,
                              int out_size, void* d_ws, size_t ws_size, hipStream_t stream) {
    const size_t NPOOL = 2 * ((size_t)E1 + E2);
    const size_t viewA = (size_t)E1 / 2 + E2 / 2 + (size_t)NCOPY * NPP + (size_t)LABHB * NL +
                         (size_t)DISHB * ND;
    const size_t viewB = (size_t)NL * H + (size_t)ND * H + (size_t)NL * H / 2 +
                         (size_t)ND * H / 2 + (size_t)NP * H / 2 + (size_t)NROW * 16 +
                         (size_t)PAT_BLOCKS * 256;
    const size_t arena = viewA > viewB ? viewA : viewB;
    const size_t fixed_f32 = 16 + HH + H + 6 * H + 256 + 32 * H + 13 * 128 + 2 * (size_t)NCNT +
                             NPOOL + (size_t)NP * H / 2 + (size_t)NL * H + (size_t)ND * H;
    const size_t need_f32 = (fixed_f32 + arena) * 4;  // ~95 MiB
    if (ws_size >= need_f32)
        run_all<float>(d_in, d_out, d_ws, stream);
    else
        run_all<bf16>(d_in, d_out, d_ws, stream);  // ~92 MiB
}